// Round 13
// baseline (416.519 us; speedup 1.0000x reference)
//
#include <hip/hip_runtime.h>

#define D 128
#define HD 128
#define DE 16
#define MSG_IN 273
#define EB 64        // edges per tile
#define NT 256
#define KP1 288      // padded msg K = 9 chunks of 32
#define NCH1 9
#define NCH2 4
#define NB 32
#define HID_PAD 132
#define CH8 (4 * EB * 64)   // ushort offset of chunk-8 region within one buffer
#define LDS1 (4 * EB * 64 + EB * 32)  // ushorts per buffer (36,864 B)
#define GRIDP 512    // persistent grid (2 blocks/CU)

typedef __attribute__((ext_vector_type(8))) short short8v;
typedef __attribute__((ext_vector_type(4))) float f32x4;
typedef unsigned short ushort_t;

#define GLOAD_LDS16(gp, lp) \
    __builtin_amdgcn_global_load_lds((const __attribute__((address_space(1))) unsigned int*)(gp), \
                                     (__attribute__((address_space(3))) unsigned int*)(lp), 16, 0, 0)

__device__ __forceinline__ unsigned short f2bf(float v) {
    unsigned int u = __builtin_bit_cast(unsigned int, v);
    u += 0x7fffu + ((u >> 16) & 1u);
    return (unsigned short)(u >> 16);
}
__device__ __forceinline__ float bf2f(ushort_t u) {
    return __builtin_bit_cast(float, (unsigned int)u << 16);
}
__device__ __forceinline__ unsigned int cvt_pk_bf16(float lo, float hi) {
    unsigned int r;
    asm("v_cvt_pk_bf16_f32 %0, %1, %2" : "=v"(r) : "v"(lo), "v"(hi));
    return r;
}

// ---------------- fused prepass: weight repack + f->bf16 + dst hist + msum zero ----------------
__global__ void fused_pre_kernel(const float* __restrict__ Wm1, const float* __restrict__ Wm2,
                                 ushort_t* __restrict__ W1p, ushort_t* __restrict__ W2p,
                                 const float* __restrict__ f, ushort_t* __restrict__ fb,
                                 const int* __restrict__ dst, int* __restrict__ cnt,
                                 float* __restrict__ msum,
                                 int n8, int E, int nq) {
    const int gid    = blockIdx.x * 256 + threadIdx.x;
    const int stride = gridDim.x * 256;
    const int rp1 = 128 * KP1;
    const int rp_elems = rp1 + HD * D;
    for (int i = gid; i < rp_elems; i += stride) {
        if (i < rp1) {
            int n = i / KP1, k = i % KP1;
            W1p[i] = f2bf((k < MSG_IN) ? Wm1[(size_t)k * HD + n] : 0.f);
        } else {
            int i2 = i - rp1;
            int n = i2 / HD, k = i2 % HD;
            W2p[i2] = f2bf(Wm2[(size_t)k * D + n]);
        }
    }
    for (int i = gid; i < n8; i += stride) {
        float4 v0 = *(const float4*)(f + (size_t)i * 8);
        float4 v1 = *(const float4*)(f + (size_t)i * 8 + 4);
        union { ushort_t us[8]; short8v v; } pk;
        pk.us[0] = f2bf(v0.x); pk.us[1] = f2bf(v0.y);
        pk.us[2] = f2bf(v0.z); pk.us[3] = f2bf(v0.w);
        pk.us[4] = f2bf(v1.x); pk.us[5] = f2bf(v1.y);
        pk.us[6] = f2bf(v1.z); pk.us[7] = f2bf(v1.w);
        *(short8v*)(fb + (size_t)i * 8) = pk.v;
    }
    for (int i = gid; i < E; i += stride) atomicAdd(&cnt[dst[i]], 1);
    float4 z = {0.f, 0.f, 0.f, 0.f};
    for (int i = gid; i < nq; i += stride) *(float4*)(msum + (size_t)i * 4) = z;
}

// ---------------- CSR build: parallel scan (4 elems/thread) -> scatter ----------------
__global__ __launch_bounds__(1024) void scan_kernel(const int* __restrict__ cnt,
                                                    int* __restrict__ roff,
                                                    int* __restrict__ cursor, int Nn) {
    __shared__ int wsum[16];
    const int t = threadIdx.x, l = t & 63, wid = t >> 6;
    int running = 0;
    for (int base = 0; base < Nn; base += 4096) {
        const int i0 = base + t * 4;
        int v0 = 0, v1 = 0, v2 = 0, v3 = 0;
        if (i0 + 3 < Nn) {
            int4 v = *(const int4*)(cnt + i0);
            v0 = v.x; v1 = v.y; v2 = v.z; v3 = v.w;
        } else {
            if (i0 + 0 < Nn) v0 = cnt[i0 + 0];
            if (i0 + 1 < Nn) v1 = cnt[i0 + 1];
            if (i0 + 2 < Nn) v2 = cnt[i0 + 2];
        }
        const int vsum = v0 + v1 + v2 + v3;
        int s = vsum;
        #pragma unroll
        for (int off = 1; off < 64; off <<= 1) {
            int u = __shfl_up(s, off, 64);
            if (l >= off) s += u;
        }
        if (l == 63) wsum[wid] = s;
        __syncthreads();
        if (wid == 0 && l < 16) {
            int xv = wsum[l];
            #pragma unroll
            for (int off = 1; off < 16; off <<= 1) {
                int u = __shfl_up(xv, off, 64);
                if (l >= off) xv += u;
            }
            wsum[l] = xv;
        }
        __syncthreads();
        const int prev  = (wid > 0) ? wsum[wid - 1] : 0;
        const int total = wsum[15];
        int ex = running + prev + (s - vsum);
        if (i0 + 0 < Nn) { roff[i0 + 0] = ex; cursor[i0 + 0] = ex; } ex += v0;
        if (i0 + 1 < Nn) { roff[i0 + 1] = ex; cursor[i0 + 1] = ex; } ex += v1;
        if (i0 + 2 < Nn) { roff[i0 + 2] = ex; cursor[i0 + 2] = ex; } ex += v2;
        if (i0 + 3 < Nn) { roff[i0 + 3] = ex; cursor[i0 + 3] = ex; }
        running += total;
        __syncthreads();
    }
}

__global__ void scatter_kernel(const int* __restrict__ dst, int* cursor,
                               int* __restrict__ perm, int* __restrict__ sdst, int E) {
    int i = blockIdx.x * 256 + threadIdx.x;
    if (i < E) {
        int d = dst[i];
        int s = atomicAdd(&cursor[d], 1);
        perm[s] = i;
        sdst[s] = d;
    }
}

// ---------------- edge kernel v13: persistent, double-buffered tile pipeline ----------------
__global__ __launch_bounds__(NT, 2) void edge_mfma_pipe_kernel(
    const ushort_t* __restrict__ fbf, const float* __restrict__ x,
    const float* __restrict__ w, const int* __restrict__ src,
    const int* __restrict__ perm, const int* __restrict__ sdst,
    const ushort_t* __restrict__ W1p, const float* __restrict__ bm1,
    const ushort_t* __restrict__ W2p, const float* __restrict__ bm2,
    float* __restrict__ msum, int E, int ntiles)
{
    __shared__ __align__(16) ushort_t lds[2][LDS1];   // 73,728 B -> 2 blocks/CU

    const int t    = threadIdx.x;
    const int lane = t & 63;
    const int wv   = t >> 6;
    const int col  = lane & 15;
    const int g    = lane >> 4;
    const int tile0 = blockIdx.x;
    if (tile0 >= ntiles) return;

    const int el8 = lane >> 3, s8 = lane & 7;
    const int sl8 = s8 ^ el8;                 // involution granule swizzle
    const int elq = lane >> 2, q = lane & 3;
    const int qp  = q ^ (elq & 3);

    // ---- helpers ----
    auto load_meta = [&](int tile, int& nsA, int& ndA, int& nsB, int& ndB,
                         int& c8ge, int& c8ns, int& c8nd,
                         int& myd, int& prevd, int& nextd) {
        const int e0 = tile * EB;
        const int slA = min(e0 + wv * 16 + el8,     E - 1);
        const int slB = min(e0 + wv * 16 + 8 + el8, E - 1);
        const int geA = perm[slA], geB = perm[slB];
        nsA = src[geA]; ndA = sdst[slA];
        nsB = src[geB]; ndB = sdst[slB];
        const int sc = min(e0 + wv * 16 + elq, E - 1);
        c8ge = perm[sc]; c8ns = src[c8ge]; c8nd = sdst[sc];
        myd   = (e0 + lane < E) ? sdst[e0 + lane] : -1;
        prevd = (e0 > 0) ? sdst[e0 - 1] : -2;
        nextd = (e0 + EB < E) ? sdst[e0 + EB] : -2;
    };
    auto load_c8 = [&](int ge, int ns, int nd, float4& wa, float4& wb, float& sq) {
        wa = make_float4(0.f, 0.f, 0.f, 0.f); wb = wa; sq = 0.f;
        if (q < 2) {
            wa = *(const float4*)(w + (size_t)ge * DE + q * 8);
            wb = *(const float4*)(w + (size_t)ge * DE + q * 8 + 4);
        } else if (q == 2) {
            float dx = x[ns*3+0] - x[nd*3+0];
            float dy = x[ns*3+1] - x[nd*3+1];
            float dz = x[ns*3+2] - x[nd*3+2];
            sq = dx*dx + dy*dy + dz*dz;
        }
    };
    auto stage_f = [&](int buf, int nsA, int ndA, int nsB, int ndB) {
        #pragma unroll
        for (int p = 0; p < 4; ++p) {
            const int n0 = (p < 2) ? nsA : ndA;
            const int n1 = (p < 2) ? nsB : ndB;
            const ushort_t* g0 = fbf + (size_t)n0 * D + (p & 1) * 64 + sl8 * 8;
            const ushort_t* g1 = fbf + (size_t)n1 * D + (p & 1) * 64 + sl8 * 8;
            GLOAD_LDS16(g0, &lds[buf][(p * EB + wv * 16    ) * 64]);
            GLOAD_LDS16(g1, &lds[buf][(p * EB + wv * 16 + 8) * 64]);
        }
    };
    auto write_c8 = [&](int buf, float4 wa, float4 wb, float sq) {
        union { ushort_t us[8]; short8v v; } pk;
        #pragma unroll
        for (int j = 0; j < 8; ++j) pk.us[j] = 0;
        if (q < 2) {
            pk.us[0] = f2bf(wa.x); pk.us[1] = f2bf(wa.y);
            pk.us[2] = f2bf(wa.z); pk.us[3] = f2bf(wa.w);
            pk.us[4] = f2bf(wb.x); pk.us[5] = f2bf(wb.y);
            pk.us[6] = f2bf(wb.z); pk.us[7] = f2bf(wb.w);
        } else if (q == 2) {
            pk.us[0] = f2bf(sq);
        }
        *(short8v*)&lds[buf][CH8 + (wv * 16 + elq) * 32 + qp * 8] = pk.v;
    };

    // ---- prologue: stage tile0; prefetch meta for tile0+GRIDP ----
    int nsA0, ndA0, nsB0, ndB0, c8ge0, c8ns0, c8nd0, myd, prevd, nextd;
    load_meta(tile0, nsA0, ndA0, nsB0, ndB0, c8ge0, c8ns0, c8nd0, myd, prevd, nextd);
    {
        float4 wa, wb; float sq;
        load_c8(c8ge0, c8ns0, c8nd0, wa, wb, sq);
        stage_f(0, nsA0, ndA0, nsB0, ndB0);
        write_c8(0, wa, wb, sq);
    }
    int nsA1=0, ndA1=0, nsB1=0, ndB1=0, c8ge1=0, c8ns1=0, c8nd1=0, myd1=-1, prevd1=-2, nextd1=-2;
    float4 wa1 = make_float4(0,0,0,0), wb1 = wa1; float sq1 = 0.f;
    if (tile0 + GRIDP < ntiles) {
        load_meta(tile0 + GRIDP, nsA1, ndA1, nsB1, ndB1, c8ge1, c8ns1, c8nd1, myd1, prevd1, nextd1);
        load_c8(c8ge1, c8ns1, c8nd1, wa1, wb1, sq1);
    }

    int buf = 0;
    for (int tile = tile0; tile < ntiles; tile += GRIDP, buf ^= 1) {
        const int e0  = tile * EB;
        const bool hn  = tile + GRIDP < ntiles;
        const bool hn2 = tile + 2 * GRIDP < ntiles;

        __syncthreads();   // B0: lds[buf] staged (gloads + c8 writes drained)

        if (hn) stage_f(buf ^ 1, nsA1, ndA1, nsB1, ndB1);   // overlap with layer1

        const ushort_t* L = lds[buf];
        ushort_t*      Lw = lds[buf];

        const size_t wrow0 = (size_t)(wv * 32 + col) * KP1;
        const size_t wrow1 = (size_t)(wv * 32 + 16 + col) * KP1;
        short8v nb0 = *(const short8v*)&W1p[wrow0 + g * 8];
        short8v nb1 = *(const short8v*)&W1p[wrow1 + g * 8];

        // ---- layer 1: [64,288] x [288,32] per wave ----
        f32x4 acc[4][2];
        {
            float bv0 = bm1[wv * 32 + col];
            float bv1 = bm1[wv * 32 + 16 + col];
            #pragma unroll
            for (int rt = 0; rt < 4; ++rt) {
                acc[rt][0] = (f32x4){bv0, bv0, bv0, bv0};
                acc[rt][1] = (f32x4){bv1, bv1, bv1, bv1};
            }
        }
        #pragma unroll
        for (int c = 0; c < NCH1; ++c) {
            short8v b0 = nb0, b1 = nb1;
            if (c + 1 < NCH1) {
                nb0 = *(const short8v*)&W1p[wrow0 + (c + 1) * 32 + g * 8];
                nb1 = *(const short8v*)&W1p[wrow1 + (c + 1) * 32 + g * 8];
            }
            short8v a[4];
            #pragma unroll
            for (int rt = 0; rt < 4; ++rt) {
                const int row = rt * 16 + col;
                if (c < 8) {
                    const int sP = (((c & 1) << 2) + g) ^ (row & 7);
                    a[rt] = *(const short8v*)&L[((c >> 1) * EB + row) * 64 + sP * 8];
                } else {
                    const int sP = g ^ (row & 3);
                    a[rt] = *(const short8v*)&L[CH8 + row * 32 + sP * 8];
                }
            }
            #pragma unroll
            for (int rt = 0; rt < 4; ++rt) {
                acc[rt][0] = __builtin_amdgcn_mfma_f32_16x16x32_bf16(a[rt], b0, acc[rt][0], 0, 0, 0);
                acc[rt][1] = __builtin_amdgcn_mfma_f32_16x16x32_bf16(a[rt], b1, acc[rt][1], 0, 0, 0);
            }
        }

        // prefetch meta for tile+2*GRIDP during compute
        int nsA2=0, ndA2=0, nsB2=0, ndB2=0, c8ge2=0, c8ns2=0, c8nd2=0, myd2=-1, prevd2=-2, nextd2=-2;
        float4 wa2 = make_float4(0,0,0,0), wb2 = wa2; float sq2 = 0.f;
        if (hn2) {
            load_meta(tile + 2 * GRIDP, nsA2, ndA2, nsB2, ndB2, c8ge2, c8ns2, c8nd2, myd2, prevd2, nextd2);
            load_c8(c8ge2, c8ns2, c8nd2, wa2, wb2, sq2);
        }

        __syncthreads();   // B1: layer-1 LDS reads done -> pairs 0-1 of buf reusable

        // hid (relu, bf16) -> pairs 0-1 of buf, same swizzle
        const int ph = wv >> 1;
        #pragma unroll
        for (int rt = 0; rt < 4; ++rt)
            #pragma unroll
            for (int j = 0; j < 2; ++j)
                #pragma unroll
                for (int r = 0; r < 4; ++r) {
                    const int row = rt * 16 + g * 4 + r;
                    float v = fmaxf(acc[rt][j][r], 0.f);
                    unsigned int pk2 = cvt_pk_bf16(v, v);
                    const int sH = (((wv & 1) << 2) + j * 2 + (col >> 3)) ^ (row & 7);
                    Lw[(ph * EB + row) * 64 + sH * 8 + (col & 7)] = (ushort_t)pk2;
                }

        __syncthreads();   // B2: hid complete block-wide

        if (hn) write_c8(buf ^ 1, wa1, wb1, sq1);   // next tile's chunk 8 from regs

        // ---- layer 2: [64,128] x [128,32] per wave ----
        const size_t w2r0 = (size_t)(wv * 32 + col) * HD;
        const size_t w2r1 = (size_t)(wv * 32 + 16 + col) * HD;
        short8v m0 = *(const short8v*)&W2p[w2r0 + g * 8];
        short8v m1 = *(const short8v*)&W2p[w2r1 + g * 8];
        f32x4 acc2[4][2];
        {
            float bv0 = bm2[wv * 32 + col];
            float bv1 = bm2[wv * 32 + 16 + col];
            #pragma unroll
            for (int rt = 0; rt < 4; ++rt) {
                acc2[rt][0] = (f32x4){bv0, bv0, bv0, bv0};
                acc2[rt][1] = (f32x4){bv1, bv1, bv1, bv1};
            }
        }
        #pragma unroll
        for (int c = 0; c < NCH2; ++c) {
            short8v b0 = m0, b1 = m1;
            if (c + 1 < NCH2) {
                m0 = *(const short8v*)&W2p[w2r0 + (c + 1) * 32 + g * 8];
                m1 = *(const short8v*)&W2p[w2r1 + (c + 1) * 32 + g * 8];
            }
            short8v a[4];
            #pragma unroll
            for (int rt = 0; rt < 4; ++rt) {
                const int row = rt * 16 + col;
                const int sP = (((c & 1) << 2) + g) ^ (row & 7);
                a[rt] = *(const short8v*)&L[((c >> 1) * EB + row) * 64 + sP * 8];
            }
            #pragma unroll
            for (int rt = 0; rt < 4; ++rt) {
                acc2[rt][0] = __builtin_amdgcn_mfma_f32_16x16x32_bf16(a[rt], b0, acc2[rt][0], 0, 0, 0);
                acc2[rt][1] = __builtin_amdgcn_mfma_f32_16x16x32_bf16(a[rt], b1, acc2[rt][1], 0, 0, 0);
            }
        }

        // ---- wave-local segment reduce -> msum (f32); ballot-derived run metadata ----
        float qs[4][2];
        #pragma unroll
        for (int rt = 0; rt < 4; ++rt) {
            qs[rt][0] = (acc2[rt][0][0] + acc2[rt][0][1]) + (acc2[rt][0][2] + acc2[rt][0][3]);
            qs[rt][1] = (acc2[rt][1][0] + acc2[rt][1][1]) + (acc2[rt][1][2] + acc2[rt][1][3]);
        }
        const int nvalid = min(EB, E - e0);
        const int dprev_l = __shfl_up(myd, 1, 64);
        const bool head = (lane == 0) || (myd != dprev_l);
        unsigned long long rem = __ballot(head && (lane < nvalid));
        while (rem) {
            const int beg = (int)__builtin_ctzll(rem);
            rem &= rem - 1;
            const int end = rem ? (int)__builtin_ctzll(rem) : nvalid;
            const int dg  = __shfl(myd, beg, 64);

            float s0 = 0.f, s1 = 0.f;
            #pragma unroll
            for (int rt = 0; rt < 4; ++rt) {
                const int qb = rt * 16 + g * 4;
                const int lo = max(qb, beg);
                const int hi = min(qb + 4, end);
                if (lo < hi) {
                    if (lo == qb && hi == qb + 4) {
                        s0 += qs[rt][0]; s1 += qs[rt][1];
                    } else {
                        #pragma unroll
                        for (int r = 0; r < 4; ++r) {
                            const int sl = qb + r;
                            if (sl >= beg && sl < end) {
                                s0 += acc2[rt][0][r]; s1 += acc2[rt][1][r];
                            }
                        }
                    }
                }
            }
            s0 += __shfl_xor(s0, 16, 64); s0 += __shfl_xor(s0, 32, 64);
            s1 += __shfl_xor(s1, 16, 64); s1 += __shfl_xor(s1, 32, 64);
            if (g == 0) {
                const bool bnd = (beg == 0 && dg == prevd) || (end == nvalid && dg == nextd);
                float* p = msum + (size_t)dg * D + wv * 32 + col;
                if (bnd) { atomicAdd(p, s0); atomicAdd(p + 16, s1); }
                else     { p[0] = s0; p[16] = s1; }
            }
        }

        // rotate meta registers
        myd = myd1; prevd = prevd1; nextd = nextd1;
        nsA1 = nsA2; ndA1 = ndA2; nsB1 = nsB2; ndB1 = ndB2;
        c8ge1 = c8ge2; c8ns1 = c8ns2; c8nd1 = c8nd2;
        myd1 = myd2; prevd1 = prevd2; nextd1 = nextd2;
        wa1 = wa2; wb1 = wb2; sq1 = sq2;
    }
}

// ---------------- node kernel: float4-vectorized staging + update MLP ----------------
template<bool MB16>
__global__ __launch_bounds__(NT, 4) void node_kernel(
    const float* __restrict__ f, const void* __restrict__ msum_v,
    const float* __restrict__ Wu1, const float* __restrict__ bu1,
    const float* __restrict__ Wu2, const float* __restrict__ bu2,
    float* out, int Nn)
{
    __shared__ __align__(16) float hin[NB][HID_PAD];
    __shared__ __align__(16) float hid[NB][HID_PAD];
    const int t  = threadIdx.x;
    const int n0 = blockIdx.x * NB;
    const int nn = min(NB, Nn - n0);

    {
        #pragma unroll
        for (int it = 0; it < 4; ++it) {
            const int idx = it * 1024 + t * 4;
            const int e   = idx >> 7;
            const int cb  = idx & 127;
            if (e < nn) {
                const size_t off = (size_t)(n0 + e) * D + cb;
                float4 mv;
                if (MB16) {
                    uint2 pk = *(const uint2*)((const ushort_t*)msum_v + off);
                    mv.x = bf2f((ushort_t)(pk.x & 0xffffu));
                    mv.y = bf2f((ushort_t)(pk.x >> 16));
                    mv.z = bf2f((ushort_t)(pk.y & 0xffffu));
                    mv.w = bf2f((ushort_t)(pk.y >> 16));
                } else {
                    mv = *(const float4*)((const float*)msum_v + off);
                }
                float4 fv = *(const float4*)&f[off];
                float4 o = {mv.x + fv.x, mv.y + fv.y, mv.z + fv.z, mv.w + fv.w};
                *(float4*)&hin[e][cb] = o;
            }
        }
    }
    __syncthreads();

    const int tc = t & 15, te2 = (t >> 4) * 2, c0 = tc * 8;
    float a1[2][8];
    #pragma unroll
    for (int c = 0; c < 8; ++c) { float bv = bu1[c0 + c]; a1[0][c] = bv; a1[1][c] = bv; }
    for (int i = 0; i < D; i += 4) {
        float m0[4], m1[4];
        *(float4*)m0 = *(const float4*)&hin[te2][i];
        *(float4*)m1 = *(const float4*)&hin[te2 + 1][i];
        #pragma unroll
        for (int r = 0; r < 4; ++r) {
            float wr[8];
            *(float4*)&wr[0] = *(const float4*)(Wu1 + (size_t)(i + r) * HD + c0);
            *(float4*)&wr[4] = *(const float4*)(Wu1 + (size_t)(i + r) * HD + c0 + 4);
            #pragma unroll
            for (int c = 0; c < 8; ++c) { a1[0][c] += m0[r]*wr[c]; a1[1][c] += m1[r]*wr[c]; }
        }
    }
    #pragma unroll
    for (int j = 0; j < 2; ++j) {
        float v[8];
        #pragma unroll
        for (int c = 0; c < 8; ++c) v[c] = fmaxf(a1[j][c], 0.f);
        *(float4*)&hid[te2 + j][c0] = *(float4*)&v[0];
        *(float4*)&hid[te2 + j][c0 + 4] = *(float4*)&v[4];
    }
    __syncthreads();
    float a2[2][8];
    #pragma unroll
    for (int c = 0; c < 8; ++c) { float bv = bu2[c0 + c]; a2[0][c] = bv; a2[1][c] = bv; }
    for (int h = 0; h < HD; h += 4) {
        float m0[4], m1[4];
        *(float4*)m0 = *(const float4*)&hid[te2][h];
        *(float4*)m1 = *(const float4*)&hid[te2 + 1][h];
        #pragma unroll
        for (int r = 0; r < 4; ++r) {
            float wr[8];
            *(float4*)&wr[0] = *(const float4*)(Wu2 + (size_t)(h + r) * D + c0);
            *(float4*)&wr[4] = *(const float4*)(Wu2 + (size_t)(h + r) * D + c0 + 4);
            #pragma unroll
            for (int c = 0; c < 8; ++c) { a2[0][c] += m0[r]*wr[c]; a2[1][c] += m1[r]*wr[c]; }
        }
    }
    #pragma unroll
    for (int j = 0; j < 2; ++j) {
        int e = te2 + j, gn = n0 + e;
        if (e < nn) {
            *(float4*)(out + (size_t)gn * D + c0) = *(float4*)&a2[j][0];
            *(float4*)(out + (size_t)gn * D + c0 + 4) = *(float4*)&a2[j][4];
        }
    }
}

// ================= fallback kernels (pk-atomic path; no CSR) =================

__global__ void repack_kernel(const float* __restrict__ Wm1, const float* __restrict__ Wm2,
                              ushort_t* __restrict__ W1p, ushort_t* __restrict__ W2p) {
    int idx = blockIdx.x * 256 + threadIdx.x;
    const int n1 = 128 * KP1;
    if (idx < n1) {
        int n = idx / KP1, k = idx % KP1;
        W1p[idx] = f2bf((k < MSG_IN) ? Wm1[(size_t)k * HD + n] : 0.f);
    } else {
        int i2 = idx - n1;
        if (i2 < HD * D) {
            int n = i2 / HD, k = i2 % HD;
            W2p[i2] = f2bf(Wm2[(size_t)k * D + n]);
        }
    }
}

__global__ void fconv_kernel(const float* __restrict__ f, ushort_t* __restrict__ fb, int n8) {
    int i = blockIdx.x * 256 + threadIdx.x;
    if (i < n8) {
        float4 v0 = *(const float4*)(f + (size_t)i * 8);
        float4 v1 = *(const float4*)(f + (size_t)i * 8 + 4);
        union { ushort_t us[8]; short8v v; } pk;
        pk.us[0] = f2bf(v0.x); pk.us[1] = f2bf(v0.y);
        pk.us[2] = f2bf(v0.z); pk.us[3] = f2bf(v0.w);
        pk.us[4] = f2bf(v1.x); pk.us[5] = f2bf(v1.y);
        pk.us[6] = f2bf(v1.z); pk.us[7] = f2bf(v1.w);
        *(short8v*)(fb + (size_t)i * 8) = pk.v;
    }
}

__global__ __launch_bounds__(NT, 4) void edge_mfma_kernel(
    const ushort_t* __restrict__ fbf, const float* __restrict__ x,
    const float* __restrict__ w, const int* __restrict__ src,
    const int* __restrict__ dst,
    const ushort_t* __restrict__ W1p, const float* __restrict__ bm1,
    const ushort_t* __restrict__ W2p, const float* __restrict__ bm2,
    ushort_t* msum, int E)
{
    __shared__ __align__(16) ushort_t lds[LDS1];
    __shared__ int s_dst[EB];

    const int t    = threadIdx.x;
    const int lane = t & 63;
    const int wv   = t >> 6;
    const int e0   = blockIdx.x * EB;

    if (t < EB) s_dst[t] = (e0 + t < E) ? dst[e0 + t] : 0;
    {
        const int el8 = lane >> 3;
        const int s   = lane & 7;
        const int sl  = s ^ el8;
        const int geA = min(e0 + wv * 16 + el8,     E - 1);
        const int geB = min(e0 + wv * 16 + 8 + el8, E - 1);
        const int nsA = src[geA], ndA = dst[geA];
        const int nsB = src[geB], ndB = dst[geB];
        #pragma unroll
        for (int p = 0; p < 4; ++p) {
            const int n0 = (p < 2) ? nsA : ndA;
            const int n1 = (p < 2) ? nsB : ndB;
            const ushort_t* g0 = fbf + (size_t)n0 * D + (p & 1) * 64 + sl * 8;
            const ushort_t* g1 = fbf + (size_t)n1 * D + (p & 1) * 64 + sl * 8;
            GLOAD_LDS16(g0, &lds[(p * EB + wv * 16    ) * 64]);
            GLOAD_LDS16(g1, &lds[(p * EB + wv * 16 + 8) * 64]);
        }
    }
    {
        const int el = lane >> 2, q = lane & 3;
        const int qp = q ^ (el & 3);
        const int ge = e0 + wv * 16 + el;
        const bool ok = ge < E;
        const int gc = min(ge, E - 1);
        union { ushort_t us[8]; short8v v; } pk;
        #pragma unroll
        for (int j = 0; j < 8; ++j) pk.us[j] = 0;
        if (ok) {
            if (q < 2) {
                float4 w0 = *(const float4*)(w + (size_t)gc * DE + q * 8);
                float4 w1 = *(const float4*)(w + (size_t)gc * DE + q * 8 + 4);
                pk.us[0] = f2bf(w0.x); pk.us[1] = f2bf(w0.y);
                pk.us[2] = f2bf(w0.z); pk.us[3] = f2bf(w0.w);
                pk.us[4] = f2bf(w1.x); pk.us[5] = f2bf(w1.y);
                pk.us[6] = f2bf(w1.z); pk.us[7] = f2bf(w1.w);
            } else if (q == 2) {
                const int ns = src[gc], nd = dst[gc];
                float dx = x[ns*3+0] - x[nd*3+0];
                float dy = x[ns*3+1] - x[nd*3+1];
                float dz = x[ns*3+2] - x[nd*3+2];
                pk.us[0] = f2bf(dx*dx + dy*dy + dz*dz);
            }
        }
        *(short8v*)&lds[CH8 + (wv * 16 + el) * 32 + qp * 8] = pk.v;
    }

    const int col = lane & 15;
    const int g   = lane >> 4;
    const size_t wrow0 = (size_t)(wv * 32 + col) * KP1;
    const size_t wrow1 = (size_t)(wv * 32 + 16 + col) * KP1;
    short8v nb0 = *(const short8v*)&W1p[wrow0 + g * 8];
    short8v nb1 = *(const short8v*)&W1p[wrow1 + g * 8];
    __syncthreads();

    f32x4 acc[4][2];
    {
        float bv0 = bm1[wv * 32 + col];
        float bv1 = bm1[wv * 32 + 16 + col];
        #pragma unroll
        for (int rt = 0; rt < 4; ++rt) {
            acc[rt][0] = (f32x4){bv0, bv0, bv0, bv0};
            acc[rt][1] = (f32x4){bv1, bv1, bv1, bv1};
        }
    }
    #pragma unroll
    for (int c = 0; c < NCH1; ++c) {
        short8v b0 = nb0, b1 = nb1;
        if (c + 1 < NCH1) {
            nb0 = *(const short8v*)&W1p[wrow0 + (c + 1) * 32 + g * 8];
            nb1 = *(const short8v*)&W1p[wrow1 + (c + 1) * 32 + g * 8];
        }
        short8v a[4];
        #pragma unroll
        for (int rt = 0; rt < 4; ++rt) {
            const int row = rt * 16 + col;
            if (c < 8) {
                const int sP = (((c & 1) << 2) + g) ^ (row & 7);
                a[rt] = *(const short8v*)&lds[((c >> 1) * EB + row) * 64 + sP * 8];
            } else {
                const int sP = g ^ (row & 3);
                a[rt] = *(const short8v*)&lds[CH8 + row * 32 + sP * 8];
            }
        }
        #pragma unroll
        for (int rt = 0; rt < 4; ++rt) {
            acc[rt][0] = __builtin_amdgcn_mfma_f32_16x16x32_bf16(a[rt], b0, acc[rt][0], 0, 0, 0);
            acc[rt][1] = __builtin_amdgcn_mfma_f32_16x16x32_bf16(a[rt], b1, acc[rt][1], 0, 0, 0);
        }
    }
    __syncthreads();

    const int ph = wv >> 1;
    #pragma unroll
    for (int rt = 0; rt < 4; ++rt)
        #pragma unroll
        for (int j = 0; j < 2; ++j)
            #pragma unroll
            for (int r = 0; r < 4; ++r) {
                const int row = rt * 16 + g * 4 + r;
                float v = fmaxf(acc[rt][j][r], 0.f);
                unsigned int pk2 = cvt_pk_bf16(v, v);
                const int sH = (((wv & 1) << 2) + j * 2 + (col >> 3)) ^ (row & 7);
                lds[(ph * EB + row) * 64 + sH * 8 + (col & 7)] = (ushort_t)pk2;
            }
    __syncthreads();

    const size_t w2r0 = (size_t)(wv * 32 + col) * HD;
    const size_t w2r1 = (size_t)(wv * 32 + 16 + col) * HD;
    short8v m0 = *(const short8v*)&W2p[w2r0 + g * 8];
    short8v m1 = *(const short8v*)&W2p[w2r1 + g * 8];
    f32x4 acc2[4][2];
    {
        float bv0 = bm2[wv * 32 + col];
        float bv1 = bm2[wv * 32 + 16 + col];
        #pragma unroll
        for (int rt = 0; rt < 4; ++rt) {
            acc2[rt][0] = (f32x4){bv0, bv0, bv0, bv0};
            acc2[rt][1] = (f32x4){bv1, bv1, bv1, bv1};
        }
    }
    #pragma unroll
    for (int c = 0; c < NCH2; ++c) {
        short8v b0 = m0, b1 = m1;
        if (c + 1 < NCH2) {
            m0 = *(const short8v*)&W2p[w2r0 + (c + 1) * 32 + g * 8];
            m1 = *(const short8v*)&W2p[w2r1 + (c + 1) * 32 + g * 8];
        }
        short8v a[4];
        #pragma unroll
        for (int rt = 0; rt < 4; ++rt) {
            const int row = rt * 16 + col;
            const int sP = (((c & 1) << 2) + g) ^ (row & 7);
            a[rt] = *(const short8v*)&lds[((c >> 1) * EB + row) * 64 + sP * 8];
        }
        #pragma unroll
        for (int rt = 0; rt < 4; ++rt) {
            acc2[rt][0] = __builtin_amdgcn_mfma_f32_16x16x32_bf16(a[rt], b0, acc2[rt][0], 0, 0, 0);
            acc2[rt][1] = __builtin_amdgcn_mfma_f32_16x16x32_bf16(a[rt], b1, acc2[rt][1], 0, 0, 0);
        }
    }

    const bool even = (col & 1) == 0;
    #pragma unroll
    for (int rt = 0; rt < 4; ++rt)
        #pragma unroll
        for (int r = 0; r < 4; ++r) {
            const int e  = rt * 16 + g * 4 + r;
            const int ge = e0 + e;
            const int dg = s_dst[e];
            #pragma unroll
            for (int j = 0; j < 2; ++j) {
                float v  = acc2[rt][j][r];
                float vn = __shfl_xor(v, 1, 64);
                if (even && ge < E) {
                    unsigned int pk2 = cvt_pk_bf16(v, vn);
                    ushort_t* p = msum + (size_t)dg * D + wv * 32 + j * 16 + col;
                    asm volatile("global_atomic_pk_add_bf16 %0, %1, off"
                                 :: "v"(p), "v"(pk2) : "memory");
                }
            }
        }
}

extern "C" void kernel_launch(void* const* d_in, const int* in_sizes, int n_in,
                              void* d_out, int out_size, void* d_ws, size_t ws_size,
                              hipStream_t stream) {
    const float* f   = (const float*)d_in[0];
    const float* x   = (const float*)d_in[1];
    const float* w   = (const float*)d_in[2];
    const int*   src = (const int*)d_in[3];
    const int*   dst = (const int*)d_in[4];
    const float* Wm1 = (const float*)d_in[5];
    const float* bm1 = (const float*)d_in[6];
    const float* Wm2 = (const float*)d_in[7];
    const float* bm2 = (const float*)d_in[8];
    const float* Wu1 = (const float*)d_in[9];
    const float* bu1 = (const float*)d_in[10];
    const float* Wu2 = (const float*)d_in[11];
    const float* bu2 = (const float*)d_in[12];

    const int Nn = in_sizes[0] / D;
    const int E  = in_sizes[3];

    const size_t wbytes = (size_t)(128 * KP1 + HD * D) * sizeof(ushort_t);
    auto align512 = [](size_t v) { return (v + 511) & ~(size_t)511; };

    const size_t fb_bytes = (size_t)Nn * D * 2;
    char* wsb = (char*)d_ws;

    // ---------------- primary: fused-reduce CSR layout ----------------
    size_t off = 0;
    const size_t o_w    = off; off = align512(off + wbytes);
    const size_t o_fb   = off; off = align512(off + fb_bytes);
    const size_t o_cnt  = off; off = align512(off + (size_t)Nn * 4);
    const size_t o_roff = off; off = align512(off + (size_t)Nn * 4);
    const size_t o_cur  = off; off = align512(off + (size_t)Nn * 4);
    const size_t o_perm = off; off = align512(off + (size_t)E * 4);
    const size_t o_sdst = off; off = align512(off + (size_t)E * 4);
    const size_t o_ms   = off; off = align512(off + (size_t)Nn * D * 4);
    const size_t primary_total = off;

    if (ws_size >= primary_total) {
        ushort_t* W1p = (ushort_t*)(wsb + o_w);
        ushort_t* W2p = W1p + 128 * KP1;
        ushort_t* fbf = (ushort_t*)(wsb + o_fb);
        int* cnt      = (int*)(wsb + o_cnt);
        int* roff     = (int*)(wsb + o_roff);
        int* cursor   = (int*)(wsb + o_cur);
        int* perm     = (int*)(wsb + o_perm);
        int* sdst     = (int*)(wsb + o_sdst);
        float* msum   = (float*)(wsb + o_ms);

        const int n8 = Nn * D / 8;
        const int nq = Nn * D / 4;
        const int ntiles = (E + EB - 1) / EB;
        hipMemsetAsync(cnt, 0, (size_t)Nn * 4, stream);
        fused_pre_kernel<<<dim3(1024), dim3(256), 0, stream>>>(
            Wm1, Wm2, W1p, W2p, f, fbf, dst, cnt, msum, n8, E, nq);
        scan_kernel<<<dim3(1), dim3(1024), 0, stream>>>(cnt, roff, cursor, Nn);
        scatter_kernel<<<dim3((E + 255) / 256), dim3(256), 0, stream>>>(dst, cursor, perm, sdst, E);
        edge_mfma_pipe_kernel<<<dim3(min(GRIDP, ntiles)), dim3(NT), 0, stream>>>(
            fbf, x, w, src, perm, sdst, W1p, bm1, W2p, bm2, msum, E, ntiles);
        node_kernel<false><<<dim3((Nn + NB - 1) / NB), dim3(NT), 0, stream>>>(
            f, msum, Wu1, bu1, Wu2, bu2, (float*)d_out, Nn);
        return;
    }

    // ---------------- fallback: pk-atomic path ----------------
    size_t off2 = 0;
    const size_t p_w  = off2; off2 = align512(off2 + wbytes);
    const size_t p_fb = off2; off2 = align512(off2 + fb_bytes);
    const size_t p_ms = off2; off2 = align512(off2 + (size_t)Nn * D * 2);
    if (ws_size >= off2) {
        ushort_t* W1p  = (ushort_t*)(wsb + p_w);
        ushort_t* W2p  = W1p + 128 * KP1;
        ushort_t* fbf  = (ushort_t*)(wsb + p_fb);
        ushort_t* msum = (ushort_t*)(wsb + p_ms);
        const int rp_elems = 128 * KP1 + HD * D;
        hipMemsetAsync(msum, 0, (size_t)Nn * D * 2, stream);
        repack_kernel<<<dim3((rp_elems + 255) / 256), dim3(256), 0, stream>>>(Wm1, Wm2, W1p, W2p);
        const int n8 = Nn * D / 8;
        fconv_kernel<<<dim3((n8 + 255) / 256), dim3(256), 0, stream>>>(f, fbf, n8);
        edge_mfma_kernel<<<dim3((E + EB - 1) / EB), dim3(NT), 0, stream>>>(
            fbf, x, w, src, dst, W1p, bm1, W2p, bm2, msum, E);
        node_kernel<true><<<dim3((Nn + NB - 1) / NB), dim3(NT), 0, stream>>>(
            f, msum, Wu1, bu1, Wu2, bu2, (float*)d_out, Nn);
        return;
    }
}

// Round 14
// 410.010 us; speedup vs baseline: 1.0159x; 1.0159x over previous
//
#include <hip/hip_runtime.h>

#define D 128
#define HD 128
#define DE 16
#define MSG_IN 273
#define EB 64        // edges per tile
#define NT 256
#define KP1 288      // padded msg K = 9 chunks of 32
#define NCH1 9
#define NCH2 4
#define NB 32
#define HID_PAD 132
#define CH8 (4 * EB * 64)   // ushort offset of chunk-8 region in lds[]
#define LDS1 (4 * EB * 64 + EB * 32)

typedef __attribute__((ext_vector_type(8))) short short8v;
typedef __attribute__((ext_vector_type(4))) float f32x4;
typedef unsigned short ushort_t;

#define GLOAD_LDS16(gp, lp) \
    __builtin_amdgcn_global_load_lds((const __attribute__((address_space(1))) unsigned int*)(gp), \
                                     (__attribute__((address_space(3))) unsigned int*)(lp), 16, 0, 0)

__device__ __forceinline__ unsigned short f2bf(float v) {
    unsigned int u = __builtin_bit_cast(unsigned int, v);
    u += 0x7fffu + ((u >> 16) & 1u);
    return (unsigned short)(u >> 16);
}
__device__ __forceinline__ float bf2f(ushort_t u) {
    return __builtin_bit_cast(float, (unsigned int)u << 16);
}
__device__ __forceinline__ unsigned int cvt_pk_bf16(float lo, float hi) {
    unsigned int r;
    asm("v_cvt_pk_bf16_f32 %0, %1, %2" : "=v"(r) : "v"(lo), "v"(hi));
    return r;
}

// ---------------- fused prepass: weight repack + f->bf16 + dst hist ----------------
__global__ void fused_pre_kernel(const float* __restrict__ Wm1, const float* __restrict__ Wm2,
                                 ushort_t* __restrict__ W1p, ushort_t* __restrict__ W2p,
                                 const float* __restrict__ f, ushort_t* __restrict__ fb,
                                 const int* __restrict__ dst, int* __restrict__ cnt,
                                 int n8, int E) {
    const int gid    = blockIdx.x * 256 + threadIdx.x;
    const int stride = gridDim.x * 256;
    const int rp1 = 128 * KP1;
    const int rp_elems = rp1 + HD * D;
    for (int i = gid; i < rp_elems; i += stride) {
        if (i < rp1) {
            int n = i / KP1, k = i % KP1;
            W1p[i] = f2bf((k < MSG_IN) ? Wm1[(size_t)k * HD + n] : 0.f);
        } else {
            int i2 = i - rp1;
            int n = i2 / HD, k = i2 % HD;
            W2p[i2] = f2bf(Wm2[(size_t)k * D + n]);
        }
    }
    for (int i = gid; i < n8; i += stride) {
        float4 v0 = *(const float4*)(f + (size_t)i * 8);
        float4 v1 = *(const float4*)(f + (size_t)i * 8 + 4);
        union { ushort_t us[8]; short8v v; } pk;
        pk.us[0] = f2bf(v0.x); pk.us[1] = f2bf(v0.y);
        pk.us[2] = f2bf(v0.z); pk.us[3] = f2bf(v0.w);
        pk.us[4] = f2bf(v1.x); pk.us[5] = f2bf(v1.y);
        pk.us[6] = f2bf(v1.z); pk.us[7] = f2bf(v1.w);
        *(short8v*)(fb + (size_t)i * 8) = pk.v;
    }
    for (int i = gid; i < E; i += stride) atomicAdd(&cnt[dst[i]], 1);
}

// ---------------- CSR build: parallel scan (4 elems/thread) -> scatter + selective zero ----------------
__global__ __launch_bounds__(1024) void scan_kernel(const int* __restrict__ cnt,
                                                    int* __restrict__ roff,
                                                    int* __restrict__ cursor, int Nn) {
    __shared__ int wsum[16];
    const int t = threadIdx.x, l = t & 63, wid = t >> 6;
    int running = 0;
    for (int base = 0; base < Nn; base += 4096) {
        const int i0 = base + t * 4;
        int v0 = 0, v1 = 0, v2 = 0, v3 = 0;
        if (i0 + 3 < Nn) {
            int4 v = *(const int4*)(cnt + i0);
            v0 = v.x; v1 = v.y; v2 = v.z; v3 = v.w;
        } else {
            if (i0 + 0 < Nn) v0 = cnt[i0 + 0];
            if (i0 + 1 < Nn) v1 = cnt[i0 + 1];
            if (i0 + 2 < Nn) v2 = cnt[i0 + 2];
        }
        const int vsum = v0 + v1 + v2 + v3;
        int s = vsum;
        #pragma unroll
        for (int off = 1; off < 64; off <<= 1) {
            int u = __shfl_up(s, off, 64);
            if (l >= off) s += u;
        }
        if (l == 63) wsum[wid] = s;
        __syncthreads();
        if (wid == 0 && l < 16) {
            int xv = wsum[l];
            #pragma unroll
            for (int off = 1; off < 16; off <<= 1) {
                int u = __shfl_up(xv, off, 64);
                if (l >= off) xv += u;
            }
            wsum[l] = xv;
        }
        __syncthreads();
        const int prev  = (wid > 0) ? wsum[wid - 1] : 0;
        const int total = wsum[15];
        int ex = running + prev + (s - vsum);
        if (i0 + 0 < Nn) { roff[i0 + 0] = ex; cursor[i0 + 0] = ex; } ex += v0;
        if (i0 + 1 < Nn) { roff[i0 + 1] = ex; cursor[i0 + 1] = ex; } ex += v1;
        if (i0 + 2 < Nn) { roff[i0 + 2] = ex; cursor[i0 + 2] = ex; } ex += v2;
        if (i0 + 3 < Nn) { roff[i0 + 3] = ex; cursor[i0 + 3] = ex; }
        running += total;
        __syncthreads();
    }
}

// scatter + zero msum rows that will be atomically accumulated (or never written)
__global__ void scatter_kernel(const int* __restrict__ dst, int* cursor,
                               const int* __restrict__ roff, const int* __restrict__ cnt,
                               int* __restrict__ perm, int* __restrict__ sdst,
                               float* __restrict__ msum, int E, int Nn) {
    const int gid    = blockIdx.x * 256 + threadIdx.x;
    const int stride = gridDim.x * 256;
    for (int i = gid; i < E; i += stride) {
        int d = dst[i];
        int s = atomicAdd(&cursor[d], 1);
        perm[s] = i;
        sdst[s] = d;
    }
    for (int n = gid; n < Nn; n += stride) {
        const int c = cnt[n];
        const int r = roff[n];
        const bool need0 = (c == 0) || (r / EB != (r + c - 1) / EB);
        if (need0) {
            float4 z = {0.f, 0.f, 0.f, 0.f};
            float* p = msum + (size_t)n * D;
            #pragma unroll
            for (int k = 0; k < 32; ++k) *(float4*)(p + k * 4) = z;
        }
    }
}

// ---------------- edge kernel v14 (= v12 body + tile_base): fused in-register segment reduce ----------------
__global__ __launch_bounds__(NT, 4) void edge_mfma_fused_kernel(
    const ushort_t* __restrict__ fbf, const float* __restrict__ x,
    const float* __restrict__ w, const int* __restrict__ src,
    const int* __restrict__ perm, const int* __restrict__ sdst,
    const ushort_t* __restrict__ W1p, const float* __restrict__ bm1,
    const ushort_t* __restrict__ W2p, const float* __restrict__ bm2,
    float* __restrict__ msum, int E, int tile_base)
{
    __shared__ __align__(16) ushort_t lds[LDS1];   // 36,864 B

    const int t    = threadIdx.x;
    const int lane = t & 63;
    const int wv   = t >> 6;
    const int e0   = (tile_base + blockIdx.x) * EB;

    const int myd  = (e0 + lane < E) ? sdst[e0 + lane] : -1;
    const int prevd = (e0 > 0) ? sdst[e0 - 1] : -2;
    const int nextd = (e0 + EB < E) ? sdst[e0 + EB] : -2;

    // ---- f staging: 8 x global_load_lds_dwordx4, pre-swizzled global source ----
    {
        const int el8 = lane >> 3;
        const int s   = lane & 7;
        const int sl  = s ^ el8;            // involution swizzle
        const int slA = min(e0 + wv * 16 + el8,     E - 1);
        const int slB = min(e0 + wv * 16 + 8 + el8, E - 1);
        const int geA = perm[slA], geB = perm[slB];
        const int nsA = src[geA], ndA = sdst[slA];
        const int nsB = src[geB], ndB = sdst[slB];
        #pragma unroll
        for (int p = 0; p < 4; ++p) {
            const int n0 = (p < 2) ? nsA : ndA;
            const int n1 = (p < 2) ? nsB : ndB;
            const ushort_t* g0 = fbf + (size_t)n0 * D + (p & 1) * 64 + sl * 8;
            const ushort_t* g1 = fbf + (size_t)n1 * D + (p & 1) * 64 + sl * 8;
            GLOAD_LDS16(g0, &lds[(p * EB + wv * 16    ) * 64]);
            GLOAD_LDS16(g1, &lds[(p * EB + wv * 16 + 8) * 64]);
        }
    }
    // ---- chunk 8: w feats (k0..15), sqd (k16), zeros; 2-bit swizzle ----
    {
        const int el = lane >> 2, q = lane & 3;
        const int qp = q ^ (el & 3);
        const int slot = e0 + wv * 16 + el;
        const bool ok = slot < E;
        const int sc = min(slot, E - 1);
        const int ge = perm[sc];
        union { ushort_t us[8]; short8v v; } pk;
        #pragma unroll
        for (int j = 0; j < 8; ++j) pk.us[j] = 0;
        if (ok) {
            if (q < 2) {
                float4 w0 = *(const float4*)(w + (size_t)ge * DE + q * 8);
                float4 w1 = *(const float4*)(w + (size_t)ge * DE + q * 8 + 4);
                pk.us[0] = f2bf(w0.x); pk.us[1] = f2bf(w0.y);
                pk.us[2] = f2bf(w0.z); pk.us[3] = f2bf(w0.w);
                pk.us[4] = f2bf(w1.x); pk.us[5] = f2bf(w1.y);
                pk.us[6] = f2bf(w1.z); pk.us[7] = f2bf(w1.w);
            } else if (q == 2) {
                const int ns = src[ge], nd = sdst[sc];
                float dx = x[ns*3+0] - x[nd*3+0];
                float dy = x[ns*3+1] - x[nd*3+1];
                float dz = x[ns*3+2] - x[nd*3+2];
                pk.us[0] = f2bf(dx*dx + dy*dy + dz*dz);
            }
        }
        *(short8v*)&lds[CH8 + (wv * 16 + el) * 32 + qp * 8] = pk.v;
    }

    const int col = lane & 15;
    const int g   = lane >> 4;

    const size_t wrow0 = (size_t)(wv * 32 + col) * KP1;
    const size_t wrow1 = (size_t)(wv * 32 + 16 + col) * KP1;
    short8v nb0 = *(const short8v*)&W1p[wrow0 + g * 8];
    short8v nb1 = *(const short8v*)&W1p[wrow1 + g * 8];

    __syncthreads();   // B0: staging complete

    // ---- layer 1: [64,288] x [288,32] per wave ----
    f32x4 acc[4][2];
    {
        float bv0 = bm1[wv * 32 + col];
        float bv1 = bm1[wv * 32 + 16 + col];
        #pragma unroll
        for (int rt = 0; rt < 4; ++rt) {
            acc[rt][0] = (f32x4){bv0, bv0, bv0, bv0};
            acc[rt][1] = (f32x4){bv1, bv1, bv1, bv1};
        }
    }
    #pragma unroll
    for (int c = 0; c < NCH1; ++c) {
        short8v b0 = nb0, b1 = nb1;
        if (c + 1 < NCH1) {
            nb0 = *(const short8v*)&W1p[wrow0 + (c + 1) * 32 + g * 8];
            nb1 = *(const short8v*)&W1p[wrow1 + (c + 1) * 32 + g * 8];
        }
        short8v a[4];
        #pragma unroll
        for (int rt = 0; rt < 4; ++rt) {
            const int row = rt * 16 + col;
            if (c < 8) {
                const int sP = (((c & 1) << 2) + g) ^ (row & 7);
                a[rt] = *(const short8v*)&lds[((c >> 1) * EB + row) * 64 + sP * 8];
            } else {
                const int sP = g ^ (row & 3);
                a[rt] = *(const short8v*)&lds[CH8 + row * 32 + sP * 8];
            }
        }
        #pragma unroll
        for (int rt = 0; rt < 4; ++rt) {
            acc[rt][0] = __builtin_amdgcn_mfma_f32_16x16x32_bf16(a[rt], b0, acc[rt][0], 0, 0, 0);
            acc[rt][1] = __builtin_amdgcn_mfma_f32_16x16x32_bf16(a[rt], b1, acc[rt][1], 0, 0, 0);
        }
    }
    __syncthreads();   // B1

    // hid (relu, bf16) -> pairs 0-1 region, same swizzle; all-lane b16 stores
    const int ph = wv >> 1;
    #pragma unroll
    for (int rt = 0; rt < 4; ++rt)
        #pragma unroll
        for (int j = 0; j < 2; ++j)
            #pragma unroll
            for (int r = 0; r < 4; ++r) {
                const int row = rt * 16 + g * 4 + r;
                float v = fmaxf(acc[rt][j][r], 0.f);
                unsigned int pk2 = cvt_pk_bf16(v, v);
                const int sH = (((wv & 1) << 2) + j * 2 + (col >> 3)) ^ (row & 7);
                lds[(ph * EB + row) * 64 + sH * 8 + (col & 7)] = (ushort_t)pk2;
            }
    __syncthreads();   // B2

    // ---- layer 2: [64,128] x [128,32] per wave ----
    const size_t w2r0 = (size_t)(wv * 32 + col) * HD;
    const size_t w2r1 = (size_t)(wv * 32 + 16 + col) * HD;
    short8v m0 = *(const short8v*)&W2p[w2r0 + g * 8];
    short8v m1 = *(const short8v*)&W2p[w2r1 + g * 8];
    f32x4 acc2[4][2];
    {
        float bv0 = bm2[wv * 32 + col];
        float bv1 = bm2[wv * 32 + 16 + col];
        #pragma unroll
        for (int rt = 0; rt < 4; ++rt) {
            acc2[rt][0] = (f32x4){bv0, bv0, bv0, bv0};
            acc2[rt][1] = (f32x4){bv1, bv1, bv1, bv1};
        }
    }
    #pragma unroll
    for (int c = 0; c < NCH2; ++c) {
        short8v b0 = m0, b1 = m1;
        if (c + 1 < NCH2) {
            m0 = *(const short8v*)&W2p[w2r0 + (c + 1) * 32 + g * 8];
            m1 = *(const short8v*)&W2p[w2r1 + (c + 1) * 32 + g * 8];
        }
        short8v a[4];
        #pragma unroll
        for (int rt = 0; rt < 4; ++rt) {
            const int row = rt * 16 + col;
            const int sP = (((c & 1) << 2) + g) ^ (row & 7);
            a[rt] = *(const short8v*)&lds[((c >> 1) * EB + row) * 64 + sP * 8];
        }
        #pragma unroll
        for (int rt = 0; rt < 4; ++rt) {
            acc2[rt][0] = __builtin_amdgcn_mfma_f32_16x16x32_bf16(a[rt], b0, acc2[rt][0], 0, 0, 0);
            acc2[rt][1] = __builtin_amdgcn_mfma_f32_16x16x32_bf16(a[rt], b1, acc2[rt][1], 0, 0, 0);
        }
    }

    // ---- wave-local segment reduce -> msum (f32); ballot-derived run metadata ----
    float qs[4][2];
    #pragma unroll
    for (int rt = 0; rt < 4; ++rt) {
        qs[rt][0] = (acc2[rt][0][0] + acc2[rt][0][1]) + (acc2[rt][0][2] + acc2[rt][0][3]);
        qs[rt][1] = (acc2[rt][1][0] + acc2[rt][1][1]) + (acc2[rt][1][2] + acc2[rt][1][3]);
    }
    const int nvalid = min(EB, E - e0);
    const int dprev_l = __shfl_up(myd, 1, 64);
    const bool head = (lane == 0) || (myd != dprev_l);
    unsigned long long rem = __ballot(head && (lane < nvalid));
    while (rem) {
        const int beg = (int)__builtin_ctzll(rem);
        rem &= rem - 1;
        const int end = rem ? (int)__builtin_ctzll(rem) : nvalid;
        const int dg  = __shfl(myd, beg, 64);

        float s0 = 0.f, s1 = 0.f;
        #pragma unroll
        for (int rt = 0; rt < 4; ++rt) {
            const int qb = rt * 16 + g * 4;
            const int lo = max(qb, beg);
            const int hi = min(qb + 4, end);
            if (lo < hi) {
                if (lo == qb && hi == qb + 4) {
                    s0 += qs[rt][0]; s1 += qs[rt][1];
                } else {
                    #pragma unroll
                    for (int r = 0; r < 4; ++r) {
                        const int sl = qb + r;
                        if (sl >= beg && sl < end) {
                            s0 += acc2[rt][0][r]; s1 += acc2[rt][1][r];
                        }
                    }
                }
            }
        }
        s0 += __shfl_xor(s0, 16, 64); s0 += __shfl_xor(s0, 32, 64);
        s1 += __shfl_xor(s1, 16, 64); s1 += __shfl_xor(s1, 32, 64);
        if (g == 0) {
            const bool bnd = (beg == 0 && dg == prevd) || (end == nvalid && dg == nextd);
            float* p = msum + (size_t)dg * D + wv * 32 + col;
            if (bnd) { atomicAdd(p, s0); atomicAdd(p + 16, s1); }
            else     { p[0] = s0; p[16] = s1; }
        }
    }
}

// ---------------- node kernel: float4-vectorized staging + update MLP ----------------
template<bool MB16>
__global__ __launch_bounds__(NT, 4) void node_kernel(
    const float* __restrict__ f, const void* __restrict__ msum_v,
    const float* __restrict__ Wu1, const float* __restrict__ bu1,
    const float* __restrict__ Wu2, const float* __restrict__ bu2,
    float* out, int Nn)
{
    __shared__ __align__(16) float hin[NB][HID_PAD];
    __shared__ __align__(16) float hid[NB][HID_PAD];
    const int t  = threadIdx.x;
    const int n0 = blockIdx.x * NB;
    const int nn = min(NB, Nn - n0);

    {
        #pragma unroll
        for (int it = 0; it < 4; ++it) {
            const int idx = it * 1024 + t * 4;
            const int e   = idx >> 7;
            const int cb  = idx & 127;
            if (e < nn) {
                const size_t off = (size_t)(n0 + e) * D + cb;
                float4 mv;
                if (MB16) {
                    uint2 pk = *(const uint2*)((const ushort_t*)msum_v + off);
                    mv.x = bf2f((ushort_t)(pk.x & 0xffffu));
                    mv.y = bf2f((ushort_t)(pk.x >> 16));
                    mv.z = bf2f((ushort_t)(pk.y & 0xffffu));
                    mv.w = bf2f((ushort_t)(pk.y >> 16));
                } else {
                    mv = *(const float4*)((const float*)msum_v + off);
                }
                float4 fv = *(const float4*)&f[off];
                float4 o = {mv.x + fv.x, mv.y + fv.y, mv.z + fv.z, mv.w + fv.w};
                *(float4*)&hin[e][cb] = o;
            }
        }
    }
    __syncthreads();

    const int tc = t & 15, te2 = (t >> 4) * 2, c0 = tc * 8;
    float a1[2][8];
    #pragma unroll
    for (int c = 0; c < 8; ++c) { float bv = bu1[c0 + c]; a1[0][c] = bv; a1[1][c] = bv; }
    for (int i = 0; i < D; i += 4) {
        float m0[4], m1[4];
        *(float4*)m0 = *(const float4*)&hin[te2][i];
        *(float4*)m1 = *(const float4*)&hin[te2 + 1][i];
        #pragma unroll
        for (int r = 0; r < 4; ++r) {
            float wr[8];
            *(float4*)&wr[0] = *(const float4*)(Wu1 + (size_t)(i + r) * HD + c0);
            *(float4*)&wr[4] = *(const float4*)(Wu1 + (size_t)(i + r) * HD + c0 + 4);
            #pragma unroll
            for (int c = 0; c < 8; ++c) { a1[0][c] += m0[r]*wr[c]; a1[1][c] += m1[r]*wr[c]; }
        }
    }
    #pragma unroll
    for (int j = 0; j < 2; ++j) {
        float v[8];
        #pragma unroll
        for (int c = 0; c < 8; ++c) v[c] = fmaxf(a1[j][c], 0.f);
        *(float4*)&hid[te2 + j][c0] = *(float4*)&v[0];
        *(float4*)&hid[te2 + j][c0 + 4] = *(float4*)&v[4];
    }
    __syncthreads();
    float a2[2][8];
    #pragma unroll
    for (int c = 0; c < 8; ++c) { float bv = bu2[c0 + c]; a2[0][c] = bv; a2[1][c] = bv; }
    for (int h = 0; h < HD; h += 4) {
        float m0[4], m1[4];
        *(float4*)m0 = *(const float4*)&hid[te2][h];
        *(float4*)m1 = *(const float4*)&hid[te2 + 1][h];
        #pragma unroll
        for (int r = 0; r < 4; ++r) {
            float wr[8];
            *(float4*)&wr[0] = *(const float4*)(Wu2 + (size_t)(h + r) * D + c0);
            *(float4*)&wr[4] = *(const float4*)(Wu2 + (size_t)(h + r) * D + c0 + 4);
            #pragma unroll
            for (int c = 0; c < 8; ++c) { a2[0][c] += m0[r]*wr[c]; a2[1][c] += m1[r]*wr[c]; }
        }
    }
    #pragma unroll
    for (int j = 0; j < 2; ++j) {
        int e = te2 + j, gn = n0 + e;
        if (e < nn) {
            *(float4*)(out + (size_t)gn * D + c0) = *(float4*)&a2[j][0];
            *(float4*)(out + (size_t)gn * D + c0 + 4) = *(float4*)&a2[j][4];
        }
    }
}

// ================= fallback kernels (pk-atomic path; no CSR) =================

__global__ void repack_kernel(const float* __restrict__ Wm1, const float* __restrict__ Wm2,
                              ushort_t* __restrict__ W1p, ushort_t* __restrict__ W2p) {
    int idx = blockIdx.x * 256 + threadIdx.x;
    const int n1 = 128 * KP1;
    if (idx < n1) {
        int n = idx / KP1, k = idx % KP1;
        W1p[idx] = f2bf((k < MSG_IN) ? Wm1[(size_t)k * HD + n] : 0.f);
    } else {
        int i2 = idx - n1;
        if (i2 < HD * D) {
            int n = i2 / HD, k = i2 % HD;
            W2p[i2] = f2bf(Wm2[(size_t)k * D + n]);
        }
    }
}

__global__ void fconv_kernel(const float* __restrict__ f, ushort_t* __restrict__ fb, int n8) {
    int i = blockIdx.x * 256 + threadIdx.x;
    if (i < n8) {
        float4 v0 = *(const float4*)(f + (size_t)i * 8);
        float4 v1 = *(const float4*)(f + (size_t)i * 8 + 4);
        union { ushort_t us[8]; short8v v; } pk;
        pk.us[0] = f2bf(v0.x); pk.us[1] = f2bf(v0.y);
        pk.us[2] = f2bf(v0.z); pk.us[3] = f2bf(v0.w);
        pk.us[4] = f2bf(v1.x); pk.us[5] = f2bf(v1.y);
        pk.us[6] = f2bf(v1.z); pk.us[7] = f2bf(v1.w);
        *(short8v*)(fb + (size_t)i * 8) = pk.v;
    }
}

__global__ __launch_bounds__(NT, 4) void edge_mfma_kernel(
    const ushort_t* __restrict__ fbf, const float* __restrict__ x,
    const float* __restrict__ w, const int* __restrict__ src,
    const int* __restrict__ dst,
    const ushort_t* __restrict__ W1p, const float* __restrict__ bm1,
    const ushort_t* __restrict__ W2p, const float* __restrict__ bm2,
    ushort_t* msum, int E)
{
    __shared__ __align__(16) ushort_t lds[LDS1];
    __shared__ int s_dst[EB];

    const int t    = threadIdx.x;
    const int lane = t & 63;
    const int wv   = t >> 6;
    const int e0   = blockIdx.x * EB;

    if (t < EB) s_dst[t] = (e0 + t < E) ? dst[e0 + t] : 0;
    {
        const int el8 = lane >> 3;
        const int s   = lane & 7;
        const int sl  = s ^ el8;
        const int geA = min(e0 + wv * 16 + el8,     E - 1);
        const int geB = min(e0 + wv * 16 + 8 + el8, E - 1);
        const int nsA = src[geA], ndA = dst[geA];
        const int nsB = src[geB], ndB = dst[geB];
        #pragma unroll
        for (int p = 0; p < 4; ++p) {
            const int n0 = (p < 2) ? nsA : ndA;
            const int n1 = (p < 2) ? nsB : ndB;
            const ushort_t* g0 = fbf + (size_t)n0 * D + (p & 1) * 64 + sl * 8;
            const ushort_t* g1 = fbf + (size_t)n1 * D + (p & 1) * 64 + sl * 8;
            GLOAD_LDS16(g0, &lds[(p * EB + wv * 16    ) * 64]);
            GLOAD_LDS16(g1, &lds[(p * EB + wv * 16 + 8) * 64]);
        }
    }
    {
        const int el = lane >> 2, q = lane & 3;
        const int qp = q ^ (el & 3);
        const int ge = e0 + wv * 16 + el;
        const bool ok = ge < E;
        const int gc = min(ge, E - 1);
        union { ushort_t us[8]; short8v v; } pk;
        #pragma unroll
        for (int j = 0; j < 8; ++j) pk.us[j] = 0;
        if (ok) {
            if (q < 2) {
                float4 w0 = *(const float4*)(w + (size_t)gc * DE + q * 8);
                float4 w1 = *(const float4*)(w + (size_t)gc * DE + q * 8 + 4);
                pk.us[0] = f2bf(w0.x); pk.us[1] = f2bf(w0.y);
                pk.us[2] = f2bf(w0.z); pk.us[3] = f2bf(w0.w);
                pk.us[4] = f2bf(w1.x); pk.us[5] = f2bf(w1.y);
                pk.us[6] = f2bf(w1.z); pk.us[7] = f2bf(w1.w);
            } else if (q == 2) {
                const int ns = src[gc], nd = dst[gc];
                float dx = x[ns*3+0] - x[nd*3+0];
                float dy = x[ns*3+1] - x[nd*3+1];
                float dz = x[ns*3+2] - x[nd*3+2];
                pk.us[0] = f2bf(dx*dx + dy*dy + dz*dz);
            }
        }
        *(short8v*)&lds[CH8 + (wv * 16 + el) * 32 + qp * 8] = pk.v;
    }

    const int col = lane & 15;
    const int g   = lane >> 4;
    const size_t wrow0 = (size_t)(wv * 32 + col) * KP1;
    const size_t wrow1 = (size_t)(wv * 32 + 16 + col) * KP1;
    short8v nb0 = *(const short8v*)&W1p[wrow0 + g * 8];
    short8v nb1 = *(const short8v*)&W1p[wrow1 + g * 8];
    __syncthreads();

    f32x4 acc[4][2];
    {
        float bv0 = bm1[wv * 32 + col];
        float bv1 = bm1[wv * 32 + 16 + col];
        #pragma unroll
        for (int rt = 0; rt < 4; ++rt) {
            acc[rt][0] = (f32x4){bv0, bv0, bv0, bv0};
            acc[rt][1] = (f32x4){bv1, bv1, bv1, bv1};
        }
    }
    #pragma unroll
    for (int c = 0; c < NCH1; ++c) {
        short8v b0 = nb0, b1 = nb1;
        if (c + 1 < NCH1) {
            nb0 = *(const short8v*)&W1p[wrow0 + (c + 1) * 32 + g * 8];
            nb1 = *(const short8v*)&W1p[wrow1 + (c + 1) * 32 + g * 8];
        }
        short8v a[4];
        #pragma unroll
        for (int rt = 0; rt < 4; ++rt) {
            const int row = rt * 16 + col;
            if (c < 8) {
                const int sP = (((c & 1) << 2) + g) ^ (row & 7);
                a[rt] = *(const short8v*)&lds[((c >> 1) * EB + row) * 64 + sP * 8];
            } else {
                const int sP = g ^ (row & 3);
                a[rt] = *(const short8v*)&lds[CH8 + row * 32 + sP * 8];
            }
        }
        #pragma unroll
        for (int rt = 0; rt < 4; ++rt) {
            acc[rt][0] = __builtin_amdgcn_mfma_f32_16x16x32_bf16(a[rt], b0, acc[rt][0], 0, 0, 0);
            acc[rt][1] = __builtin_amdgcn_mfma_f32_16x16x32_bf16(a[rt], b1, acc[rt][1], 0, 0, 0);
        }
    }
    __syncthreads();

    const int ph = wv >> 1;
    #pragma unroll
    for (int rt = 0; rt < 4; ++rt)
        #pragma unroll
        for (int j = 0; j < 2; ++j)
            #pragma unroll
            for (int r = 0; r < 4; ++r) {
                const int row = rt * 16 + g * 4 + r;
                float v = fmaxf(acc[rt][j][r], 0.f);
                unsigned int pk2 = cvt_pk_bf16(v, v);
                const int sH = (((wv & 1) << 2) + j * 2 + (col >> 3)) ^ (row & 7);
                lds[(ph * EB + row) * 64 + sH * 8 + (col & 7)] = (ushort_t)pk2;
            }
    __syncthreads();

    const size_t w2r0 = (size_t)(wv * 32 + col) * HD;
    const size_t w2r1 = (size_t)(wv * 32 + 16 + col) * HD;
    short8v m0 = *(const short8v*)&W2p[w2r0 + g * 8];
    short8v m1 = *(const short8v*)&W2p[w2r1 + g * 8];
    f32x4 acc2[4][2];
    {
        float bv0 = bm2[wv * 32 + col];
        float bv1 = bm2[wv * 32 + 16 + col];
        #pragma unroll
        for (int rt = 0; rt < 4; ++rt) {
            acc2[rt][0] = (f32x4){bv0, bv0, bv0, bv0};
            acc2[rt][1] = (f32x4){bv1, bv1, bv1, bv1};
        }
    }
    #pragma unroll
    for (int c = 0; c < NCH2; ++c) {
        short8v b0 = m0, b1 = m1;
        if (c + 1 < NCH2) {
            m0 = *(const short8v*)&W2p[w2r0 + (c + 1) * 32 + g * 8];
            m1 = *(const short8v*)&W2p[w2r1 + (c + 1) * 32 + g * 8];
        }
        short8v a[4];
        #pragma unroll
        for (int rt = 0; rt < 4; ++rt) {
            const int row = rt * 16 + col;
            const int sP = (((c & 1) << 2) + g) ^ (row & 7);
            a[rt] = *(const short8v*)&lds[((c >> 1) * EB + row) * 64 + sP * 8];
        }
        #pragma unroll
        for (int rt = 0; rt < 4; ++rt) {
            acc2[rt][0] = __builtin_amdgcn_mfma_f32_16x16x32_bf16(a[rt], b0, acc2[rt][0], 0, 0, 0);
            acc2[rt][1] = __builtin_amdgcn_mfma_f32_16x16x32_bf16(a[rt], b1, acc2[rt][1], 0, 0, 0);
        }
    }

    const bool even = (col & 1) == 0;
    #pragma unroll
    for (int rt = 0; rt < 4; ++rt)
        #pragma unroll
        for (int r = 0; r < 4; ++r) {
            const int e  = rt * 16 + g * 4 + r;
            const int ge = e0 + e;
            const int dg = s_dst[e];
            #pragma unroll
            for (int j = 0; j < 2; ++j) {
                float v  = acc2[rt][j][r];
                float vn = __shfl_xor(v, 1, 64);
                if (even && ge < E) {
                    unsigned int pk2 = cvt_pk_bf16(v, vn);
                    ushort_t* p = msum + (size_t)dg * D + wv * 32 + j * 16 + col;
                    asm volatile("global_atomic_pk_add_bf16 %0, %1, off"
                                 :: "v"(p), "v"(pk2) : "memory");
                }
            }
        }
}

extern "C" void kernel_launch(void* const* d_in, const int* in_sizes, int n_in,
                              void* d_out, int out_size, void* d_ws, size_t ws_size,
                              hipStream_t stream) {
    const float* f   = (const float*)d_in[0];
    const float* x   = (const float*)d_in[1];
    const float* w   = (const float*)d_in[2];
    const int*   src = (const int*)d_in[3];
    const int*   dst = (const int*)d_in[4];
    const float* Wm1 = (const float*)d_in[5];
    const float* bm1 = (const float*)d_in[6];
    const float* Wm2 = (const float*)d_in[7];
    const float* bm2 = (const float*)d_in[8];
    const float* Wu1 = (const float*)d_in[9];
    const float* bu1 = (const float*)d_in[10];
    const float* Wu2 = (const float*)d_in[11];
    const float* bu2 = (const float*)d_in[12];

    const int Nn = in_sizes[0] / D;
    const int E  = in_sizes[3];

    const size_t wbytes = (size_t)(128 * KP1 + HD * D) * sizeof(ushort_t);
    auto align512 = [](size_t v) { return (v + 511) & ~(size_t)511; };

    const size_t fb_bytes = (size_t)Nn * D * 2;
    char* wsb = (char*)d_ws;

    // ---------------- primary: fused-reduce CSR layout ----------------
    size_t off = 0;
    const size_t o_w    = off; off = align512(off + wbytes);
    const size_t o_fb   = off; off = align512(off + fb_bytes);
    const size_t o_cnt  = off; off = align512(off + (size_t)Nn * 4);
    const size_t o_roff = off; off = align512(off + (size_t)Nn * 4);
    const size_t o_cur  = off; off = align512(off + (size_t)Nn * 4);
    const size_t o_perm = off; off = align512(off + (size_t)E * 4);
    const size_t o_sdst = off; off = align512(off + (size_t)E * 4);
    const size_t o_ms   = off; off = align512(off + (size_t)Nn * D * 4);
    const size_t primary_total = off;

    if (ws_size >= primary_total) {
        ushort_t* W1p = (ushort_t*)(wsb + o_w);
        ushort_t* W2p = W1p + 128 * KP1;
        ushort_t* fbf = (ushort_t*)(wsb + o_fb);
        int* cnt      = (int*)(wsb + o_cnt);
        int* roff     = (int*)(wsb + o_roff);
        int* cursor   = (int*)(wsb + o_cur);
        int* perm     = (int*)(wsb + o_perm);
        int* sdst     = (int*)(wsb + o_sdst);
        float* msum   = (float*)(wsb + o_ms);

        const int n8 = Nn * D / 8;
        const int ntiles = (E + EB - 1) / EB;
        const int half1 = ntiles / 2;
        const int half2 = ntiles - half1;
        hipMemsetAsync(cnt, 0, (size_t)Nn * 4, stream);
        fused_pre_kernel<<<dim3(1024), dim3(256), 0, stream>>>(
            Wm1, Wm2, W1p, W2p, f, fbf, dst, cnt, n8, E);
        scan_kernel<<<dim3(1), dim3(1024), 0, stream>>>(cnt, roff, cursor, Nn);
        scatter_kernel<<<dim3((E + 255) / 256), dim3(256), 0, stream>>>(
            dst, cursor, roff, cnt, perm, sdst, msum, E, Nn);
        edge_mfma_fused_kernel<<<dim3(half1), dim3(NT), 0, stream>>>(
            fbf, x, w, src, perm, sdst, W1p, bm1, W2p, bm2, msum, E, 0);
        edge_mfma_fused_kernel<<<dim3(half2), dim3(NT), 0, stream>>>(
            fbf, x, w, src, perm, sdst, W1p, bm1, W2p, bm2, msum, E, half1);
        node_kernel<false><<<dim3((Nn + NB - 1) / NB), dim3(NT), 0, stream>>>(
            f, msum, Wu1, bu1, Wu2, bu2, (float*)d_out, Nn);
        return;
    }

    // ---------------- fallback: pk-atomic path ----------------
    size_t off2 = 0;
    const size_t p_w  = off2; off2 = align512(off2 + wbytes);
    const size_t p_fb = off2; off2 = align512(off2 + fb_bytes);
    const size_t p_ms = off2; off2 = align512(off2 + (size_t)Nn * D * 2);
    if (ws_size >= off2) {
        ushort_t* W1p  = (ushort_t*)(wsb + p_w);
        ushort_t* W2p  = W1p + 128 * KP1;
        ushort_t* fbf  = (ushort_t*)(wsb + p_fb);
        ushort_t* msum = (ushort_t*)(wsb + p_ms);
        const int rp_elems = 128 * KP1 + HD * D;
        hipMemsetAsync(msum, 0, (size_t)Nn * D * 2, stream);
        repack_kernel<<<dim3((rp_elems + 255) / 256), dim3(256), 0, stream>>>(Wm1, Wm2, W1p, W2p);
        const int n8 = Nn * D / 8;
        fconv_kernel<<<dim3((n8 + 255) / 256), dim3(256), 0, stream>>>(f, fbf, n8);
        edge_mfma_kernel<<<dim3((E + EB - 1) / EB), dim3(NT), 0, stream>>>(
            fbf, x, w, src, dst, W1p, bm1, W2p, bm2, msum, E);
        node_kernel<true><<<dim3((Nn + NB - 1) / NB), dim3(NT), 0, stream>>>(
            f, msum, Wu1, bu1, Wu2, bu2, (float*)d_out, Nn);
        return;
    }
}

// Round 15
// 321.192 us; speedup vs baseline: 1.2968x; 1.2765x over previous
//
#include <hip/hip_runtime.h>

#define D 128
#define HD 128
#define DE 16
#define MSG_IN 273
#define EB 64        // edges per tile
#define NT 256
#define KP1 288      // padded msg K = 9 chunks of 32
#define NCH1 9
#define NCH2 4
#define NB 32
#define HID_PAD 132
#define CH8 (4 * EB * 64)   // ushort offset of chunk-8 region in lds[]
#define LDS1 (4 * EB * 64 + EB * 32)

typedef __attribute__((ext_vector_type(8))) short short8v;
typedef __attribute__((ext_vector_type(4))) float f32x4;
typedef unsigned short ushort_t;

#define GLOAD_LDS16(gp, lp) \
    __builtin_amdgcn_global_load_lds((const __attribute__((address_space(1))) unsigned int*)(gp), \
                                     (__attribute__((address_space(3))) unsigned int*)(lp), 16, 0, 0)

__device__ __forceinline__ unsigned short f2bf(float v) {
    unsigned int u = __builtin_bit_cast(unsigned int, v);
    u += 0x7fffu + ((u >> 16) & 1u);
    return (unsigned short)(u >> 16);
}
__device__ __forceinline__ float bf2f(ushort_t u) {
    return __builtin_bit_cast(float, (unsigned int)u << 16);
}
__device__ __forceinline__ unsigned int cvt_pk_bf16(float lo, float hi) {
    unsigned int r;
    asm("v_cvt_pk_bf16_f32 %0, %1, %2" : "=v"(r) : "v"(lo), "v"(hi));
    return r;
}

// ---------------- fused prepass: weight repack (msg + node MLP) + f->bf16 + dst hist ----------------
__global__ void fused_pre_kernel(const float* __restrict__ Wm1, const float* __restrict__ Wm2,
                                 const float* __restrict__ Wu1, const float* __restrict__ Wu2,
                                 ushort_t* __restrict__ W1p, ushort_t* __restrict__ W2p,
                                 ushort_t* __restrict__ Wu1p, ushort_t* __restrict__ Wu2p,
                                 const float* __restrict__ f, ushort_t* __restrict__ fb,
                                 const int* __restrict__ dst, int* __restrict__ cnt,
                                 int n8, int E) {
    const int gid    = blockIdx.x * 256 + threadIdx.x;
    const int stride = gridDim.x * 256;
    const int rp1 = 128 * KP1;
    const int rp2 = rp1 + HD * D;
    const int rp_elems = rp2 + 2 * HD * D;   // + Wu1, Wu2
    for (int i = gid; i < rp_elems; i += stride) {
        if (i < rp1) {
            int n = i / KP1, k = i % KP1;
            W1p[i] = f2bf((k < MSG_IN) ? Wm1[(size_t)k * HD + n] : 0.f);
        } else if (i < rp2) {
            int i2 = i - rp1;
            int n = i2 / HD, k = i2 % HD;
            W2p[i2] = f2bf(Wm2[(size_t)k * D + n]);
        } else {
            int i2 = (i - rp2);
            const bool second = i2 >= HD * D;
            if (second) i2 -= HD * D;
            int n = i2 / HD, k = i2 % HD;
            if (second) Wu2p[i2] = f2bf(Wu2[(size_t)k * D + n]);
            else        Wu1p[i2] = f2bf(Wu1[(size_t)k * HD + n]);
        }
    }
    for (int i = gid; i < n8; i += stride) {
        float4 v0 = *(const float4*)(f + (size_t)i * 8);
        float4 v1 = *(const float4*)(f + (size_t)i * 8 + 4);
        union { ushort_t us[8]; short8v v; } pk;
        pk.us[0] = f2bf(v0.x); pk.us[1] = f2bf(v0.y);
        pk.us[2] = f2bf(v0.z); pk.us[3] = f2bf(v0.w);
        pk.us[4] = f2bf(v1.x); pk.us[5] = f2bf(v1.y);
        pk.us[6] = f2bf(v1.z); pk.us[7] = f2bf(v1.w);
        *(short8v*)(fb + (size_t)i * 8) = pk.v;
    }
    for (int i = gid; i < E; i += stride) atomicAdd(&cnt[dst[i]], 1);
}

// ---------------- CSR build: parallel scan (4 elems/thread) -> scatter + selective zero ----------------
__global__ __launch_bounds__(1024) void scan_kernel(const int* __restrict__ cnt,
                                                    int* __restrict__ roff,
                                                    int* __restrict__ cursor, int Nn) {
    __shared__ int wsum[16];
    const int t = threadIdx.x, l = t & 63, wid = t >> 6;
    int running = 0;
    for (int base = 0; base < Nn; base += 4096) {
        const int i0 = base + t * 4;
        int v0 = 0, v1 = 0, v2 = 0, v3 = 0;
        if (i0 + 3 < Nn) {
            int4 v = *(const int4*)(cnt + i0);
            v0 = v.x; v1 = v.y; v2 = v.z; v3 = v.w;
        } else {
            if (i0 + 0 < Nn) v0 = cnt[i0 + 0];
            if (i0 + 1 < Nn) v1 = cnt[i0 + 1];
            if (i0 + 2 < Nn) v2 = cnt[i0 + 2];
        }
        const int vsum = v0 + v1 + v2 + v3;
        int s = vsum;
        #pragma unroll
        for (int off = 1; off < 64; off <<= 1) {
            int u = __shfl_up(s, off, 64);
            if (l >= off) s += u;
        }
        if (l == 63) wsum[wid] = s;
        __syncthreads();
        if (wid == 0 && l < 16) {
            int xv = wsum[l];
            #pragma unroll
            for (int off = 1; off < 16; off <<= 1) {
                int u = __shfl_up(xv, off, 64);
                if (l >= off) xv += u;
            }
            wsum[l] = xv;
        }
        __syncthreads();
        const int prev  = (wid > 0) ? wsum[wid - 1] : 0;
        const int total = wsum[15];
        int ex = running + prev + (s - vsum);
        if (i0 + 0 < Nn) { roff[i0 + 0] = ex; cursor[i0 + 0] = ex; } ex += v0;
        if (i0 + 1 < Nn) { roff[i0 + 1] = ex; cursor[i0 + 1] = ex; } ex += v1;
        if (i0 + 2 < Nn) { roff[i0 + 2] = ex; cursor[i0 + 2] = ex; } ex += v2;
        if (i0 + 3 < Nn) { roff[i0 + 3] = ex; cursor[i0 + 3] = ex; }
        running += total;
        __syncthreads();
    }
}

// scatter + zero msum rows that will be atomically accumulated (or never written)
__global__ void scatter_kernel(const int* __restrict__ dst, int* cursor,
                               const int* __restrict__ roff, const int* __restrict__ cnt,
                               int* __restrict__ perm, int* __restrict__ sdst,
                               float* __restrict__ msum, int E, int Nn) {
    const int gid    = blockIdx.x * 256 + threadIdx.x;
    const int stride = gridDim.x * 256;
    for (int i = gid; i < E; i += stride) {
        int d = dst[i];
        int s = atomicAdd(&cursor[d], 1);
        perm[s] = i;
        sdst[s] = d;
    }
    for (int n = gid; n < Nn; n += stride) {
        const int c = cnt[n];
        const int r = roff[n];
        const bool need0 = (c == 0) || (r / EB != (r + c - 1) / EB);
        if (need0) {
            float4 z = {0.f, 0.f, 0.f, 0.f};
            float* p = msum + (size_t)n * D;
            #pragma unroll
            for (int k = 0; k < 32; ++k) *(float4*)(p + k * 4) = z;
        }
    }
}

// ---------------- edge kernel: fused in-register segment reduce ----------------
__global__ __launch_bounds__(NT, 4) void edge_mfma_fused_kernel(
    const ushort_t* __restrict__ fbf, const float* __restrict__ x,
    const float* __restrict__ w, const int* __restrict__ src,
    const int* __restrict__ perm, const int* __restrict__ sdst,
    const ushort_t* __restrict__ W1p, const float* __restrict__ bm1,
    const ushort_t* __restrict__ W2p, const float* __restrict__ bm2,
    float* __restrict__ msum, int E, int tile_base)
{
    __shared__ __align__(16) ushort_t lds[LDS1];   // 36,864 B

    const int t    = threadIdx.x;
    const int lane = t & 63;
    const int wv   = t >> 6;
    const int e0   = (tile_base + blockIdx.x) * EB;

    const int myd  = (e0 + lane < E) ? sdst[e0 + lane] : -1;
    const int prevd = (e0 > 0) ? sdst[e0 - 1] : -2;
    const int nextd = (e0 + EB < E) ? sdst[e0 + EB] : -2;

    // ---- f staging: 8 x global_load_lds_dwordx4, pre-swizzled global source ----
    {
        const int el8 = lane >> 3;
        const int s   = lane & 7;
        const int sl  = s ^ el8;            // involution swizzle
        const int slA = min(e0 + wv * 16 + el8,     E - 1);
        const int slB = min(e0 + wv * 16 + 8 + el8, E - 1);
        const int geA = perm[slA], geB = perm[slB];
        const int nsA = src[geA], ndA = sdst[slA];
        const int nsB = src[geB], ndB = sdst[slB];
        #pragma unroll
        for (int p = 0; p < 4; ++p) {
            const int n0 = (p < 2) ? nsA : ndA;
            const int n1 = (p < 2) ? nsB : ndB;
            const ushort_t* g0 = fbf + (size_t)n0 * D + (p & 1) * 64 + sl * 8;
            const ushort_t* g1 = fbf + (size_t)n1 * D + (p & 1) * 64 + sl * 8;
            GLOAD_LDS16(g0, &lds[(p * EB + wv * 16    ) * 64]);
            GLOAD_LDS16(g1, &lds[(p * EB + wv * 16 + 8) * 64]);
        }
    }
    // ---- chunk 8: w feats (k0..15), sqd (k16), zeros; 2-bit swizzle ----
    {
        const int el = lane >> 2, q = lane & 3;
        const int qp = q ^ (el & 3);
        const int slot = e0 + wv * 16 + el;
        const bool ok = slot < E;
        const int sc = min(slot, E - 1);
        const int ge = perm[sc];
        union { ushort_t us[8]; short8v v; } pk;
        #pragma unroll
        for (int j = 0; j < 8; ++j) pk.us[j] = 0;
        if (ok) {
            if (q < 2) {
                float4 w0 = *(const float4*)(w + (size_t)ge * DE + q * 8);
                float4 w1 = *(const float4*)(w + (size_t)ge * DE + q * 8 + 4);
                pk.us[0] = f2bf(w0.x); pk.us[1] = f2bf(w0.y);
                pk.us[2] = f2bf(w0.z); pk.us[3] = f2bf(w0.w);
                pk.us[4] = f2bf(w1.x); pk.us[5] = f2bf(w1.y);
                pk.us[6] = f2bf(w1.z); pk.us[7] = f2bf(w1.w);
            } else if (q == 2) {
                const int ns = src[ge], nd = sdst[sc];
                float dx = x[ns*3+0] - x[nd*3+0];
                float dy = x[ns*3+1] - x[nd*3+1];
                float dz = x[ns*3+2] - x[nd*3+2];
                pk.us[0] = f2bf(dx*dx + dy*dy + dz*dz);
            }
        }
        *(short8v*)&lds[CH8 + (wv * 16 + el) * 32 + qp * 8] = pk.v;
    }

    const int col = lane & 15;
    const int g   = lane >> 4;

    const size_t wrow0 = (size_t)(wv * 32 + col) * KP1;
    const size_t wrow1 = (size_t)(wv * 32 + 16 + col) * KP1;
    short8v nb0 = *(const short8v*)&W1p[wrow0 + g * 8];
    short8v nb1 = *(const short8v*)&W1p[wrow1 + g * 8];

    __syncthreads();   // B0: staging complete

    // ---- layer 1: [64,288] x [288,32] per wave ----
    f32x4 acc[4][2];
    {
        float bv0 = bm1[wv * 32 + col];
        float bv1 = bm1[wv * 32 + 16 + col];
        #pragma unroll
        for (int rt = 0; rt < 4; ++rt) {
            acc[rt][0] = (f32x4){bv0, bv0, bv0, bv0};
            acc[rt][1] = (f32x4){bv1, bv1, bv1, bv1};
        }
    }
    #pragma unroll
    for (int c = 0; c < NCH1; ++c) {
        short8v b0 = nb0, b1 = nb1;
        if (c + 1 < NCH1) {
            nb0 = *(const short8v*)&W1p[wrow0 + (c + 1) * 32 + g * 8];
            nb1 = *(const short8v*)&W1p[wrow1 + (c + 1) * 32 + g * 8];
        }
        short8v a[4];
        #pragma unroll
        for (int rt = 0; rt < 4; ++rt) {
            const int row = rt * 16 + col;
            if (c < 8) {
                const int sP = (((c & 1) << 2) + g) ^ (row & 7);
                a[rt] = *(const short8v*)&lds[((c >> 1) * EB + row) * 64 + sP * 8];
            } else {
                const int sP = g ^ (row & 3);
                a[rt] = *(const short8v*)&lds[CH8 + row * 32 + sP * 8];
            }
        }
        #pragma unroll
        for (int rt = 0; rt < 4; ++rt) {
            acc[rt][0] = __builtin_amdgcn_mfma_f32_16x16x32_bf16(a[rt], b0, acc[rt][0], 0, 0, 0);
            acc[rt][1] = __builtin_amdgcn_mfma_f32_16x16x32_bf16(a[rt], b1, acc[rt][1], 0, 0, 0);
        }
    }
    __syncthreads();   // B1

    // hid (relu, bf16) -> pairs 0-1 region, same swizzle; all-lane b16 stores
    const int ph = wv >> 1;
    #pragma unroll
    for (int rt = 0; rt < 4; ++rt)
        #pragma unroll
        for (int j = 0; j < 2; ++j)
            #pragma unroll
            for (int r = 0; r < 4; ++r) {
                const int row = rt * 16 + g * 4 + r;
                float v = fmaxf(acc[rt][j][r], 0.f);
                unsigned int pk2 = cvt_pk_bf16(v, v);
                const int sH = (((wv & 1) << 2) + j * 2 + (col >> 3)) ^ (row & 7);
                lds[(ph * EB + row) * 64 + sH * 8 + (col & 7)] = (ushort_t)pk2;
            }
    __syncthreads();   // B2

    // ---- layer 2: [64,128] x [128,32] per wave ----
    const size_t w2r0 = (size_t)(wv * 32 + col) * HD;
    const size_t w2r1 = (size_t)(wv * 32 + 16 + col) * HD;
    short8v m0 = *(const short8v*)&W2p[w2r0 + g * 8];
    short8v m1 = *(const short8v*)&W2p[w2r1 + g * 8];
    f32x4 acc2[4][2];
    {
        float bv0 = bm2[wv * 32 + col];
        float bv1 = bm2[wv * 32 + 16 + col];
        #pragma unroll
        for (int rt = 0; rt < 4; ++rt) {
            acc2[rt][0] = (f32x4){bv0, bv0, bv0, bv0};
            acc2[rt][1] = (f32x4){bv1, bv1, bv1, bv1};
        }
    }
    #pragma unroll
    for (int c = 0; c < NCH2; ++c) {
        short8v b0 = m0, b1 = m1;
        if (c + 1 < NCH2) {
            m0 = *(const short8v*)&W2p[w2r0 + (c + 1) * 32 + g * 8];
            m1 = *(const short8v*)&W2p[w2r1 + (c + 1) * 32 + g * 8];
        }
        short8v a[4];
        #pragma unroll
        for (int rt = 0; rt < 4; ++rt) {
            const int row = rt * 16 + col;
            const int sP = (((c & 1) << 2) + g) ^ (row & 7);
            a[rt] = *(const short8v*)&lds[((c >> 1) * EB + row) * 64 + sP * 8];
        }
        #pragma unroll
        for (int rt = 0; rt < 4; ++rt) {
            acc2[rt][0] = __builtin_amdgcn_mfma_f32_16x16x32_bf16(a[rt], b0, acc2[rt][0], 0, 0, 0);
            acc2[rt][1] = __builtin_amdgcn_mfma_f32_16x16x32_bf16(a[rt], b1, acc2[rt][1], 0, 0, 0);
        }
    }

    // ---- wave-local segment reduce -> msum (f32); ballot-derived run metadata ----
    float qs[4][2];
    #pragma unroll
    for (int rt = 0; rt < 4; ++rt) {
        qs[rt][0] = (acc2[rt][0][0] + acc2[rt][0][1]) + (acc2[rt][0][2] + acc2[rt][0][3]);
        qs[rt][1] = (acc2[rt][1][0] + acc2[rt][1][1]) + (acc2[rt][1][2] + acc2[rt][1][3]);
    }
    const int nvalid = min(EB, E - e0);
    const int dprev_l = __shfl_up(myd, 1, 64);
    const bool head = (lane == 0) || (myd != dprev_l);
    unsigned long long rem = __ballot(head && (lane < nvalid));
    while (rem) {
        const int beg = (int)__builtin_ctzll(rem);
        rem &= rem - 1;
        const int end = rem ? (int)__builtin_ctzll(rem) : nvalid;
        const int dg  = __shfl(myd, beg, 64);

        float s0 = 0.f, s1 = 0.f;
        #pragma unroll
        for (int rt = 0; rt < 4; ++rt) {
            const int qb = rt * 16 + g * 4;
            const int lo = max(qb, beg);
            const int hi = min(qb + 4, end);
            if (lo < hi) {
                if (lo == qb && hi == qb + 4) {
                    s0 += qs[rt][0]; s1 += qs[rt][1];
                } else {
                    #pragma unroll
                    for (int r = 0; r < 4; ++r) {
                        const int sl = qb + r;
                        if (sl >= beg && sl < end) {
                            s0 += acc2[rt][0][r]; s1 += acc2[rt][1][r];
                        }
                    }
                }
            }
        }
        s0 += __shfl_xor(s0, 16, 64); s0 += __shfl_xor(s0, 32, 64);
        s1 += __shfl_xor(s1, 16, 64); s1 += __shfl_xor(s1, 32, 64);
        if (g == 0) {
            const bool bnd = (beg == 0 && dg == prevd) || (end == nvalid && dg == nextd);
            float* p = msum + (size_t)dg * D + wv * 32 + col;
            if (bnd) { atomicAdd(p, s0); atomicAdd(p + 16, s1); }
            else     { p[0] = s0; p[16] = s1; }
        }
    }
}

// ---------------- node kernel v15: MFMA bf16 update MLP ----------------
// 64 nodes/block, 4 waves; each wave computes all 64 rows x 32 output cols.
// LDS: [pair 0-1][64 rows][64 k] bf16 with granule swizzle; hid aliases after B1.
__global__ __launch_bounds__(NT, 4) void node_mfma_kernel(
    const float* __restrict__ f, const float* __restrict__ msum,
    const ushort_t* __restrict__ Wu1p, const float* __restrict__ bu1,
    const ushort_t* __restrict__ Wu2p, const float* __restrict__ bu2,
    float* __restrict__ out, int Nn)
{
    __shared__ __align__(16) ushort_t lds[2 * 64 * 64];   // 16,384 B

    const int t    = threadIdx.x;
    const int lane = t & 63;
    const int wv   = t >> 6;
    const int col  = lane & 15;
    const int g    = lane >> 4;
    const int n0   = blockIdx.x * 64;

    // ---- stage hin = bf16(msum + f): 1024 granules of 8 bf16 ----
    #pragma unroll
    for (int it = 0; it < 4; ++it) {
        const int gidx = it * 256 + t;
        const int row  = gidx >> 4;         // 0..63
        const int gr   = gidx & 15;         // granule within row (16 x 8 cols)
        const int pair = gr >> 3, s = gr & 7;
        const int sP   = s ^ (row & 7);
        const int gn   = n0 + row;
        union { ushort_t us[8]; short8v v; } pk;
        if (gn < Nn) {
            const size_t off = (size_t)gn * D + gr * 8;
            float4 m0 = *(const float4*)(msum + off);
            float4 m1 = *(const float4*)(msum + off + 4);
            float4 f0 = *(const float4*)(f + off);
            float4 f1 = *(const float4*)(f + off + 4);
            pk.us[0] = f2bf(m0.x + f0.x); pk.us[1] = f2bf(m0.y + f0.y);
            pk.us[2] = f2bf(m0.z + f0.z); pk.us[3] = f2bf(m0.w + f0.w);
            pk.us[4] = f2bf(m1.x + f1.x); pk.us[5] = f2bf(m1.y + f1.y);
            pk.us[6] = f2bf(m1.z + f1.z); pk.us[7] = f2bf(m1.w + f1.w);
        } else {
            #pragma unroll
            for (int j = 0; j < 8; ++j) pk.us[j] = 0;
        }
        *(short8v*)&lds[(pair * 64 + row) * 64 + sP * 8] = pk.v;
    }

    const size_t wrow0 = (size_t)(wv * 32 + col) * HD;
    const size_t wrow1 = (size_t)(wv * 32 + 16 + col) * HD;
    short8v nb0 = *(const short8v*)&Wu1p[wrow0 + g * 8];
    short8v nb1 = *(const short8v*)&Wu1p[wrow1 + g * 8];

    __syncthreads();   // B0: hin staged

    // ---- layer 1: [64,128] x [128,32] per wave ----
    f32x4 acc[4][2];
    {
        float bv0 = bu1[wv * 32 + col];
        float bv1 = bu1[wv * 32 + 16 + col];
        #pragma unroll
        for (int rt = 0; rt < 4; ++rt) {
            acc[rt][0] = (f32x4){bv0, bv0, bv0, bv0};
            acc[rt][1] = (f32x4){bv1, bv1, bv1, bv1};
        }
    }
    #pragma unroll
    for (int c = 0; c < 4; ++c) {
        short8v b0 = nb0, b1 = nb1;
        if (c + 1 < 4) {
            nb0 = *(const short8v*)&Wu1p[wrow0 + (c + 1) * 32 + g * 8];
            nb1 = *(const short8v*)&Wu1p[wrow1 + (c + 1) * 32 + g * 8];
        }
        short8v a[4];
        #pragma unroll
        for (int rt = 0; rt < 4; ++rt) {
            const int row = rt * 16 + col;
            const int sP = (((c & 1) << 2) + g) ^ (row & 7);
            a[rt] = *(const short8v*)&lds[((c >> 1) * 64 + row) * 64 + sP * 8];
        }
        #pragma unroll
        for (int rt = 0; rt < 4; ++rt) {
            acc[rt][0] = __builtin_amdgcn_mfma_f32_16x16x32_bf16(a[rt], b0, acc[rt][0], 0, 0, 0);
            acc[rt][1] = __builtin_amdgcn_mfma_f32_16x16x32_bf16(a[rt], b1, acc[rt][1], 0, 0, 0);
        }
    }
    __syncthreads();   // B1: layer-1 reads done -> region reusable

    // hid (relu, bf16) -> same region, same swizzle; all-lane b16 stores
    const int ph = wv >> 1;
    #pragma unroll
    for (int rt = 0; rt < 4; ++rt)
        #pragma unroll
        for (int j = 0; j < 2; ++j)
            #pragma unroll
            for (int r = 0; r < 4; ++r) {
                const int row = rt * 16 + g * 4 + r;
                float v = fmaxf(acc[rt][j][r], 0.f);
                unsigned int pk2 = cvt_pk_bf16(v, v);
                const int sH = (((wv & 1) << 2) + j * 2 + (col >> 3)) ^ (row & 7);
                lds[(ph * 64 + row) * 64 + sH * 8 + (col & 7)] = (ushort_t)pk2;
            }
    __syncthreads();   // B2

    // ---- layer 2: [64,128] x [128,32] per wave ----
    const size_t w2r0 = (size_t)(wv * 32 + col) * HD;
    const size_t w2r1 = (size_t)(wv * 32 + 16 + col) * HD;
    short8v m0 = *(const short8v*)&Wu2p[w2r0 + g * 8];
    short8v m1 = *(const short8v*)&Wu2p[w2r1 + g * 8];
    f32x4 acc2[4][2];
    {
        float bv0 = bu2[wv * 32 + col];
        float bv1 = bu2[wv * 32 + 16 + col];
        #pragma unroll
        for (int rt = 0; rt < 4; ++rt) {
            acc2[rt][0] = (f32x4){bv0, bv0, bv0, bv0};
            acc2[rt][1] = (f32x4){bv1, bv1, bv1, bv1};
        }
    }
    #pragma unroll
    for (int c = 0; c < 4; ++c) {
        short8v b0 = m0, b1 = m1;
        if (c + 1 < 4) {
            m0 = *(const short8v*)&Wu2p[w2r0 + (c + 1) * 32 + g * 8];
            m1 = *(const short8v*)&Wu2p[w2r1 + (c + 1) * 32 + g * 8];
        }
        short8v a[4];
        #pragma unroll
        for (int rt = 0; rt < 4; ++rt) {
            const int row = rt * 16 + col;
            const int sP = (((c & 1) << 2) + g) ^ (row & 7);
            a[rt] = *(const short8v*)&lds[((c >> 1) * 64 + row) * 64 + sP * 8];
        }
        #pragma unroll
        for (int rt = 0; rt < 4; ++rt) {
            acc2[rt][0] = __builtin_amdgcn_mfma_f32_16x16x32_bf16(a[rt], b0, acc2[rt][0], 0, 0, 0);
            acc2[rt][1] = __builtin_amdgcn_mfma_f32_16x16x32_bf16(a[rt], b1, acc2[rt][1], 0, 0, 0);
        }
    }

    // ---- write out (fp32) ----
    #pragma unroll
    for (int rt = 0; rt < 4; ++rt)
        #pragma unroll
        for (int r = 0; r < 4; ++r) {
            const int row = rt * 16 + g * 4 + r;
            const int gn = n0 + row;
            if (gn < Nn) {
                out[(size_t)gn * D + wv * 32 + col]      = acc2[rt][0][r];
                out[(size_t)gn * D + wv * 32 + 16 + col] = acc2[rt][1][r];
            }
        }
}

// ---------------- fallback node kernel (fp32 MLP, templated msum dtype) ----------------
template<bool MB16>
__global__ __launch_bounds__(NT, 4) void node_kernel(
    const float* __restrict__ f, const void* __restrict__ msum_v,
    const float* __restrict__ Wu1, const float* __restrict__ bu1,
    const float* __restrict__ Wu2, const float* __restrict__ bu2,
    float* out, int Nn)
{
    __shared__ __align__(16) float hin[NB][HID_PAD];
    __shared__ __align__(16) float hid[NB][HID_PAD];
    const int t  = threadIdx.x;
    const int n0 = blockIdx.x * NB;
    const int nn = min(NB, Nn - n0);

    {
        #pragma unroll
        for (int it = 0; it < 4; ++it) {
            const int idx = it * 1024 + t * 4;
            const int e   = idx >> 7;
            const int cb  = idx & 127;
            if (e < nn) {
                const size_t off = (size_t)(n0 + e) * D + cb;
                float4 mv;
                if (MB16) {
                    uint2 pk = *(const uint2*)((const ushort_t*)msum_v + off);
                    mv.x = bf2f((ushort_t)(pk.x & 0xffffu));
                    mv.y = bf2f((ushort_t)(pk.x >> 16));
                    mv.z = bf2f((ushort_t)(pk.y & 0xffffu));
                    mv.w = bf2f((ushort_t)(pk.y >> 16));
                } else {
                    mv = *(const float4*)((const float*)msum_v + off);
                }
                float4 fv = *(const float4*)&f[off];
                float4 o = {mv.x + fv.x, mv.y + fv.y, mv.z + fv.z, mv.w + fv.w};
                *(float4*)&hin[e][cb] = o;
            }
        }
    }
    __syncthreads();

    const int tc = t & 15, te2 = (t >> 4) * 2, c0 = tc * 8;
    float a1[2][8];
    #pragma unroll
    for (int c = 0; c < 8; ++c) { float bv = bu1[c0 + c]; a1[0][c] = bv; a1[1][c] = bv; }
    for (int i = 0; i < D; i += 4) {
        float m0[4], m1[4];
        *(float4*)m0 = *(const float4*)&hin[te2][i];
        *(float4*)m1 = *(const float4*)&hin[te2 + 1][i];
        #pragma unroll
        for (int r = 0; r < 4; ++r) {
            float wr[8];
            *(float4*)&wr[0] = *(const float4*)(Wu1 + (size_t)(i + r) * HD + c0);
            *(float4*)&wr[4] = *(const float4*)(Wu1 + (size_t)(i + r) * HD + c0 + 4);
            #pragma unroll
            for (int c = 0; c < 8; ++c) { a1[0][c] += m0[r]*wr[c]; a1[1][c] += m1[r]*wr[c]; }
        }
    }
    #pragma unroll
    for (int j = 0; j < 2; ++j) {
        float v[8];
        #pragma unroll
        for (int c = 0; c < 8; ++c) v[c] = fmaxf(a1[j][c], 0.f);
        *(float4*)&hid[te2 + j][c0] = *(float4*)&v[0];
        *(float4*)&hid[te2 + j][c0 + 4] = *(float4*)&v[4];
    }
    __syncthreads();
    float a2[2][8];
    #pragma unroll
    for (int c = 0; c < 8; ++c) { float bv = bu2[c0 + c]; a2[0][c] = bv; a2[1][c] = bv; }
    for (int h = 0; h < HD; h += 4) {
        float m0[4], m1[4];
        *(float4*)m0 = *(const float4*)&hid[te2][h];
        *(float4*)m1 = *(const float4*)&hid[te2 + 1][h];
        #pragma unroll
        for (int r = 0; r < 4; ++r) {
            float wr[8];
            *(float4*)&wr[0] = *(const float4*)(Wu2 + (size_t)(h + r) * D + c0);
            *(float4*)&wr[4] = *(const float4*)(Wu2 + (size_t)(h + r) * D + c0 + 4);
            #pragma unroll
            for (int c = 0; c < 8; ++c) { a2[0][c] += m0[r]*wr[c]; a2[1][c] += m1[r]*wr[c]; }
        }
    }
    #pragma unroll
    for (int j = 0; j < 2; ++j) {
        int e = te2 + j, gn = n0 + e;
        if (e < nn) {
            *(float4*)(out + (size_t)gn * D + c0) = *(float4*)&a2[j][0];
            *(float4*)(out + (size_t)gn * D + c0 + 4) = *(float4*)&a2[j][4];
        }
    }
}

// ================= fallback kernels (pk-atomic path; no CSR) =================

__global__ void repack_kernel(const float* __restrict__ Wm1, const float* __restrict__ Wm2,
                              ushort_t* __restrict__ W1p, ushort_t* __restrict__ W2p) {
    int idx = blockIdx.x * 256 + threadIdx.x;
    const int n1 = 128 * KP1;
    if (idx < n1) {
        int n = idx / KP1, k = idx % KP1;
        W1p[idx] = f2bf((k < MSG_IN) ? Wm1[(size_t)k * HD + n] : 0.f);
    } else {
        int i2 = idx - n1;
        if (i2 < HD * D) {
            int n = i2 / HD, k = i2 % HD;
            W2p[i2] = f2bf(Wm2[(size_t)k * D + n]);
        }
    }
}

__global__ void fconv_kernel(const float* __restrict__ f, ushort_t* __restrict__ fb, int n8) {
    int i = blockIdx.x * 256 + threadIdx.x;
    if (i < n8) {
        float4 v0 = *(const float4*)(f + (size_t)i * 8);
        float4 v1 = *(const float4*)(f + (size_t)i * 8 + 4);
        union { ushort_t us[8]; short8v v; } pk;
        pk.us[0] = f2bf(v0.x); pk.us[1] = f2bf(v0.y);
        pk.us[2] = f2bf(v0.z); pk.us[3] = f2bf(v0.w);
        pk.us[4] = f2bf(v1.x); pk.us[5] = f2bf(v1.y);
        pk.us[6] = f2bf(v1.z); pk.us[7] = f2bf(v1.w);
        *(short8v*)(fb + (size_t)i * 8) = pk.v;
    }
}

__global__ __launch_bounds__(NT, 4) void edge_mfma_kernel(
    const ushort_t* __restrict__ fbf, const float* __restrict__ x,
    const float* __restrict__ w, const int* __restrict__ src,
    const int* __restrict__ dst,
    const ushort_t* __restrict__ W1p, const float* __restrict__ bm1,
    const ushort_t* __restrict__ W2p, const float* __restrict__ bm2,
    ushort_t* msum, int E)
{
    __shared__ __align__(16) ushort_t lds[LDS1];
    __shared__ int s_dst[EB];

    const int t    = threadIdx.x;
    const int lane = t & 63;
    const int wv   = t >> 6;
    const int e0   = blockIdx.x * EB;

    if (t < EB) s_dst[t] = (e0 + t < E) ? dst[e0 + t] : 0;
    {
        const int el8 = lane >> 3;
        const int s   = lane & 7;
        const int sl  = s ^ el8;
        const int geA = min(e0 + wv * 16 + el8,     E - 1);
        const int geB = min(e0 + wv * 16 + 8 + el8, E - 1);
        const int nsA = src[geA], ndA = dst[geA];
        const int nsB = src[geB], ndB = dst[geB];
        #pragma unroll
        for (int p = 0; p < 4; ++p) {
            const int n0 = (p < 2) ? nsA : ndA;
            const int n1 = (p < 2) ? nsB : ndB;
            const ushort_t* g0 = fbf + (size_t)n0 * D + (p & 1) * 64 + sl * 8;
            const ushort_t* g1 = fbf + (size_t)n1 * D + (p & 1) * 64 + sl * 8;
            GLOAD_LDS16(g0, &lds[(p * EB + wv * 16    ) * 64]);
            GLOAD_LDS16(g1, &lds[(p * EB + wv * 16 + 8) * 64]);
        }
    }
    {
        const int el = lane >> 2, q = lane & 3;
        const int qp = q ^ (el & 3);
        const int ge = e0 + wv * 16 + el;
        const bool ok = ge < E;
        const int gc = min(ge, E - 1);
        union { ushort_t us[8]; short8v v; } pk;
        #pragma unroll
        for (int j = 0; j < 8; ++j) pk.us[j] = 0;
        if (ok) {
            if (q < 2) {
                float4 w0 = *(const float4*)(w + (size_t)gc * DE + q * 8);
                float4 w1 = *(const float4*)(w + (size_t)gc * DE + q * 8 + 4);
                pk.us[0] = f2bf(w0.x); pk.us[1] = f2bf(w0.y);
                pk.us[2] = f2bf(w0.z); pk.us[3] = f2bf(w0.w);
                pk.us[4] = f2bf(w1.x); pk.us[5] = f2bf(w1.y);
                pk.us[6] = f2bf(w1.z); pk.us[7] = f2bf(w1.w);
            } else if (q == 2) {
                const int ns = src[gc], nd = dst[gc];
                float dx = x[ns*3+0] - x[nd*3+0];
                float dy = x[ns*3+1] - x[nd*3+1];
                float dz = x[ns*3+2] - x[nd*3+2];
                pk.us[0] = f2bf(dx*dx + dy*dy + dz*dz);
            }
        }
        *(short8v*)&lds[CH8 + (wv * 16 + el) * 32 + qp * 8] = pk.v;
    }

    const int col = lane & 15;
    const int g   = lane >> 4;
    const size_t wrow0 = (size_t)(wv * 32 + col) * KP1;
    const size_t wrow1 = (size_t)(wv * 32 + 16 + col) * KP1;
    short8v nb0 = *(const short8v*)&W1p[wrow0 + g * 8];
    short8v nb1 = *(const short8v*)&W1p[wrow1 + g * 8];
    __syncthreads();

    f32x4 acc[4][2];
    {
        float bv0 = bm1[wv * 32 + col];
        float bv1 = bm1[wv * 32 + 16 + col];
        #pragma unroll
        for (int rt = 0; rt < 4; ++rt) {
            acc[rt][0] = (f32x4){bv0, bv0, bv0, bv0};
            acc[rt][1] = (f32x4){bv1, bv1, bv1, bv1};
        }
    }
    #pragma unroll
    for (int c = 0; c < NCH1; ++c) {
        short8v b0 = nb0, b1 = nb1;
        if (c + 1 < NCH1) {
            nb0 = *(const short8v*)&W1p[wrow0 + (c + 1) * 32 + g * 8];
            nb1 = *(const short8v*)&W1p[wrow1 + (c + 1) * 32 + g * 8];
        }
        short8v a[4];
        #pragma unroll
        for (int rt = 0; rt < 4; ++rt) {
            const int row = rt * 16 + col;
            if (c < 8) {
                const int sP = (((c & 1) << 2) + g) ^ (row & 7);
                a[rt] = *(const short8v*)&lds[((c >> 1) * EB + row) * 64 + sP * 8];
            } else {
                const int sP = g ^ (row & 3);
                a[rt] = *(const short8v*)&lds[CH8 + row * 32 + sP * 8];
            }
        }
        #pragma unroll
        for (int rt = 0; rt < 4; ++rt) {
            acc[rt][0] = __builtin_amdgcn_mfma_f32_16x16x32_bf16(a[rt], b0, acc[rt][0], 0, 0, 0);
            acc[rt][1] = __builtin_amdgcn_mfma_f32_16x16x32_bf16(a[rt], b1, acc[rt][1], 0, 0, 0);
        }
    }
    __syncthreads();

    const int ph = wv >> 1;
    #pragma unroll
    for (int rt = 0; rt < 4; ++rt)
        #pragma unroll
        for (int j = 0; j < 2; ++j)
            #pragma unroll
            for (int r = 0; r < 4; ++r) {
                const int row = rt * 16 + g * 4 + r;
                float v = fmaxf(acc[rt][j][r], 0.f);
                unsigned int pk2 = cvt_pk_bf16(v, v);
                const int sH = (((wv & 1) << 2) + j * 2 + (col >> 3)) ^ (row & 7);
                lds[(ph * EB + row) * 64 + sH * 8 + (col & 7)] = (ushort_t)pk2;
            }
    __syncthreads();

    const size_t w2r0 = (size_t)(wv * 32 + col) * HD;
    const size_t w2r1 = (size_t)(wv * 32 + 16 + col) * HD;
    short8v m0 = *(const short8v*)&W2p[w2r0 + g * 8];
    short8v m1 = *(const short8v*)&W2p[w2r1 + g * 8];
    f32x4 acc2[4][2];
    {
        float bv0 = bm2[wv * 32 + col];
        float bv1 = bm2[wv * 32 + 16 + col];
        #pragma unroll
        for (int rt = 0; rt < 4; ++rt) {
            acc2[rt][0] = (f32x4){bv0, bv0, bv0, bv0};
            acc2[rt][1] = (f32x4){bv1, bv1, bv1, bv1};
        }
    }
    #pragma unroll
    for (int c = 0; c < NCH2; ++c) {
        short8v b0 = m0, b1 = m1;
        if (c + 1 < NCH2) {
            m0 = *(const short8v*)&W2p[w2r0 + (c + 1) * 32 + g * 8];
            m1 = *(const short8v*)&W2p[w2r1 + (c + 1) * 32 + g * 8];
        }
        short8v a[4];
        #pragma unroll
        for (int rt = 0; rt < 4; ++rt) {
            const int row = rt * 16 + col;
            const int sP = (((c & 1) << 2) + g) ^ (row & 7);
            a[rt] = *(const short8v*)&lds[((c >> 1) * EB + row) * 64 + sP * 8];
        }
        #pragma unroll
        for (int rt = 0; rt < 4; ++rt) {
            acc2[rt][0] = __builtin_amdgcn_mfma_f32_16x16x32_bf16(a[rt], b0, acc2[rt][0], 0, 0, 0);
            acc2[rt][1] = __builtin_amdgcn_mfma_f32_16x16x32_bf16(a[rt], b1, acc2[rt][1], 0, 0, 0);
        }
    }

    const bool even = (col & 1) == 0;
    #pragma unroll
    for (int rt = 0; rt < 4; ++rt)
        #pragma unroll
        for (int r = 0; r < 4; ++r) {
            const int e  = rt * 16 + g * 4 + r;
            const int ge = e0 + e;
            const int dg = s_dst[e];
            #pragma unroll
            for (int j = 0; j < 2; ++j) {
                float v  = acc2[rt][j][r];
                float vn = __shfl_xor(v, 1, 64);
                if (even && ge < E) {
                    unsigned int pk2 = cvt_pk_bf16(v, vn);
                    ushort_t* p = msum + (size_t)dg * D + wv * 32 + j * 16 + col;
                    asm volatile("global_atomic_pk_add_bf16 %0, %1, off"
                                 :: "v"(p), "v"(pk2) : "memory");
                }
            }
        }
}

extern "C" void kernel_launch(void* const* d_in, const int* in_sizes, int n_in,
                              void* d_out, int out_size, void* d_ws, size_t ws_size,
                              hipStream_t stream) {
    const float* f   = (const float*)d_in[0];
    const float* x   = (const float*)d_in[1];
    const float* w   = (const float*)d_in[2];
    const int*   src = (const int*)d_in[3];
    const int*   dst = (const int*)d_in[4];
    const float* Wm1 = (const float*)d_in[5];
    const float* bm1 = (const float*)d_in[6];
    const float* Wm2 = (const float*)d_in[7];
    const float* bm2 = (const float*)d_in[8];
    const float* Wu1 = (const float*)d_in[9];
    const float* bu1 = (const float*)d_in[10];
    const float* Wu2 = (const float*)d_in[11];
    const float* bu2 = (const float*)d_in[12];

    const int Nn = in_sizes[0] / D;
    const int E  = in_sizes[3];

    const size_t wbytes  = (size_t)(128 * KP1 + HD * D) * sizeof(ushort_t);
    const size_t wubytes = (size_t)(2 * HD * D) * sizeof(ushort_t);
    auto align512 = [](size_t v) { return (v + 511) & ~(size_t)511; };

    const size_t fb_bytes = (size_t)Nn * D * 2;
    char* wsb = (char*)d_ws;

    // ---------------- primary: fused-reduce CSR layout ----------------
    size_t off = 0;
    const size_t o_w    = off; off = align512(off + wbytes);
    const size_t o_wu   = off; off = align512(off + wubytes);
    const size_t o_fb   = off; off = align512(off + fb_bytes);
    const size_t o_cnt  = off; off = align512(off + (size_t)Nn * 4);
    const size_t o_roff = off; off = align512(off + (size_t)Nn * 4);
    const size_t o_cur  = off; off = align512(off + (size_t)Nn * 4);
    const size_t o_perm = off; off = align512(off + (size_t)E * 4);
    const size_t o_sdst = off; off = align512(off + (size_t)E * 4);
    const size_t o_ms   = off; off = align512(off + (size_t)Nn * D * 4);
    const size_t primary_total = off;

    if (ws_size >= primary_total) {
        ushort_t* W1p  = (ushort_t*)(wsb + o_w);
        ushort_t* W2p  = W1p + 128 * KP1;
        ushort_t* Wu1p = (ushort_t*)(wsb + o_wu);
        ushort_t* Wu2p = Wu1p + HD * D;
        ushort_t* fbf  = (ushort_t*)(wsb + o_fb);
        int* cnt       = (int*)(wsb + o_cnt);
        int* roff      = (int*)(wsb + o_roff);
        int* cursor    = (int*)(wsb + o_cur);
        int* perm      = (int*)(wsb + o_perm);
        int* sdst      = (int*)(wsb + o_sdst);
        float* msum    = (float*)(wsb + o_ms);

        const int n8 = Nn * D / 8;
        const int ntiles = (E + EB - 1) / EB;
        const int half1 = ntiles / 2;
        const int half2 = ntiles - half1;
        hipMemsetAsync(cnt, 0, (size_t)Nn * 4, stream);
        fused_pre_kernel<<<dim3(1024), dim3(256), 0, stream>>>(
            Wm1, Wm2, Wu1, Wu2, W1p, W2p, Wu1p, Wu2p, f, fbf, dst, cnt, n8, E);
        scan_kernel<<<dim3(1), dim3(1024), 0, stream>>>(cnt, roff, cursor, Nn);
        scatter_kernel<<<dim3((E + 255) / 256), dim3(256), 0, stream>>>(
            dst, cursor, roff, cnt, perm, sdst, msum, E, Nn);
        edge_mfma_fused_kernel<<<dim3(half1), dim3(NT), 0, stream>>>(
            fbf, x, w, src, perm, sdst, W1p, bm1, W2p, bm2, msum, E, 0);
        edge_mfma_fused_kernel<<<dim3(half2), dim3(NT), 0, stream>>>(
            fbf, x, w, src, perm, sdst, W1p, bm1, W2p, bm2, msum, E, half1);
        node_mfma_kernel<<<dim3((Nn + 63) / 64), dim3(NT), 0, stream>>>(
            f, msum, Wu1p, bu1, Wu2p, bu2, (float*)d_out, Nn);
        return;
    }

    // ---------------- fallback: pk-atomic path ----------------
    size_t off2 = 0;
    const size_t p_w  = off2; off2 = align512(off2 + wbytes);
    const size_t p_fb = off2; off2 = align512(off2 + fb_bytes);
    const size_t p_ms = off2; off2 = align512(off2 + (size_t)Nn * D * 2);
    if (ws_size >= off2) {
        ushort_t* W1p  = (ushort_t*)(wsb + p_w);
        ushort_t* W2p  = W1p + 128 * KP1;
        ushort_t* fbf  = (ushort_t*)(wsb + p_fb);
        ushort_t* msum = (ushort_t*)(wsb + p_ms);
        const int rp_elems = 128 * KP1 + HD * D;
        hipMemsetAsync(msum, 0, (size_t)Nn * D * 2, stream);
        repack_kernel<<<dim3((rp_elems + 255) / 256), dim3(256), 0, stream>>>(Wm1, Wm2, W1p, W2p);
        const int n8 = Nn * D / 8;
        fconv_kernel<<<dim3((n8 + 255) / 256), dim3(256), 0, stream>>>(f, fbf, n8);
        edge_mfma_kernel<<<dim3((E + EB - 1) / EB), dim3(NT), 0, stream>>>(
            fbf, x, w, src, dst, W1p, bm1, W2p, bm2, msum, E);
        node_kernel<true><<<dim3((Nn + NB - 1) / NB), dim3(NT), 0, stream>>>(
            f, msum, Wu1, bu1, Wu2, bu2, (float*)d_out, Nn);
        return;
    }
}

// Round 17
// 304.213 us; speedup vs baseline: 1.3692x; 1.0558x over previous
//
#include <hip/hip_runtime.h>

#define D 128
#define HD 128
#define DE 16
#define MSG_IN 273
#define EB 64        // edges per tile
#define NT 256
#define KP1 288      // padded msg K = 9 chunks of 32
#define NCH1 9
#define NCH2 4
#define NB 32
#define HID_PAD 132
#define CH8 (4 * EB * 64)   // ushort offset of chunk-8 region in lds[]
#define LDS1 (4 * EB * 64 + EB * 32)

typedef __attribute__((ext_vector_type(8))) short short8v;
typedef __attribute__((ext_vector_type(4))) float f32x4;
typedef unsigned short ushort_t;

#define GLOAD_LDS16(gp, lp) \
    __builtin_amdgcn_global_load_lds((const __attribute__((address_space(1))) unsigned int*)(gp), \
                                     (__attribute__((address_space(3))) unsigned int*)(lp), 16, 0, 0)

__device__ __forceinline__ unsigned short f2bf(float v) {
    unsigned int u = __builtin_bit_cast(unsigned int, v);
    u += 0x7fffu + ((u >> 16) & 1u);
    return (unsigned short)(u >> 16);
}
__device__ __forceinline__ float bf2f(ushort_t u) {
    return __builtin_bit_cast(float, (unsigned int)u << 16);
}
__device__ __forceinline__ unsigned int cvt_pk_bf16(float lo, float hi) {
    unsigned int r;
    asm("v_cvt_pk_bf16_f32 %0, %1, %2" : "=v"(r) : "v"(lo), "v"(hi));
    return r;
}

// ---------------- fused prepass: weight repack (msg + node MLP) + f->bf16 + dst hist ----------------
__global__ void fused_pre_kernel(const float* __restrict__ Wm1, const float* __restrict__ Wm2,
                                 const float* __restrict__ Wu1, const float* __restrict__ Wu2,
                                 ushort_t* __restrict__ W1p, ushort_t* __restrict__ W2p,
                                 ushort_t* __restrict__ Wu1p, ushort_t* __restrict__ Wu2p,
                                 const float* __restrict__ f, ushort_t* __restrict__ fb,
                                 const int* __restrict__ dst, int* __restrict__ cnt,
                                 int n8, int E) {
    const int gid    = blockIdx.x * 256 + threadIdx.x;
    const int stride = gridDim.x * 256;
    const int rp1 = 128 * KP1;
    const int rp2 = rp1 + HD * D;
    const int rp_elems = rp2 + 2 * HD * D;
    for (int i = gid; i < rp_elems; i += stride) {
        if (i < rp1) {
            int n = i / KP1, k = i % KP1;
            W1p[i] = f2bf((k < MSG_IN) ? Wm1[(size_t)k * HD + n] : 0.f);
        } else if (i < rp2) {
            int i2 = i - rp1;
            int n = i2 / HD, k = i2 % HD;
            W2p[i2] = f2bf(Wm2[(size_t)k * D + n]);
        } else {
            int i2 = (i - rp2);
            const bool second = i2 >= HD * D;
            if (second) i2 -= HD * D;
            int n = i2 / HD, k = i2 % HD;
            if (second) Wu2p[i2] = f2bf(Wu2[(size_t)k * D + n]);
            else        Wu1p[i2] = f2bf(Wu1[(size_t)k * HD + n]);
        }
    }
    for (int i = gid; i < n8; i += stride) {
        float4 v0 = *(const float4*)(f + (size_t)i * 8);
        float4 v1 = *(const float4*)(f + (size_t)i * 8 + 4);
        union { ushort_t us[8]; short8v v; } pk;
        pk.us[0] = f2bf(v0.x); pk.us[1] = f2bf(v0.y);
        pk.us[2] = f2bf(v0.z); pk.us[3] = f2bf(v0.w);
        pk.us[4] = f2bf(v1.x); pk.us[5] = f2bf(v1.y);
        pk.us[6] = f2bf(v1.z); pk.us[7] = f2bf(v1.w);
        *(short8v*)(fb + (size_t)i * 8) = pk.v;
    }
    for (int i = gid; i < E; i += stride) atomicAdd(&cnt[dst[i]], 1);
}

// ---------------- CSR build: parallel scan -> scatter + selective zero ----------------
__global__ __launch_bounds__(1024) void scan_kernel(const int* __restrict__ cnt,
                                                    int* __restrict__ roff,
                                                    int* __restrict__ cursor, int Nn) {
    __shared__ int wsum[16];
    const int t = threadIdx.x, l = t & 63, wid = t >> 6;
    int running = 0;
    for (int base = 0; base < Nn; base += 4096) {
        const int i0 = base + t * 4;
        int v0 = 0, v1 = 0, v2 = 0, v3 = 0;
        if (i0 + 3 < Nn) {
            int4 v = *(const int4*)(cnt + i0);
            v0 = v.x; v1 = v.y; v2 = v.z; v3 = v.w;
        } else {
            if (i0 + 0 < Nn) v0 = cnt[i0 + 0];
            if (i0 + 1 < Nn) v1 = cnt[i0 + 1];
            if (i0 + 2 < Nn) v2 = cnt[i0 + 2];
        }
        const int vsum = v0 + v1 + v2 + v3;
        int s = vsum;
        #pragma unroll
        for (int off = 1; off < 64; off <<= 1) {
            int u = __shfl_up(s, off, 64);
            if (l >= off) s += u;
        }
        if (l == 63) wsum[wid] = s;
        __syncthreads();
        if (wid == 0 && l < 16) {
            int xv = wsum[l];
            #pragma unroll
            for (int off = 1; off < 16; off <<= 1) {
                int u = __shfl_up(xv, off, 64);
                if (l >= off) xv += u;
            }
            wsum[l] = xv;
        }
        __syncthreads();
        const int prev  = (wid > 0) ? wsum[wid - 1] : 0;
        const int total = wsum[15];
        int ex = running + prev + (s - vsum);
        if (i0 + 0 < Nn) { roff[i0 + 0] = ex; cursor[i0 + 0] = ex; } ex += v0;
        if (i0 + 1 < Nn) { roff[i0 + 1] = ex; cursor[i0 + 1] = ex; } ex += v1;
        if (i0 + 2 < Nn) { roff[i0 + 2] = ex; cursor[i0 + 2] = ex; } ex += v2;
        if (i0 + 3 < Nn) { roff[i0 + 3] = ex; cursor[i0 + 3] = ex; }
        running += total;
        __syncthreads();
    }
}

__global__ void scatter_kernel(const int* __restrict__ dst, int* cursor,
                               const int* __restrict__ roff, const int* __restrict__ cnt,
                               int* __restrict__ perm, int* __restrict__ sdst,
                               float* __restrict__ msum, int E, int Nn) {
    const int gid    = blockIdx.x * 256 + threadIdx.x;
    const int stride = gridDim.x * 256;
    for (int i = gid; i < E; i += stride) {
        int d = dst[i];
        int s = atomicAdd(&cursor[d], 1);
        perm[s] = i;
        sdst[s] = d;
    }
    for (int n = gid; n < Nn; n += stride) {
        const int c = cnt[n];
        const int r = roff[n];
        const bool need0 = (c == 0) || (r / EB != (r + c - 1) / EB);
        if (need0) {
            float4 z = {0.f, 0.f, 0.f, 0.f};
            float* p = msum + (size_t)n * D;
            #pragma unroll
            for (int k = 0; k < 32; ++k) *(float4*)(p + k * 4) = z;
        }
    }
}

// ---------------- edge kernel v17: dedup'd f[dst] staging + fused segment reduce ----------------
// Pairs 0-1: f[src] per-slot (gload_lds). Pairs 2-3: DISTINCT f[dst] rows only (reg-staged),
// indexed by run-id. hid aliases pairs 0-1 after B1.
__global__ __launch_bounds__(NT, 4) void edge_mfma_fused_kernel(
    const ushort_t* __restrict__ fbf, const float* __restrict__ x,
    const float* __restrict__ w, const int* __restrict__ src,
    const int* __restrict__ perm, const int* __restrict__ sdst,
    const ushort_t* __restrict__ W1p, const float* __restrict__ bm1,
    const ushort_t* __restrict__ W2p, const float* __restrict__ bm2,
    float* __restrict__ msum, int E)
{
    __shared__ __align__(16) ushort_t lds[LDS1];   // 36,864 B
    __shared__ int s_rid[EB];
    __shared__ int s_dgs[EB];

    const int t    = threadIdx.x;
    const int lane = t & 63;
    const int wv   = t >> 6;
    const int e0   = blockIdx.x * EB;
    const int nvalid = min(EB, E - e0);

    const int myd  = (e0 + lane < E) ? sdst[e0 + lane] : -1;
    const int prevd = (e0 > 0) ? sdst[e0 - 1] : -2;
    const int nextd = (e0 + EB < E) ? sdst[e0 + EB] : -2;

    // ---- run metadata: ballot heads -> s_rid (slot->run), s_dgs (run->dst) ----
    const int dprev_l = __shfl_up(myd, 1, 64);
    const bool head = (lane == 0) || (myd != dprev_l);
    const unsigned long long mask = __ballot(head && (lane < nvalid));
    const unsigned long long le = (lane == 63) ? ~0ull : ((1ull << (lane + 1)) - 1ull);
    const int rid = (int)__popcll(mask & le) - 1;
    const int ndist = (int)__popcll(mask);
    s_rid[lane] = (rid < 0) ? 0 : rid;
    if (head && lane < nvalid) s_dgs[rid] = myd;

    // ---- f[src] staging: pairs 0-1 via gload_lds (pre-swizzled source) ----
    {
        const int el8 = lane >> 3;
        const int s   = lane & 7;
        const int sl  = s ^ el8;            // involution swizzle
        const int slA = min(e0 + wv * 16 + el8,     E - 1);
        const int slB = min(e0 + wv * 16 + 8 + el8, E - 1);
        const int nsA = src[perm[slA]];
        const int nsB = src[perm[slB]];
        #pragma unroll
        for (int p = 0; p < 2; ++p) {
            const ushort_t* g0 = fbf + (size_t)nsA * D + p * 64 + sl * 8;
            const ushort_t* g1 = fbf + (size_t)nsB * D + p * 64 + sl * 8;
            GLOAD_LDS16(g0, &lds[(p * EB + wv * 16    ) * 64]);
            GLOAD_LDS16(g1, &lds[(p * EB + wv * 16 + 8) * 64]);
        }
    }
    // ---- f[dst] staging: DISTINCT rows only, pairs 2-3, reg-staged ----
    {
        const int ntask = ndist * 16;       // 16 granules (16B) per distinct row
        for (int idx = t; idx < ntask; idx += NT) {
            const int rowr = idx >> 4;
            const int gr   = idx & 15;
            const int dg   = s_dgs[rowr];
            short8v v = *(const short8v*)(fbf + (size_t)dg * D + gr * 8);
            const int pair = 2 + (gr >> 3);
            const int phys = (gr & 7) ^ (rowr & 7);
            *(short8v*)&lds[(pair * EB + rowr) * 64 + phys * 8] = v;
        }
    }
    // ---- chunk 8: w feats (k0..15), sqd (k16), zeros; 2-bit swizzle ----
    {
        const int el = lane >> 2, q = lane & 3;
        const int qp = q ^ (el & 3);
        const int slot = e0 + wv * 16 + el;
        const bool ok = slot < E;
        const int sc = min(slot, E - 1);
        const int ge = perm[sc];
        union { ushort_t us[8]; short8v v; } pk;
        #pragma unroll
        for (int j = 0; j < 8; ++j) pk.us[j] = 0;
        if (ok) {
            if (q < 2) {
                float4 w0 = *(const float4*)(w + (size_t)ge * DE + q * 8);
                float4 w1 = *(const float4*)(w + (size_t)ge * DE + q * 8 + 4);
                pk.us[0] = f2bf(w0.x); pk.us[1] = f2bf(w0.y);
                pk.us[2] = f2bf(w0.z); pk.us[3] = f2bf(w0.w);
                pk.us[4] = f2bf(w1.x); pk.us[5] = f2bf(w1.y);
                pk.us[6] = f2bf(w1.z); pk.us[7] = f2bf(w1.w);
            } else if (q == 2) {
                const int ns = src[ge], nd = sdst[sc];
                float dx = x[ns*3+0] - x[nd*3+0];
                float dy = x[ns*3+1] - x[nd*3+1];
                float dz = x[ns*3+2] - x[nd*3+2];
                pk.us[0] = f2bf(dx*dx + dy*dy + dz*dz);
            }
        }
        *(short8v*)&lds[CH8 + (wv * 16 + el) * 32 + qp * 8] = pk.v;
    }

    const int col = lane & 15;
    const int g   = lane >> 4;

    const size_t wrow0 = (size_t)(wv * 32 + col) * KP1;
    const size_t wrow1 = (size_t)(wv * 32 + 16 + col) * KP1;
    short8v nb0 = *(const short8v*)&W1p[wrow0 + g * 8];
    short8v nb1 = *(const short8v*)&W1p[wrow1 + g * 8];

    int rid4[4];
    #pragma unroll
    for (int rt = 0; rt < 4; ++rt) rid4[rt] = s_rid[rt * 16 + col];

    __syncthreads();   // B0: staging complete

    // ---- layer 1: [64,288] x [288,32] per wave ----
    f32x4 acc[4][2];
    {
        float bv0 = bm1[wv * 32 + col];
        float bv1 = bm1[wv * 32 + 16 + col];
        #pragma unroll
        for (int rt = 0; rt < 4; ++rt) {
            acc[rt][0] = (f32x4){bv0, bv0, bv0, bv0};
            acc[rt][1] = (f32x4){bv1, bv1, bv1, bv1};
        }
    }
    #pragma unroll
    for (int c = 0; c < NCH1; ++c) {
        short8v b0 = nb0, b1 = nb1;
        if (c + 1 < NCH1) {
            nb0 = *(const short8v*)&W1p[wrow0 + (c + 1) * 32 + g * 8];
            nb1 = *(const short8v*)&W1p[wrow1 + (c + 1) * 32 + g * 8];
        }
        short8v a[4];
        #pragma unroll
        for (int rt = 0; rt < 4; ++rt) {
            if (c < 4) {
                const int row = rt * 16 + col;
                const int sP = (((c & 1) << 2) + g) ^ (row & 7);
                a[rt] = *(const short8v*)&lds[((c >> 1) * EB + row) * 64 + sP * 8];
            } else if (c < 8) {
                const int rowd = rid4[rt];
                const int sP = (((c & 1) << 2) + g) ^ (rowd & 7);
                a[rt] = *(const short8v*)&lds[((c >> 1) * EB + rowd) * 64 + sP * 8];
            } else {
                const int row = rt * 16 + col;
                const int sP = g ^ (row & 3);
                a[rt] = *(const short8v*)&lds[CH8 + row * 32 + sP * 8];
            }
        }
        #pragma unroll
        for (int rt = 0; rt < 4; ++rt) {
            acc[rt][0] = __builtin_amdgcn_mfma_f32_16x16x32_bf16(a[rt], b0, acc[rt][0], 0, 0, 0);
            acc[rt][1] = __builtin_amdgcn_mfma_f32_16x16x32_bf16(a[rt], b1, acc[rt][1], 0, 0, 0);
        }
    }
    __syncthreads();   // B1: layer-1 reads done -> pairs 0-1 reusable

    // hid (relu, bf16) -> pairs 0-1 region, same swizzle; all-lane b16 stores
    const int ph = wv >> 1;
    #pragma unroll
    for (int rt = 0; rt < 4; ++rt)
        #pragma unroll
        for (int j = 0; j < 2; ++j)
            #pragma unroll
            for (int r = 0; r < 4; ++r) {
                const int row = rt * 16 + g * 4 + r;
                float v = fmaxf(acc[rt][j][r], 0.f);
                unsigned int pk2 = cvt_pk_bf16(v, v);
                const int sH = (((wv & 1) << 2) + j * 2 + (col >> 3)) ^ (row & 7);
                lds[(ph * EB + row) * 64 + sH * 8 + (col & 7)] = (ushort_t)pk2;
            }
    __syncthreads();   // B2

    // ---- layer 2: [64,128] x [128,32] per wave ----
    const size_t w2r0 = (size_t)(wv * 32 + col) * HD;
    const size_t w2r1 = (size_t)(wv * 32 + 16 + col) * HD;
    short8v m0 = *(const short8v*)&W2p[w2r0 + g * 8];
    short8v m1 = *(const short8v*)&W2p[w2r1 + g * 8];
    f32x4 acc2[4][2];
    {
        float bv0 = bm2[wv * 32 + col];
        float bv1 = bm2[wv * 32 + 16 + col];
        #pragma unroll
        for (int rt = 0; rt < 4; ++rt) {
            acc2[rt][0] = (f32x4){bv0, bv0, bv0, bv0};
            acc2[rt][1] = (f32x4){bv1, bv1, bv1, bv1};
        }
    }
    #pragma unroll
    for (int c = 0; c < NCH2; ++c) {
        short8v b0 = m0, b1 = m1;
        if (c + 1 < NCH2) {
            m0 = *(const short8v*)&W2p[w2r0 + (c + 1) * 32 + g * 8];
            m1 = *(const short8v*)&W2p[w2r1 + (c + 1) * 32 + g * 8];
        }
        short8v a[4];
        #pragma unroll
        for (int rt = 0; rt < 4; ++rt) {
            const int row = rt * 16 + col;
            const int sP = (((c & 1) << 2) + g) ^ (row & 7);
            a[rt] = *(const short8v*)&lds[((c >> 1) * EB + row) * 64 + sP * 8];
        }
        #pragma unroll
        for (int rt = 0; rt < 4; ++rt) {
            acc2[rt][0] = __builtin_amdgcn_mfma_f32_16x16x32_bf16(a[rt], b0, acc2[rt][0], 0, 0, 0);
            acc2[rt][1] = __builtin_amdgcn_mfma_f32_16x16x32_bf16(a[rt], b1, acc2[rt][1], 0, 0, 0);
        }
    }

    // ---- wave-local segment reduce -> msum (f32); reuse ballot mask ----
    float qs[4][2];
    #pragma unroll
    for (int rt = 0; rt < 4; ++rt) {
        qs[rt][0] = (acc2[rt][0][0] + acc2[rt][0][1]) + (acc2[rt][0][2] + acc2[rt][0][3]);
        qs[rt][1] = (acc2[rt][1][0] + acc2[rt][1][1]) + (acc2[rt][1][2] + acc2[rt][1][3]);
    }
    unsigned long long rem = mask;
    while (rem) {
        const int beg = (int)__builtin_ctzll(rem);
        rem &= rem - 1;
        const int end = rem ? (int)__builtin_ctzll(rem) : nvalid;
        const int dg  = __shfl(myd, beg, 64);

        float s0 = 0.f, s1 = 0.f;
        #pragma unroll
        for (int rt = 0; rt < 4; ++rt) {
            const int qb = rt * 16 + g * 4;
            const int lo = max(qb, beg);
            const int hi = min(qb + 4, end);
            if (lo < hi) {
                if (lo == qb && hi == qb + 4) {
                    s0 += qs[rt][0]; s1 += qs[rt][1];
                } else {
                    #pragma unroll
                    for (int r = 0; r < 4; ++r) {
                        const int sl = qb + r;
                        if (sl >= beg && sl < end) {
                            s0 += acc2[rt][0][r]; s1 += acc2[rt][1][r];
                        }
                    }
                }
            }
        }
        s0 += __shfl_xor(s0, 16, 64); s0 += __shfl_xor(s0, 32, 64);
        s1 += __shfl_xor(s1, 16, 64); s1 += __shfl_xor(s1, 32, 64);
        if (g == 0) {
            const bool bnd = (beg == 0 && dg == prevd) || (end == nvalid && dg == nextd);
            float* p = msum + (size_t)dg * D + wv * 32 + col;
            if (bnd) { atomicAdd(p, s0); atomicAdd(p + 16, s1); }
            else     { p[0] = s0; p[16] = s1; }
        }
    }
}

// ---------------- node kernel: MFMA bf16 update MLP ----------------
__global__ __launch_bounds__(NT, 4) void node_mfma_kernel(
    const float* __restrict__ f, const float* __restrict__ msum,
    const ushort_t* __restrict__ Wu1p, const float* __restrict__ bu1,
    const ushort_t* __restrict__ Wu2p, const float* __restrict__ bu2,
    float* __restrict__ out, int Nn)
{
    __shared__ __align__(16) ushort_t lds[2 * 64 * 64];   // 16,384 B

    const int t    = threadIdx.x;
    const int lane = t & 63;
    const int wv   = t >> 6;
    const int col  = lane & 15;
    const int g    = lane >> 4;
    const int n0   = blockIdx.x * 64;

    #pragma unroll
    for (int it = 0; it < 4; ++it) {
        const int gidx = it * 256 + t;
        const int row  = gidx >> 4;
        const int gr   = gidx & 15;
        const int pair = gr >> 3, s = gr & 7;
        const int sP   = s ^ (row & 7);
        const int gn   = n0 + row;
        union { ushort_t us[8]; short8v v; } pk;
        if (gn < Nn) {
            const size_t off = (size_t)gn * D + gr * 8;
            float4 m0 = *(const float4*)(msum + off);
            float4 m1 = *(const float4*)(msum + off + 4);
            float4 f0 = *(const float4*)(f + off);
            float4 f1 = *(const float4*)(f + off + 4);
            pk.us[0] = f2bf(m0.x + f0.x); pk.us[1] = f2bf(m0.y + f0.y);
            pk.us[2] = f2bf(m0.z + f0.z); pk.us[3] = f2bf(m0.w + f0.w);
            pk.us[4] = f2bf(m1.x + f1.x); pk.us[5] = f2bf(m1.y + f1.y);
            pk.us[6] = f2bf(m1.z + f1.z); pk.us[7] = f2bf(m1.w + f1.w);
        } else {
            #pragma unroll
            for (int j = 0; j < 8; ++j) pk.us[j] = 0;
        }
        *(short8v*)&lds[(pair * 64 + row) * 64 + sP * 8] = pk.v;
    }

    const size_t wrow0 = (size_t)(wv * 32 + col) * HD;
    const size_t wrow1 = (size_t)(wv * 32 + 16 + col) * HD;
    short8v nb0 = *(const short8v*)&Wu1p[wrow0 + g * 8];
    short8v nb1 = *(const short8v*)&Wu1p[wrow1 + g * 8];

    __syncthreads();

    f32x4 acc[4][2];
    {
        float bv0 = bu1[wv * 32 + col];
        float bv1 = bu1[wv * 32 + 16 + col];
        #pragma unroll
        for (int rt = 0; rt < 4; ++rt) {
            acc[rt][0] = (f32x4){bv0, bv0, bv0, bv0};
            acc[rt][1] = (f32x4){bv1, bv1, bv1, bv1};
        }
    }
    #pragma unroll
    for (int c = 0; c < 4; ++c) {
        short8v b0 = nb0, b1 = nb1;
        if (c + 1 < 4) {
            nb0 = *(const short8v*)&Wu1p[wrow0 + (c + 1) * 32 + g * 8];
            nb1 = *(const short8v*)&Wu1p[wrow1 + (c + 1) * 32 + g * 8];
        }
        short8v a[4];
        #pragma unroll
        for (int rt = 0; rt < 4; ++rt) {
            const int row = rt * 16 + col;
            const int sP = (((c & 1) << 2) + g) ^ (row & 7);
            a[rt] = *(const short8v*)&lds[((c >> 1) * 64 + row) * 64 + sP * 8];
        }
        #pragma unroll
        for (int rt = 0; rt < 4; ++rt) {
            acc[rt][0] = __builtin_amdgcn_mfma_f32_16x16x32_bf16(a[rt], b0, acc[rt][0], 0, 0, 0);
            acc[rt][1] = __builtin_amdgcn_mfma_f32_16x16x32_bf16(a[rt], b1, acc[rt][1], 0, 0, 0);
        }
    }
    __syncthreads();

    const int ph = wv >> 1;
    #pragma unroll
    for (int rt = 0; rt < 4; ++rt)
        #pragma unroll
        for (int j = 0; j < 2; ++j)
            #pragma unroll
            for (int r = 0; r < 4; ++r) {
                const int row = rt * 16 + g * 4 + r;
                float v = fmaxf(acc[rt][j][r], 0.f);
                unsigned int pk2 = cvt_pk_bf16(v, v);
                const int sH = (((wv & 1) << 2) + j * 2 + (col >> 3)) ^ (row & 7);
                lds[(ph * 64 + row) * 64 + sH * 8 + (col & 7)] = (ushort_t)pk2;
            }
    __syncthreads();

    const size_t w2r0 = (size_t)(wv * 32 + col) * HD;
    const size_t w2r1 = (size_t)(wv * 32 + 16 + col) * HD;
    short8v m0 = *(const short8v*)&Wu2p[w2r0 + g * 8];
    short8v m1 = *(const short8v*)&Wu2p[w2r1 + g * 8];
    f32x4 acc2[4][2];
    {
        float bv0 = bu2[wv * 32 + col];
        float bv1 = bu2[wv * 32 + 16 + col];
        #pragma unroll
        for (int rt = 0; rt < 4; ++rt) {
            acc2[rt][0] = (f32x4){bv0, bv0, bv0, bv0};
            acc2[rt][1] = (f32x4){bv1, bv1, bv1, bv1};
        }
    }
    #pragma unroll
    for (int c = 0; c < 4; ++c) {
        short8v b0 = m0, b1 = m1;
        if (c + 1 < 4) {
            m0 = *(const short8v*)&Wu2p[w2r0 + (c + 1) * 32 + g * 8];
            m1 = *(const short8v*)&Wu2p[w2r1 + (c + 1) * 32 + g * 8];
        }
        short8v a[4];
        #pragma unroll
        for (int rt = 0; rt < 4; ++rt) {
            const int row = rt * 16 + col;
            const int sP = (((c & 1) << 2) + g) ^ (row & 7);
            a[rt] = *(const short8v*)&lds[((c >> 1) * 64 + row) * 64 + sP * 8];
        }
        #pragma unroll
        for (int rt = 0; rt < 4; ++rt) {
            acc2[rt][0] = __builtin_amdgcn_mfma_f32_16x16x32_bf16(a[rt], b0, acc2[rt][0], 0, 0, 0);
            acc2[rt][1] = __builtin_amdgcn_mfma_f32_16x16x32_bf16(a[rt], b1, acc2[rt][1], 0, 0, 0);
        }
    }

    #pragma unroll
    for (int rt = 0; rt < 4; ++rt)
        #pragma unroll
        for (int r = 0; r < 4; ++r) {
            const int row = rt * 16 + g * 4 + r;
            const int gn = n0 + row;
            if (gn < Nn) {
                out[(size_t)gn * D + wv * 32 + col]      = acc2[rt][0][r];
                out[(size_t)gn * D + wv * 32 + 16 + col] = acc2[rt][1][r];
            }
        }
}

// ================= fallback kernels (bf16 pk-atomic path; no CSR) =================

__global__ void repack_kernel(const float* __restrict__ Wm1, const float* __restrict__ Wm2,
                              ushort_t* __restrict__ W1p, ushort_t* __restrict__ W2p) {
    int idx = blockIdx.x * 256 + threadIdx.x;
    const int n1 = 128 * KP1;
    if (idx < n1) {
        int n = idx / KP1, k = idx % KP1;
        W1p[idx] = f2bf((k < MSG_IN) ? Wm1[(size_t)k * HD + n] : 0.f);
    } else {
        int i2 = idx - n1;
        if (i2 < HD * D) {
            int n = i2 / HD, k = i2 % HD;
            W2p[i2] = f2bf(Wm2[(size_t)k * D + n]);
        }
    }
}

__global__ void fconv_kernel(const float* __restrict__ f, ushort_t* __restrict__ fb, int n8) {
    int i = blockIdx.x * 256 + threadIdx.x;
    if (i < n8) {
        float4 v0 = *(const float4*)(f + (size_t)i * 8);
        float4 v1 = *(const float4*)(f + (size_t)i * 8 + 4);
        union { ushort_t us[8]; short8v v; } pk;
        pk.us[0] = f2bf(v0.x); pk.us[1] = f2bf(v0.y);
        pk.us[2] = f2bf(v0.z); pk.us[3] = f2bf(v0.w);
        pk.us[4] = f2bf(v1.x); pk.us[5] = f2bf(v1.y);
        pk.us[6] = f2bf(v1.z); pk.us[7] = f2bf(v1.w);
        *(short8v*)(fb + (size_t)i * 8) = pk.v;
    }
}

__global__ __launch_bounds__(NT, 4) void edge_mfma_kernel(
    const ushort_t* __restrict__ fbf, const float* __restrict__ x,
    const float* __restrict__ w, const int* __restrict__ src,
    const int* __restrict__ dst,
    const ushort_t* __restrict__ W1p, const float* __restrict__ bm1,
    const ushort_t* __restrict__ W2p, const float* __restrict__ bm2,
    ushort_t* msum, int E)
{
    __shared__ __align__(16) ushort_t lds[LDS1];
    __shared__ int s_dst[EB];

    const int t    = threadIdx.x;
    const int lane = t & 63;
    const int wv   = t >> 6;
    const int e0   = blockIdx.x * EB;

    if (t < EB) s_dst[t] = (e0 + t < E) ? dst[e0 + t] : 0;
    {
        const int el8 = lane >> 3;
        const int s   = lane & 7;
        const int sl  = s ^ el8;
        const int geA = min(e0 + wv * 16 + el8,     E - 1);
        const int geB = min(e0 + wv * 16 + 8 + el8, E - 1);
        const int nsA = src[geA], ndA = dst[geA];
        const int nsB = src[geB], ndB = dst[geB];
        #pragma unroll
        for (int p = 0; p < 4; ++p) {
            const int n0 = (p < 2) ? nsA : ndA;
            const int n1 = (p < 2) ? nsB : ndB;
            const ushort_t* g0 = fbf + (size_t)n0 * D + (p & 1) * 64 + sl * 8;
            const ushort_t* g1 = fbf + (size_t)n1 * D + (p & 1) * 64 + sl * 8;
            GLOAD_LDS16(g0, &lds[(p * EB + wv * 16    ) * 64]);
            GLOAD_LDS16(g1, &lds[(p * EB + wv * 16 + 8) * 64]);
        }
    }
    {
        const int el = lane >> 2, q = lane & 3;
        const int qp = q ^ (el & 3);
        const int ge = e0 + wv * 16 + el;
        const bool ok = ge < E;
        const int gc = min(ge, E - 1);
        union { ushort_t us[8]; short8v v; } pk;
        #pragma unroll
        for (int j = 0; j < 8; ++j) pk.us[j] = 0;
        if (ok) {
            if (q < 2) {
                float4 w0 = *(const float4*)(w + (size_t)gc * DE + q * 8);
                float4 w1 = *(const float4*)(w + (size_t)gc * DE + q * 8 + 4);
                pk.us[0] = f2bf(w0.x); pk.us[1] = f2bf(w0.y);
                pk.us[2] = f2bf(w0.z); pk.us[3] = f2bf(w0.w);
                pk.us[4] = f2bf(w1.x); pk.us[5] = f2bf(w1.y);
                pk.us[6] = f2bf(w1.z); pk.us[7] = f2bf(w1.w);
            } else if (q == 2) {
                const int ns = src[gc], nd = dst[gc];
                float dx = x[ns*3+0] - x[nd*3+0];
                float dy = x[ns*3+1] - x[nd*3+1];
                float dz = x[ns*3+2] - x[nd*3+2];
                pk.us[0] = f2bf(dx*dx + dy*dy + dz*dz);
            }
        }
        *(short8v*)&lds[CH8 + (wv * 16 + el) * 32 + qp * 8] = pk.v;
    }

    const int col = lane & 15;
    const int g   = lane >> 4;
    const size_t wrow0 = (size_t)(wv * 32 + col) * KP1;
    const size_t wrow1 = (size_t)(wv * 32 + 16 + col) * KP1;
    short8v nb0 = *(const short8v*)&W1p[wrow0 + g * 8];
    short8v nb1 = *(const short8v*)&W1p[wrow1 + g * 8];
    __syncthreads();

    f32x4 acc[4][2];
    {
        float bv0 = bm1[wv * 32 + col];
        float bv1 = bm1[wv * 32 + 16 + col];
        #pragma unroll
        for (int rt = 0; rt < 4; ++rt) {
            acc[rt][0] = (f32x4){bv0, bv0, bv0, bv0};
            acc[rt][1] = (f32x4){bv1, bv1, bv1, bv1};
        }
    }
    #pragma unroll
    for (int c = 0; c < 9; ++c) {
        short8v b0 = nb0, b1 = nb1;
        if (c + 1 < 9) {
            nb0 = *(const short8v*)&W1p[wrow0 + (c + 1) * 32 + g * 8];
            nb1 = *(const short8v*)&W1p[wrow1 + (c + 1) * 32 + g * 8];
        }
        short8v a[4];
        #pragma unroll
        for (int rt = 0; rt < 4; ++rt) {
            const int row = rt * 16 + col;
            if (c < 8) {
                const int sP = (((c & 1) << 2) + g) ^ (row & 7);
                a[rt] = *(const short8v*)&lds[((c >> 1) * EB + row) * 64 + sP * 8];
            } else {
                const int sP = g ^ (row & 3);
                a[rt] = *(const short8v*)&lds[CH8 + row * 32 + sP * 8];
            }
        }
        #pragma unroll
        for (int rt = 0; rt < 4; ++rt) {
            acc[rt][0] = __builtin_amdgcn_mfma_f32_16x16x32_bf16(a[rt], b0, acc[rt][0], 0, 0, 0);
            acc[rt][1] = __builtin_amdgcn_mfma_f32_16x16x32_bf16(a[rt], b1, acc[rt][1], 0, 0, 0);
        }
    }
    __syncthreads();

    const int ph = wv >> 1;
    #pragma unroll
    for (int rt = 0; rt < 4; ++rt)
        #pragma unroll
        for (int j = 0; j < 2; ++j)
            #pragma unroll
            for (int r = 0; r < 4; ++r) {
                const int row = rt * 16 + g * 4 + r;
                float v = fmaxf(acc[rt][j][r], 0.f);
                unsigned int pk2 = cvt_pk_bf16(v, v);
                const int sH = (((wv & 1) << 2) + j * 2 + (col >> 3)) ^ (row & 7);
                lds[(ph * EB + row) * 64 + sH * 8 + (col & 7)] = (ushort_t)pk2;
            }
    __syncthreads();

    const size_t w2r0 = (size_t)(wv * 32 + col) * HD;
    const size_t w2r1 = (size_t)(wv * 32 + 16 + col) * HD;
    short8v m0 = *(const short8v*)&W2p[w2r0 + g * 8];
    short8v m1 = *(const short8v*)&W2p[w2r1 + g * 8];
    f32x4 acc2[4][2];
    {
        float bv0 = bm2[wv * 32 + col];
        float bv1 = bm2[wv * 32 + 16 + col];
        #pragma unroll
        for (int rt = 0; rt < 4; ++rt) {
            acc2[rt][0] = (f32x4){bv0, bv0, bv0, bv0};
            acc2[rt][1] = (f32x4){bv1, bv1, bv1, bv1};
        }
    }
    #pragma unroll
    for (int c = 0; c < NCH2; ++c) {
        short8v b0 = m0, b1 = m1;
        if (c + 1 < NCH2) {
            m0 = *(const short8v*)&W2p[w2r0 + (c + 1) * 32 + g * 8];
            m1 = *(const short8v*)&W2p[w2r1 + (c + 1) * 32 + g * 8];
        }
        short8v a[4];
        #pragma unroll
        for (int rt = 0; rt < 4; ++rt) {
            const int row = rt * 16 + col;
            const int sP = (((c & 1) << 2) + g) ^ (row & 7);
            a[rt] = *(const short8v*)&lds[((c >> 1) * EB + row) * 64 + sP * 8];
        }
        #pragma unroll
        for (int rt = 0; rt < 4; ++rt) {
            acc2[rt][0] = __builtin_amdgcn_mfma_f32_16x16x32_bf16(a[rt], b0, acc2[rt][0], 0, 0, 0);
            acc2[rt][1] = __builtin_amdgcn_mfma_f32_16x16x32_bf16(a[rt], b1, acc2[rt][1], 0, 0, 0);
        }
    }

    const bool even = (col & 1) == 0;
    #pragma unroll
    for (int rt = 0; rt < 4; ++rt)
        #pragma unroll
        for (int r = 0; r < 4; ++r) {
            const int e  = rt * 16 + g * 4 + r;
            const int ge = e0 + e;
            const int dg = s_dst[e];
            #pragma unroll
            for (int j = 0; j < 2; ++j) {
                float v  = acc2[rt][j][r];
                float vn = __shfl_xor(v, 1, 64);
                if (even && ge < E) {
                    unsigned int pk2 = cvt_pk_bf16(v, vn);
                    ushort_t* p = msum + (size_t)dg * D + wv * 32 + j * 16 + col;
                    asm volatile("global_atomic_pk_add_bf16 %0, %1, off"
                                 :: "v"(p), "v"(pk2) : "memory");
                }
            }
        }
}

template<bool MB16>
__global__ __launch_bounds__(NT, 4) void node_kernel(
    const float* __restrict__ f, const void* __restrict__ msum_v,
    const float* __restrict__ Wu1, const float* __restrict__ bu1,
    const float* __restrict__ Wu2, const float* __restrict__ bu2,
    float* out, int Nn)
{
    __shared__ __align__(16) float hin[NB][HID_PAD];
    __shared__ __align__(16) float hid[NB][HID_PAD];
    const int t  = threadIdx.x;
    const int n0 = blockIdx.x * NB;
    const int nn = min(NB, Nn - n0);

    {
        #pragma unroll
        for (int it = 0; it < 4; ++it) {
            const int idx = it * 1024 + t * 4;
            const int e   = idx >> 7;
            const int cb  = idx & 127;
            if (e < nn) {
                const size_t off = (size_t)(n0 + e) * D + cb;
                float4 mv;
                if (MB16) {
                    uint2 pk = *(const uint2*)((const ushort_t*)msum_v + off);
                    mv.x = bf2f((ushort_t)(pk.x & 0xffffu));
                    mv.y = bf2f((ushort_t)(pk.x >> 16));
                    mv.z = bf2f((ushort_t)(pk.y & 0xffffu));
                    mv.w = bf2f((ushort_t)(pk.y >> 16));
                } else {
                    mv = *(const float4*)((const float*)msum_v + off);
                }
                float4 fv = *(const float4*)&f[off];
                float4 o = {mv.x + fv.x, mv.y + fv.y, mv.z + fv.z, mv.w + fv.w};
                *(float4*)&hin[e][cb] = o;
            }
        }
    }
    __syncthreads();

    const int tc = t & 15, te2 = (t >> 4) * 2, c0 = tc * 8;
    float a1[2][8];
    #pragma unroll
    for (int c = 0; c < 8; ++c) { float bv = bu1[c0 + c]; a1[0][c] = bv; a1[1][c] = bv; }
    for (int i = 0; i < D; i += 4) {
        float m0[4], m1[4];
        *(float4*)m0 = *(const float4*)&hin[te2][i];
        *(float4*)m1 = *(const float4*)&hin[te2 + 1][i];
        #pragma unroll
        for (int r = 0; r < 4; ++r) {
            float wr[8];
            *(float4*)&wr[0] = *(const float4*)(Wu1 + (size_t)(i + r) * HD + c0);
            *(float4*)&wr[4] = *(const float4*)(Wu1 + (size_t)(i + r) * HD + c0 + 4);
            #pragma unroll
            for (int c = 0; c < 8; ++c) { a1[0][c] += m0[r]*wr[c]; a1[1][c] += m1[r]*wr[c]; }
        }
    }
    #pragma unroll
    for (int j = 0; j < 2; ++j) {
        float v[8];
        #pragma unroll
        for (int c = 0; c < 8; ++c) v[c] = fmaxf(a1[j][c], 0.f);
        *(float4*)&hid[te2 + j][c0] = *(float4*)&v[0];
        *(float4*)&hid[te2 + j][c0 + 4] = *(float4*)&v[4];
    }
    __syncthreads();
    float a2[2][8];
    #pragma unroll
    for (int c = 0; c < 8; ++c) { float bv = bu2[c0 + c]; a2[0][c] = bv; a2[1][c] = bv; }
    for (int h = 0; h < HD; h += 4) {
        float m0[4], m1[4];
        *(float4*)m0 = *(const float4*)&hid[te2][h];
        *(float4*)m1 = *(const float4*)&hid[te2 + 1][h];
        #pragma unroll
        for (int r = 0; r < 4; ++r) {
            float wr[8];
            *(float4*)&wr[0] = *(const float4*)(Wu2 + (size_t)(h + r) * D + c0);
            *(float4*)&wr[4] = *(const float4*)(Wu2 + (size_t)(h + r) * D + c0 + 4);
            #pragma unroll
            for (int c = 0; c < 8; ++c) { a2[0][c] += m0[r]*wr[c]; a2[1][c] += m1[r]*wr[c]; }
        }
    }
    #pragma unroll
    for (int j = 0; j < 2; ++j) {
        int e = te2 + j, gn = n0 + e;
        if (e < nn) {
            *(float4*)(out + (size_t)gn * D + c0) = *(float4*)&a2[j][0];
            *(float4*)(out + (size_t)gn * D + c0 + 4) = *(float4*)&a2[j][4];
        }
    }
}

extern "C" void kernel_launch(void* const* d_in, const int* in_sizes, int n_in,
                              void* d_out, int out_size, void* d_ws, size_t ws_size,
                              hipStream_t stream) {
    const float* f   = (const float*)d_in[0];
    const float* x   = (const float*)d_in[1];
    const float* w   = (const float*)d_in[2];
    const int*   src = (const int*)d_in[3];
    const int*   dst = (const int*)d_in[4];
    const float* Wm1 = (const float*)d_in[5];
    const float* bm1 = (const float*)d_in[6];
    const float* Wm2 = (const float*)d_in[7];
    const float* bm2 = (const float*)d_in[8];
    const float* Wu1 = (const float*)d_in[9];
    const float* bu1 = (const float*)d_in[10];
    const float* Wu2 = (const float*)d_in[11];
    const float* bu2 = (const float*)d_in[12];

    const int Nn = in_sizes[0] / D;
    const int E  = in_sizes[3];

    const size_t wbytes  = (size_t)(128 * KP1 + HD * D) * sizeof(ushort_t);
    const size_t wubytes = (size_t)(2 * HD * D) * sizeof(ushort_t);
    auto align512 = [](size_t v) { return (v + 511) & ~(size_t)511; };

    const size_t fb_bytes = (size_t)Nn * D * 2;
    char* wsb = (char*)d_ws;

    // ---------------- primary: fused-reduce CSR layout ----------------
    size_t off = 0;
    const size_t o_w    = off; off = align512(off + wbytes);
    const size_t o_wu   = off; off = align512(off + wubytes);
    const size_t o_fb   = off; off = align512(off + fb_bytes);
    const size_t o_cnt  = off; off = align512(off + (size_t)Nn * 4);
    const size_t o_roff = off; off = align512(off + (size_t)Nn * 4);
    const size_t o_cur  = off; off = align512(off + (size_t)Nn * 4);
    const size_t o_perm = off; off = align512(off + (size_t)E * 4);
    const size_t o_sdst = off; off = align512(off + (size_t)E * 4);
    const size_t o_ms   = off; off = align512(off + (size_t)Nn * D * 4);
    const size_t primary_total = off;

    if (ws_size >= primary_total) {
        ushort_t* W1p  = (ushort_t*)(wsb + o_w);
        ushort_t* W2p  = W1p + 128 * KP1;
        ushort_t* Wu1p = (ushort_t*)(wsb + o_wu);
        ushort_t* Wu2p = Wu1p + HD * D;
        ushort_t* fbf  = (ushort_t*)(wsb + o_fb);
        int* cnt       = (int*)(wsb + o_cnt);
        int* roff      = (int*)(wsb + o_roff);
        int* cursor    = (int*)(wsb + o_cur);
        int* perm      = (int*)(wsb + o_perm);
        int* sdst      = (int*)(wsb + o_sdst);
        float* msum    = (float*)(wsb + o_ms);

        const int n8 = Nn * D / 8;
        const int ntiles = (E + EB - 1) / EB;
        hipMemsetAsync(cnt, 0, (size_t)Nn * 4, stream);
        fused_pre_kernel<<<dim3(1024), dim3(256), 0, stream>>>(
            Wm1, Wm2, Wu1, Wu2, W1p, W2p, Wu1p, Wu2p, f, fbf, dst, cnt, n8, E);
        scan_kernel<<<dim3(1), dim3(1024), 0, stream>>>(cnt, roff, cursor, Nn);
        scatter_kernel<<<dim3((E + 255) / 256), dim3(256), 0, stream>>>(
            dst, cursor, roff, cnt, perm, sdst, msum, E, Nn);
        edge_mfma_fused_kernel<<<dim3(ntiles), dim3(NT), 0, stream>>>(
            fbf, x, w, src, perm, sdst, W1p, bm1, W2p, bm2, msum, E);
        node_mfma_kernel<<<dim3((Nn + 63) / 64), dim3(NT), 0, stream>>>(
            f, msum, Wu1p, bu1, Wu2p, bu2, (float*)d_out, Nn);
        return;
    }

    // ---------------- fallback: bf16 pk-atomic path ----------------
    size_t off2 = 0;
    const size_t p_w  = off2; off2 = align512(off2 + wbytes);
    const size_t p_fb = off2; off2 = align512(off2 + fb_bytes);
    const size_t p_ms = off2; off2 = align512(off2 + (size_t)Nn * D * 2);
    if (ws_size >= off2) {
        ushort_t* W1p  = (ushort_t*)(wsb + p_w);
        ushort_t* W2p  = W1p + 128 * KP1;
        ushort_t* fbf  = (ushort_t*)(wsb + p_fb);
        ushort_t* msum = (ushort_t*)(wsb + p_ms);
        const int rp_elems = 128 * KP1 + HD * D;
        hipMemsetAsync(msum, 0, (size_t)Nn * D * 2, stream);
        repack_kernel<<<dim3((rp_elems + 255) / 256), dim3(256), 0, stream>>>(Wm1, Wm2, W1p, W2p);
        const int n8 = Nn * D / 8;
        fconv_kernel<<<dim3((n8 + 255) / 256), dim3(256), 0, stream>>>(f, fbf, n8);
        edge_mfma_kernel<<<dim3((E + EB - 1) / EB), dim3(NT), 0, stream>>>(
            fbf, x, w, src, dst, W1p, bm1, W2p, bm2, msum, E);
        node_kernel<true><<<dim3((Nn + NB - 1) / NB), dim3(NT), 0, stream>>>(
            f, msum, Wu1, bu1, Wu2, bu2, (float*)d_out, Nn);
        return;
    }
}

// Round 19
// 267.899 us; speedup vs baseline: 1.5548x; 1.1356x over previous
//
#include <hip/hip_runtime.h>
#include <hip/hip_fp8.h>

#define D 128
#define HD 128
#define DE 16
#define MSG_IN 273
#define EB 64        // edges per tile
#define NT 256
#define KP1 288      // padded msg K = 9 chunks of 32
#define NCH2 4
#define NB 32
#define HID_PAD 132
#define CH8 (4 * EB * 64)
#define LDS1 (4 * EB * 64 + EB * 32)
// edge_lin LDS layout (bytes): A fp8 [0,8192) ; B bf16 [8192,24576) ; c8 bf16 [24576,28672)
#define OB 8192
#define OC 24576

typedef __attribute__((ext_vector_type(8))) short short8v;
typedef __attribute__((ext_vector_type(4))) float f32x4;
typedef unsigned short ushort_t;
typedef unsigned char uchar_t;

#define GLOAD_LDS16(gp, lp) \
    __builtin_amdgcn_global_load_lds((const __attribute__((address_space(1))) unsigned int*)(gp), \
                                     (__attribute__((address_space(3))) unsigned int*)(lp), 16, 0, 0)

__device__ __forceinline__ unsigned short f2bf(float v) {
    unsigned int u = __builtin_bit_cast(unsigned int, v);
    u += 0x7fffu + ((u >> 16) & 1u);
    return (unsigned short)(u >> 16);
}
__device__ __forceinline__ float bf2f(ushort_t u) {
    return __builtin_bit_cast(float, (unsigned int)u << 16);
}
__device__ __forceinline__ unsigned int cvt_pk_bf16(float lo, float hi) {
    unsigned int r;
    asm("v_cvt_pk_bf16_f32 %0, %1, %2" : "=v"(r) : "v"(lo), "v"(hi));
    return r;
}
__device__ __forceinline__ uchar_t f8e(float v) {   // f32 -> e4m3 (HIP library)
    __hip_fp8_e4m3 t(v);
    return (uchar_t)t.__x;
}
// e4m3fn -> f32: normals 2^(e-7)(1+m/8); subnormals m/8*2^-6; sign bit preserved.
__device__ __forceinline__ float f8d(unsigned b) {
    unsigned t = ((b & 0x7fu) << 20) | ((b & 0x80u) << 24);
    return __builtin_bit_cast(float, t) * 0x1p120f;
}

// ---------------- fused prepass: repack weights, f->bf16, w->bf16, dst hist ----------------
__global__ void fused_pre_kernel(const float* __restrict__ Wm1, const float* __restrict__ Wm2,
                                 const float* __restrict__ Wu1, const float* __restrict__ Wu2,
                                 ushort_t* __restrict__ W1p, ushort_t* __restrict__ W2p,
                                 ushort_t* __restrict__ Wu1p, ushort_t* __restrict__ Wu2p,
                                 const float* __restrict__ f, ushort_t* __restrict__ fb,
                                 const float* __restrict__ w, ushort_t* __restrict__ wbf,
                                 const int* __restrict__ dst, int* __restrict__ cnt,
                                 int n8, int nw8, int E) {
    const int gid    = blockIdx.x * 256 + threadIdx.x;
    const int stride = gridDim.x * 256;
    const int rp1 = 128 * KP1;
    const int rp2 = rp1 + HD * D;
    const int rp_elems = rp2 + 2 * HD * D;
    for (int i = gid; i < rp_elems; i += stride) {
        if (i < rp1) {
            int n = i / KP1, k = i % KP1;
            W1p[i] = f2bf((k < MSG_IN) ? Wm1[(size_t)k * HD + n] : 0.f);
        } else if (i < rp2) {
            int i2 = i - rp1;
            int n = i2 / HD, k = i2 % HD;
            W2p[i2] = f2bf(Wm2[(size_t)k * D + n]);
        } else {
            int i2 = (i - rp2);
            const bool second = i2 >= HD * D;
            if (second) i2 -= HD * D;
            int n = i2 / HD, k = i2 % HD;
            if (second) Wu2p[i2] = f2bf(Wu2[(size_t)k * D + n]);
            else        Wu1p[i2] = f2bf(Wu1[(size_t)k * HD + n]);
        }
    }
    for (int i = gid; i < n8; i += stride) {
        float4 v0 = *(const float4*)(f + (size_t)i * 8);
        float4 v1 = *(const float4*)(f + (size_t)i * 8 + 4);
        union { ushort_t us[8]; short8v v; } pk;
        pk.us[0] = f2bf(v0.x); pk.us[1] = f2bf(v0.y);
        pk.us[2] = f2bf(v0.z); pk.us[3] = f2bf(v0.w);
        pk.us[4] = f2bf(v1.x); pk.us[5] = f2bf(v1.y);
        pk.us[6] = f2bf(v1.z); pk.us[7] = f2bf(v1.w);
        *(short8v*)(fb + (size_t)i * 8) = pk.v;
    }
    for (int i = gid; i < nw8; i += stride) {
        float4 v0 = *(const float4*)(w + (size_t)i * 8);
        float4 v1 = *(const float4*)(w + (size_t)i * 8 + 4);
        union { ushort_t us[8]; short8v v; } pk;
        pk.us[0] = f2bf(v0.x); pk.us[1] = f2bf(v0.y);
        pk.us[2] = f2bf(v0.z); pk.us[3] = f2bf(v0.w);
        pk.us[4] = f2bf(v1.x); pk.us[5] = f2bf(v1.y);
        pk.us[6] = f2bf(v1.z); pk.us[7] = f2bf(v1.w);
        *(short8v*)(wbf + (size_t)i * 8) = pk.v;
    }
    for (int i = gid; i < E; i += stride) atomicAdd(&cnt[dst[i]], 1);
}

// ---------------- CSR build: parallel scan -> scatter + selective zero (of mh) ----------------
__global__ __launch_bounds__(1024) void scan_kernel(const int* __restrict__ cnt,
                                                    int* __restrict__ roff,
                                                    int* __restrict__ cursor, int Nn) {
    __shared__ int wsum[16];
    const int t = threadIdx.x, l = t & 63, wid = t >> 6;
    int running = 0;
    for (int base = 0; base < Nn; base += 4096) {
        const int i0 = base + t * 4;
        int v0 = 0, v1 = 0, v2 = 0, v3 = 0;
        if (i0 + 3 < Nn) {
            int4 v = *(const int4*)(cnt + i0);
            v0 = v.x; v1 = v.y; v2 = v.z; v3 = v.w;
        } else {
            if (i0 + 0 < Nn) v0 = cnt[i0 + 0];
            if (i0 + 1 < Nn) v1 = cnt[i0 + 1];
            if (i0 + 2 < Nn) v2 = cnt[i0 + 2];
        }
        const int vsum = v0 + v1 + v2 + v3;
        int s = vsum;
        #pragma unroll
        for (int off = 1; off < 64; off <<= 1) {
            int u = __shfl_up(s, off, 64);
            if (l >= off) s += u;
        }
        if (l == 63) wsum[wid] = s;
        __syncthreads();
        if (wid == 0 && l < 16) {
            int xv = wsum[l];
            #pragma unroll
            for (int off = 1; off < 16; off <<= 1) {
                int u = __shfl_up(xv, off, 64);
                if (l >= off) xv += u;
            }
            wsum[l] = xv;
        }
        __syncthreads();
        const int prev  = (wid > 0) ? wsum[wid - 1] : 0;
        const int total = wsum[15];
        int ex = running + prev + (s - vsum);
        if (i0 + 0 < Nn) { roff[i0 + 0] = ex; cursor[i0 + 0] = ex; } ex += v0;
        if (i0 + 1 < Nn) { roff[i0 + 1] = ex; cursor[i0 + 1] = ex; } ex += v1;
        if (i0 + 2 < Nn) { roff[i0 + 2] = ex; cursor[i0 + 2] = ex; } ex += v2;
        if (i0 + 3 < Nn) { roff[i0 + 3] = ex; cursor[i0 + 3] = ex; }
        running += total;
        __syncthreads();
    }
}

__global__ void scatter_kernel(const int* __restrict__ dst, int* cursor,
                               const int* __restrict__ roff, const int* __restrict__ cnt,
                               int* __restrict__ perm, int* __restrict__ sdst,
                               float* __restrict__ mh, int E, int Nn) {
    const int gid    = blockIdx.x * 256 + threadIdx.x;
    const int stride = gridDim.x * 256;
    for (int i = gid; i < E; i += stride) {
        int d = dst[i];
        int s = atomicAdd(&cursor[d], 1);
        perm[s] = i;
        sdst[s] = d;
    }
    for (int n = gid; n < Nn; n += stride) {
        const int c = cnt[n];
        const int r = roff[n];
        const bool need0 = (c == 0) || (r / EB != (r + c - 1) / EB);
        if (need0) {
            float4 z = {0.f, 0.f, 0.f, 0.f};
            float* p = mh + (size_t)n * D;
            #pragma unroll
            for (int k = 0; k < 32; ++k) *(float4*)(p + k * 4) = z;
        }
    }
}

// ---------------- AB precompute: A = f@Wm1[0:128] -> fp8, B = f@Wm1[128:256] -> bf16 ----------------
__global__ __launch_bounds__(NT, 4) void ab_kernel(
    const ushort_t* __restrict__ fbf,
    const ushort_t* __restrict__ W1p,
    uchar_t* __restrict__ Af, ushort_t* __restrict__ Bf16, int Nn)
{
    __shared__ __align__(16) ushort_t lds[2 * 64 * 64];   // 16 KB

    const int t    = threadIdx.x;
    const int lane = t & 63;
    const int wv   = t >> 6;
    const int col  = lane & 15;
    const int g    = lane >> 4;
    const int n0   = blockIdx.x * 64;

    // stage f rows (bf16) into swizzled [pair][64][64]
    #pragma unroll
    for (int it = 0; it < 4; ++it) {
        const int gidx = it * 256 + t;
        const int row  = gidx >> 4;
        const int gr   = gidx & 15;
        const int pair = gr >> 3, s = gr & 7;
        const int sP   = s ^ (row & 7);
        const int gn   = min(n0 + row, Nn - 1);
        short8v v = *(const short8v*)(fbf + (size_t)gn * D + gr * 8);
        *(short8v*)&lds[(pair * 64 + row) * 64 + sP * 8] = v;
    }
    __syncthreads();

    const bool even = (col & 1) == 0;
    #pragma unroll
    for (int half = 0; half < 2; ++half) {          // 0: A (fp8), 1: B (bf16)
        f32x4 acc[4][2];
        #pragma unroll
        for (int rt = 0; rt < 4; ++rt) {
            acc[rt][0] = (f32x4){0.f, 0.f, 0.f, 0.f};
            acc[rt][1] = (f32x4){0.f, 0.f, 0.f, 0.f};
        }
        const int kbase = half * 128;
        #pragma unroll
        for (int c = 0; c < 4; ++c) {
            short8v b0 = *(const short8v*)&W1p[(size_t)(wv * 32 + col) * KP1 + kbase + c * 32 + g * 8];
            short8v b1 = *(const short8v*)&W1p[(size_t)(wv * 32 + 16 + col) * KP1 + kbase + c * 32 + g * 8];
            short8v a[4];
            #pragma unroll
            for (int rt = 0; rt < 4; ++rt) {
                const int row = rt * 16 + col;
                const int sP = (((c & 1) << 2) + g) ^ (row & 7);
                a[rt] = *(const short8v*)&lds[((c >> 1) * 64 + row) * 64 + sP * 8];
            }
            #pragma unroll
            for (int rt = 0; rt < 4; ++rt) {
                acc[rt][0] = __builtin_amdgcn_mfma_f32_16x16x32_bf16(a[rt], b0, acc[rt][0], 0, 0, 0);
                acc[rt][1] = __builtin_amdgcn_mfma_f32_16x16x32_bf16(a[rt], b1, acc[rt][1], 0, 0, 0);
            }
        }
        #pragma unroll
        for (int rt = 0; rt < 4; ++rt)
            #pragma unroll
            for (int j = 0; j < 2; ++j)
                #pragma unroll
                for (int r = 0; r < 4; ++r) {
                    const int row = rt * 16 + g * 4 + r;
                    const int gn = n0 + row;
                    float v  = acc[rt][j][r];
                    float vn = __shfl_xor(v, 1, 64);
                    if (even && gn < Nn) {
                        const int ca = wv * 32 + j * 16 + col;
                        if (half == 0) {
                            ushort_t pk = (ushort_t)f8e(v) | ((ushort_t)f8e(vn) << 8);
                            *(ushort_t*)(Af + (size_t)gn * D + ca) = pk;
                        } else {
                            *(unsigned int*)(Bf16 + (size_t)gn * D + ca) = cvt_pk_bf16(v, vn);
                        }
                    }
                }
    }
}

// ---------------- edge kernel v19: A[src](fp8) + B[dst](dedup bf16) + C_e MFMA,
//                  relu, fused segment reduce -> mh (f32) ----------------
__global__ __launch_bounds__(NT, 4) void edge_lin_kernel(
    const uchar_t* __restrict__ Af, const ushort_t* __restrict__ Bf16,
    const float* __restrict__ x, const ushort_t* __restrict__ wbf,
    const int* __restrict__ src,
    const int* __restrict__ perm, const int* __restrict__ sdst,
    const ushort_t* __restrict__ W1p, const float* __restrict__ bm1,
    float* __restrict__ mh, int E)
{
    __shared__ __align__(16) uchar_t lds8[28672];   // A 8K | B 16K | c8 4K
    __shared__ int s_rid[EB];
    __shared__ int s_dgs[EB];

    const int t    = threadIdx.x;
    const int lane = t & 63;
    const int wv   = t >> 6;
    const int e0   = blockIdx.x * EB;
    const int nvalid = min(EB, E - e0);

    const int myd  = (e0 + lane < E) ? sdst[e0 + lane] : -1;
    const int prevd = (e0 > 0) ? sdst[e0 - 1] : -2;
    const int nextd = (e0 + EB < E) ? sdst[e0 + EB] : -2;

    // run metadata (identical across waves -> benign shared writes)
    const int dprev_l = __shfl_up(myd, 1, 64);
    const bool head = (lane == 0) || (myd != dprev_l);
    const unsigned long long mask = __ballot(head && (lane < nvalid));
    const unsigned long long le = (lane == 63) ? ~0ull : ((1ull << (lane + 1)) - 1ull);
    const int rid = (int)__popcll(mask & le) - 1;
    const int ndist = (int)__popcll(mask);
    s_rid[lane] = (rid < 0) ? 0 : rid;
    if (head && lane < nvalid) s_dgs[rid] = myd;

    // ---- A[src] staging: fp8 rows (128 B) via gload_lds, granule-swizzled source ----
    {
        const int el8 = lane >> 3;
        const int s   = lane & 7;
        const int sl  = s ^ el8;
        const int slA = min(e0 + wv * 16 + el8,     E - 1);
        const int slB = min(e0 + wv * 16 + 8 + el8, E - 1);
        const int nsA = src[perm[slA]];
        const int nsB = src[perm[slB]];
        GLOAD_LDS16(Af + (size_t)nsA * D + sl * 16, &lds8[(wv * 16    ) * 128]);
        GLOAD_LDS16(Af + (size_t)nsB * D + sl * 16, &lds8[(wv * 16 + 8) * 128]);
    }
    // ---- B[dst] staging: distinct rows only (bf16, 256 B), reg-staged, 16-gran swizzle ----
    {
        const int ntask = ndist * 16;       // 16 granules (16B) per row
        for (int idx = t; idx < ntask; idx += NT) {
            const int rowr = idx >> 4;
            const int gr   = idx & 15;
            const int dg   = s_dgs[rowr];
            uint4 v = *(const uint4*)(Bf16 + (size_t)dg * D + gr * 8);
            const int phys = gr ^ (rowr & 15);
            *(uint4*)&lds8[OB + rowr * 256 + phys * 16] = v;
        }
    }
    // ---- chunk 8 (bf16): w feats (k0..15), sqd (k16), zeros; granule-swizzled ----
    {
        const int el = lane >> 2, q = lane & 3;
        const int qp = q ^ (el & 3);
        const int slot = e0 + wv * 16 + el;
        const bool ok = slot < E;
        const int sc = min(slot, E - 1);
        const int ge = perm[sc];
        union { ushort_t us[8]; short8v v; } pk;
        #pragma unroll
        for (int j = 0; j < 8; ++j) pk.us[j] = 0;
        if (ok) {
            if (q < 2) {
                pk.v = *(const short8v*)(wbf + (size_t)ge * DE + q * 8);
            } else if (q == 2) {
                const int ns = src[ge], nd = sdst[sc];
                float dx = x[ns*3+0] - x[nd*3+0];
                float dy = x[ns*3+1] - x[nd*3+1];
                float dz = x[ns*3+2] - x[nd*3+2];
                pk.us[0] = f2bf(dx*dx + dy*dy + dz*dz);
            }
        }
        *(short8v*)&lds8[OC + (wv * 16 + el) * 64 + qp * 16] = pk.v;
    }

    const int col = lane & 15;
    const int g   = lane >> 4;

    // C-chunk B-frags (k=256..287 of W1p)
    short8v bc0 = *(const short8v*)&W1p[(size_t)(wv * 32 + col) * KP1 + 256 + g * 8];
    short8v bc1 = *(const short8v*)&W1p[(size_t)(wv * 32 + 16 + col) * KP1 + 256 + g * 8];

    __syncthreads();   // B0: staging + run metadata complete

    // ---- acc = bm1 + C_e (single K=32 MFMA chunk) ----
    f32x4 acc[4][2];
    {
        float bv0 = bm1[wv * 32 + col];
        float bv1 = bm1[wv * 32 + 16 + col];
        #pragma unroll
        for (int rt = 0; rt < 4; ++rt) {
            acc[rt][0] = (f32x4){bv0, bv0, bv0, bv0};
            acc[rt][1] = (f32x4){bv1, bv1, bv1, bv1};
        }
    }
    #pragma unroll
    for (int rt = 0; rt < 4; ++rt) {
        const int row = rt * 16 + col;
        const int sP8 = g ^ (row & 3);
        short8v a = *(const short8v*)&lds8[OC + row * 64 + sP8 * 16];
        acc[rt][0] = __builtin_amdgcn_mfma_f32_16x16x32_bf16(a, bc0, acc[rt][0], 0, 0, 0);
        acc[rt][1] = __builtin_amdgcn_mfma_f32_16x16x32_bf16(a, bc1, acc[rt][1], 0, 0, 0);
    }

    // ---- h = relu(acc + A + B); C/D row = rt*16 + g*4 + r (FIXED: rid by C/D row) ----
    float h[4][2][4];
    #pragma unroll
    for (int rt = 0; rt < 4; ++rt) {
        #pragma unroll
        for (int r = 0; r < 4; ++r) {
            const int row = rt * 16 + g * 4 + r;
            const int rd  = s_rid[row];
            #pragma unroll
            for (int j = 0; j < 2; ++j) {
                const int ca = wv * 32 + j * 16 + col;
                const uchar_t ab = lds8[row * 128 + (((ca >> 4) ^ (row & 7)) << 4) + (ca & 15)];
                const ushort_t bb = *(const ushort_t*)&lds8[OB + rd * 256 + (((ca >> 3) ^ (rd & 15)) << 4) + (ca & 7) * 2];
                h[rt][j][r] = fmaxf(acc[rt][j][r] + f8d(ab) + bf2f(bb), 0.f);
            }
        }
    }

    // ---- wave-local segment reduce -> mh (f32) ----
    float qs[4][2];
    #pragma unroll
    for (int rt = 0; rt < 4; ++rt) {
        qs[rt][0] = (h[rt][0][0] + h[rt][0][1]) + (h[rt][0][2] + h[rt][0][3]);
        qs[rt][1] = (h[rt][1][0] + h[rt][1][1]) + (h[rt][1][2] + h[rt][1][3]);
    }
    unsigned long long rem = mask;
    while (rem) {
        const int beg = (int)__builtin_ctzll(rem);
        rem &= rem - 1;
        const int end = rem ? (int)__builtin_ctzll(rem) : nvalid;
        const int dg  = __shfl(myd, beg, 64);

        float s0 = 0.f, s1 = 0.f;
        #pragma unroll
        for (int rt = 0; rt < 4; ++rt) {
            const int qb = rt * 16 + g * 4;
            const int lo = max(qb, beg);
            const int hi = min(qb + 4, end);
            if (lo < hi) {
                if (lo == qb && hi == qb + 4) {
                    s0 += qs[rt][0]; s1 += qs[rt][1];
                } else {
                    #pragma unroll
                    for (int r = 0; r < 4; ++r) {
                        const int sl = qb + r;
                        if (sl >= beg && sl < end) {
                            s0 += h[rt][0][r]; s1 += h[rt][1][r];
                        }
                    }
                }
            }
        }
        s0 += __shfl_xor(s0, 16, 64); s0 += __shfl_xor(s0, 32, 64);
        s1 += __shfl_xor(s1, 16, 64); s1 += __shfl_xor(s1, 32, 64);
        if (g == 0) {
            const bool bnd = (beg == 0 && dg == prevd) || (end == nvalid && dg == nextd);
            float* p = mh + (size_t)dg * D + wv * 32 + col;
            if (bnd) { atomicAdd(p, s0); atomicAdd(p + 16, s1); }
            else     { p[0] = s0; p[16] = s1; }
        }
    }
}

// ---------------- mh -> msum: msum = mh@Wm2 + cnt*bm2 ----------------
__global__ __launch_bounds__(NT, 4) void mh2msum_kernel(
    const float* __restrict__ mh, const int* __restrict__ cnt,
    const ushort_t* __restrict__ W2p, const float* __restrict__ bm2,
    float* __restrict__ msum, int Nn)
{
    __shared__ __align__(16) ushort_t lds[2 * 64 * 64];   // 16 KB
    __shared__ int s_cnt[64];

    const int t    = threadIdx.x;
    const int lane = t & 63;
    const int wv   = t >> 6;
    const int col  = lane & 15;
    const int g    = lane >> 4;
    const int n0   = blockIdx.x * 64;

    if (t < 64) s_cnt[t] = (n0 + t < Nn) ? cnt[n0 + t] : 0;

    #pragma unroll
    for (int it = 0; it < 4; ++it) {
        const int gidx = it * 256 + t;
        const int row  = gidx >> 4;
        const int gr   = gidx & 15;
        const int pair = gr >> 3, s = gr & 7;
        const int sP   = s ^ (row & 7);
        const int gn   = n0 + row;
        union { ushort_t us[8]; short8v v; } pk;
        if (gn < Nn) {
            const size_t off = (size_t)gn * D + gr * 8;
            float4 m0 = *(const float4*)(mh + off);
            float4 m1 = *(const float4*)(mh + off + 4);
            pk.us[0] = f2bf(m0.x); pk.us[1] = f2bf(m0.y);
            pk.us[2] = f2bf(m0.z); pk.us[3] = f2bf(m0.w);
            pk.us[4] = f2bf(m1.x); pk.us[5] = f2bf(m1.y);
            pk.us[6] = f2bf(m1.z); pk.us[7] = f2bf(m1.w);
        } else {
            #pragma unroll
            for (int j = 0; j < 8; ++j) pk.us[j] = 0;
        }
        *(short8v*)&lds[(pair * 64 + row) * 64 + sP * 8] = pk.v;
    }
    __syncthreads();

    f32x4 acc[4][2];
    {
        const float bv0 = bm2[wv * 32 + col];
        const float bv1 = bm2[wv * 32 + 16 + col];
        #pragma unroll
        for (int rt = 0; rt < 4; ++rt)
            #pragma unroll
            for (int r = 0; r < 4; ++r) {
                const float cn = (float)s_cnt[rt * 16 + g * 4 + r];
                acc[rt][0][r] = cn * bv0;
                acc[rt][1][r] = cn * bv1;
            }
    }
    #pragma unroll
    for (int c = 0; c < 4; ++c) {
        short8v b0 = *(const short8v*)&W2p[(size_t)(wv * 32 + col) * HD + c * 32 + g * 8];
        short8v b1 = *(const short8v*)&W2p[(size_t)(wv * 32 + 16 + col) * HD + c * 32 + g * 8];
        short8v a[4];
        #pragma unroll
        for (int rt = 0; rt < 4; ++rt) {
            const int row = rt * 16 + col;
            const int sP = (((c & 1) << 2) + g) ^ (row & 7);
            a[rt] = *(const short8v*)&lds[((c >> 1) * 64 + row) * 64 + sP * 8];
        }
        #pragma unroll
        for (int rt = 0; rt < 4; ++rt) {
            acc[rt][0] = __builtin_amdgcn_mfma_f32_16x16x32_bf16(a[rt], b0, acc[rt][0], 0, 0, 0);
            acc[rt][1] = __builtin_amdgcn_mfma_f32_16x16x32_bf16(a[rt], b1, acc[rt][1], 0, 0, 0);
        }
    }

    #pragma unroll
    for (int rt = 0; rt < 4; ++rt)
        #pragma unroll
        for (int r = 0; r < 4; ++r) {
            const int row = rt * 16 + g * 4 + r;
            const int gn = n0 + row;
            if (gn < Nn) {
                msum[(size_t)gn * D + wv * 32 + col]      = acc[rt][0][r];
                msum[(size_t)gn * D + wv * 32 + 16 + col] = acc[rt][1][r];
            }
        }
}

// ---------------- node kernel: MFMA bf16 update MLP ----------------
__global__ __launch_bounds__(NT, 4) void node_mfma_kernel(
    const float* __restrict__ f, const float* __restrict__ msum,
    const ushort_t* __restrict__ Wu1p, const float* __restrict__ bu1,
    const ushort_t* __restrict__ Wu2p, const float* __restrict__ bu2,
    float* __restrict__ out, int Nn)
{
    __shared__ __align__(16) ushort_t lds[2 * 64 * 64];

    const int t    = threadIdx.x;
    const int lane = t & 63;
    const int wv   = t >> 6;
    const int col  = lane & 15;
    const int g    = lane >> 4;
    const int n0   = blockIdx.x * 64;

    #pragma unroll
    for (int it = 0; it < 4; ++it) {
        const int gidx = it * 256 + t;
        const int row  = gidx >> 4;
        const int gr   = gidx & 15;
        const int pair = gr >> 3, s = gr & 7;
        const int sP   = s ^ (row & 7);
        const int gn   = n0 + row;
        union { ushort_t us[8]; short8v v; } pk;
        if (gn < Nn) {
            const size_t off = (size_t)gn * D + gr * 8;
            float4 m0 = *(const float4*)(msum + off);
            float4 m1 = *(const float4*)(msum + off + 4);
            float4 f0 = *(const float4*)(f + off);
            float4 f1 = *(const float4*)(f + off + 4);
            pk.us[0] = f2bf(m0.x + f0.x); pk.us[1] = f2bf(m0.y + f0.y);
            pk.us[2] = f2bf(m0.z + f0.z); pk.us[3] = f2bf(m0.w + f0.w);
            pk.us[4] = f2bf(m1.x + f1.x); pk.us[5] = f2bf(m1.y + f1.y);
            pk.us[6] = f2bf(m1.z + f1.z); pk.us[7] = f2bf(m1.w + f1.w);
        } else {
            #pragma unroll
            for (int j = 0; j < 8; ++j) pk.us[j] = 0;
        }
        *(short8v*)&lds[(pair * 64 + row) * 64 + sP * 8] = pk.v;
    }

    const size_t wrow0 = (size_t)(wv * 32 + col) * HD;
    const size_t wrow1 = (size_t)(wv * 32 + 16 + col) * HD;
    short8v nb0 = *(const short8v*)&Wu1p[wrow0 + g * 8];
    short8v nb1 = *(const short8v*)&Wu1p[wrow1 + g * 8];

    __syncthreads();

    f32x4 acc[4][2];
    {
        float bv0 = bu1[wv * 32 + col];
        float bv1 = bu1[wv * 32 + 16 + col];
        #pragma unroll
        for (int rt = 0; rt < 4; ++rt) {
            acc[rt][0] = (f32x4){bv0, bv0, bv0, bv0};
            acc[rt][1] = (f32x4){bv1, bv1, bv1, bv1};
        }
    }
    #pragma unroll
    for (int c = 0; c < 4; ++c) {
        short8v b0 = nb0, b1 = nb1;
        if (c + 1 < 4) {
            nb0 = *(const short8v*)&Wu1p[wrow0 + (c + 1) * 32 + g * 8];
            nb1 = *(const short8v*)&Wu1p[wrow1 + (c + 1) * 32 + g * 8];
        }
        short8v a[4];
        #pragma unroll
        for (int rt = 0; rt < 4; ++rt) {
            const int row = rt * 16 + col;
            const int sP = (((c & 1) << 2) + g) ^ (row & 7);
            a[rt] = *(const short8v*)&lds[((c >> 1) * 64 + row) * 64 + sP * 8];
        }
        #pragma unroll
        for (int rt = 0; rt < 4; ++rt) {
            acc[rt][0] = __builtin_amdgcn_mfma_f32_16x16x32_bf16(a[rt], b0, acc[rt][0], 0, 0, 0);
            acc[rt][1] = __builtin_amdgcn_mfma_f32_16x16x32_bf16(a[rt], b1, acc[rt][1], 0, 0, 0);
        }
    }
    __syncthreads();

    const int ph = wv >> 1;
    #pragma unroll
    for (int rt = 0; rt < 4; ++rt)
        #pragma unroll
        for (int j = 0; j < 2; ++j)
            #pragma unroll
            for (int r = 0; r < 4; ++r) {
                const int row = rt * 16 + g * 4 + r;
                float v = fmaxf(acc[rt][j][r], 0.f);
                unsigned int pk2 = cvt_pk_bf16(v, v);
                const int sH = (((wv & 1) << 2) + j * 2 + (col >> 3)) ^ (row & 7);
                lds[(ph * 64 + row) * 64 + sH * 8 + (col & 7)] = (ushort_t)pk2;
            }
    __syncthreads();

    const size_t w2r0 = (size_t)(wv * 32 + col) * HD;
    const size_t w2r1 = (size_t)(wv * 32 + 16 + col) * HD;
    short8v m0 = *(const short8v*)&Wu2p[w2r0 + g * 8];
    short8v m1 = *(const short8v*)&Wu2p[w2r1 + g * 8];
    f32x4 acc2[4][2];
    {
        float bv0 = bu2[wv * 32 + col];
        float bv1 = bu2[wv * 32 + 16 + col];
        #pragma unroll
        for (int rt = 0; rt < 4; ++rt) {
            acc2[rt][0] = (f32x4){bv0, bv0, bv0, bv0};
            acc2[rt][1] = (f32x4){bv1, bv1, bv1, bv1};
        }
    }
    #pragma unroll
    for (int c = 0; c < 4; ++c) {
        short8v b0 = m0, b1 = m1;
        if (c + 1 < 4) {
            m0 = *(const short8v*)&Wu2p[w2r0 + (c + 1) * 32 + g * 8];
            m1 = *(const short8v*)&Wu2p[w2r1 + (c + 1) * 32 + g * 8];
        }
        short8v a[4];
        #pragma unroll
        for (int rt = 0; rt < 4; ++rt) {
            const int row = rt * 16 + col;
            const int sP = (((c & 1) << 2) + g) ^ (row & 7);
            a[rt] = *(const short8v*)&lds[((c >> 1) * 64 + row) * 64 + sP * 8];
        }
        #pragma unroll
        for (int rt = 0; rt < 4; ++rt) {
            acc2[rt][0] = __builtin_amdgcn_mfma_f32_16x16x32_bf16(a[rt], b0, acc2[rt][0], 0, 0, 0);
            acc2[rt][1] = __builtin_amdgcn_mfma_f32_16x16x32_bf16(a[rt], b1, acc2[rt][1], 0, 0, 0);
        }
    }

    #pragma unroll
    for (int rt = 0; rt < 4; ++rt)
        #pragma unroll
        for (int r = 0; r < 4; ++r) {
            const int row = rt * 16 + g * 4 + r;
            const int gn = n0 + row;
            if (gn < Nn) {
                out[(size_t)gn * D + wv * 32 + col]      = acc2[rt][0][r];
                out[(size_t)gn * D + wv * 32 + 16 + col] = acc2[rt][1][r];
            }
        }
}

// ================= fallback kernels (bf16 pk-atomic path; unchanged) =================

__global__ void repack_kernel(const float* __restrict__ Wm1, const float* __restrict__ Wm2,
                              ushort_t* __restrict__ W1p, ushort_t* __restrict__ W2p) {
    int idx = blockIdx.x * 256 + threadIdx.x;
    const int n1 = 128 * KP1;
    if (idx < n1) {
        int n = idx / KP1, k = idx % KP1;
        W1p[idx] = f2bf((k < MSG_IN) ? Wm1[(size_t)k * HD + n] : 0.f);
    } else {
        int i2 = idx - n1;
        if (i2 < HD * D) {
            int n = i2 / HD, k = i2 % HD;
            W2p[i2] = f2bf(Wm2[(size_t)k * D + n]);
        }
    }
}

__global__ void fconv_kernel(const float* __restrict__ f, ushort_t* __restrict__ fb, int n8) {
    int i = blockIdx.x * 256 + threadIdx.x;
    if (i < n8) {
        float4 v0 = *(const float4*)(f + (size_t)i * 8);
        float4 v1 = *(const float4*)(f + (size_t)i * 8 + 4);
        union { ushort_t us[8]; short8v v; } pk;
        pk.us[0] = f2bf(v0.x); pk.us[1] = f2bf(v0.y);
        pk.us[2] = f2bf(v0.z); pk.us[3] = f2bf(v0.w);
        pk.us[4] = f2bf(v1.x); pk.us[5] = f2bf(v1.y);
        pk.us[6] = f2bf(v1.z); pk.us[7] = f2bf(v1.w);
        *(short8v*)(fb + (size_t)i * 8) = pk.v;
    }
}

__global__ __launch_bounds__(NT, 4) void edge_mfma_kernel(
    const ushort_t* __restrict__ fbf, const float* __restrict__ x,
    const float* __restrict__ w, const int* __restrict__ src,
    const int* __restrict__ dst,
    const ushort_t* __restrict__ W1p, const float* __restrict__ bm1,
    const ushort_t* __restrict__ W2p, const float* __restrict__ bm2,
    ushort_t* msum, int E)
{
    __shared__ __align__(16) ushort_t lds[LDS1];
    __shared__ int s_dst[EB];

    const int t    = threadIdx.x;
    const int lane = t & 63;
    const int wv   = t >> 6;
    const int e0   = blockIdx.x * EB;

    if (t < EB) s_dst[t] = (e0 + t < E) ? dst[e0 + t] : 0;
    {
        const int el8 = lane >> 3;
        const int s   = lane & 7;
        const int sl  = s ^ el8;
        const int geA = min(e0 + wv * 16 + el8,     E - 1);
        const int geB = min(e0 + wv * 16 + 8 + el8, E - 1);
        const int nsA = src[geA], ndA = dst[geA];
        const int nsB = src[geB], ndB = dst[geB];
        #pragma unroll
        for (int p = 0; p < 4; ++p) {
            const int n0 = (p < 2) ? nsA : ndA;
            const int n1 = (p < 2) ? nsB : ndB;
            const ushort_t* g0 = fbf + (size_t)n0 * D + (p & 1) * 64 + sl * 8;
            const ushort_t* g1 = fbf + (size_t)n1 * D + (p & 1) * 64 + sl * 8;
            GLOAD_LDS16(g0, &lds[(p * EB + wv * 16    ) * 64]);
            GLOAD_LDS16(g1, &lds[(p * EB + wv * 16 + 8) * 64]);
        }
    }
    {
        const int el = lane >> 2, q = lane & 3;
        const int qp = q ^ (el & 3);
        const int ge = e0 + wv * 16 + el;
        const bool ok = ge < E;
        const int gc = min(ge, E - 1);
        union { ushort_t us[8]; short8v v; } pk;
        #pragma unroll
        for (int j = 0; j < 8; ++j) pk.us[j] = 0;
        if (ok) {
            if (q < 2) {
                float4 w0 = *(const float4*)(w + (size_t)gc * DE + q * 8);
                float4 w1 = *(const float4*)(w + (size_t)gc * DE + q * 8 + 4);
                pk.us[0] = f2bf(w0.x); pk.us[1] = f2bf(w0.y);
                pk.us[2] = f2bf(w0.z); pk.us[3] = f2bf(w0.w);
                pk.us[4] = f2bf(w1.x); pk.us[5] = f2bf(w1.y);
                pk.us[6] = f2bf(w1.z); pk.us[7] = f2bf(w1.w);
            } else if (q == 2) {
                const int ns = src[gc], nd = dst[gc];
                float dx = x[ns*3+0] - x[nd*3+0];
                float dy = x[ns*3+1] - x[nd*3+1];
                float dz = x[ns*3+2] - x[nd*3+2];
                pk.us[0] = f2bf(dx*dx + dy*dy + dz*dz);
            }
        }
        *(short8v*)&lds[CH8 + (wv * 16 + el) * 32 + qp * 8] = pk.v;
    }

    const int col = lane & 15;
    const int g   = lane >> 4;
    const size_t wrow0 = (size_t)(wv * 32 + col) * KP1;
    const size_t wrow1 = (size_t)(wv * 32 + 16 + col) * KP1;
    short8v nb0 = *(const short8v*)&W1p[wrow0 + g * 8];
    short8v nb1 = *(const short8v*)&W1p[wrow1 + g * 8];
    __syncthreads();

    f32x4 acc[4][2];
    {
        float bv0 = bm1[wv * 32 + col];
        float bv1 = bm1[wv * 32 + 16 + col];
        #pragma unroll
        for (int rt = 0; rt < 4; ++rt) {
            acc[rt][0] = (f32x4){bv0, bv0, bv0, bv0};
            acc[rt][1] = (f32x4){bv1, bv1, bv1, bv1};
        }
    }
    #pragma unroll
    for (int c = 0; c < 9; ++c) {
        short8v b0 = nb0, b1 = nb1;
        if (c + 1 < 9) {
            nb0 = *(const short8v*)&W1p[wrow0 + (c + 1) * 32 + g * 8];
            nb1 = *(const short8v*)&W1p[wrow1 + (c + 1) * 32 + g * 8];
        }
        short8v a[4];
        #pragma unroll
        for (int rt = 0; rt < 4; ++rt) {
            const int row = rt * 16 + col;
            if (c < 8) {
                const int sP = (((c & 1) << 2) + g) ^ (row & 7);
                a[rt] = *(const short8v*)&lds[((c >> 1) * EB + row) * 64 + sP * 8];
            } else {
                const int sP = g ^ (row & 3);
                a[rt] = *(const short8v*)&lds[CH8 + row * 32 + sP * 8];
            }
        }
        #pragma unroll
        for (int rt = 0; rt < 4; ++rt) {
            acc[rt][0] = __builtin_amdgcn_mfma_f32_16x16x32_bf16(a[rt], b0, acc[rt][0], 0, 0, 0);
            acc[rt][1] = __builtin_amdgcn_mfma_f32_16x16x32_bf16(a[rt], b1, acc[rt][1], 0, 0, 0);
        }
    }
    __syncthreads();

    const int ph = wv >> 1;
    #pragma unroll
    for (int rt = 0; rt < 4; ++rt)
        #pragma unroll
        for (int j = 0; j < 2; ++j)
            #pragma unroll
            for (int r = 0; r < 4; ++r) {
                const int row = rt * 16 + g * 4 + r;
                float v = fmaxf(acc[rt][j][r], 0.f);
                unsigned int pk2 = cvt_pk_bf16(v, v);
                const int sH = (((wv & 1) << 2) + j * 2 + (col >> 3)) ^ (row & 7);
                lds[(ph * EB + row) * 64 + sH * 8 + (col & 7)] = (ushort_t)pk2;
            }
    __syncthreads();

    const size_t w2r0 = (size_t)(wv * 32 + col) * HD;
    const size_t w2r1 = (size_t)(wv * 32 + 16 + col) * HD;
    short8v m0 = *(const short8v*)&W2p[w2r0 + g * 8];
    short8v m1 = *(const short8v*)&W2p[w2r1 + g * 8];
    f32x4 acc2[4][2];
    {
        float bv0 = bm2[wv * 32 + col];
        float bv1 = bm2[wv * 32 + 16 + col];
        #pragma unroll
        for (int rt = 0; rt < 4; ++rt) {
            acc2[rt][0] = (f32x4){bv0, bv0, bv0, bv0};
            acc2[rt][1] = (f32x4){bv1, bv1, bv1, bv1};
        }
    }
    #pragma unroll
    for (int c = 0; c < NCH2; ++c) {
        short8v b0 = m0, b1 = m1;
        if (c + 1 < NCH2) {
            m0 = *(const short8v*)&W2p[w2r0 + (c + 1) * 32 + g * 8];
            m1 = *(const short8v*)&W2p[w2r1 + (c + 1) * 32 + g * 8];
        }
        short8v a[4];
        #pragma unroll
        for (int rt = 0; rt < 4; ++rt) {
            const int row = rt * 16 + col;
            const int sP = (((c & 1) << 2) + g) ^ (row & 7);
            a[rt] = *(const short8v*)&lds[((c >> 1) * EB + row) * 64 + sP * 8];
        }
        #pragma unroll
        for (int rt = 0; rt < 4; ++rt) {
            acc2[rt][0] = __builtin_amdgcn_mfma_f32_16x16x32_bf16(a[rt], b0, acc2[rt][0], 0, 0, 0);
            acc2[rt][1] = __builtin_amdgcn_mfma_f32_16x16x32_bf16(a[rt], b1, acc2[rt][1], 0, 0, 0);
        }
    }

    const bool even = (col & 1) == 0;
    #pragma unroll
    for (int rt = 0; rt < 4; ++rt)
        #pragma unroll
        for (int r = 0; r < 4; ++r) {
            const int e  = rt * 16 + g * 4 + r;
            const int ge = e0 + e;
            const int dg = s_dst[e];
            #pragma unroll
            for (int j = 0; j < 2; ++j) {
                float v  = acc2[rt][j][r];
                float vn = __shfl_xor(v, 1, 64);
                if (even && ge < E) {
                    unsigned int pk2 = cvt_pk_bf16(v, vn);
                    ushort_t* p = msum + (size_t)dg * D + wv * 32 + j * 16 + col;
                    asm volatile("global_atomic_pk_add_bf16 %0, %1, off"
                                 :: "v"(p), "v"(pk2) : "memory");
                }
            }
        }
}

template<bool MB16>
__global__ __launch_bounds__(NT, 4) void node_kernel(
    const float* __restrict__ f, const void* __restrict__ msum_v,
    const float* __restrict__ Wu1, const float* __restrict__ bu1,
    const float* __restrict__ Wu2, const float* __restrict__ bu2,
    float* out, int Nn)
{
    __shared__ __align__(16) float hin[NB][HID_PAD];
    __shared__ __align__(16) float hid[NB][HID_PAD];
    const int t  = threadIdx.x;
    const int n0 = blockIdx.x * NB;
    const int nn = min(NB, Nn - n0);

    {
        #pragma unroll
        for (int it = 0; it < 4; ++it) {
            const int idx = it * 1024 + t * 4;
            const int e   = idx >> 7;
            const int cb  = idx & 127;
            if (e < nn) {
                const size_t off = (size_t)(n0 + e) * D + cb;
                float4 mv;
                if (MB16) {
                    uint2 pk = *(const uint2*)((const ushort_t*)msum_v + off);
                    mv.x = bf2f((ushort_t)(pk.x & 0xffffu));
                    mv.y = bf2f((ushort_t)(pk.x >> 16));
                    mv.z = bf2f((ushort_t)(pk.y & 0xffffu));
                    mv.w = bf2f((ushort_t)(pk.y >> 16));
                } else {
                    mv = *(const float4*)((const float*)msum_v + off);
                }
                float4 fv = *(const float4*)&f[off];
                float4 o = {mv.x + fv.x, mv.y + fv.y, mv.z + fv.z, mv.w + fv.w};
                *(float4*)&hin[e][cb] = o;
            }
        }
    }
    __syncthreads();

    const int tc = t & 15, te2 = (t >> 4) * 2, c0 = tc * 8;
    float a1[2][8];
    #pragma unroll
    for (int c = 0; c < 8; ++c) { float bv = bu1[c0 + c]; a1[0][c] = bv; a1[1][c] = bv; }
    for (int i = 0; i < D; i += 4) {
        float m0[4], m1[4];
        *(float4*)m0 = *(const float4*)&hin[te2][i];
        *(float4*)m1 = *(const float4*)&hin[te2 + 1][i];
        #pragma unroll
        for (int r = 0; r < 4; ++r) {
            float wr[8];
            *(float4*)&wr[0] = *(const float4*)(Wu1 + (size_t)(i + r) * HD + c0);
            *(float4*)&wr[4] = *(const float4*)(Wu1 + (size_t)(i + r) * HD + c0 + 4);
            #pragma unroll
            for (int c = 0; c < 8; ++c) { a1[0][c] += m0[r]*wr[c]; a1[1][c] += m1[r]*wr[c]; }
        }
    }
    #pragma unroll
    for (int j = 0; j < 2; ++j) {
        float v[8];
        #pragma unroll
        for (int c = 0; c < 8; ++c) v[c] = fmaxf(a1[j][c], 0.f);
        *(float4*)&hid[te2 + j][c0] = *(float4*)&v[0];
        *(float4*)&hid[te2 + j][c0 + 4] = *(float4*)&v[4];
    }
    __syncthreads();
    float a2[2][8];
    #pragma unroll
    for (int c = 0; c < 8; ++c) { float bv = bu2[c0 + c]; a2[0][c] = bv; a2[1][c] = bv; }
    for (int h = 0; h < HD; h += 4) {
        float m0[4], m1[4];
        *(float4*)m0 = *(const float4*)&hid[te2][h];
        *(float4*)m1 = *(const float4*)&hid[te2 + 1][h];
        #pragma unroll
        for (int r = 0; r < 4; ++r) {
            float wr[8];
            *(float4*)&wr[0] = *(const float4*)(Wu2 + (size_t)(h + r) * D + c0);
            *(float4*)&wr[4] = *(const float4*)(Wu2 + (size_t)(h + r) * D + c0 + 4);
            #pragma unroll
            for (int c = 0; c < 8; ++c) { a2[0][c] += m0[r]*wr[c]; a2[1][c] += m1[r]*wr[c]; }
        }
    }
    #pragma unroll
    for (int j = 0; j < 2; ++j) {
        int e = te2 + j, gn = n0 + e;
        if (e < nn) {
            *(float4*)(out + (size_t)gn * D + c0) = *(float4*)&a2[j][0];
            *(float4*)(out + (size_t)gn * D + c0 + 4) = *(float4*)&a2[j][4];
        }
    }
}

extern "C" void kernel_launch(void* const* d_in, const int* in_sizes, int n_in,
                              void* d_out, int out_size, void* d_ws, size_t ws_size,
                              hipStream_t stream) {
    const float* f   = (const float*)d_in[0];
    const float* x   = (const float*)d_in[1];
    const float* w   = (const float*)d_in[2];
    const int*   src = (const int*)d_in[3];
    const int*   dst = (const int*)d_in[4];
    const float* Wm1 = (const float*)d_in[5];
    const float* bm1 = (const float*)d_in[6];
    const float* Wm2 = (const float*)d_in[7];
    const float* bm2 = (const float*)d_in[8];
    const float* Wu1 = (const float*)d_in[9];
    const float* bu1 = (const float*)d_in[10];
    const float* Wu2 = (const float*)d_in[11];
    const float* bu2 = (const float*)d_in[12];

    const int Nn = in_sizes[0] / D;
    const int E  = in_sizes[3];

    const size_t wbytes  = (size_t)(128 * KP1 + HD * D) * sizeof(ushort_t);
    const size_t wubytes = (size_t)(2 * HD * D) * sizeof(ushort_t);
    auto align512 = [](size_t v) { return (v + 511) & ~(size_t)511; };
    char* wsb = (char*)d_ws;

    // ---------------- primary: linear-trick path (A fp8, B bf16) ----------------
    size_t off = 0;
    const size_t o_w    = off; off = align512(off + wbytes);
    const size_t o_wu   = off; off = align512(off + wubytes);
    const size_t o_fb   = off; off = align512(off + (size_t)Nn * D * 2);
    const size_t o_wbf  = off; off = align512(off + (size_t)E * DE * 2);
    const size_t o_af   = off; off = align512(off + (size_t)Nn * D);
    const size_t o_bf16 = off; off = align512(off + (size_t)Nn * D * 2);
    const size_t o_cnt  = off; off = align512(off + (size_t)Nn * 4);
    const size_t o_roff = off; off = align512(off + (size_t)Nn * 4);
    const size_t o_cur  = off; off = align512(off + (size_t)Nn * 4);
    const size_t o_perm = off; off = align512(off + (size_t)E * 4);
    const size_t o_sdst = off; off = align512(off + (size_t)E * 4);
    const size_t o_mh   = off; off = align512(off + (size_t)Nn * D * 4);
    const size_t o_ms   = off; off = align512(off + (size_t)Nn * D * 4);
    const size_t primary_total = off;

    if (ws_size >= primary_total) {
        ushort_t* W1p  = (ushort_t*)(wsb + o_w);
        ushort_t* W2p  = W1p + 128 * KP1;
        ushort_t* Wu1p = (ushort_t*)(wsb + o_wu);
        ushort_t* Wu2p = Wu1p + HD * D;
        ushort_t* fbf  = (ushort_t*)(wsb + o_fb);
        ushort_t* wbf  = (ushort_t*)(wsb + o_wbf);
        uchar_t*  Af   = (uchar_t*)(wsb + o_af);
        ushort_t* Bf16 = (ushort_t*)(wsb + o_bf16);
        int* cnt       = (int*)(wsb + o_cnt);
        int* roff      = (int*)(wsb + o_roff);
        int* cursor    = (int*)(wsb + o_cur);
        int* perm      = (int*)(wsb + o_perm);
        int* sdst      = (int*)(wsb + o_sdst);
        float* mh      = (float*)(wsb + o_mh);
        float* msum    = (float*)(wsb + o_ms);

        const int n8  = Nn * D / 8;
        const int nw8 = E * DE / 8;
        const int ntiles = (E + EB - 1) / EB;
        const int nblk   = (Nn + 63) / 64;
        hipMemsetAsync(cnt, 0, (size_t)Nn * 4, stream);
        fused_pre_kernel<<<dim3(1024), dim3(256), 0, stream>>>(
            Wm1, Wm2, Wu1, Wu2, W1p, W2p, Wu1p, Wu2p, f, fbf, w, wbf, dst, cnt, n8, nw8, E);
        scan_kernel<<<dim3(1), dim3(1024), 0, stream>>>(cnt, roff, cursor, Nn);
        scatter_kernel<<<dim3((E + 255) / 256), dim3(256), 0, stream>>>(
            dst, cursor, roff, cnt, perm, sdst, mh, E, Nn);
        ab_kernel<<<dim3(nblk), dim3(NT), 0, stream>>>(fbf, W1p, Af, Bf16, Nn);
        edge_lin_kernel<<<dim3(ntiles), dim3(NT), 0, stream>>>(
            Af, Bf16, x, wbf, src, perm, sdst, W1p, bm1, mh, E);
        mh2msum_kernel<<<dim3(nblk), dim3(NT), 0, stream>>>(mh, cnt, W2p, bm2, msum, Nn);
        node_mfma_kernel<<<dim3(nblk), dim3(NT), 0, stream>>>(
            f, msum, Wu1p, bu1, Wu2p, bu2, (float*)d_out, Nn);
        return;
    }

    // ---------------- fallback: bf16 pk-atomic path ----------------
    size_t off2 = 0;
    const size_t p_w  = off2; off2 = align512(off2 + wbytes);
    const size_t p_fb = off2; off2 = align512(off2 + (size_t)Nn * D * 2);
    const size_t p_ms = off2; off2 = align512(off2 + (size_t)Nn * D * 2);
    if (ws_size >= off2) {
        ushort_t* W1p  = (ushort_t*)(wsb + p_w);
        ushort_t* W2p  = W1p + 128 * KP1;
        ushort_t* fbf  = (ushort_t*)(wsb + p_fb);
        ushort_t* msum = (ushort_t*)(wsb + p_ms);
        const int rp_elems = 128 * KP1 + HD * D;
        hipMemsetAsync(msum, 0, (size_t)Nn * D * 2, stream);
        repack_kernel<<<dim3((rp_elems + 255) / 256), dim3(256), 0, stream>>>(Wm1, Wm2, W1p, W2p);
        const int n8 = Nn * D / 8;
        fconv_kernel<<<dim3((n8 + 255) / 256), dim3(256), 0, stream>>>(f, fbf, n8);
        edge_mfma_kernel<<<dim3((E + EB - 1) / EB), dim3(NT), 0, stream>>>(
            fbf, x, w, src, dst, W1p, bm1, W2p, bm2, msum, E);
        node_kernel<true><<<dim3((Nn + NB - 1) / NB), dim3(NT), 0, stream>>>(
            f, msum, Wu1, bu1, Wu2, bu2, (float*)d_out, Nn);
        return;
    }
}

// Round 20
// 261.036 us; speedup vs baseline: 1.5956x; 1.0263x over previous
//
#include <hip/hip_runtime.h>
#include <hip/hip_fp8.h>

#define D 128
#define HD 128
#define DE 16
#define MSG_IN 273
#define EB 64        // edges per tile
#define NT 256
#define KP1 288      // padded msg K = 9 chunks of 32
#define NCH2 4
#define NB 32
#define HID_PAD 132
#define CH8 (4 * EB * 64)
#define LDS1 (4 * EB * 64 + EB * 32)
// edge_lin LDS layout (bytes): A fp8 [0,8192) ; B bf16 [8192,24576) ; c8 bf16 [24576,28672)
#define OB 8192
#define OC 24576

typedef __attribute__((ext_vector_type(8))) short short8v;
typedef __attribute__((ext_vector_type(4))) float f32x4;
typedef unsigned short ushort_t;
typedef unsigned char uchar_t;

#define GLOAD_LDS16(gp, lp) \
    __builtin_amdgcn_global_load_lds((const __attribute__((address_space(1))) unsigned int*)(gp), \
                                     (__attribute__((address_space(3))) unsigned int*)(lp), 16, 0, 0)

__device__ __forceinline__ unsigned short f2bf(float v) {
    unsigned int u = __builtin_bit_cast(unsigned int, v);
    u += 0x7fffu + ((u >> 16) & 1u);
    return (unsigned short)(u >> 16);
}
__device__ __forceinline__ float bf2f(ushort_t u) {
    return __builtin_bit_cast(float, (unsigned int)u << 16);
}
__device__ __forceinline__ unsigned int cvt_pk_bf16(float lo, float hi) {
    unsigned int r;
    asm("v_cvt_pk_bf16_f32 %0, %1, %2" : "=v"(r) : "v"(lo), "v"(hi));
    return r;
}
__device__ __forceinline__ uchar_t f8e(float v) {   // f32 -> e4m3 (HIP library)
    __hip_fp8_e4m3 t(v);
    return (uchar_t)t.__x;
}
// e4m3fn -> f32: normals 2^(e-7)(1+m/8); subnormals m/8*2^-6; sign bit preserved.
__device__ __forceinline__ float f8d(unsigned b) {
    unsigned t = ((b & 0x7fu) << 20) | ((b & 0x80u) << 24);
    return __builtin_bit_cast(float, t) * 0x1p120f;
}

// ---------------- fused prepass: repack weights, w->bf16, dst hist ----------------
__global__ void fused_pre_kernel(const float* __restrict__ Wm1, const float* __restrict__ Wm2,
                                 const float* __restrict__ Wu1, const float* __restrict__ Wu2,
                                 ushort_t* __restrict__ W1p, ushort_t* __restrict__ W2p,
                                 ushort_t* __restrict__ Wu1p, ushort_t* __restrict__ Wu2p,
                                 const float* __restrict__ w, ushort_t* __restrict__ wbf,
                                 const int* __restrict__ dst, int* __restrict__ cnt,
                                 int nw8, int E) {
    const int gid    = blockIdx.x * 256 + threadIdx.x;
    const int stride = gridDim.x * 256;
    const int rp1 = 128 * KP1;
    const int rp2 = rp1 + HD * D;
    const int rp_elems = rp2 + 2 * HD * D;
    for (int i = gid; i < rp_elems; i += stride) {
        if (i < rp1) {
            int n = i / KP1, k = i % KP1;
            W1p[i] = f2bf((k < MSG_IN) ? Wm1[(size_t)k * HD + n] : 0.f);
        } else if (i < rp2) {
            int i2 = i - rp1;
            int n = i2 / HD, k = i2 % HD;
            W2p[i2] = f2bf(Wm2[(size_t)k * D + n]);
        } else {
            int i2 = (i - rp2);
            const bool second = i2 >= HD * D;
            if (second) i2 -= HD * D;
            int n = i2 / HD, k = i2 % HD;
            if (second) Wu2p[i2] = f2bf(Wu2[(size_t)k * D + n]);
            else        Wu1p[i2] = f2bf(Wu1[(size_t)k * HD + n]);
        }
    }
    for (int i = gid; i < nw8; i += stride) {
        float4 v0 = *(const float4*)(w + (size_t)i * 8);
        float4 v1 = *(const float4*)(w + (size_t)i * 8 + 4);
        union { ushort_t us[8]; short8v v; } pk;
        pk.us[0] = f2bf(v0.x); pk.us[1] = f2bf(v0.y);
        pk.us[2] = f2bf(v0.z); pk.us[3] = f2bf(v0.w);
        pk.us[4] = f2bf(v1.x); pk.us[5] = f2bf(v1.y);
        pk.us[6] = f2bf(v1.z); pk.us[7] = f2bf(v1.w);
        *(short8v*)(wbf + (size_t)i * 8) = pk.v;
    }
    for (int i = gid; i < E; i += stride) atomicAdd(&cnt[dst[i]], 1);
}

// ---------------- CSR build: parallel scan -> scatter + selective zero (of mh) ----------------
__global__ __launch_bounds__(1024) void scan_kernel(const int* __restrict__ cnt,
                                                    int* __restrict__ roff,
                                                    int* __restrict__ cursor, int Nn) {
    __shared__ int wsum[16];
    const int t = threadIdx.x, l = t & 63, wid = t >> 6;
    int running = 0;
    for (int base = 0; base < Nn; base += 4096) {
        const int i0 = base + t * 4;
        int v0 = 0, v1 = 0, v2 = 0, v3 = 0;
        if (i0 + 3 < Nn) {
            int4 v = *(const int4*)(cnt + i0);
            v0 = v.x; v1 = v.y; v2 = v.z; v3 = v.w;
        } else {
            if (i0 + 0 < Nn) v0 = cnt[i0 + 0];
            if (i0 + 1 < Nn) v1 = cnt[i0 + 1];
            if (i0 + 2 < Nn) v2 = cnt[i0 + 2];
        }
        const int vsum = v0 + v1 + v2 + v3;
        int s = vsum;
        #pragma unroll
        for (int off = 1; off < 64; off <<= 1) {
            int u = __shfl_up(s, off, 64);
            if (l >= off) s += u;
        }
        if (l == 63) wsum[wid] = s;
        __syncthreads();
        if (wid == 0 && l < 16) {
            int xv = wsum[l];
            #pragma unroll
            for (int off = 1; off < 16; off <<= 1) {
                int u = __shfl_up(xv, off, 64);
                if (l >= off) xv += u;
            }
            wsum[l] = xv;
        }
        __syncthreads();
        const int prev  = (wid > 0) ? wsum[wid - 1] : 0;
        const int total = wsum[15];
        int ex = running + prev + (s - vsum);
        if (i0 + 0 < Nn) { roff[i0 + 0] = ex; cursor[i0 + 0] = ex; } ex += v0;
        if (i0 + 1 < Nn) { roff[i0 + 1] = ex; cursor[i0 + 1] = ex; } ex += v1;
        if (i0 + 2 < Nn) { roff[i0 + 2] = ex; cursor[i0 + 2] = ex; } ex += v2;
        if (i0 + 3 < Nn) { roff[i0 + 3] = ex; cursor[i0 + 3] = ex; }
        running += total;
        __syncthreads();
    }
}

__global__ void scatter_kernel(const int* __restrict__ dst, int* cursor,
                               const int* __restrict__ roff, const int* __restrict__ cnt,
                               int* __restrict__ perm, int* __restrict__ sdst,
                               float* __restrict__ mh, int E, int Nn) {
    const int gid    = blockIdx.x * 256 + threadIdx.x;
    const int stride = gridDim.x * 256;
    for (int i = gid; i < E; i += stride) {
        int d = dst[i];
        int s = atomicAdd(&cursor[d], 1);
        perm[s] = i;
        sdst[s] = d;
    }
    for (int n = gid; n < Nn; n += stride) {
        const int c = cnt[n];
        const int r = roff[n];
        const bool need0 = (c == 0) || (r / EB != (r + c - 1) / EB);
        if (need0) {
            float4 z = {0.f, 0.f, 0.f, 0.f};
            float* p = mh + (size_t)n * D;
            #pragma unroll
            for (int k = 0; k < 32; ++k) *(float4*)(p + k * 4) = z;
        }
    }
}

// ---------------- AB precompute: A = f@Wm1[0:128] -> fp8, B = f@Wm1[128:256] -> bf16 ----------------
// Reads f (fp32) directly; converts to bf16 during staging.
__global__ __launch_bounds__(NT, 4) void ab_kernel(
    const float* __restrict__ f,
    const ushort_t* __restrict__ W1p,
    uchar_t* __restrict__ Af, ushort_t* __restrict__ Bf16, int Nn)
{
    __shared__ __align__(16) ushort_t lds[2 * 64 * 64];   // 16 KB

    const int t    = threadIdx.x;
    const int lane = t & 63;
    const int wv   = t >> 6;
    const int col  = lane & 15;
    const int g    = lane >> 4;
    const int n0   = blockIdx.x * 64;

    // stage f rows (fp32 -> bf16) into swizzled [pair][64][64]
    #pragma unroll
    for (int it = 0; it < 4; ++it) {
        const int gidx = it * 256 + t;
        const int row  = gidx >> 4;
        const int gr   = gidx & 15;
        const int pair = gr >> 3, s = gr & 7;
        const int sP   = s ^ (row & 7);
        const int gn   = min(n0 + row, Nn - 1);
        const size_t off = (size_t)gn * D + gr * 8;
        float4 v0 = *(const float4*)(f + off);
        float4 v1 = *(const float4*)(f + off + 4);
        union { ushort_t us[8]; short8v v; } pk;
        pk.us[0] = f2bf(v0.x); pk.us[1] = f2bf(v0.y);
        pk.us[2] = f2bf(v0.z); pk.us[3] = f2bf(v0.w);
        pk.us[4] = f2bf(v1.x); pk.us[5] = f2bf(v1.y);
        pk.us[6] = f2bf(v1.z); pk.us[7] = f2bf(v1.w);
        *(short8v*)&lds[(pair * 64 + row) * 64 + sP * 8] = pk.v;
    }
    __syncthreads();

    const bool even = (col & 1) == 0;
    #pragma unroll
    for (int half = 0; half < 2; ++half) {          // 0: A (fp8), 1: B (bf16)
        f32x4 acc[4][2];
        #pragma unroll
        for (int rt = 0; rt < 4; ++rt) {
            acc[rt][0] = (f32x4){0.f, 0.f, 0.f, 0.f};
            acc[rt][1] = (f32x4){0.f, 0.f, 0.f, 0.f};
        }
        const int kbase = half * 128;
        #pragma unroll
        for (int c = 0; c < 4; ++c) {
            short8v b0 = *(const short8v*)&W1p[(size_t)(wv * 32 + col) * KP1 + kbase + c * 32 + g * 8];
            short8v b1 = *(const short8v*)&W1p[(size_t)(wv * 32 + 16 + col) * KP1 + kbase + c * 32 + g * 8];
            short8v a[4];
            #pragma unroll
            for (int rt = 0; rt < 4; ++rt) {
                const int row = rt * 16 + col;
                const int sP = (((c & 1) << 2) + g) ^ (row & 7);
                a[rt] = *(const short8v*)&lds[((c >> 1) * 64 + row) * 64 + sP * 8];
            }
            #pragma unroll
            for (int rt = 0; rt < 4; ++rt) {
                acc[rt][0] = __builtin_amdgcn_mfma_f32_16x16x32_bf16(a[rt], b0, acc[rt][0], 0, 0, 0);
                acc[rt][1] = __builtin_amdgcn_mfma_f32_16x16x32_bf16(a[rt], b1, acc[rt][1], 0, 0, 0);
            }
        }
        #pragma unroll
        for (int rt = 0; rt < 4; ++rt)
            #pragma unroll
            for (int j = 0; j < 2; ++j)
                #pragma unroll
                for (int r = 0; r < 4; ++r) {
                    const int row = rt * 16 + g * 4 + r;
                    const int gn = n0 + row;
                    float v  = acc[rt][j][r];
                    float vn = __shfl_xor(v, 1, 64);
                    if (even && gn < Nn) {
                        const int ca = wv * 32 + j * 16 + col;
                        if (half == 0) {
                            ushort_t pk = (ushort_t)f8e(v) | ((ushort_t)f8e(vn) << 8);
                            *(ushort_t*)(Af + (size_t)gn * D + ca) = pk;
                        } else {
                            *(unsigned int*)(Bf16 + (size_t)gn * D + ca) = cvt_pk_bf16(v, vn);
                        }
                    }
                }
    }
}

// ---------------- edge kernel: A[src](fp8) + B[dst](dedup bf16) + C_e MFMA,
//                  relu, fused segment reduce -> mh (f32)  [unchanged from r19] ----------------
__global__ __launch_bounds__(NT, 4) void edge_lin_kernel(
    const uchar_t* __restrict__ Af, const ushort_t* __restrict__ Bf16,
    const float* __restrict__ x, const ushort_t* __restrict__ wbf,
    const int* __restrict__ src,
    const int* __restrict__ perm, const int* __restrict__ sdst,
    const ushort_t* __restrict__ W1p, const float* __restrict__ bm1,
    float* __restrict__ mh, int E)
{
    __shared__ __align__(16) uchar_t lds8[28672];   // A 8K | B 16K | c8 4K
    __shared__ int s_rid[EB];
    __shared__ int s_dgs[EB];

    const int t    = threadIdx.x;
    const int lane = t & 63;
    const int wv   = t >> 6;
    const int e0   = blockIdx.x * EB;
    const int nvalid = min(EB, E - e0);

    const int myd  = (e0 + lane < E) ? sdst[e0 + lane] : -1;
    const int prevd = (e0 > 0) ? sdst[e0 - 1] : -2;
    const int nextd = (e0 + EB < E) ? sdst[e0 + EB] : -2;

    const int dprev_l = __shfl_up(myd, 1, 64);
    const bool head = (lane == 0) || (myd != dprev_l);
    const unsigned long long mask = __ballot(head && (lane < nvalid));
    const unsigned long long le = (lane == 63) ? ~0ull : ((1ull << (lane + 1)) - 1ull);
    const int rid = (int)__popcll(mask & le) - 1;
    const int ndist = (int)__popcll(mask);
    s_rid[lane] = (rid < 0) ? 0 : rid;
    if (head && lane < nvalid) s_dgs[rid] = myd;

    {
        const int el8 = lane >> 3;
        const int s   = lane & 7;
        const int sl  = s ^ el8;
        const int slA = min(e0 + wv * 16 + el8,     E - 1);
        const int slB = min(e0 + wv * 16 + 8 + el8, E - 1);
        const int nsA = src[perm[slA]];
        const int nsB = src[perm[slB]];
        GLOAD_LDS16(Af + (size_t)nsA * D + sl * 16, &lds8[(wv * 16    ) * 128]);
        GLOAD_LDS16(Af + (size_t)nsB * D + sl * 16, &lds8[(wv * 16 + 8) * 128]);
    }
    {
        const int ntask = ndist * 16;
        for (int idx = t; idx < ntask; idx += NT) {
            const int rowr = idx >> 4;
            const int gr   = idx & 15;
            const int dg   = s_dgs[rowr];
            uint4 v = *(const uint4*)(Bf16 + (size_t)dg * D + gr * 8);
            const int phys = gr ^ (rowr & 15);
            *(uint4*)&lds8[OB + rowr * 256 + phys * 16] = v;
        }
    }
    {
        const int el = lane >> 2, q = lane & 3;
        const int qp = q ^ (el & 3);
        const int slot = e0 + wv * 16 + el;
        const bool ok = slot < E;
        const int sc = min(slot, E - 1);
        const int ge = perm[sc];
        union { ushort_t us[8]; short8v v; } pk;
        #pragma unroll
        for (int j = 0; j < 8; ++j) pk.us[j] = 0;
        if (ok) {
            if (q < 2) {
                pk.v = *(const short8v*)(wbf + (size_t)ge * DE + q * 8);
            } else if (q == 2) {
                const int ns = src[ge], nd = sdst[sc];
                float dx = x[ns*3+0] - x[nd*3+0];
                float dy = x[ns*3+1] - x[nd*3+1];
                float dz = x[ns*3+2] - x[nd*3+2];
                pk.us[0] = f2bf(dx*dx + dy*dy + dz*dz);
            }
        }
        *(short8v*)&lds8[OC + (wv * 16 + el) * 64 + qp * 16] = pk.v;
    }

    const int col = lane & 15;
    const int g   = lane >> 4;

    short8v bc0 = *(const short8v*)&W1p[(size_t)(wv * 32 + col) * KP1 + 256 + g * 8];
    short8v bc1 = *(const short8v*)&W1p[(size_t)(wv * 32 + 16 + col) * KP1 + 256 + g * 8];

    __syncthreads();   // B0

    f32x4 acc[4][2];
    {
        float bv0 = bm1[wv * 32 + col];
        float bv1 = bm1[wv * 32 + 16 + col];
        #pragma unroll
        for (int rt = 0; rt < 4; ++rt) {
            acc[rt][0] = (f32x4){bv0, bv0, bv0, bv0};
            acc[rt][1] = (f32x4){bv1, bv1, bv1, bv1};
        }
    }
    #pragma unroll
    for (int rt = 0; rt < 4; ++rt) {
        const int row = rt * 16 + col;
        const int sP8 = g ^ (row & 3);
        short8v a = *(const short8v*)&lds8[OC + row * 64 + sP8 * 16];
        acc[rt][0] = __builtin_amdgcn_mfma_f32_16x16x32_bf16(a, bc0, acc[rt][0], 0, 0, 0);
        acc[rt][1] = __builtin_amdgcn_mfma_f32_16x16x32_bf16(a, bc1, acc[rt][1], 0, 0, 0);
    }

    float h[4][2][4];
    #pragma unroll
    for (int rt = 0; rt < 4; ++rt) {
        #pragma unroll
        for (int r = 0; r < 4; ++r) {
            const int row = rt * 16 + g * 4 + r;
            const int rd  = s_rid[row];
            #pragma unroll
            for (int j = 0; j < 2; ++j) {
                const int ca = wv * 32 + j * 16 + col;
                const uchar_t ab = lds8[row * 128 + (((ca >> 4) ^ (row & 7)) << 4) + (ca & 15)];
                const ushort_t bb = *(const ushort_t*)&lds8[OB + rd * 256 + (((ca >> 3) ^ (rd & 15)) << 4) + (ca & 7) * 2];
                h[rt][j][r] = fmaxf(acc[rt][j][r] + f8d(ab) + bf2f(bb), 0.f);
            }
        }
    }

    float qs[4][2];
    #pragma unroll
    for (int rt = 0; rt < 4; ++rt) {
        qs[rt][0] = (h[rt][0][0] + h[rt][0][1]) + (h[rt][0][2] + h[rt][0][3]);
        qs[rt][1] = (h[rt][1][0] + h[rt][1][1]) + (h[rt][1][2] + h[rt][1][3]);
    }
    unsigned long long rem = mask;
    while (rem) {
        const int beg = (int)__builtin_ctzll(rem);
        rem &= rem - 1;
        const int end = rem ? (int)__builtin_ctzll(rem) : nvalid;
        const int dg  = __shfl(myd, beg, 64);

        float s0 = 0.f, s1 = 0.f;
        #pragma unroll
        for (int rt = 0; rt < 4; ++rt) {
            const int qb = rt * 16 + g * 4;
            const int lo = max(qb, beg);
            const int hi = min(qb + 4, end);
            if (lo < hi) {
                if (lo == qb && hi == qb + 4) {
                    s0 += qs[rt][0]; s1 += qs[rt][1];
                } else {
                    #pragma unroll
                    for (int r = 0; r < 4; ++r) {
                        const int sl = qb + r;
                        if (sl >= beg && sl < end) {
                            s0 += h[rt][0][r]; s1 += h[rt][1][r];
                        }
                    }
                }
            }
        }
        s0 += __shfl_xor(s0, 16, 64); s0 += __shfl_xor(s0, 32, 64);
        s1 += __shfl_xor(s1, 16, 64); s1 += __shfl_xor(s1, 32, 64);
        if (g == 0) {
            const bool bnd = (beg == 0 && dg == prevd) || (end == nvalid && dg == nextd);
            float* p = mh + (size_t)dg * D + wv * 32 + col;
            if (bnd) { atomicAdd(p, s0); atomicAdd(p + 16, s1); }
            else     { p[0] = s0; p[16] = s1; }
        }
    }
}

// ---------------- node_fused: msum = mh@Wm2 + cnt*bm2; hin = msum + f; node MLP -> out ----------------
__global__ __launch_bounds__(NT, 4) void node_fused_kernel(
    const float* __restrict__ f, const float* __restrict__ mh,
    const int* __restrict__ cnt,
    const ushort_t* __restrict__ W2p, const float* __restrict__ bm2,
    const ushort_t* __restrict__ Wu1p, const float* __restrict__ bu1,
    const ushort_t* __restrict__ Wu2p, const float* __restrict__ bu2,
    float* __restrict__ out, int Nn)
{
    __shared__ __align__(16) ushort_t lds[2 * 64 * 64];   // 16 KB
    __shared__ int s_cnt[64];

    const int t    = threadIdx.x;
    const int lane = t & 63;
    const int wv   = t >> 6;
    const int col  = lane & 15;
    const int g    = lane >> 4;
    const int n0   = blockIdx.x * 64;

    if (t < 64) s_cnt[t] = (n0 + t < Nn) ? cnt[n0 + t] : 0;

    // ---- stage mh (f32 -> bf16) swizzled ----
    #pragma unroll
    for (int it = 0; it < 4; ++it) {
        const int gidx = it * 256 + t;
        const int row  = gidx >> 4;
        const int gr   = gidx & 15;
        const int pair = gr >> 3, s = gr & 7;
        const int sP   = s ^ (row & 7);
        const int gn   = n0 + row;
        union { ushort_t us[8]; short8v v; } pk;
        if (gn < Nn) {
            const size_t off = (size_t)gn * D + gr * 8;
            float4 m0 = *(const float4*)(mh + off);
            float4 m1 = *(const float4*)(mh + off + 4);
            pk.us[0] = f2bf(m0.x); pk.us[1] = f2bf(m0.y);
            pk.us[2] = f2bf(m0.z); pk.us[3] = f2bf(m0.w);
            pk.us[4] = f2bf(m1.x); pk.us[5] = f2bf(m1.y);
            pk.us[6] = f2bf(m1.z); pk.us[7] = f2bf(m1.w);
        } else {
            #pragma unroll
            for (int j = 0; j < 8; ++j) pk.us[j] = 0;
        }
        *(short8v*)&lds[(pair * 64 + row) * 64 + sP * 8] = pk.v;
    }
    __syncthreads();   // B0: mh staged

    // ---- msum = mh@Wm2 + cnt*bm2 ----
    f32x4 acc[4][2];
    {
        const float bv0 = bm2[wv * 32 + col];
        const float bv1 = bm2[wv * 32 + 16 + col];
        #pragma unroll
        for (int rt = 0; rt < 4; ++rt)
            #pragma unroll
            for (int r = 0; r < 4; ++r) {
                const float cn = (float)s_cnt[rt * 16 + g * 4 + r];
                acc[rt][0][r] = cn * bv0;
                acc[rt][1][r] = cn * bv1;
            }
    }
    #pragma unroll
    for (int c = 0; c < 4; ++c) {
        short8v b0 = *(const short8v*)&W2p[(size_t)(wv * 32 + col) * HD + c * 32 + g * 8];
        short8v b1 = *(const short8v*)&W2p[(size_t)(wv * 32 + 16 + col) * HD + c * 32 + g * 8];
        short8v a[4];
        #pragma unroll
        for (int rt = 0; rt < 4; ++rt) {
            const int row = rt * 16 + col;
            const int sP = (((c & 1) << 2) + g) ^ (row & 7);
            a[rt] = *(const short8v*)&lds[((c >> 1) * 64 + row) * 64 + sP * 8];
        }
        #pragma unroll
        for (int rt = 0; rt < 4; ++rt) {
            acc[rt][0] = __builtin_amdgcn_mfma_f32_16x16x32_bf16(a[rt], b0, acc[rt][0], 0, 0, 0);
            acc[rt][1] = __builtin_amdgcn_mfma_f32_16x16x32_bf16(a[rt], b1, acc[rt][1], 0, 0, 0);
        }
    }
    __syncthreads();   // B1: all mh reads done; LDS reusable

    // ---- hin = msum + f (fragment-position f reads), write bf16 to LDS ----
    const int ph = wv >> 1;
    #pragma unroll
    for (int rt = 0; rt < 4; ++rt)
        #pragma unroll
        for (int r = 0; r < 4; ++r) {
            const int row = rt * 16 + g * 4 + r;
            const int gn = n0 + row;
            #pragma unroll
            for (int j = 0; j < 2; ++j) {
                const int ca = wv * 32 + j * 16 + col;
                float v = 0.f;
                if (gn < Nn) v = acc[rt][j][r] + f[(size_t)gn * D + ca];
                unsigned int pk2 = cvt_pk_bf16(v, v);
                const int sH = (((wv & 1) << 2) + j * 2 + (col >> 3)) ^ (row & 7);
                lds[(ph * 64 + row) * 64 + sH * 8 + (col & 7)] = (ushort_t)pk2;
            }
        }
    __syncthreads();   // B2: hin complete

    // ---- node layer 1 ----
    const size_t wrow0 = (size_t)(wv * 32 + col) * HD;
    const size_t wrow1 = (size_t)(wv * 32 + 16 + col) * HD;
    f32x4 acc1[4][2];
    {
        float bv0 = bu1[wv * 32 + col];
        float bv1 = bu1[wv * 32 + 16 + col];
        #pragma unroll
        for (int rt = 0; rt < 4; ++rt) {
            acc1[rt][0] = (f32x4){bv0, bv0, bv0, bv0};
            acc1[rt][1] = (f32x4){bv1, bv1, bv1, bv1};
        }
    }
    #pragma unroll
    for (int c = 0; c < 4; ++c) {
        short8v b0 = *(const short8v*)&Wu1p[wrow0 + c * 32 + g * 8];
        short8v b1 = *(const short8v*)&Wu1p[wrow1 + c * 32 + g * 8];
        short8v a[4];
        #pragma unroll
        for (int rt = 0; rt < 4; ++rt) {
            const int row = rt * 16 + col;
            const int sP = (((c & 1) << 2) + g) ^ (row & 7);
            a[rt] = *(const short8v*)&lds[((c >> 1) * 64 + row) * 64 + sP * 8];
        }
        #pragma unroll
        for (int rt = 0; rt < 4; ++rt) {
            acc1[rt][0] = __builtin_amdgcn_mfma_f32_16x16x32_bf16(a[rt], b0, acc1[rt][0], 0, 0, 0);
            acc1[rt][1] = __builtin_amdgcn_mfma_f32_16x16x32_bf16(a[rt], b1, acc1[rt][1], 0, 0, 0);
        }
    }
    __syncthreads();   // B3: hin reads done

    // hid (relu, bf16)
    #pragma unroll
    for (int rt = 0; rt < 4; ++rt)
        #pragma unroll
        for (int j = 0; j < 2; ++j)
            #pragma unroll
            for (int r = 0; r < 4; ++r) {
                const int row = rt * 16 + g * 4 + r;
                float v = fmaxf(acc1[rt][j][r], 0.f);
                unsigned int pk2 = cvt_pk_bf16(v, v);
                const int sH = (((wv & 1) << 2) + j * 2 + (col >> 3)) ^ (row & 7);
                lds[(ph * 64 + row) * 64 + sH * 8 + (col & 7)] = (ushort_t)pk2;
            }
    __syncthreads();   // B4: hid complete

    // ---- node layer 2 -> out ----
    f32x4 acc2[4][2];
    {
        float bv0 = bu2[wv * 32 + col];
        float bv1 = bu2[wv * 32 + 16 + col];
        #pragma unroll
        for (int rt = 0; rt < 4; ++rt) {
            acc2[rt][0] = (f32x4){bv0, bv0, bv0, bv0};
            acc2[rt][1] = (f32x4){bv1, bv1, bv1, bv1};
        }
    }
    #pragma unroll
    for (int c = 0; c < 4; ++c) {
        short8v b0 = *(const short8v*)&Wu2p[wrow0 + c * 32 + g * 8];
        short8v b1 = *(const short8v*)&Wu2p[wrow1 + c * 32 + g * 8];
        short8v a[4];
        #pragma unroll
        for (int rt = 0; rt < 4; ++rt) {
            const int row = rt * 16 + col;
            const int sP = (((c & 1) << 2) + g) ^ (row & 7);
            a[rt] = *(const short8v*)&lds[((c >> 1) * 64 + row) * 64 + sP * 8];
        }
        #pragma unroll
        for (int rt = 0; rt < 4; ++rt) {
            acc2[rt][0] = __builtin_amdgcn_mfma_f32_16x16x32_bf16(a[rt], b0, acc2[rt][0], 0, 0, 0);
            acc2[rt][1] = __builtin_amdgcn_mfma_f32_16x16x32_bf16(a[rt], b1, acc2[rt][1], 0, 0, 0);
        }
    }

    #pragma unroll
    for (int rt = 0; rt < 4; ++rt)
        #pragma unroll
        for (int r = 0; r < 4; ++r) {
            const int row = rt * 16 + g * 4 + r;
            const int gn = n0 + row;
            if (gn < Nn) {
                out[(size_t)gn * D + wv * 32 + col]      = acc2[rt][0][r];
                out[(size_t)gn * D + wv * 32 + 16 + col] = acc2[rt][1][r];
            }
        }
}

// ================= fallback kernels (bf16 pk-atomic path; unchanged) =================

__global__ void repack_kernel(const float* __restrict__ Wm1, const float* __restrict__ Wm2,
                              ushort_t* __restrict__ W1p, ushort_t* __restrict__ W2p) {
    int idx = blockIdx.x * 256 + threadIdx.x;
    const int n1 = 128 * KP1;
    if (idx < n1) {
        int n = idx / KP1, k = idx % KP1;
        W1p[idx] = f2bf((k < MSG_IN) ? Wm1[(size_t)k * HD + n] : 0.f);
    } else {
        int i2 = idx - n1;
        if (i2 < HD * D) {
            int n = i2 / HD, k = i2 % HD;
            W2p[i2] = f2bf(Wm2[(size_t)k * D + n]);
        }
    }
}

__global__ void fconv_kernel(const float* __restrict__ f, ushort_t* __restrict__ fb, int n8) {
    int i = blockIdx.x * 256 + threadIdx.x;
    if (i < n8) {
        float4 v0 = *(const float4*)(f + (size_t)i * 8);
        float4 v1 = *(const float4*)(f + (size_t)i * 8 + 4);
        union { ushort_t us[8]; short8v v; } pk;
        pk.us[0] = f2bf(v0.x); pk.us[1] = f2bf(v0.y);
        pk.us[2] = f2bf(v0.z); pk.us[3] = f2bf(v0.w);
        pk.us[4] = f2bf(v1.x); pk.us[5] = f2bf(v1.y);
        pk.us[6] = f2bf(v1.z); pk.us[7] = f2bf(v1.w);
        *(short8v*)(fb + (size_t)i * 8) = pk.v;
    }
}

__global__ __launch_bounds__(NT, 4) void edge_mfma_kernel(
    const ushort_t* __restrict__ fbf, const float* __restrict__ x,
    const float* __restrict__ w, const int* __restrict__ src,
    const int* __restrict__ dst,
    const ushort_t* __restrict__ W1p, const float* __restrict__ bm1,
    const ushort_t* __restrict__ W2p, const float* __restrict__ bm2,
    ushort_t* msum, int E)
{
    __shared__ __align__(16) ushort_t lds[LDS1];
    __shared__ int s_dst[EB];

    const int t    = threadIdx.x;
    const int lane = t & 63;
    const int wv   = t >> 6;
    const int e0   = blockIdx.x * EB;

    if (t < EB) s_dst[t] = (e0 + t < E) ? dst[e0 + t] : 0;
    {
        const int el8 = lane >> 3;
        const int s   = lane & 7;
        const int sl  = s ^ el8;
        const int geA = min(e0 + wv * 16 + el8,     E - 1);
        const int geB = min(e0 + wv * 16 + 8 + el8, E - 1);
        const int nsA = src[geA], ndA = dst[geA];
        const int nsB = src[geB], ndB = dst[geB];
        #pragma unroll
        for (int p = 0; p < 4; ++p) {
            const int n0 = (p < 2) ? nsA : ndA;
            const int n1 = (p < 2) ? nsB : ndB;
            const ushort_t* g0 = fbf + (size_t)n0 * D + (p & 1) * 64 + sl * 8;
            const ushort_t* g1 = fbf + (size_t)n1 * D + (p & 1) * 64 + sl * 8;
            GLOAD_LDS16(g0, &lds[(p * EB + wv * 16    ) * 64]);
            GLOAD_LDS16(g1, &lds[(p * EB + wv * 16 + 8) * 64]);
        }
    }
    {
        const int el = lane >> 2, q = lane & 3;
        const int qp = q ^ (el & 3);
        const int ge = e0 + wv * 16 + el;
        const bool ok = ge < E;
        const int gc = min(ge, E - 1);
        union { ushort_t us[8]; short8v v; } pk;
        #pragma unroll
        for (int j = 0; j < 8; ++j) pk.us[j] = 0;
        if (ok) {
            if (q < 2) {
                float4 w0 = *(const float4*)(w + (size_t)gc * DE + q * 8);
                float4 w1 = *(const float4*)(w + (size_t)gc * DE + q * 8 + 4);
                pk.us[0] = f2bf(w0.x); pk.us[1] = f2bf(w0.y);
                pk.us[2] = f2bf(w0.z); pk.us[3] = f2bf(w0.w);
                pk.us[4] = f2bf(w1.x); pk.us[5] = f2bf(w1.y);
                pk.us[6] = f2bf(w1.z); pk.us[7] = f2bf(w1.w);
            } else if (q == 2) {
                const int ns = src[gc], nd = dst[gc];
                float dx = x[ns*3+0] - x[nd*3+0];
                float dy = x[ns*3+1] - x[nd*3+1];
                float dz = x[ns*3+2] - x[nd*3+2];
                pk.us[0] = f2bf(dx*dx + dy*dy + dz*dz);
            }
        }
        *(short8v*)&lds[CH8 + (wv * 16 + el) * 32 + qp * 8] = pk.v;
    }

    const int col = lane & 15;
    const int g   = lane >> 4;
    const size_t wrow0 = (size_t)(wv * 32 + col) * KP1;
    const size_t wrow1 = (size_t)(wv * 32 + 16 + col) * KP1;
    short8v nb0 = *(const short8v*)&W1p[wrow0 + g * 8];
    short8v nb1 = *(const short8v*)&W1p[wrow1 + g * 8];
    __syncthreads();

    f32x4 acc[4][2];
    {
        float bv0 = bm1[wv * 32 + col];
        float bv1 = bm1[wv * 32 + 16 + col];
        #pragma unroll
        for (int rt = 0; rt < 4; ++rt) {
            acc[rt][0] = (f32x4){bv0, bv0, bv0, bv0};
            acc[rt][1] = (f32x4){bv1, bv1, bv1, bv1};
        }
    }
    #pragma unroll
    for (int c = 0; c < 9; ++c) {
        short8v b0 = nb0, b1 = nb1;
        if (c + 1 < 9) {
            nb0 = *(const short8v*)&W1p[wrow0 + (c + 1) * 32 + g * 8];
            nb1 = *(const short8v*)&W1p[wrow1 + (c + 1) * 32 + g * 8];
        }
        short8v a[4];
        #pragma unroll
        for (int rt = 0; rt < 4; ++rt) {
            const int row = rt * 16 + col;
            if (c < 8) {
                const int sP = (((c & 1) << 2) + g) ^ (row & 7);
                a[rt] = *(const short8v*)&lds[((c >> 1) * EB + row) * 64 + sP * 8];
            } else {
                const int sP = g ^ (row & 3);
                a[rt] = *(const short8v*)&lds[CH8 + row * 32 + sP * 8];
            }
        }
        #pragma unroll
        for (int rt = 0; rt < 4; ++rt) {
            acc[rt][0] = __builtin_amdgcn_mfma_f32_16x16x32_bf16(a[rt], b0, acc[rt][0], 0, 0, 0);
            acc[rt][1] = __builtin_amdgcn_mfma_f32_16x16x32_bf16(a[rt], b1, acc[rt][1], 0, 0, 0);
        }
    }
    __syncthreads();

    const int ph = wv >> 1;
    #pragma unroll
    for (int rt = 0; rt < 4; ++rt)
        #pragma unroll
        for (int j = 0; j < 2; ++j)
            #pragma unroll
            for (int r = 0; r < 4; ++r) {
                const int row = rt * 16 + g * 4 + r;
                float v = fmaxf(acc[rt][j][r], 0.f);
                unsigned int pk2 = cvt_pk_bf16(v, v);
                const int sH = (((wv & 1) << 2) + j * 2 + (col >> 3)) ^ (row & 7);
                lds[(ph * EB + row) * 64 + sH * 8 + (col & 7)] = (ushort_t)pk2;
            }
    __syncthreads();

    const size_t w2r0 = (size_t)(wv * 32 + col) * HD;
    const size_t w2r1 = (size_t)(wv * 32 + 16 + col) * HD;
    short8v m0 = *(const short8v*)&W2p[w2r0 + g * 8];
    short8v m1 = *(const short8v*)&W2p[w2r1 + g * 8];
    f32x4 acc2[4][2];
    {
        float bv0 = bm2[wv * 32 + col];
        float bv1 = bm2[wv * 32 + 16 + col];
        #pragma unroll
        for (int rt = 0; rt < 4; ++rt) {
            acc2[rt][0] = (f32x4){bv0, bv0, bv0, bv0};
            acc2[rt][1] = (f32x4){bv1, bv1, bv1, bv1};
        }
    }
    #pragma unroll
    for (int c = 0; c < NCH2; ++c) {
        short8v b0 = m0, b1 = m1;
        if (c + 1 < NCH2) {
            m0 = *(const short8v*)&W2p[w2r0 + (c + 1) * 32 + g * 8];
            m1 = *(const short8v*)&W2p[w2r1 + (c + 1) * 32 + g * 8];
        }
        short8v a[4];
        #pragma unroll
        for (int rt = 0; rt < 4; ++rt) {
            const int row = rt * 16 + col;
            const int sP = (((c & 1) << 2) + g) ^ (row & 7);
            a[rt] = *(const short8v*)&lds[((c >> 1) * EB + row) * 64 + sP * 8];
        }
        #pragma unroll
        for (int rt = 0; rt < 4; ++rt) {
            acc2[rt][0] = __builtin_amdgcn_mfma_f32_16x16x32_bf16(a[rt], b0, acc2[rt][0], 0, 0, 0);
            acc2[rt][1] = __builtin_amdgcn_mfma_f32_16x16x32_bf16(a[rt], b1, acc2[rt][1], 0, 0, 0);
        }
    }

    const bool even = (col & 1) == 0;
    #pragma unroll
    for (int rt = 0; rt < 4; ++rt)
        #pragma unroll
        for (int r = 0; r < 4; ++r) {
            const int e  = rt * 16 + g * 4 + r;
            const int ge = e0 + e;
            const int dg = s_dst[e];
            #pragma unroll
            for (int j = 0; j < 2; ++j) {
                float v  = acc2[rt][j][r];
                float vn = __shfl_xor(v, 1, 64);
                if (even && ge < E) {
                    unsigned int pk2 = cvt_pk_bf16(v, vn);
                    ushort_t* p = msum + (size_t)dg * D + wv * 32 + j * 16 + col;
                    asm volatile("global_atomic_pk_add_bf16 %0, %1, off"
                                 :: "v"(p), "v"(pk2) : "memory");
                }
            }
        }
}

template<bool MB16>
__global__ __launch_bounds__(NT, 4) void node_kernel(
    const float* __restrict__ f, const void* __restrict__ msum_v,
    const float* __restrict__ Wu1, const float* __restrict__ bu1,
    const float* __restrict__ Wu2, const float* __restrict__ bu2,
    float* out, int Nn)
{
    __shared__ __align__(16) float hin[NB][HID_PAD];
    __shared__ __align__(16) float hid[NB][HID_PAD];
    const int t  = threadIdx.x;
    const int n0 = blockIdx.x * NB;
    const int nn = min(NB, Nn - n0);

    {
        #pragma unroll
        for (int it = 0; it < 4; ++it) {
            const int idx = it * 1024 + t * 4;
            const int e   = idx >> 7;
            const int cb  = idx & 127;
            if (e < nn) {
                const size_t off = (size_t)(n0 + e) * D + cb;
                float4 mv;
                if (MB16) {
                    uint2 pk = *(const uint2*)((const ushort_t*)msum_v + off);
                    mv.x = bf2f((ushort_t)(pk.x & 0xffffu));
                    mv.y = bf2f((ushort_t)(pk.x >> 16));
                    mv.z = bf2f((ushort_t)(pk.y & 0xffffu));
                    mv.w = bf2f((ushort_t)(pk.y >> 16));
                } else {
                    mv = *(const float4*)((const float*)msum_v + off);
                }
                float4 fv = *(const float4*)&f[off];
                float4 o = {mv.x + fv.x, mv.y + fv.y, mv.z + fv.z, mv.w + fv.w};
                *(float4*)&hin[e][cb] = o;
            }
        }
    }
    __syncthreads();

    const int tc = t & 15, te2 = (t >> 4) * 2, c0 = tc * 8;
    float a1[2][8];
    #pragma unroll
    for (int c = 0; c < 8; ++c) { float bv = bu1[c0 + c]; a1[0][c] = bv; a1[1][c] = bv; }
    for (int i = 0; i < D; i += 4) {
        float m0[4], m1[4];
        *(float4*)m0 = *(const float4*)&hin[te2][i];
        *(float4*)m1 = *(const float4*)&hin[te2 + 1][i];
        #pragma unroll
        for (int r = 0; r < 4; ++r) {
            float wr[8];
            *(float4*)&wr[0] = *(const float4*)(Wu1 + (size_t)(i + r) * HD + c0);
            *(float4*)&wr[4] = *(const float4*)(Wu1 + (size_t)(i + r) * HD + c0 + 4);
            #pragma unroll
            for (int c = 0; c < 8; ++c) { a1[0][c] += m0[r]*wr[c]; a1[1][c] += m1[r]*wr[c]; }
        }
    }
    #pragma unroll
    for (int j = 0; j < 2; ++j) {
        float v[8];
        #pragma unroll
        for (int c = 0; c < 8; ++c) v[c] = fmaxf(a1[j][c], 0.f);
        *(float4*)&hid[te2 + j][c0] = *(float4*)&v[0];
        *(float4*)&hid[te2 + j][c0 + 4] = *(float4*)&v[4];
    }
    __syncthreads();
    float a2[2][8];
    #pragma unroll
    for (int c = 0; c < 8; ++c) { float bv = bu2[c0 + c]; a2[0][c] = bv; a2[1][c] = bv; }
    for (int h = 0; h < HD; h += 4) {
        float m0[4], m1[4];
        *(float4*)m0 = *(const float4*)&hid[te2][h];
        *(float4*)m1 = *(const float4*)&hid[te2 + 1][h];
        #pragma unroll
        for (int r = 0; r < 4; ++r) {
            float wr[8];
            *(float4*)&wr[0] = *(const float4*)(Wu2 + (size_t)(h + r) * D + c0);
            *(float4*)&wr[4] = *(const float4*)(Wu2 + (size_t)(h + r) * D + c0 + 4);
            #pragma unroll
            for (int c = 0; c < 8; ++c) { a2[0][c] += m0[r]*wr[c]; a2[1][c] += m1[r]*wr[c]; }
        }
    }
    #pragma unroll
    for (int j = 0; j < 2; ++j) {
        int e = te2 + j, gn = n0 + e;
        if (e < nn) {
            *(float4*)(out + (size_t)gn * D + c0) = *(float4*)&a2[j][0];
            *(float4*)(out + (size_t)gn * D + c0 + 4) = *(float4*)&a2[j][4];
        }
    }
}

extern "C" void kernel_launch(void* const* d_in, const int* in_sizes, int n_in,
                              void* d_out, int out_size, void* d_ws, size_t ws_size,
                              hipStream_t stream) {
    const float* f   = (const float*)d_in[0];
    const float* x   = (const float*)d_in[1];
    const float* w   = (const float*)d_in[2];
    const int*   src = (const int*)d_in[3];
    const int*   dst = (const int*)d_in[4];
    const float* Wm1 = (const float*)d_in[5];
    const float* bm1 = (const float*)d_in[6];
    const float* Wm2 = (const float*)d_in[7];
    const float* bm2 = (const float*)d_in[8];
    const float* Wu1 = (const float*)d_in[9];
    const float* bu1 = (const float*)d_in[10];
    const float* Wu2 = (const float*)d_in[11];
    const float* bu2 = (const float*)d_in[12];

    const int Nn = in_sizes[0] / D;
    const int E  = in_sizes[3];

    const size_t wbytes  = (size_t)(128 * KP1 + HD * D) * sizeof(ushort_t);
    const size_t wubytes = (size_t)(2 * HD * D) * sizeof(ushort_t);
    auto align512 = [](size_t v) { return (v + 511) & ~(size_t)511; };
    char* wsb = (char*)d_ws;

    // ---------------- primary: linear-trick path (A fp8, B bf16), fused tail ----------------
    size_t off = 0;
    const size_t o_w    = off; off = align512(off + wbytes);
    const size_t o_wu   = off; off = align512(off + wubytes);
    const size_t o_wbf  = off; off = align512(off + (size_t)E * DE * 2);
    const size_t o_af   = off; off = align512(off + (size_t)Nn * D);
    const size_t o_bf16 = off; off = align512(off + (size_t)Nn * D * 2);
    const size_t o_cnt  = off; off = align512(off + (size_t)Nn * 4);
    const size_t o_roff = off; off = align512(off + (size_t)Nn * 4);
    const size_t o_cur  = off; off = align512(off + (size_t)Nn * 4);
    const size_t o_perm = off; off = align512(off + (size_t)E * 4);
    const size_t o_sdst = off; off = align512(off + (size_t)E * 4);
    const size_t o_mh   = off; off = align512(off + (size_t)Nn * D * 4);
    const size_t primary_total = off;

    if (ws_size >= primary_total) {
        ushort_t* W1p  = (ushort_t*)(wsb + o_w);
        ushort_t* W2p  = W1p + 128 * KP1;
        ushort_t* Wu1p = (ushort_t*)(wsb + o_wu);
        ushort_t* Wu2p = Wu1p + HD * D;
        ushort_t* wbf  = (ushort_t*)(wsb + o_wbf);
        uchar_t*  Af   = (uchar_t*)(wsb + o_af);
        ushort_t* Bf16 = (ushort_t*)(wsb + o_bf16);
        int* cnt       = (int*)(wsb + o_cnt);
        int* roff      = (int*)(wsb + o_roff);
        int* cursor    = (int*)(wsb + o_cur);
        int* perm      = (int*)(wsb + o_perm);
        int* sdst      = (int*)(wsb + o_sdst);
        float* mh      = (float*)(wsb + o_mh);

        const int nw8 = E * DE / 8;
        const int ntiles = (E + EB - 1) / EB;
        const int nblk   = (Nn + 63) / 64;
        hipMemsetAsync(cnt, 0, (size_t)Nn * 4, stream);
        fused_pre_kernel<<<dim3(1024), dim3(256), 0, stream>>>(
            Wm1, Wm2, Wu1, Wu2, W1p, W2p, Wu1p, Wu2p, w, wbf, dst, cnt, nw8, E);
        scan_kernel<<<dim3(1), dim3(1024), 0, stream>>>(cnt, roff, cursor, Nn);
        scatter_kernel<<<dim3((E + 255) / 256), dim3(256), 0, stream>>>(
            dst, cursor, roff, cnt, perm, sdst, mh, E, Nn);
        ab_kernel<<<dim3(nblk), dim3(NT), 0, stream>>>(f, W1p, Af, Bf16, Nn);
        edge_lin_kernel<<<dim3(ntiles), dim3(NT), 0, stream>>>(
            Af, Bf16, x, wbf, src, perm, sdst, W1p, bm1, mh, E);
        node_fused_kernel<<<dim3(nblk), dim3(NT), 0, stream>>>(
            f, mh, cnt, W2p, bm2, Wu1p, bu1, Wu2p, bu2, (float*)d_out, Nn);
        return;
    }

    // ---------------- fallback: bf16 pk-atomic path ----------------
    size_t off2 = 0;
    const size_t p_w  = off2; off2 = align512(off2 + wbytes);
    const size_t p_fb = off2; off2 = align512(off2 + (size_t)Nn * D * 2);
    const size_t p_ms = off2; off2 = align512(off2 + (size_t)Nn * D * 2);
    if (ws_size >= off2) {
        ushort_t* W1p  = (ushort_t*)(wsb + p_w);
        ushort_t* W2p  = W1p + 128 * KP1;
        ushort_t* fbf  = (ushort_t*)(wsb + p_fb);
        ushort_t* msum = (ushort_t*)(wsb + p_ms);
        const int rp_elems = 128 * KP1 + HD * D;
        hipMemsetAsync(msum, 0, (size_t)Nn * D * 2, stream);
        repack_kernel<<<dim3((rp_elems + 255) / 256), dim3(256), 0, stream>>>(Wm1, Wm2, W1p, W2p);
        const int n8 = Nn * D / 8;
        fconv_kernel<<<dim3((n8 + 255) / 256), dim3(256), 0, stream>>>(f, fbf, n8);
        edge_mfma_kernel<<<dim3((E + EB - 1) / EB), dim3(NT), 0, stream>>>(
            fbf, x, w, src, dst, W1p, bm1, W2p, bm2, msum, E);
        node_kernel<true><<<dim3((Nn + NB - 1) / NB), dim3(NT), 0, stream>>>(
            f, msum, Wu1, bu1, Wu2, bu2, (float*)d_out, Nn);
        return;
    }
}

// Round 21
// 254.317 us; speedup vs baseline: 1.6378x; 1.0264x over previous
//
#include <hip/hip_runtime.h>
#include <hip/hip_fp8.h>

#define D 128
#define HD 128
#define DE 16
#define MSG_IN 273
#define EB 64        // edges per tile
#define NT 256
#define KP1 288      // padded msg K = 9 chunks of 32
#define NCH2 4
#define NB 32
#define HID_PAD 132
#define CH8 (4 * EB * 64)
#define LDS1 (4 * EB * 64 + EB * 32)
// edge_lin LDS layout (bytes): A fp8 [0,8192) ; B bf16 [8192,24576) ; c8 bf16 [24576,28672)
#define OB 8192
#define OC 24576

typedef __attribute__((ext_vector_type(8))) short short8v;
typedef __attribute__((ext_vector_type(4))) float f32x4;
typedef unsigned short ushort_t;
typedef unsigned char uchar_t;

#define GLOAD_LDS16(gp, lp) \
    __builtin_amdgcn_global_load_lds((const __attribute__((address_space(1))) unsigned int*)(gp), \
                                     (__attribute__((address_space(3))) unsigned int*)(lp), 16, 0, 0)

__device__ __forceinline__ unsigned short f2bf(float v) {
    unsigned int u = __builtin_bit_cast(unsigned int, v);
    u += 0x7fffu + ((u >> 16) & 1u);
    return (unsigned short)(u >> 16);
}
__device__ __forceinline__ float bf2f(ushort_t u) {
    return __builtin_bit_cast(float, (unsigned int)u << 16);
}
__device__ __forceinline__ unsigned int cvt_pk_bf16(float lo, float hi) {
    unsigned int r;
    asm("v_cvt_pk_bf16_f32 %0, %1, %2" : "=v"(r) : "v"(lo), "v"(hi));
    return r;
}
__device__ __forceinline__ uchar_t f8e(float v) {   // f32 -> e4m3 (HIP library)
    __hip_fp8_e4m3 t(v);
    return (uchar_t)t.__x;
}
// e4m3fn -> f32: normals 2^(e-7)(1+m/8); subnormals m/8*2^-6; sign bit preserved.
__device__ __forceinline__ float f8d(unsigned b) {
    unsigned t = ((b & 0x7fu) << 20) | ((b & 0x80u) << 24);
    return __builtin_bit_cast(float, t) * 0x1p120f;
}

// ---------------- fused prepass: repack weights + dst hist ----------------
__global__ void fused_pre_kernel(const float* __restrict__ Wm1, const float* __restrict__ Wm2,
                                 const float* __restrict__ Wu1, const float* __restrict__ Wu2,
                                 ushort_t* __restrict__ W1p, ushort_t* __restrict__ W2p,
                                 ushort_t* __restrict__ Wu1p, ushort_t* __restrict__ Wu2p,
                                 const int* __restrict__ dst, int* __restrict__ cnt,
                                 int E) {
    const int gid    = blockIdx.x * 256 + threadIdx.x;
    const int stride = gridDim.x * 256;
    const int rp1 = 128 * KP1;
    const int rp2 = rp1 + HD * D;
    const int rp_elems = rp2 + 2 * HD * D;
    for (int i = gid; i < rp_elems; i += stride) {
        if (i < rp1) {
            int n = i / KP1, k = i % KP1;
            W1p[i] = f2bf((k < MSG_IN) ? Wm1[(size_t)k * HD + n] : 0.f);
        } else if (i < rp2) {
            int i2 = i - rp1;
            int n = i2 / HD, k = i2 % HD;
            W2p[i2] = f2bf(Wm2[(size_t)k * D + n]);
        } else {
            int i2 = (i - rp2);
            const bool second = i2 >= HD * D;
            if (second) i2 -= HD * D;
            int n = i2 / HD, k = i2 % HD;
            if (second) Wu2p[i2] = f2bf(Wu2[(size_t)k * D + n]);
            else        Wu1p[i2] = f2bf(Wu1[(size_t)k * HD + n]);
        }
    }
    for (int i = gid; i < E; i += stride) atomicAdd(&cnt[dst[i]], 1);
}

// ---------------- CSR build: parallel scan -> scatter + selective zero (of mh) ----------------
__global__ __launch_bounds__(1024) void scan_kernel(const int* __restrict__ cnt,
                                                    int* __restrict__ roff,
                                                    int* __restrict__ cursor, int Nn) {
    __shared__ int wsum[16];
    const int t = threadIdx.x, l = t & 63, wid = t >> 6;
    int running = 0;
    for (int base = 0; base < Nn; base += 4096) {
        const int i0 = base + t * 4;
        int v0 = 0, v1 = 0, v2 = 0, v3 = 0;
        if (i0 + 3 < Nn) {
            int4 v = *(const int4*)(cnt + i0);
            v0 = v.x; v1 = v.y; v2 = v.z; v3 = v.w;
        } else {
            if (i0 + 0 < Nn) v0 = cnt[i0 + 0];
            if (i0 + 1 < Nn) v1 = cnt[i0 + 1];
            if (i0 + 2 < Nn) v2 = cnt[i0 + 2];
        }
        const int vsum = v0 + v1 + v2 + v3;
        int s = vsum;
        #pragma unroll
        for (int off = 1; off < 64; off <<= 1) {
            int u = __shfl_up(s, off, 64);
            if (l >= off) s += u;
        }
        if (l == 63) wsum[wid] = s;
        __syncthreads();
        if (wid == 0 && l < 16) {
            int xv = wsum[l];
            #pragma unroll
            for (int off = 1; off < 16; off <<= 1) {
                int u = __shfl_up(xv, off, 64);
                if (l >= off) xv += u;
            }
            wsum[l] = xv;
        }
        __syncthreads();
        const int prev  = (wid > 0) ? wsum[wid - 1] : 0;
        const int total = wsum[15];
        int ex = running + prev + (s - vsum);
        if (i0 + 0 < Nn) { roff[i0 + 0] = ex; cursor[i0 + 0] = ex; } ex += v0;
        if (i0 + 1 < Nn) { roff[i0 + 1] = ex; cursor[i0 + 1] = ex; } ex += v1;
        if (i0 + 2 < Nn) { roff[i0 + 2] = ex; cursor[i0 + 2] = ex; } ex += v2;
        if (i0 + 3 < Nn) { roff[i0 + 3] = ex; cursor[i0 + 3] = ex; }
        running += total;
        __syncthreads();
    }
}

__global__ void scatter_kernel(const int* __restrict__ dst, int* cursor,
                               const int* __restrict__ roff, const int* __restrict__ cnt,
                               int* __restrict__ perm, int* __restrict__ sdst,
                               float* __restrict__ mh, int E, int Nn) {
    const int gid    = blockIdx.x * 256 + threadIdx.x;
    const int stride = gridDim.x * 256;
    for (int i = gid; i < E; i += stride) {
        int d = dst[i];
        int s = atomicAdd(&cursor[d], 1);
        perm[s] = i;
        sdst[s] = d;
    }
    for (int n = gid; n < Nn; n += stride) {
        const int c = cnt[n];
        const int r = roff[n];
        const bool need0 = (c == 0) || (r / EB != (r + c - 1) / EB);
        if (need0) {
            float4 z = {0.f, 0.f, 0.f, 0.f};
            float* p = mh + (size_t)n * D;
            #pragma unroll
            for (int k = 0; k < 32; ++k) *(float4*)(p + k * 4) = z;
        }
    }
}

// ---------------- AB precompute: A = f@Wm1[0:128] -> fp8, B = f@Wm1[128:256] -> bf16 ----------------
__global__ __launch_bounds__(NT, 4) void ab_kernel(
    const float* __restrict__ f,
    const ushort_t* __restrict__ W1p,
    uchar_t* __restrict__ Af, ushort_t* __restrict__ Bf16, int Nn)
{
    __shared__ __align__(16) ushort_t lds[2 * 64 * 64];   // 16 KB

    const int t    = threadIdx.x;
    const int lane = t & 63;
    const int wv   = t >> 6;
    const int col  = lane & 15;
    const int g    = lane >> 4;
    const int n0   = blockIdx.x * 64;

    // stage f rows (fp32 -> bf16) into swizzled [pair][64][64]
    #pragma unroll
    for (int it = 0; it < 4; ++it) {
        const int gidx = it * 256 + t;
        const int row  = gidx >> 4;
        const int gr   = gidx & 15;
        const int pair = gr >> 3, s = gr & 7;
        const int sP   = s ^ (row & 7);
        const int gn   = min(n0 + row, Nn - 1);
        const size_t off = (size_t)gn * D + gr * 8;
        float4 v0 = *(const float4*)(f + off);
        float4 v1 = *(const float4*)(f + off + 4);
        union { ushort_t us[8]; short8v v; } pk;
        pk.us[0] = f2bf(v0.x); pk.us[1] = f2bf(v0.y);
        pk.us[2] = f2bf(v0.z); pk.us[3] = f2bf(v0.w);
        pk.us[4] = f2bf(v1.x); pk.us[5] = f2bf(v1.y);
        pk.us[6] = f2bf(v1.z); pk.us[7] = f2bf(v1.w);
        *(short8v*)&lds[(pair * 64 + row) * 64 + sP * 8] = pk.v;
    }
    __syncthreads();

    const bool even = (col & 1) == 0;
    #pragma unroll
    for (int half = 0; half < 2; ++half) {          // 0: A (fp8), 1: B (bf16)
        f32x4 acc[4][2];
        #pragma unroll
        for (int rt = 0; rt < 4; ++rt) {
            acc[rt][0] = (f32x4){0.f, 0.f, 0.f, 0.f};
            acc[rt][1] = (f32x4){0.f, 0.f, 0.f, 0.f};
        }
        const int kbase = half * 128;
        #pragma unroll
        for (int c = 0; c < 4; ++c) {
            short8v b0 = *(const short8v*)&W1p[(size_t)(wv * 32 + col) * KP1 + kbase + c * 32 + g * 8];
            short8v b1 = *(const short8v*)&W1p[(size_t)(wv * 32 + 16 + col) * KP1 + kbase + c * 32 + g * 8];
            short8v a[4];
            #pragma unroll
            for (int rt = 0; rt < 4; ++rt) {
                const int row = rt * 16 + col;
                const int sP = (((c & 1) << 2) + g) ^ (row & 7);
                a[rt] = *(const short8v*)&lds[((c >> 1) * 64 + row) * 64 + sP * 8];
            }
            #pragma unroll
            for (int rt = 0; rt < 4; ++rt) {
                acc[rt][0] = __builtin_amdgcn_mfma_f32_16x16x32_bf16(a[rt], b0, acc[rt][0], 0, 0, 0);
                acc[rt][1] = __builtin_amdgcn_mfma_f32_16x16x32_bf16(a[rt], b1, acc[rt][1], 0, 0, 0);
            }
        }
        #pragma unroll
        for (int rt = 0; rt < 4; ++rt)
            #pragma unroll
            for (int j = 0; j < 2; ++j)
                #pragma unroll
                for (int r = 0; r < 4; ++r) {
                    const int row = rt * 16 + g * 4 + r;
                    const int gn = n0 + row;
                    float v  = acc[rt][j][r];
                    float vn = __shfl_xor(v, 1, 64);
                    if (even && gn < Nn) {
                        const int ca = wv * 32 + j * 16 + col;
                        if (half == 0) {
                            ushort_t pk = (ushort_t)f8e(v) | ((ushort_t)f8e(vn) << 8);
                            *(ushort_t*)(Af + (size_t)gn * D + ca) = pk;
                        } else {
                            *(unsigned int*)(Bf16 + (size_t)gn * D + ca) = cvt_pk_bf16(v, vn);
                        }
                    }
                }
    }
}

// ---------------- edge kernel v21: strength-reduced h-addressing, occ 5 ----------------
__global__ __launch_bounds__(NT, 5) void edge_lin_kernel(
    const uchar_t* __restrict__ Af, const ushort_t* __restrict__ Bf16,
    const float* __restrict__ x, const float* __restrict__ w,
    const int* __restrict__ src,
    const int* __restrict__ perm, const int* __restrict__ sdst,
    const ushort_t* __restrict__ W1p, const float* __restrict__ bm1,
    float* __restrict__ mh, int E)
{
    __shared__ __align__(16) uchar_t lds8[28672];   // A 8K | B 16K | c8 4K
    __shared__ int s_rid[EB];
    __shared__ int s_dgs[EB];

    const int t    = threadIdx.x;
    const int lane = t & 63;
    const int wv   = t >> 6;
    const int e0   = blockIdx.x * EB;
    const int nvalid = min(EB, E - e0);

    const int myd  = (e0 + lane < E) ? sdst[e0 + lane] : -1;
    const int prevd = (e0 > 0) ? sdst[e0 - 1] : -2;
    const int nextd = (e0 + EB < E) ? sdst[e0 + EB] : -2;

    const int dprev_l = __shfl_up(myd, 1, 64);
    const bool head = (lane == 0) || (myd != dprev_l);
    const unsigned long long mask = __ballot(head && (lane < nvalid));
    const unsigned long long le = (lane == 63) ? ~0ull : ((1ull << (lane + 1)) - 1ull);
    const int rid = (int)__popcll(mask & le) - 1;
    const int ndist = (int)__popcll(mask);
    s_rid[lane] = (rid < 0) ? 0 : rid;
    if (head && lane < nvalid) s_dgs[rid] = myd;

    {
        const int el8 = lane >> 3;
        const int s   = lane & 7;
        const int sl  = s ^ el8;
        const int slA = min(e0 + wv * 16 + el8,     E - 1);
        const int slB = min(e0 + wv * 16 + 8 + el8, E - 1);
        const int nsA = src[perm[slA]];
        const int nsB = src[perm[slB]];
        GLOAD_LDS16(Af + (size_t)nsA * D + sl * 16, &lds8[(wv * 16    ) * 128]);
        GLOAD_LDS16(Af + (size_t)nsB * D + sl * 16, &lds8[(wv * 16 + 8) * 128]);
    }
    {
        const int ntask = ndist * 16;
        for (int idx = t; idx < ntask; idx += NT) {
            const int rowr = idx >> 4;
            const int gr   = idx & 15;
            const int dg   = s_dgs[rowr];
            uint4 v = *(const uint4*)(Bf16 + (size_t)dg * D + gr * 8);
            const int phys = gr ^ (rowr & 15);
            *(uint4*)&lds8[OB + rowr * 256 + phys * 16] = v;
        }
    }
    {
        const int el = lane >> 2, q = lane & 3;
        const int qp = q ^ (el & 3);
        const int slot = e0 + wv * 16 + el;
        const bool ok = slot < E;
        const int sc = min(slot, E - 1);
        const int ge = perm[sc];
        union { ushort_t us[8]; short8v v; } pk;
        #pragma unroll
        for (int j = 0; j < 8; ++j) pk.us[j] = 0;
        if (ok) {
            if (q < 2) {
                float4 w0 = *(const float4*)(w + (size_t)ge * DE + q * 8);
                float4 w1 = *(const float4*)(w + (size_t)ge * DE + q * 8 + 4);
                pk.us[0] = f2bf(w0.x); pk.us[1] = f2bf(w0.y);
                pk.us[2] = f2bf(w0.z); pk.us[3] = f2bf(w0.w);
                pk.us[4] = f2bf(w1.x); pk.us[5] = f2bf(w1.y);
                pk.us[6] = f2bf(w1.z); pk.us[7] = f2bf(w1.w);
            } else if (q == 2) {
                const int ns = src[ge], nd = sdst[sc];
                float dx = x[ns*3+0] - x[nd*3+0];
                float dy = x[ns*3+1] - x[nd*3+1];
                float dz = x[ns*3+2] - x[nd*3+2];
                pk.us[0] = f2bf(dx*dx + dy*dy + dz*dz);
            }
        }
        *(short8v*)&lds8[OC + (wv * 16 + el) * 64 + qp * 16] = pk.v;
    }

    const int col = lane & 15;
    const int g   = lane >> 4;

    short8v bc0 = *(const short8v*)&W1p[(size_t)(wv * 32 + col) * KP1 + 256 + g * 8];
    short8v bc1 = *(const short8v*)&W1p[(size_t)(wv * 32 + 16 + col) * KP1 + 256 + g * 8];

    __syncthreads();   // B0

    f32x4 acc[4][2];
    {
        float bv0 = bm1[wv * 32 + col];
        float bv1 = bm1[wv * 32 + 16 + col];
        #pragma unroll
        for (int rt = 0; rt < 4; ++rt) {
            acc[rt][0] = (f32x4){bv0, bv0, bv0, bv0};
            acc[rt][1] = (f32x4){bv1, bv1, bv1, bv1};
        }
    }
    #pragma unroll
    for (int rt = 0; rt < 4; ++rt) {
        const int row = rt * 16 + col;
        const int sP8 = g ^ (row & 3);
        short8v a = *(const short8v*)&lds8[OC + row * 64 + sP8 * 16];
        acc[rt][0] = __builtin_amdgcn_mfma_f32_16x16x32_bf16(a, bc0, acc[rt][0], 0, 0, 0);
        acc[rt][1] = __builtin_amdgcn_mfma_f32_16x16x32_bf16(a, bc1, acc[rt][1], 0, 0, 0);
    }

    // ---- h = relu(acc + A + B); strength-reduced addressing:
    // A: cg = 2wv + j -> addr_j1 = addr_j0 ^ 16. B: cb = 4wv + 2j + (col>>3) -> addr_j1 = addr_j0 ^ 32.
    float h[4][2][4];
    const int cgA = 2 * wv;
    const int cbB = 4 * wv + (col >> 3);
    const int coB = (col & 7) * 2;
    #pragma unroll
    for (int rt = 0; rt < 4; ++rt) {
        #pragma unroll
        for (int r = 0; r < 4; ++r) {
            const int row = rt * 16 + g * 4 + r;
            const int rd  = s_rid[row];
            const int aadr = row * 128 + ((cgA ^ (row & 7)) << 4) + col;
            const int badr = OB + rd * 256 + ((cbB ^ (rd & 15)) << 4) + coB;
            const uchar_t  a0 = lds8[aadr];
            const uchar_t  a1 = lds8[aadr ^ 16];
            const ushort_t b0 = *(const ushort_t*)&lds8[badr];
            const ushort_t b1 = *(const ushort_t*)&lds8[badr ^ 32];
            h[rt][0][r] = fmaxf(acc[rt][0][r] + f8d(a0) + bf2f(b0), 0.f);
            h[rt][1][r] = fmaxf(acc[rt][1][r] + f8d(a1) + bf2f(b1), 0.f);
        }
    }

    // ---- wave-local segment reduce -> mh (f32) ----
    float qs[4][2];
    #pragma unroll
    for (int rt = 0; rt < 4; ++rt) {
        qs[rt][0] = (h[rt][0][0] + h[rt][0][1]) + (h[rt][0][2] + h[rt][0][3]);
        qs[rt][1] = (h[rt][1][0] + h[rt][1][1]) + (h[rt][1][2] + h[rt][1][3]);
    }
    unsigned long long rem = mask;
    while (rem) {
        const int beg = (int)__builtin_ctzll(rem);
        rem &= rem - 1;
        const int end = rem ? (int)__builtin_ctzll(rem) : nvalid;
        const int dg  = __shfl(myd, beg, 64);

        float s0 = 0.f, s1 = 0.f;
        #pragma unroll
        for (int rt = 0; rt < 4; ++rt) {
            const int qb = rt * 16 + g * 4;
            const int lo = max(qb, beg);
            const int hi = min(qb + 4, end);
            if (lo < hi) {
                if (lo == qb && hi == qb + 4) {
                    s0 += qs[rt][0]; s1 += qs[rt][1];
                } else {
                    #pragma unroll
                    for (int r = 0; r < 4; ++r) {
                        const int sl = qb + r;
                        if (sl >= beg && sl < end) {
                            s0 += h[rt][0][r]; s1 += h[rt][1][r];
                        }
                    }
                }
            }
        }
        s0 += __shfl_xor(s0, 16, 64); s0 += __shfl_xor(s0, 32, 64);
        s1 += __shfl_xor(s1, 16, 64); s1 += __shfl_xor(s1, 32, 64);
        if (g == 0) {
            const bool bnd = (beg == 0 && dg == prevd) || (end == nvalid && dg == nextd);
            float* p = mh + (size_t)dg * D + wv * 32 + col;
            if (bnd) { atomicAdd(p, s0); atomicAdd(p + 16, s1); }
            else     { p[0] = s0; p[16] = s1; }
        }
    }
}

// ---------------- node_fused: msum = mh@Wm2 + cnt*bm2; hin = msum + f; node MLP -> out ----------------
__global__ __launch_bounds__(NT, 4) void node_fused_kernel(
    const float* __restrict__ f, const float* __restrict__ mh,
    const int* __restrict__ cnt,
    const ushort_t* __restrict__ W2p, const float* __restrict__ bm2,
    const ushort_t* __restrict__ Wu1p, const float* __restrict__ bu1,
    const ushort_t* __restrict__ Wu2p, const float* __restrict__ bu2,
    float* __restrict__ out, int Nn)
{
    __shared__ __align__(16) ushort_t lds[2 * 64 * 64];   // 16 KB
    __shared__ int s_cnt[64];

    const int t    = threadIdx.x;
    const int lane = t & 63;
    const int wv   = t >> 6;
    const int col  = lane & 15;
    const int g    = lane >> 4;
    const int n0   = blockIdx.x * 64;

    if (t < 64) s_cnt[t] = (n0 + t < Nn) ? cnt[n0 + t] : 0;

    #pragma unroll
    for (int it = 0; it < 4; ++it) {
        const int gidx = it * 256 + t;
        const int row  = gidx >> 4;
        const int gr   = gidx & 15;
        const int pair = gr >> 3, s = gr & 7;
        const int sP   = s ^ (row & 7);
        const int gn   = n0 + row;
        union { ushort_t us[8]; short8v v; } pk;
        if (gn < Nn) {
            const size_t off = (size_t)gn * D + gr * 8;
            float4 m0 = *(const float4*)(mh + off);
            float4 m1 = *(const float4*)(mh + off + 4);
            pk.us[0] = f2bf(m0.x); pk.us[1] = f2bf(m0.y);
            pk.us[2] = f2bf(m0.z); pk.us[3] = f2bf(m0.w);
            pk.us[4] = f2bf(m1.x); pk.us[5] = f2bf(m1.y);
            pk.us[6] = f2bf(m1.z); pk.us[7] = f2bf(m1.w);
        } else {
            #pragma unroll
            for (int j = 0; j < 8; ++j) pk.us[j] = 0;
        }
        *(short8v*)&lds[(pair * 64 + row) * 64 + sP * 8] = pk.v;
    }
    __syncthreads();   // B0: mh staged

    f32x4 acc[4][2];
    {
        const float bv0 = bm2[wv * 32 + col];
        const float bv1 = bm2[wv * 32 + 16 + col];
        #pragma unroll
        for (int rt = 0; rt < 4; ++rt)
            #pragma unroll
            for (int r = 0; r < 4; ++r) {
                const float cn = (float)s_cnt[rt * 16 + g * 4 + r];
                acc[rt][0][r] = cn * bv0;
                acc[rt][1][r] = cn * bv1;
            }
    }
    #pragma unroll
    for (int c = 0; c < 4; ++c) {
        short8v b0 = *(const short8v*)&W2p[(size_t)(wv * 32 + col) * HD + c * 32 + g * 8];
        short8v b1 = *(const short8v*)&W2p[(size_t)(wv * 32 + 16 + col) * HD + c * 32 + g * 8];
        short8v a[4];
        #pragma unroll
        for (int rt = 0; rt < 4; ++rt) {
            const int row = rt * 16 + col;
            const int sP = (((c & 1) << 2) + g) ^ (row & 7);
            a[rt] = *(const short8v*)&lds[((c >> 1) * 64 + row) * 64 + sP * 8];
        }
        #pragma unroll
        for (int rt = 0; rt < 4; ++rt) {
            acc[rt][0] = __builtin_amdgcn_mfma_f32_16x16x32_bf16(a[rt], b0, acc[rt][0], 0, 0, 0);
            acc[rt][1] = __builtin_amdgcn_mfma_f32_16x16x32_bf16(a[rt], b1, acc[rt][1], 0, 0, 0);
        }
    }
    __syncthreads();   // B1

    const int ph = wv >> 1;
    #pragma unroll
    for (int rt = 0; rt < 4; ++rt)
        #pragma unroll
        for (int r = 0; r < 4; ++r) {
            const int row = rt * 16 + g * 4 + r;
            const int gn = n0 + row;
            #pragma unroll
            for (int j = 0; j < 2; ++j) {
                const int ca = wv * 32 + j * 16 + col;
                float v = 0.f;
                if (gn < Nn) v = acc[rt][j][r] + f[(size_t)gn * D + ca];
                unsigned int pk2 = cvt_pk_bf16(v, v);
                const int sH = (((wv & 1) << 2) + j * 2 + (col >> 3)) ^ (row & 7);
                lds[(ph * 64 + row) * 64 + sH * 8 + (col & 7)] = (ushort_t)pk2;
            }
        }
    __syncthreads();   // B2

    const size_t wrow0 = (size_t)(wv * 32 + col) * HD;
    const size_t wrow1 = (size_t)(wv * 32 + 16 + col) * HD;
    f32x4 acc1[4][2];
    {
        float bv0 = bu1[wv * 32 + col];
        float bv1 = bu1[wv * 32 + 16 + col];
        #pragma unroll
        for (int rt = 0; rt < 4; ++rt) {
            acc1[rt][0] = (f32x4){bv0, bv0, bv0, bv0};
            acc1[rt][1] = (f32x4){bv1, bv1, bv1, bv1};
        }
    }
    #pragma unroll
    for (int c = 0; c < 4; ++c) {
        short8v b0 = *(const short8v*)&Wu1p[wrow0 + c * 32 + g * 8];
        short8v b1 = *(const short8v*)&Wu1p[wrow1 + c * 32 + g * 8];
        short8v a[4];
        #pragma unroll
        for (int rt = 0; rt < 4; ++rt) {
            const int row = rt * 16 + col;
            const int sP = (((c & 1) << 2) + g) ^ (row & 7);
            a[rt] = *(const short8v*)&lds[((c >> 1) * 64 + row) * 64 + sP * 8];
        }
        #pragma unroll
        for (int rt = 0; rt < 4; ++rt) {
            acc1[rt][0] = __builtin_amdgcn_mfma_f32_16x16x32_bf16(a[rt], b0, acc1[rt][0], 0, 0, 0);
            acc1[rt][1] = __builtin_amdgcn_mfma_f32_16x16x32_bf16(a[rt], b1, acc1[rt][1], 0, 0, 0);
        }
    }
    __syncthreads();   // B3

    #pragma unroll
    for (int rt = 0; rt < 4; ++rt)
        #pragma unroll
        for (int j = 0; j < 2; ++j)
            #pragma unroll
            for (int r = 0; r < 4; ++r) {
                const int row = rt * 16 + g * 4 + r;
                float v = fmaxf(acc1[rt][j][r], 0.f);
                unsigned int pk2 = cvt_pk_bf16(v, v);
                const int sH = (((wv & 1) << 2) + j * 2 + (col >> 3)) ^ (row & 7);
                lds[(ph * 64 + row) * 64 + sH * 8 + (col & 7)] = (ushort_t)pk2;
            }
    __syncthreads();   // B4

    f32x4 acc2[4][2];
    {
        float bv0 = bu2[wv * 32 + col];
        float bv1 = bu2[wv * 32 + 16 + col];
        #pragma unroll
        for (int rt = 0; rt < 4; ++rt) {
            acc2[rt][0] = (f32x4){bv0, bv0, bv0, bv0};
            acc2[rt][1] = (f32x4){bv1, bv1, bv1, bv1};
        }
    }
    #pragma unroll
    for (int c = 0; c < 4; ++c) {
        short8v b0 = *(const short8v*)&Wu2p[wrow0 + c * 32 + g * 8];
        short8v b1 = *(const short8v*)&Wu2p[wrow1 + c * 32 + g * 8];
        short8v a[4];
        #pragma unroll
        for (int rt = 0; rt < 4; ++rt) {
            const int row = rt * 16 + col;
            const int sP = (((c & 1) << 2) + g) ^ (row & 7);
            a[rt] = *(const short8v*)&lds[((c >> 1) * 64 + row) * 64 + sP * 8];
        }
        #pragma unroll
        for (int rt = 0; rt < 4; ++rt) {
            acc2[rt][0] = __builtin_amdgcn_mfma_f32_16x16x32_bf16(a[rt], b0, acc2[rt][0], 0, 0, 0);
            acc2[rt][1] = __builtin_amdgcn_mfma_f32_16x16x32_bf16(a[rt], b1, acc2[rt][1], 0, 0, 0);
        }
    }

    #pragma unroll
    for (int rt = 0; rt < 4; ++rt)
        #pragma unroll
        for (int r = 0; r < 4; ++r) {
            const int row = rt * 16 + g * 4 + r;
            const int gn = n0 + row;
            if (gn < Nn) {
                out[(size_t)gn * D + wv * 32 + col]      = acc2[rt][0][r];
                out[(size_t)gn * D + wv * 32 + 16 + col] = acc2[rt][1][r];
            }
        }
}

// ================= fallback kernels (bf16 pk-atomic path; unchanged) =================

__global__ void repack_kernel(const float* __restrict__ Wm1, const float* __restrict__ Wm2,
                              ushort_t* __restrict__ W1p, ushort_t* __restrict__ W2p) {
    int idx = blockIdx.x * 256 + threadIdx.x;
    const int n1 = 128 * KP1;
    if (idx < n1) {
        int n = idx / KP1, k = idx % KP1;
        W1p[idx] = f2bf((k < MSG_IN) ? Wm1[(size_t)k * HD + n] : 0.f);
    } else {
        int i2 = idx - n1;
        if (i2 < HD * D) {
            int n = i2 / HD, k = i2 % HD;
            W2p[i2] = f2bf(Wm2[(size_t)k * D + n]);
        }
    }
}

__global__ void fconv_kernel(const float* __restrict__ f, ushort_t* __restrict__ fb, int n8) {
    int i = blockIdx.x * 256 + threadIdx.x;
    if (i < n8) {
        float4 v0 = *(const float4*)(f + (size_t)i * 8);
        float4 v1 = *(const float4*)(f + (size_t)i * 8 + 4);
        union { ushort_t us[8]; short8v v; } pk;
        pk.us[0] = f2bf(v0.x); pk.us[1] = f2bf(v0.y);
        pk.us[2] = f2bf(v0.z); pk.us[3] = f2bf(v0.w);
        pk.us[4] = f2bf(v1.x); pk.us[5] = f2bf(v1.y);
        pk.us[6] = f2bf(v1.z); pk.us[7] = f2bf(v1.w);
        *(short8v*)(fb + (size_t)i * 8) = pk.v;
    }
}

__global__ __launch_bounds__(NT, 4) void edge_mfma_kernel(
    const ushort_t* __restrict__ fbf, const float* __restrict__ x,
    const float* __restrict__ w, const int* __restrict__ src,
    const int* __restrict__ dst,
    const ushort_t* __restrict__ W1p, const float* __restrict__ bm1,
    const ushort_t* __restrict__ W2p, const float* __restrict__ bm2,
    ushort_t* msum, int E)
{
    __shared__ __align__(16) ushort_t lds[LDS1];
    __shared__ int s_dst[EB];

    const int t    = threadIdx.x;
    const int lane = t & 63;
    const int wv   = t >> 6;
    const int e0   = blockIdx.x * EB;

    if (t < EB) s_dst[t] = (e0 + t < E) ? dst[e0 + t] : 0;
    {
        const int el8 = lane >> 3;
        const int s   = lane & 7;
        const int sl  = s ^ el8;
        const int geA = min(e0 + wv * 16 + el8,     E - 1);
        const int geB = min(e0 + wv * 16 + 8 + el8, E - 1);
        const int nsA = src[geA], ndA = dst[geA];
        const int nsB = src[geB], ndB = dst[geB];
        #pragma unroll
        for (int p = 0; p < 4; ++p) {
            const int n0 = (p < 2) ? nsA : ndA;
            const int n1 = (p < 2) ? nsB : ndB;
            const ushort_t* g0 = fbf + (size_t)n0 * D + (p & 1) * 64 + sl * 8;
            const ushort_t* g1 = fbf + (size_t)n1 * D + (p & 1) * 64 + sl * 8;
            GLOAD_LDS16(g0, &lds[(p * EB + wv * 16    ) * 64]);
            GLOAD_LDS16(g1, &lds[(p * EB + wv * 16 + 8) * 64]);
        }
    }
    {
        const int el = lane >> 2, q = lane & 3;
        const int qp = q ^ (el & 3);
        const int ge = e0 + wv * 16 + el;
        const bool ok = ge < E;
        const int gc = min(ge, E - 1);
        union { ushort_t us[8]; short8v v; } pk;
        #pragma unroll
        for (int j = 0; j < 8; ++j) pk.us[j] = 0;
        if (ok) {
            if (q < 2) {
                float4 w0 = *(const float4*)(w + (size_t)gc * DE + q * 8);
                float4 w1 = *(const float4*)(w + (size_t)gc * DE + q * 8 + 4);
                pk.us[0] = f2bf(w0.x); pk.us[1] = f2bf(w0.y);
                pk.us[2] = f2bf(w0.z); pk.us[3] = f2bf(w0.w);
                pk.us[4] = f2bf(w1.x); pk.us[5] = f2bf(w1.y);
                pk.us[6] = f2bf(w1.z); pk.us[7] = f2bf(w1.w);
            } else if (q == 2) {
                const int ns = src[gc], nd = dst[gc];
                float dx = x[ns*3+0] - x[nd*3+0];
                float dy = x[ns*3+1] - x[nd*3+1];
                float dz = x[ns*3+2] - x[nd*3+2];
                pk.us[0] = f2bf(dx*dx + dy*dy + dz*dz);
            }
        }
        *(short8v*)&lds[CH8 + (wv * 16 + el) * 32 + qp * 8] = pk.v;
    }

    const int col = lane & 15;
    const int g   = lane >> 4;
    const size_t wrow0 = (size_t)(wv * 32 + col) * KP1;
    const size_t wrow1 = (size_t)(wv * 32 + 16 + col) * KP1;
    short8v nb0 = *(const short8v*)&W1p[wrow0 + g * 8];
    short8v nb1 = *(const short8v*)&W1p[wrow1 + g * 8];
    __syncthreads();

    f32x4 acc[4][2];
    {
        float bv0 = bm1[wv * 32 + col];
        float bv1 = bm1[wv * 32 + 16 + col];
        #pragma unroll
        for (int rt = 0; rt < 4; ++rt) {
            acc[rt][0] = (f32x4){bv0, bv0, bv0, bv0};
            acc[rt][1] = (f32x4){bv1, bv1, bv1, bv1};
        }
    }
    #pragma unroll
    for (int c = 0; c < 9; ++c) {
        short8v b0 = nb0, b1 = nb1;
        if (c + 1 < 9) {
            nb0 = *(const short8v*)&W1p[wrow0 + (c + 1) * 32 + g * 8];
            nb1 = *(const short8v*)&W1p[wrow1 + (c + 1) * 32 + g * 8];
        }
        short8v a[4];
        #pragma unroll
        for (int rt = 0; rt < 4; ++rt) {
            const int row = rt * 16 + col;
            if (c < 8) {
                const int sP = (((c & 1) << 2) + g) ^ (row & 7);
                a[rt] = *(const short8v*)&lds[((c >> 1) * EB + row) * 64 + sP * 8];
            } else {
                const int sP = g ^ (row & 3);
                a[rt] = *(const short8v*)&lds[CH8 + row * 32 + sP * 8];
            }
        }
        #pragma unroll
        for (int rt = 0; rt < 4; ++rt) {
            acc[rt][0] = __builtin_amdgcn_mfma_f32_16x16x32_bf16(a[rt], b0, acc[rt][0], 0, 0, 0);
            acc[rt][1] = __builtin_amdgcn_mfma_f32_16x16x32_bf16(a[rt], b1, acc[rt][1], 0, 0, 0);
        }
    }
    __syncthreads();

    const int ph = wv >> 1;
    #pragma unroll
    for (int rt = 0; rt < 4; ++rt)
        #pragma unroll
        for (int j = 0; j < 2; ++j)
            #pragma unroll
            for (int r = 0; r < 4; ++r) {
                const int row = rt * 16 + g * 4 + r;
                float v = fmaxf(acc[rt][j][r], 0.f);
                unsigned int pk2 = cvt_pk_bf16(v, v);
                const int sH = (((wv & 1) << 2) + j * 2 + (col >> 3)) ^ (row & 7);
                lds[(ph * EB + row) * 64 + sH * 8 + (col & 7)] = (ushort_t)pk2;
            }
    __syncthreads();

    const size_t w2r0 = (size_t)(wv * 32 + col) * HD;
    const size_t w2r1 = (size_t)(wv * 32 + 16 + col) * HD;
    short8v m0 = *(const short8v*)&W2p[w2r0 + g * 8];
    short8v m1 = *(const short8v*)&W2p[w2r1 + g * 8];
    f32x4 acc2[4][2];
    {
        float bv0 = bm2[wv * 32 + col];
        float bv1 = bm2[wv * 32 + 16 + col];
        #pragma unroll
        for (int rt = 0; rt < 4; ++rt) {
            acc2[rt][0] = (f32x4){bv0, bv0, bv0, bv0};
            acc2[rt][1] = (f32x4){bv1, bv1, bv1, bv1};
        }
    }
    #pragma unroll
    for (int c = 0; c < NCH2; ++c) {
        short8v b0 = m0, b1 = m1;
        if (c + 1 < NCH2) {
            m0 = *(const short8v*)&W2p[w2r0 + (c + 1) * 32 + g * 8];
            m1 = *(const short8v*)&W2p[w2r1 + (c + 1) * 32 + g * 8];
        }
        short8v a[4];
        #pragma unroll
        for (int rt = 0; rt < 4; ++rt) {
            const int row = rt * 16 + col;
            const int sP = (((c & 1) << 2) + g) ^ (row & 7);
            a[rt] = *(const short8v*)&lds[((c >> 1) * EB + row) * 64 + sP * 8];
        }
        #pragma unroll
        for (int rt = 0; rt < 4; ++rt) {
            acc2[rt][0] = __builtin_amdgcn_mfma_f32_16x16x32_bf16(a[rt], b0, acc2[rt][0], 0, 0, 0);
            acc2[rt][1] = __builtin_amdgcn_mfma_f32_16x16x32_bf16(a[rt], b1, acc2[rt][1], 0, 0, 0);
        }
    }

    const bool even = (col & 1) == 0;
    #pragma unroll
    for (int rt = 0; rt < 4; ++rt)
        #pragma unroll
        for (int r = 0; r < 4; ++r) {
            const int e  = rt * 16 + g * 4 + r;
            const int ge = e0 + e;
            const int dg = s_dst[e];
            #pragma unroll
            for (int j = 0; j < 2; ++j) {
                float v  = acc2[rt][j][r];
                float vn = __shfl_xor(v, 1, 64);
                if (even && ge < E) {
                    unsigned int pk2 = cvt_pk_bf16(v, vn);
                    ushort_t* p = msum + (size_t)dg * D + wv * 32 + j * 16 + col;
                    asm volatile("global_atomic_pk_add_bf16 %0, %1, off"
                                 :: "v"(p), "v"(pk2) : "memory");
                }
            }
        }
}

template<bool MB16>
__global__ __launch_bounds__(NT, 4) void node_kernel(
    const float* __restrict__ f, const void* __restrict__ msum_v,
    const float* __restrict__ Wu1, const float* __restrict__ bu1,
    const float* __restrict__ Wu2, const float* __restrict__ bu2,
    float* out, int Nn)
{
    __shared__ __align__(16) float hin[NB][HID_PAD];
    __shared__ __align__(16) float hid[NB][HID_PAD];
    const int t  = threadIdx.x;
    const int n0 = blockIdx.x * NB;
    const int nn = min(NB, Nn - n0);

    {
        #pragma unroll
        for (int it = 0; it < 4; ++it) {
            const int idx = it * 1024 + t * 4;
            const int e   = idx >> 7;
            const int cb  = idx & 127;
            if (e < nn) {
                const size_t off = (size_t)(n0 + e) * D + cb;
                float4 mv;
                if (MB16) {
                    uint2 pk = *(const uint2*)((const ushort_t*)msum_v + off);
                    mv.x = bf2f((ushort_t)(pk.x & 0xffffu));
                    mv.y = bf2f((ushort_t)(pk.x >> 16));
                    mv.z = bf2f((ushort_t)(pk.y & 0xffffu));
                    mv.w = bf2f((ushort_t)(pk.y >> 16));
                } else {
                    mv = *(const float4*)((const float*)msum_v + off);
                }
                float4 fv = *(const float4*)&f[off];
                float4 o = {mv.x + fv.x, mv.y + fv.y, mv.z + fv.z, mv.w + fv.w};
                *(float4*)&hin[e][cb] = o;
            }
        }
    }
    __syncthreads();

    const int tc = t & 15, te2 = (t >> 4) * 2, c0 = tc * 8;
    float a1[2][8];
    #pragma unroll
    for (int c = 0; c < 8; ++c) { float bv = bu1[c0 + c]; a1[0][c] = bv; a1[1][c] = bv; }
    for (int i = 0; i < D; i += 4) {
        float m0[4], m1[4];
        *(float4*)m0 = *(const float4*)&hin[te2][i];
        *(float4*)m1 = *(const float4*)&hin[te2 + 1][i];
        #pragma unroll
        for (int r = 0; r < 4; ++r) {
            float wr[8];
            *(float4*)&wr[0] = *(const float4*)(Wu1 + (size_t)(i + r) * HD + c0);
            *(float4*)&wr[4] = *(const float4*)(Wu1 + (size_t)(i + r) * HD + c0 + 4);
            #pragma unroll
            for (int c = 0; c < 8; ++c) { a1[0][c] += m0[r]*wr[c]; a1[1][c] += m1[r]*wr[c]; }
        }
    }
    #pragma unroll
    for (int j = 0; j < 2; ++j) {
        float v[8];
        #pragma unroll
        for (int c = 0; c < 8; ++c) v[c] = fmaxf(a1[j][c], 0.f);
        *(float4*)&hid[te2 + j][c0] = *(float4*)&v[0];
        *(float4*)&hid[te2 + j][c0 + 4] = *(float4*)&v[4];
    }
    __syncthreads();
    float a2[2][8];
    #pragma unroll
    for (int c = 0; c < 8; ++c) { float bv = bu2[c0 + c]; a2[0][c] = bv; a2[1][c] = bv; }
    for (int h = 0; h < HD; h += 4) {
        float m0[4], m1[4];
        *(float4*)m0 = *(const float4*)&hid[te2][h];
        *(float4*)m1 = *(const float4*)&hid[te2 + 1][h];
        #pragma unroll
        for (int r = 0; r < 4; ++r) {
            float wr[8];
            *(float4*)&wr[0] = *(const float4*)(Wu2 + (size_t)(h + r) * D + c0);
            *(float4*)&wr[4] = *(const float4*)(Wu2 + (size_t)(h + r) * D + c0 + 4);
            #pragma unroll
            for (int c = 0; c < 8; ++c) { a2[0][c] += m0[r]*wr[c]; a2[1][c] += m1[r]*wr[c]; }
        }
    }
    #pragma unroll
    for (int j = 0; j < 2; ++j) {
        int e = te2 + j, gn = n0 + e;
        if (e < nn) {
            *(float4*)(out + (size_t)gn * D + c0) = *(float4*)&a2[j][0];
            *(float4*)(out + (size_t)gn * D + c0 + 4) = *(float4*)&a2[j][4];
        }
    }
}

extern "C" void kernel_launch(void* const* d_in, const int* in_sizes, int n_in,
                              void* d_out, int out_size, void* d_ws, size_t ws_size,
                              hipStream_t stream) {
    const float* f   = (const float*)d_in[0];
    const float* x   = (const float*)d_in[1];
    const float* w   = (const float*)d_in[2];
    const int*   src = (const int*)d_in[3];
    const int*   dst = (const int*)d_in[4];
    const float* Wm1 = (const float*)d_in[5];
    const float* bm1 = (const float*)d_in[6];
    const float* Wm2 = (const float*)d_in[7];
    const float* bm2 = (const float*)d_in[8];
    const float* Wu1 = (const float*)d_in[9];
    const float* bu1 = (const float*)d_in[10];
    const float* Wu2 = (const float*)d_in[11];
    const float* bu2 = (const float*)d_in[12];

    const int Nn = in_sizes[0] / D;
    const int E  = in_sizes[3];

    const size_t wbytes  = (size_t)(128 * KP1 + HD * D) * sizeof(ushort_t);
    const size_t wubytes = (size_t)(2 * HD * D) * sizeof(ushort_t);
    auto align512 = [](size_t v) { return (v + 511) & ~(size_t)511; };
    char* wsb = (char*)d_ws;

    // ---------------- primary: linear-trick path (A fp8, B bf16), fused tail ----------------
    size_t off = 0;
    const size_t o_w    = off; off = align512(off + wbytes);
    const size_t o_wu   = off; off = align512(off + wubytes);
    const size_t o_af   = off; off = align512(off + (size_t)Nn * D);
    const size_t o_bf16 = off; off = align512(off + (size_t)Nn * D * 2);
    const size_t o_cnt  = off; off = align512(off + (size_t)Nn * 4);
    const size_t o_roff = off; off = align512(off + (size_t)Nn * 4);
    const size_t o_cur  = off; off = align512(off + (size_t)Nn * 4);
    const size_t o_perm = off; off = align512(off + (size_t)E * 4);
    const size_t o_sdst = off; off = align512(off + (size_t)E * 4);
    const size_t o_mh   = off; off = align512(off + (size_t)Nn * D * 4);
    const size_t primary_total = off;

    if (ws_size >= primary_total) {
        ushort_t* W1p  = (ushort_t*)(wsb + o_w);
        ushort_t* W2p  = W1p + 128 * KP1;
        ushort_t* Wu1p = (ushort_t*)(wsb + o_wu);
        ushort_t* Wu2p = Wu1p + HD * D;
        uchar_t*  Af   = (uchar_t*)(wsb + o_af);
        ushort_t* Bf16 = (ushort_t*)(wsb + o_bf16);
        int* cnt       = (int*)(wsb + o_cnt);
        int* roff      = (int*)(wsb + o_roff);
        int* cursor    = (int*)(wsb + o_cur);
        int* perm      = (int*)(wsb + o_perm);
        int* sdst      = (int*)(wsb + o_sdst);
        float* mh      = (float*)(wsb + o_mh);

        const int ntiles = (E + EB - 1) / EB;
        const int nblk   = (Nn + 63) / 64;
        hipMemsetAsync(cnt, 0, (size_t)Nn * 4, stream);
        fused_pre_kernel<<<dim3(1024), dim3(256), 0, stream>>>(
            Wm1, Wm2, Wu1, Wu2, W1p, W2p, Wu1p, Wu2p, dst, cnt, E);
        scan_kernel<<<dim3(1), dim3(1024), 0, stream>>>(cnt, roff, cursor, Nn);
        scatter_kernel<<<dim3((E + 255) / 256), dim3(256), 0, stream>>>(
            dst, cursor, roff, cnt, perm, sdst, mh, E, Nn);
        ab_kernel<<<dim3(nblk), dim3(NT), 0, stream>>>(f, W1p, Af, Bf16, Nn);
        edge_lin_kernel<<<dim3(ntiles), dim3(NT), 0, stream>>>(
            Af, Bf16, x, w, src, perm, sdst, W1p, bm1, mh, E);
        node_fused_kernel<<<dim3(nblk), dim3(NT), 0, stream>>>(
            f, mh, cnt, W2p, bm2, Wu1p, bu1, Wu2p, bu2, (float*)d_out, Nn);
        return;
    }

    // ---------------- fallback: bf16 pk-atomic path ----------------
    size_t off2 = 0;
    const size_t p_w  = off2; off2 = align512(off2 + wbytes);
    const size_t p_fb = off2; off2 = align512(off2 + (size_t)Nn * D * 2);
    const size_t p_ms = off2; off2 = align512(off2 + (size_t)Nn * D * 2);
    if (ws_size >= off2) {
        ushort_t* W1p  = (ushort_t*)(wsb + p_w);
        ushort_t* W2p  = W1p + 128 * KP1;
        ushort_t* fbf  = (ushort_t*)(wsb + p_fb);
        ushort_t* msum = (ushort_t*)(wsb + p_ms);
        const int rp_elems = 128 * KP1 + HD * D;
        hipMemsetAsync(msum, 0, (size_t)Nn * D * 2, stream);
        repack_kernel<<<dim3((rp_elems + 255) / 256), dim3(256), 0, stream>>>(Wm1, Wm2, W1p, W2p);
        const int n8 = Nn * D / 8;
        fconv_kernel<<<dim3((n8 + 255) / 256), dim3(256), 0, stream>>>(f, fbf, n8);
        edge_mfma_kernel<<<dim3((E + EB - 1) / EB), dim3(NT), 0, stream>>>(
            fbf, x, w, src, dst, W1p, bm1, W2p, bm2, msum, E);
        node_kernel<true><<<dim3((Nn + NB - 1) / NB), dim3(NT), 0, stream>>>(
            f, msum, Wu1, bu1, Wu2, bu2, (float*)d_out, Nn);
        return;
    }
}

// Round 22
// 252.629 us; speedup vs baseline: 1.6487x; 1.0067x over previous
//
#include <hip/hip_runtime.h>
#include <hip/hip_fp8.h>

#define D 128
#define HD 128
#define DE 16
#define MSG_IN 273
#define EB 64        // edges per tile
#define NT 256
#define KP1 288      // padded msg K = 9 chunks of 32
#define NCH2 4
#define NB 32
#define HID_PAD 132
#define CH8 (4 * EB * 64)
#define LDS1 (4 * EB * 64 + EB * 32)
// edge_lin LDS layout (bytes): A fp8 [0,8192) ; B bf16 [8192,24576) ; c8 bf16 [24576,28672)
#define OB 8192
#define OC 24576

typedef __attribute__((ext_vector_type(8))) short short8v;
typedef __attribute__((ext_vector_type(4))) float f32x4;
typedef unsigned short ushort_t;
typedef unsigned char uchar_t;

#define GLOAD_LDS16(gp, lp) \
    __builtin_amdgcn_global_load_lds((const __attribute__((address_space(1))) unsigned int*)(gp), \
                                     (__attribute__((address_space(3))) unsigned int*)(lp), 16, 0, 0)

__device__ __forceinline__ unsigned short f2bf(float v) {
    unsigned int u = __builtin_bit_cast(unsigned int, v);
    u += 0x7fffu + ((u >> 16) & 1u);
    return (unsigned short)(u >> 16);
}
__device__ __forceinline__ float bf2f(ushort_t u) {
    return __builtin_bit_cast(float, (unsigned int)u << 16);
}
__device__ __forceinline__ unsigned int cvt_pk_bf16(float lo, float hi) {
    unsigned int r;
    asm("v_cvt_pk_bf16_f32 %0, %1, %2" : "=v"(r) : "v"(lo), "v"(hi));
    return r;
}
__device__ __forceinline__ uchar_t f8e(float v) {   // f32 -> e4m3 (HIP library)
    __hip_fp8_e4m3 t(v);
    return (uchar_t)t.__x;
}
// e4m3fn -> f32: normals 2^(e-7)(1+m/8); subnormals m/8*2^-6; sign bit preserved.
__device__ __forceinline__ float f8d(unsigned b) {
    unsigned t = ((b & 0x7fu) << 20) | ((b & 0x80u) << 24);
    return __builtin_bit_cast(float, t) * 0x1p120f;
}

// ---------------- fused prepass: repack weights + dst hist ----------------
__global__ void fused_pre_kernel(const float* __restrict__ Wm1, const float* __restrict__ Wm2,
                                 const float* __restrict__ Wu1, const float* __restrict__ Wu2,
                                 ushort_t* __restrict__ W1p, ushort_t* __restrict__ W2p,
                                 ushort_t* __restrict__ Wu1p, ushort_t* __restrict__ Wu2p,
                                 const int* __restrict__ dst, int* __restrict__ cnt,
                                 int E) {
    const int gid    = blockIdx.x * 256 + threadIdx.x;
    const int stride = gridDim.x * 256;
    const int rp1 = 128 * KP1;
    const int rp2 = rp1 + HD * D;
    const int rp_elems = rp2 + 2 * HD * D;
    for (int i = gid; i < rp_elems; i += stride) {
        if (i < rp1) {
            int n = i / KP1, k = i % KP1;
            W1p[i] = f2bf((k < MSG_IN) ? Wm1[(size_t)k * HD + n] : 0.f);
        } else if (i < rp2) {
            int i2 = i - rp1;
            int n = i2 / HD, k = i2 % HD;
            W2p[i2] = f2bf(Wm2[(size_t)k * D + n]);
        } else {
            int i2 = (i - rp2);
            const bool second = i2 >= HD * D;
            if (second) i2 -= HD * D;
            int n = i2 / HD, k = i2 % HD;
            if (second) Wu2p[i2] = f2bf(Wu2[(size_t)k * D + n]);
            else        Wu1p[i2] = f2bf(Wu1[(size_t)k * HD + n]);
        }
    }
    for (int i = gid; i < E; i += stride) atomicAdd(&cnt[dst[i]], 1);
}

// ---------------- CSR build: parallel scan -> scatter + w->bf16 + selective zero ----------------
__global__ __launch_bounds__(1024) void scan_kernel(const int* __restrict__ cnt,
                                                    int* __restrict__ roff,
                                                    int* __restrict__ cursor, int Nn) {
    __shared__ int wsum[16];
    const int t = threadIdx.x, l = t & 63, wid = t >> 6;
    int running = 0;
    for (int base = 0; base < Nn; base += 4096) {
        const int i0 = base + t * 4;
        int v0 = 0, v1 = 0, v2 = 0, v3 = 0;
        if (i0 + 3 < Nn) {
            int4 v = *(const int4*)(cnt + i0);
            v0 = v.x; v1 = v.y; v2 = v.z; v3 = v.w;
        } else {
            if (i0 + 0 < Nn) v0 = cnt[i0 + 0];
            if (i0 + 1 < Nn) v1 = cnt[i0 + 1];
            if (i0 + 2 < Nn) v2 = cnt[i0 + 2];
        }
        const int vsum = v0 + v1 + v2 + v3;
        int s = vsum;
        #pragma unroll
        for (int off = 1; off < 64; off <<= 1) {
            int u = __shfl_up(s, off, 64);
            if (l >= off) s += u;
        }
        if (l == 63) wsum[wid] = s;
        __syncthreads();
        if (wid == 0 && l < 16) {
            int xv = wsum[l];
            #pragma unroll
            for (int off = 1; off < 16; off <<= 1) {
                int u = __shfl_up(xv, off, 64);
                if (l >= off) xv += u;
            }
            wsum[l] = xv;
        }
        __syncthreads();
        const int prev  = (wid > 0) ? wsum[wid - 1] : 0;
        const int total = wsum[15];
        int ex = running + prev + (s - vsum);
        if (i0 + 0 < Nn) { roff[i0 + 0] = ex; cursor[i0 + 0] = ex; } ex += v0;
        if (i0 + 1 < Nn) { roff[i0 + 1] = ex; cursor[i0 + 1] = ex; } ex += v1;
        if (i0 + 2 < Nn) { roff[i0 + 2] = ex; cursor[i0 + 2] = ex; } ex += v2;
        if (i0 + 3 < Nn) { roff[i0 + 3] = ex; cursor[i0 + 3] = ex; }
        running += total;
        __syncthreads();
    }
}

__global__ void scatter_kernel(const int* __restrict__ dst, int* cursor,
                               const int* __restrict__ roff, const int* __restrict__ cnt,
                               int* __restrict__ perm, int* __restrict__ sdst,
                               const float* __restrict__ w, ushort_t* __restrict__ wbf,
                               float* __restrict__ mh, int E, int Nn) {
    const int gid    = blockIdx.x * 256 + threadIdx.x;
    const int stride = gridDim.x * 256;
    for (int i = gid; i < E; i += stride) {
        int d = dst[i];
        int s = atomicAdd(&cursor[d], 1);
        perm[s] = i;
        sdst[s] = d;
        // ride-along: w row i -> bf16
        const float* wp = w + (size_t)i * DE;
        ushort_t* op = wbf + (size_t)i * DE;
        #pragma unroll
        for (int q = 0; q < 2; ++q) {
            float4 v0 = *(const float4*)(wp + q * 8);
            float4 v1 = *(const float4*)(wp + q * 8 + 4);
            union { ushort_t us[8]; short8v v; } pk;
            pk.us[0] = f2bf(v0.x); pk.us[1] = f2bf(v0.y);
            pk.us[2] = f2bf(v0.z); pk.us[3] = f2bf(v0.w);
            pk.us[4] = f2bf(v1.x); pk.us[5] = f2bf(v1.y);
            pk.us[6] = f2bf(v1.z); pk.us[7] = f2bf(v1.w);
            *(short8v*)(op + q * 8) = pk.v;
        }
    }
    for (int n = gid; n < Nn; n += stride) {
        const int c = cnt[n];
        const int r = roff[n];
        const bool need0 = (c == 0) || (r / EB != (r + c - 1) / EB);
        if (need0) {
            float4 z = {0.f, 0.f, 0.f, 0.f};
            float* p = mh + (size_t)n * D;
            #pragma unroll
            for (int k = 0; k < 32; ++k) *(float4*)(p + k * 4) = z;
        }
    }
}

// ---------------- AB precompute: A = f@Wm1[0:128] -> fp8, B = f@Wm1[128:256] -> bf16 ----------------
__global__ __launch_bounds__(NT, 4) void ab_kernel(
    const float* __restrict__ f,
    const ushort_t* __restrict__ W1p,
    uchar_t* __restrict__ Af, ushort_t* __restrict__ Bf16, int Nn)
{
    __shared__ __align__(16) ushort_t lds[2 * 64 * 64];   // 16 KB

    const int t    = threadIdx.x;
    const int lane = t & 63;
    const int wv   = t >> 6;
    const int col  = lane & 15;
    const int g    = lane >> 4;
    const int n0   = blockIdx.x * 64;

    #pragma unroll
    for (int it = 0; it < 4; ++it) {
        const int gidx = it * 256 + t;
        const int row  = gidx >> 4;
        const int gr   = gidx & 15;
        const int pair = gr >> 3, s = gr & 7;
        const int sP   = s ^ (row & 7);
        const int gn   = min(n0 + row, Nn - 1);
        const size_t off = (size_t)gn * D + gr * 8;
        float4 v0 = *(const float4*)(f + off);
        float4 v1 = *(const float4*)(f + off + 4);
        union { ushort_t us[8]; short8v v; } pk;
        pk.us[0] = f2bf(v0.x); pk.us[1] = f2bf(v0.y);
        pk.us[2] = f2bf(v0.z); pk.us[3] = f2bf(v0.w);
        pk.us[4] = f2bf(v1.x); pk.us[5] = f2bf(v1.y);
        pk.us[6] = f2bf(v1.z); pk.us[7] = f2bf(v1.w);
        *(short8v*)&lds[(pair * 64 + row) * 64 + sP * 8] = pk.v;
    }
    __syncthreads();

    const bool even = (col & 1) == 0;
    #pragma unroll
    for (int half = 0; half < 2; ++half) {          // 0: A (fp8), 1: B (bf16)
        f32x4 acc[4][2];
        #pragma unroll
        for (int rt = 0; rt < 4; ++rt) {
            acc[rt][0] = (f32x4){0.f, 0.f, 0.f, 0.f};
            acc[rt][1] = (f32x4){0.f, 0.f, 0.f, 0.f};
        }
        const int kbase = half * 128;
        #pragma unroll
        for (int c = 0; c < 4; ++c) {
            short8v b0 = *(const short8v*)&W1p[(size_t)(wv * 32 + col) * KP1 + kbase + c * 32 + g * 8];
            short8v b1 = *(const short8v*)&W1p[(size_t)(wv * 32 + 16 + col) * KP1 + kbase + c * 32 + g * 8];
            short8v a[4];
            #pragma unroll
            for (int rt = 0; rt < 4; ++rt) {
                const int row = rt * 16 + col;
                const int sP = (((c & 1) << 2) + g) ^ (row & 7);
                a[rt] = *(const short8v*)&lds[((c >> 1) * 64 + row) * 64 + sP * 8];
            }
            #pragma unroll
            for (int rt = 0; rt < 4; ++rt) {
                acc[rt][0] = __builtin_amdgcn_mfma_f32_16x16x32_bf16(a[rt], b0, acc[rt][0], 0, 0, 0);
                acc[rt][1] = __builtin_amdgcn_mfma_f32_16x16x32_bf16(a[rt], b1, acc[rt][1], 0, 0, 0);
            }
        }
        #pragma unroll
        for (int rt = 0; rt < 4; ++rt)
            #pragma unroll
            for (int j = 0; j < 2; ++j)
                #pragma unroll
                for (int r = 0; r < 4; ++r) {
                    const int row = rt * 16 + g * 4 + r;
                    const int gn = n0 + row;
                    float v  = acc[rt][j][r];
                    float vn = __shfl_xor(v, 1, 64);
                    if (even && gn < Nn) {
                        const int ca = wv * 32 + j * 16 + col;
                        if (half == 0) {
                            ushort_t pk = (ushort_t)f8e(v) | ((ushort_t)f8e(vn) << 8);
                            *(ushort_t*)(Af + (size_t)gn * D + ca) = pk;
                        } else {
                            *(unsigned int*)(Bf16 + (size_t)gn * D + ca) = cvt_pk_bf16(v, vn);
                        }
                    }
                }
    }
}

// ---------------- edge kernel v22: bf16 wbf restored; strength-reduced h-addressing ----------------
__global__ __launch_bounds__(NT, 5) void edge_lin_kernel(
    const uchar_t* __restrict__ Af, const ushort_t* __restrict__ Bf16,
    const float* __restrict__ x, const ushort_t* __restrict__ wbf,
    const int* __restrict__ src,
    const int* __restrict__ perm, const int* __restrict__ sdst,
    const ushort_t* __restrict__ W1p, const float* __restrict__ bm1,
    float* __restrict__ mh, int E)
{
    __shared__ __align__(16) uchar_t lds8[28672];   // A 8K | B 16K | c8 4K
    __shared__ int s_rid[EB];
    __shared__ int s_dgs[EB];

    const int t    = threadIdx.x;
    const int lane = t & 63;
    const int wv   = t >> 6;
    const int e0   = blockIdx.x * EB;
    const int nvalid = min(EB, E - e0);

    const int myd  = (e0 + lane < E) ? sdst[e0 + lane] : -1;
    const int prevd = (e0 > 0) ? sdst[e0 - 1] : -2;
    const int nextd = (e0 + EB < E) ? sdst[e0 + EB] : -2;

    const int dprev_l = __shfl_up(myd, 1, 64);
    const bool head = (lane == 0) || (myd != dprev_l);
    const unsigned long long mask = __ballot(head && (lane < nvalid));
    const unsigned long long le = (lane == 63) ? ~0ull : ((1ull << (lane + 1)) - 1ull);
    const int rid = (int)__popcll(mask & le) - 1;
    const int ndist = (int)__popcll(mask);
    s_rid[lane] = (rid < 0) ? 0 : rid;
    if (head && lane < nvalid) s_dgs[rid] = myd;

    {
        const int el8 = lane >> 3;
        const int s   = lane & 7;
        const int sl  = s ^ el8;
        const int slA = min(e0 + wv * 16 + el8,     E - 1);
        const int slB = min(e0 + wv * 16 + 8 + el8, E - 1);
        const int nsA = src[perm[slA]];
        const int nsB = src[perm[slB]];
        GLOAD_LDS16(Af + (size_t)nsA * D + sl * 16, &lds8[(wv * 16    ) * 128]);
        GLOAD_LDS16(Af + (size_t)nsB * D + sl * 16, &lds8[(wv * 16 + 8) * 128]);
    }
    {
        const int ntask = ndist * 16;
        for (int idx = t; idx < ntask; idx += NT) {
            const int rowr = idx >> 4;
            const int gr   = idx & 15;
            const int dg   = s_dgs[rowr];
            uint4 v = *(const uint4*)(Bf16 + (size_t)dg * D + gr * 8);
            const int phys = gr ^ (rowr & 15);
            *(uint4*)&lds8[OB + rowr * 256 + phys * 16] = v;
        }
    }
    {
        const int el = lane >> 2, q = lane & 3;
        const int qp = q ^ (el & 3);
        const int slot = e0 + wv * 16 + el;
        const bool ok = slot < E;
        const int sc = min(slot, E - 1);
        const int ge = perm[sc];
        union { ushort_t us[8]; short8v v; } pk;
        #pragma unroll
        for (int j = 0; j < 8; ++j) pk.us[j] = 0;
        if (ok) {
            if (q < 2) {
                pk.v = *(const short8v*)(wbf + (size_t)ge * DE + q * 8);
            } else if (q == 2) {
                const int ns = src[ge], nd = sdst[sc];
                float dx = x[ns*3+0] - x[nd*3+0];
                float dy = x[ns*3+1] - x[nd*3+1];
                float dz = x[ns*3+2] - x[nd*3+2];
                pk.us[0] = f2bf(dx*dx + dy*dy + dz*dz);
            }
        }
        *(short8v*)&lds8[OC + (wv * 16 + el) * 64 + qp * 16] = pk.v;
    }

    const int col = lane & 15;
    const int g   = lane >> 4;

    short8v bc0 = *(const short8v*)&W1p[(size_t)(wv * 32 + col) * KP1 + 256 + g * 8];
    short8v bc1 = *(const short8v*)&W1p[(size_t)(wv * 32 + 16 + col) * KP1 + 256 + g * 8];

    __syncthreads();   // B0

    f32x4 acc[4][2];
    {
        float bv0 = bm1[wv * 32 + col];
        float bv1 = bm1[wv * 32 + 16 + col];
        #pragma unroll
        for (int rt = 0; rt < 4; ++rt) {
            acc[rt][0] = (f32x4){bv0, bv0, bv0, bv0};
            acc[rt][1] = (f32x4){bv1, bv1, bv1, bv1};
        }
    }
    #pragma unroll
    for (int rt = 0; rt < 4; ++rt) {
        const int row = rt * 16 + col;
        const int sP8 = g ^ (row & 3);
        short8v a = *(const short8v*)&lds8[OC + row * 64 + sP8 * 16];
        acc[rt][0] = __builtin_amdgcn_mfma_f32_16x16x32_bf16(a, bc0, acc[rt][0], 0, 0, 0);
        acc[rt][1] = __builtin_amdgcn_mfma_f32_16x16x32_bf16(a, bc1, acc[rt][1], 0, 0, 0);
    }

    // ---- h = relu(acc + A + B); strength-reduced addressing ----
    float h[4][2][4];
    const int cgA = 2 * wv;
    const int cbB = 4 * wv + (col >> 3);
    const int coB = (col & 7) * 2;
    #pragma unroll
    for (int rt = 0; rt < 4; ++rt) {
        #pragma unroll
        for (int r = 0; r < 4; ++r) {
            const int row = rt * 16 + g * 4 + r;
            const int rd  = s_rid[row];
            const int aadr = row * 128 + ((cgA ^ (row & 7)) << 4) + col;
            const int badr = OB + rd * 256 + ((cbB ^ (rd & 15)) << 4) + coB;
            const uchar_t  a0 = lds8[aadr];
            const uchar_t  a1 = lds8[aadr ^ 16];
            const ushort_t b0 = *(const ushort_t*)&lds8[badr];
            const ushort_t b1 = *(const ushort_t*)&lds8[badr ^ 32];
            h[rt][0][r] = fmaxf(acc[rt][0][r] + f8d(a0) + bf2f(b0), 0.f);
            h[rt][1][r] = fmaxf(acc[rt][1][r] + f8d(a1) + bf2f(b1), 0.f);
        }
    }

    // ---- wave-local segment reduce -> mh (f32) ----
    float qs[4][2];
    #pragma unroll
    for (int rt = 0; rt < 4; ++rt) {
        qs[rt][0] = (h[rt][0][0] + h[rt][0][1]) + (h[rt][0][2] + h[rt][0][3]);
        qs[rt][1] = (h[rt][1][0] + h[rt][1][1]) + (h[rt][1][2] + h[rt][1][3]);
    }
    unsigned long long rem = mask;
    while (rem) {
        const int beg = (int)__builtin_ctzll(rem);
        rem &= rem - 1;
        const int end = rem ? (int)__builtin_ctzll(rem) : nvalid;
        const int dg  = __shfl(myd, beg, 64);

        float s0 = 0.f, s1 = 0.f;
        #pragma unroll
        for (int rt = 0; rt < 4; ++rt) {
            const int qb = rt * 16 + g * 4;
            const int lo = max(qb, beg);
            const int hi = min(qb + 4, end);
            if (lo < hi) {
                if (lo == qb && hi == qb + 4) {
                    s0 += qs[rt][0]; s1 += qs[rt][1];
                } else {
                    #pragma unroll
                    for (int r = 0; r < 4; ++r) {
                        const int sl = qb + r;
                        if (sl >= beg && sl < end) {
                            s0 += h[rt][0][r]; s1 += h[rt][1][r];
                        }
                    }
                }
            }
        }
        s0 += __shfl_xor(s0, 16, 64); s0 += __shfl_xor(s0, 32, 64);
        s1 += __shfl_xor(s1, 16, 64); s1 += __shfl_xor(s1, 32, 64);
        if (g == 0) {
            const bool bnd = (beg == 0 && dg == prevd) || (end == nvalid && dg == nextd);
            float* p = mh + (size_t)dg * D + wv * 32 + col;
            if (bnd) { atomicAdd(p, s0); atomicAdd(p + 16, s1); }
            else     { p[0] = s0; p[16] = s1; }
        }
    }
}

// ---------------- node_fused: msum = mh@Wm2 + cnt*bm2; hin = msum + f; node MLP -> out ----------------
__global__ __launch_bounds__(NT, 4) void node_fused_kernel(
    const float* __restrict__ f, const float* __restrict__ mh,
    const int* __restrict__ cnt,
    const ushort_t* __restrict__ W2p, const float* __restrict__ bm2,
    const ushort_t* __restrict__ Wu1p, const float* __restrict__ bu1,
    const ushort_t* __restrict__ Wu2p, const float* __restrict__ bu2,
    float* __restrict__ out, int Nn)
{
    __shared__ __align__(16) ushort_t lds[2 * 64 * 64];   // 16 KB
    __shared__ int s_cnt[64];

    const int t    = threadIdx.x;
    const int lane = t & 63;
    const int wv   = t >> 6;
    const int col  = lane & 15;
    const int g    = lane >> 4;
    const int n0   = blockIdx.x * 64;

    if (t < 64) s_cnt[t] = (n0 + t < Nn) ? cnt[n0 + t] : 0;

    #pragma unroll
    for (int it = 0; it < 4; ++it) {
        const int gidx = it * 256 + t;
        const int row  = gidx >> 4;
        const int gr   = gidx & 15;
        const int pair = gr >> 3, s = gr & 7;
        const int sP   = s ^ (row & 7);
        const int gn   = n0 + row;
        union { ushort_t us[8]; short8v v; } pk;
        if (gn < Nn) {
            const size_t off = (size_t)gn * D + gr * 8;
            float4 m0 = *(const float4*)(mh + off);
            float4 m1 = *(const float4*)(mh + off + 4);
            pk.us[0] = f2bf(m0.x); pk.us[1] = f2bf(m0.y);
            pk.us[2] = f2bf(m0.z); pk.us[3] = f2bf(m0.w);
            pk.us[4] = f2bf(m1.x); pk.us[5] = f2bf(m1.y);
            pk.us[6] = f2bf(m1.z); pk.us[7] = f2bf(m1.w);
        } else {
            #pragma unroll
            for (int j = 0; j < 8; ++j) pk.us[j] = 0;
        }
        *(short8v*)&lds[(pair * 64 + row) * 64 + sP * 8] = pk.v;
    }
    __syncthreads();   // B0: mh staged

    f32x4 acc[4][2];
    {
        const float bv0 = bm2[wv * 32 + col];
        const float bv1 = bm2[wv * 32 + 16 + col];
        #pragma unroll
        for (int rt = 0; rt < 4; ++rt)
            #pragma unroll
            for (int r = 0; r < 4; ++r) {
                const float cn = (float)s_cnt[rt * 16 + g * 4 + r];
                acc[rt][0][r] = cn * bv0;
                acc[rt][1][r] = cn * bv1;
            }
    }
    #pragma unroll
    for (int c = 0; c < 4; ++c) {
        short8v b0 = *(const short8v*)&W2p[(size_t)(wv * 32 + col) * HD + c * 32 + g * 8];
        short8v b1 = *(const short8v*)&W2p[(size_t)(wv * 32 + 16 + col) * HD + c * 32 + g * 8];
        short8v a[4];
        #pragma unroll
        for (int rt = 0; rt < 4; ++rt) {
            const int row = rt * 16 + col;
            const int sP = (((c & 1) << 2) + g) ^ (row & 7);
            a[rt] = *(const short8v*)&lds[((c >> 1) * 64 + row) * 64 + sP * 8];
        }
        #pragma unroll
        for (int rt = 0; rt < 4; ++rt) {
            acc[rt][0] = __builtin_amdgcn_mfma_f32_16x16x32_bf16(a[rt], b0, acc[rt][0], 0, 0, 0);
            acc[rt][1] = __builtin_amdgcn_mfma_f32_16x16x32_bf16(a[rt], b1, acc[rt][1], 0, 0, 0);
        }
    }
    __syncthreads();   // B1

    const int ph = wv >> 1;
    #pragma unroll
    for (int rt = 0; rt < 4; ++rt)
        #pragma unroll
        for (int r = 0; r < 4; ++r) {
            const int row = rt * 16 + g * 4 + r;
            const int gn = n0 + row;
            #pragma unroll
            for (int j = 0; j < 2; ++j) {
                const int ca = wv * 32 + j * 16 + col;
                float v = 0.f;
                if (gn < Nn) v = acc[rt][j][r] + f[(size_t)gn * D + ca];
                unsigned int pk2 = cvt_pk_bf16(v, v);
                const int sH = (((wv & 1) << 2) + j * 2 + (col >> 3)) ^ (row & 7);
                lds[(ph * 64 + row) * 64 + sH * 8 + (col & 7)] = (ushort_t)pk2;
            }
        }
    __syncthreads();   // B2

    const size_t wrow0 = (size_t)(wv * 32 + col) * HD;
    const size_t wrow1 = (size_t)(wv * 32 + 16 + col) * HD;
    f32x4 acc1[4][2];
    {
        float bv0 = bu1[wv * 32 + col];
        float bv1 = bu1[wv * 32 + 16 + col];
        #pragma unroll
        for (int rt = 0; rt < 4; ++rt) {
            acc1[rt][0] = (f32x4){bv0, bv0, bv0, bv0};
            acc1[rt][1] = (f32x4){bv1, bv1, bv1, bv1};
        }
    }
    #pragma unroll
    for (int c = 0; c < 4; ++c) {
        short8v b0 = *(const short8v*)&Wu1p[wrow0 + c * 32 + g * 8];
        short8v b1 = *(const short8v*)&Wu1p[wrow1 + c * 32 + g * 8];
        short8v a[4];
        #pragma unroll
        for (int rt = 0; rt < 4; ++rt) {
            const int row = rt * 16 + col;
            const int sP = (((c & 1) << 2) + g) ^ (row & 7);
            a[rt] = *(const short8v*)&lds[((c >> 1) * 64 + row) * 64 + sP * 8];
        }
        #pragma unroll
        for (int rt = 0; rt < 4; ++rt) {
            acc1[rt][0] = __builtin_amdgcn_mfma_f32_16x16x32_bf16(a[rt], b0, acc1[rt][0], 0, 0, 0);
            acc1[rt][1] = __builtin_amdgcn_mfma_f32_16x16x32_bf16(a[rt], b1, acc1[rt][1], 0, 0, 0);
        }
    }
    __syncthreads();   // B3

    #pragma unroll
    for (int rt = 0; rt < 4; ++rt)
        #pragma unroll
        for (int j = 0; j < 2; ++j)
            #pragma unroll
            for (int r = 0; r < 4; ++r) {
                const int row = rt * 16 + g * 4 + r;
                float v = fmaxf(acc1[rt][j][r], 0.f);
                unsigned int pk2 = cvt_pk_bf16(v, v);
                const int sH = (((wv & 1) << 2) + j * 2 + (col >> 3)) ^ (row & 7);
                lds[(ph * 64 + row) * 64 + sH * 8 + (col & 7)] = (ushort_t)pk2;
            }
    __syncthreads();   // B4

    f32x4 acc2[4][2];
    {
        float bv0 = bu2[wv * 32 + col];
        float bv1 = bu2[wv * 32 + 16 + col];
        #pragma unroll
        for (int rt = 0; rt < 4; ++rt) {
            acc2[rt][0] = (f32x4){bv0, bv0, bv0, bv0};
            acc2[rt][1] = (f32x4){bv1, bv1, bv1, bv1};
        }
    }
    #pragma unroll
    for (int c = 0; c < 4; ++c) {
        short8v b0 = *(const short8v*)&Wu2p[wrow0 + c * 32 + g * 8];
        short8v b1 = *(const short8v*)&Wu2p[wrow1 + c * 32 + g * 8];
        short8v a[4];
        #pragma unroll
        for (int rt = 0; rt < 4; ++rt) {
            const int row = rt * 16 + col;
            const int sP = (((c & 1) << 2) + g) ^ (row & 7);
            a[rt] = *(const short8v*)&lds[((c >> 1) * 64 + row) * 64 + sP * 8];
        }
        #pragma unroll
        for (int rt = 0; rt < 4; ++rt) {
            acc2[rt][0] = __builtin_amdgcn_mfma_f32_16x16x32_bf16(a[rt], b0, acc2[rt][0], 0, 0, 0);
            acc2[rt][1] = __builtin_amdgcn_mfma_f32_16x16x32_bf16(a[rt], b1, acc2[rt][1], 0, 0, 0);
        }
    }

    #pragma unroll
    for (int rt = 0; rt < 4; ++rt)
        #pragma unroll
        for (int r = 0; r < 4; ++r) {
            const int row = rt * 16 + g * 4 + r;
            const int gn = n0 + row;
            if (gn < Nn) {
                out[(size_t)gn * D + wv * 32 + col]      = acc2[rt][0][r];
                out[(size_t)gn * D + wv * 32 + 16 + col] = acc2[rt][1][r];
            }
        }
}

// ================= fallback kernels (bf16 pk-atomic path; unchanged) =================

__global__ void repack_kernel(const float* __restrict__ Wm1, const float* __restrict__ Wm2,
                              ushort_t* __restrict__ W1p, ushort_t* __restrict__ W2p) {
    int idx = blockIdx.x * 256 + threadIdx.x;
    const int n1 = 128 * KP1;
    if (idx < n1) {
        int n = idx / KP1, k = idx % KP1;
        W1p[idx] = f2bf((k < MSG_IN) ? Wm1[(size_t)k * HD + n] : 0.f);
    } else {
        int i2 = idx - n1;
        if (i2 < HD * D) {
            int n = i2 / HD, k = i2 % HD;
            W2p[i2] = f2bf(Wm2[(size_t)k * D + n]);
        }
    }
}

__global__ void fconv_kernel(const float* __restrict__ f, ushort_t* __restrict__ fb, int n8) {
    int i = blockIdx.x * 256 + threadIdx.x;
    if (i < n8) {
        float4 v0 = *(const float4*)(f + (size_t)i * 8);
        float4 v1 = *(const float4*)(f + (size_t)i * 8 + 4);
        union { ushort_t us[8]; short8v v; } pk;
        pk.us[0] = f2bf(v0.x); pk.us[1] = f2bf(v0.y);
        pk.us[2] = f2bf(v0.z); pk.us[3] = f2bf(v0.w);
        pk.us[4] = f2bf(v1.x); pk.us[5] = f2bf(v1.y);
        pk.us[6] = f2bf(v1.z); pk.us[7] = f2bf(v1.w);
        *(short8v*)(fb + (size_t)i * 8) = pk.v;
    }
}

__global__ __launch_bounds__(NT, 4) void edge_mfma_kernel(
    const ushort_t* __restrict__ fbf, const float* __restrict__ x,
    const float* __restrict__ w, const int* __restrict__ src,
    const int* __restrict__ dst,
    const ushort_t* __restrict__ W1p, const float* __restrict__ bm1,
    const ushort_t* __restrict__ W2p, const float* __restrict__ bm2,
    ushort_t* msum, int E)
{
    __shared__ __align__(16) ushort_t lds[LDS1];
    __shared__ int s_dst[EB];

    const int t    = threadIdx.x;
    const int lane = t & 63;
    const int wv   = t >> 6;
    const int e0   = blockIdx.x * EB;

    if (t < EB) s_dst[t] = (e0 + t < E) ? dst[e0 + t] : 0;
    {
        const int el8 = lane >> 3;
        const int s   = lane & 7;
        const int sl  = s ^ el8;
        const int geA = min(e0 + wv * 16 + el8,     E - 1);
        const int geB = min(e0 + wv * 16 + 8 + el8, E - 1);
        const int nsA = src[geA], ndA = dst[geA];
        const int nsB = src[geB], ndB = dst[geB];
        #pragma unroll
        for (int p = 0; p < 4; ++p) {
            const int n0 = (p < 2) ? nsA : ndA;
            const int n1 = (p < 2) ? nsB : ndB;
            const ushort_t* g0 = fbf + (size_t)n0 * D + (p & 1) * 64 + sl * 8;
            const ushort_t* g1 = fbf + (size_t)n1 * D + (p & 1) * 64 + sl * 8;
            GLOAD_LDS16(g0, &lds[(p * EB + wv * 16    ) * 64]);
            GLOAD_LDS16(g1, &lds[(p * EB + wv * 16 + 8) * 64]);
        }
    }
    {
        const int el = lane >> 2, q = lane & 3;
        const int qp = q ^ (el & 3);
        const int ge = e0 + wv * 16 + el;
        const bool ok = ge < E;
        const int gc = min(ge, E - 1);
        union { ushort_t us[8]; short8v v; } pk;
        #pragma unroll
        for (int j = 0; j < 8; ++j) pk.us[j] = 0;
        if (ok) {
            if (q < 2) {
                float4 w0 = *(const float4*)(w + (size_t)gc * DE + q * 8);
                float4 w1 = *(const float4*)(w + (size_t)gc * DE + q * 8 + 4);
                pk.us[0] = f2bf(w0.x); pk.us[1] = f2bf(w0.y);
                pk.us[2] = f2bf(w0.z); pk.us[3] = f2bf(w0.w);
                pk.us[4] = f2bf(w1.x); pk.us[5] = f2bf(w1.y);
                pk.us[6] = f2bf(w1.z); pk.us[7] = f2bf(w1.w);
            } else if (q == 2) {
                const int ns = src[gc], nd = dst[gc];
                float dx = x[ns*3+0] - x[nd*3+0];
                float dy = x[ns*3+1] - x[nd*3+1];
                float dz = x[ns*3+2] - x[nd*3+2];
                pk.us[0] = f2bf(dx*dx + dy*dy + dz*dz);
            }
        }
        *(short8v*)&lds[CH8 + (wv * 16 + el) * 32 + qp * 8] = pk.v;
    }

    const int col = lane & 15;
    const int g   = lane >> 4;
    const size_t wrow0 = (size_t)(wv * 32 + col) * KP1;
    const size_t wrow1 = (size_t)(wv * 32 + 16 + col) * KP1;
    short8v nb0 = *(const short8v*)&W1p[wrow0 + g * 8];
    short8v nb1 = *(const short8v*)&W1p[wrow1 + g * 8];
    __syncthreads();

    f32x4 acc[4][2];
    {
        float bv0 = bm1[wv * 32 + col];
        float bv1 = bm1[wv * 32 + 16 + col];
        #pragma unroll
        for (int rt = 0; rt < 4; ++rt) {
            acc[rt][0] = (f32x4){bv0, bv0, bv0, bv0};
            acc[rt][1] = (f32x4){bv1, bv1, bv1, bv1};
        }
    }
    #pragma unroll
    for (int c = 0; c < 9; ++c) {
        short8v b0 = nb0, b1 = nb1;
        if (c + 1 < 9) {
            nb0 = *(const short8v*)&W1p[wrow0 + (c + 1) * 32 + g * 8];
            nb1 = *(const short8v*)&W1p[wrow1 + (c + 1) * 32 + g * 8];
        }
        short8v a[4];
        #pragma unroll
        for (int rt = 0; rt < 4; ++rt) {
            const int row = rt * 16 + col;
            if (c < 8) {
                const int sP = (((c & 1) << 2) + g) ^ (row & 7);
                a[rt] = *(const short8v*)&lds[((c >> 1) * EB + row) * 64 + sP * 8];
            } else {
                const int sP = g ^ (row & 3);
                a[rt] = *(const short8v*)&lds[CH8 + row * 32 + sP * 8];
            }
        }
        #pragma unroll
        for (int rt = 0; rt < 4; ++rt) {
            acc[rt][0] = __builtin_amdgcn_mfma_f32_16x16x32_bf16(a[rt], b0, acc[rt][0], 0, 0, 0);
            acc[rt][1] = __builtin_amdgcn_mfma_f32_16x16x32_bf16(a[rt], b1, acc[rt][1], 0, 0, 0);
        }
    }
    __syncthreads();

    const int ph = wv >> 1;
    #pragma unroll
    for (int rt = 0; rt < 4; ++rt)
        #pragma unroll
        for (int j = 0; j < 2; ++j)
            #pragma unroll
            for (int r = 0; r < 4; ++r) {
                const int row = rt * 16 + g * 4 + r;
                float v = fmaxf(acc[rt][j][r], 0.f);
                unsigned int pk2 = cvt_pk_bf16(v, v);
                const int sH = (((wv & 1) << 2) + j * 2 + (col >> 3)) ^ (row & 7);
                lds[(ph * EB + row) * 64 + sH * 8 + (col & 7)] = (ushort_t)pk2;
            }
    __syncthreads();

    const size_t w2r0 = (size_t)(wv * 32 + col) * HD;
    const size_t w2r1 = (size_t)(wv * 32 + 16 + col) * HD;
    short8v m0 = *(const short8v*)&W2p[w2r0 + g * 8];
    short8v m1 = *(const short8v*)&W2p[w2r1 + g * 8];
    f32x4 acc2[4][2];
    {
        float bv0 = bm2[wv * 32 + col];
        float bv1 = bm2[wv * 32 + 16 + col];
        #pragma unroll
        for (int rt = 0; rt < 4; ++rt) {
            acc2[rt][0] = (f32x4){bv0, bv0, bv0, bv0};
            acc2[rt][1] = (f32x4){bv1, bv1, bv1, bv1};
        }
    }
    #pragma unroll
    for (int c = 0; c < NCH2; ++c) {
        short8v b0 = m0, b1 = m1;
        if (c + 1 < NCH2) {
            m0 = *(const short8v*)&W2p[w2r0 + (c + 1) * 32 + g * 8];
            m1 = *(const short8v*)&W2p[w2r1 + (c + 1) * 32 + g * 8];
        }
        short8v a[4];
        #pragma unroll
        for (int rt = 0; rt < 4; ++rt) {
            const int row = rt * 16 + col;
            const int sP = (((c & 1) << 2) + g) ^ (row & 7);
            a[rt] = *(const short8v*)&lds[((c >> 1) * EB + row) * 64 + sP * 8];
        }
        #pragma unroll
        for (int rt = 0; rt < 4; ++rt) {
            acc2[rt][0] = __builtin_amdgcn_mfma_f32_16x16x32_bf16(a[rt], b0, acc2[rt][0], 0, 0, 0);
            acc2[rt][1] = __builtin_amdgcn_mfma_f32_16x16x32_bf16(a[rt], b1, acc2[rt][1], 0, 0, 0);
        }
    }

    const bool even = (col & 1) == 0;
    #pragma unroll
    for (int rt = 0; rt < 4; ++rt)
        #pragma unroll
        for (int r = 0; r < 4; ++r) {
            const int e  = rt * 16 + g * 4 + r;
            const int ge = e0 + e;
            const int dg = s_dst[e];
            #pragma unroll
            for (int j = 0; j < 2; ++j) {
                float v  = acc2[rt][j][r];
                float vn = __shfl_xor(v, 1, 64);
                if (even && ge < E) {
                    unsigned int pk2 = cvt_pk_bf16(v, vn);
                    ushort_t* p = msum + (size_t)dg * D + wv * 32 + j * 16 + col;
                    asm volatile("global_atomic_pk_add_bf16 %0, %1, off"
                                 :: "v"(p), "v"(pk2) : "memory");
                }
            }
        }
}

template<bool MB16>
__global__ __launch_bounds__(NT, 4) void node_kernel(
    const float* __restrict__ f, const void* __restrict__ msum_v,
    const float* __restrict__ Wu1, const float* __restrict__ bu1,
    const float* __restrict__ Wu2, const float* __restrict__ bu2,
    float* out, int Nn)
{
    __shared__ __align__(16) float hin[NB][HID_PAD];
    __shared__ __align__(16) float hid[NB][HID_PAD];
    const int t  = threadIdx.x;
    const int n0 = blockIdx.x * NB;
    const int nn = min(NB, Nn - n0);

    {
        #pragma unroll
        for (int it = 0; it < 4; ++it) {
            const int idx = it * 1024 + t * 4;
            const int e   = idx >> 7;
            const int cb  = idx & 127;
            if (e < nn) {
                const size_t off = (size_t)(n0 + e) * D + cb;
                float4 mv;
                if (MB16) {
                    uint2 pk = *(const uint2*)((const ushort_t*)msum_v + off);
                    mv.x = bf2f((ushort_t)(pk.x & 0xffffu));
                    mv.y = bf2f((ushort_t)(pk.x >> 16));
                    mv.z = bf2f((ushort_t)(pk.y & 0xffffu));
                    mv.w = bf2f((ushort_t)(pk.y >> 16));
                } else {
                    mv = *(const float4*)((const float*)msum_v + off);
                }
                float4 fv = *(const float4*)&f[off];
                float4 o = {mv.x + fv.x, mv.y + fv.y, mv.z + fv.z, mv.w + fv.w};
                *(float4*)&hin[e][cb] = o;
            }
        }
    }
    __syncthreads();

    const int tc = t & 15, te2 = (t >> 4) * 2, c0 = tc * 8;
    float a1[2][8];
    #pragma unroll
    for (int c = 0; c < 8; ++c) { float bv = bu1[c0 + c]; a1[0][c] = bv; a1[1][c] = bv; }
    for (int i = 0; i < D; i += 4) {
        float m0[4], m1[4];
        *(float4*)m0 = *(const float4*)&hin[te2][i];
        *(float4*)m1 = *(const float4*)&hin[te2 + 1][i];
        #pragma unroll
        for (int r = 0; r < 4; ++r) {
            float wr[8];
            *(float4*)&wr[0] = *(const float4*)(Wu1 + (size_t)(i + r) * HD + c0);
            *(float4*)&wr[4] = *(const float4*)(Wu1 + (size_t)(i + r) * HD + c0 + 4);
            #pragma unroll
            for (int c = 0; c < 8; ++c) { a1[0][c] += m0[r]*wr[c]; a1[1][c] += m1[r]*wr[c]; }
        }
    }
    #pragma unroll
    for (int j = 0; j < 2; ++j) {
        float v[8];
        #pragma unroll
        for (int c = 0; c < 8; ++c) v[c] = fmaxf(a1[j][c], 0.f);
        *(float4*)&hid[te2 + j][c0] = *(float4*)&v[0];
        *(float4*)&hid[te2 + j][c0 + 4] = *(float4*)&v[4];
    }
    __syncthreads();
    float a2[2][8];
    #pragma unroll
    for (int c = 0; c < 8; ++c) { float bv = bu2[c0 + c]; a2[0][c] = bv; a2[1][c] = bv; }
    for (int h = 0; h < HD; h += 4) {
        float m0[4], m1[4];
        *(float4*)m0 = *(const float4*)&hid[te2][h];
        *(float4*)m1 = *(const float4*)&hid[te2 + 1][h];
        #pragma unroll
        for (int r = 0; r < 4; ++r) {
            float wr[8];
            *(float4*)&wr[0] = *(const float4*)(Wu2 + (size_t)(h + r) * D + c0);
            *(float4*)&wr[4] = *(const float4*)(Wu2 + (size_t)(h + r) * D + c0 + 4);
            #pragma unroll
            for (int c = 0; c < 8; ++c) { a2[0][c] += m0[r]*wr[c]; a2[1][c] += m1[r]*wr[c]; }
        }
    }
    #pragma unroll
    for (int j = 0; j < 2; ++j) {
        int e = te2 + j, gn = n0 + e;
        if (e < nn) {
            *(float4*)(out + (size_t)gn * D + c0) = *(float4*)&a2[j][0];
            *(float4*)(out + (size_t)gn * D + c0 + 4) = *(float4*)&a2[j][4];
        }
    }
}

extern "C" void kernel_launch(void* const* d_in, const int* in_sizes, int n_in,
                              void* d_out, int out_size, void* d_ws, size_t ws_size,
                              hipStream_t stream) {
    const float* f   = (const float*)d_in[0];
    const float* x   = (const float*)d_in[1];
    const float* w   = (const float*)d_in[2];
    const int*   src = (const int*)d_in[3];
    const int*   dst = (const int*)d_in[4];
    const float* Wm1 = (const float*)d_in[5];
    const float* bm1 = (const float*)d_in[6];
    const float* Wm2 = (const float*)d_in[7];
    const float* bm2 = (const float*)d_in[8];
    const float* Wu1 = (const float*)d_in[9];
    const float* bu1 = (const float*)d_in[10];
    const float* Wu2 = (const float*)d_in[11];
    const float* bu2 = (const float*)d_in[12];

    const int Nn = in_sizes[0] / D;
    const int E  = in_sizes[3];

    const size_t wbytes  = (size_t)(128 * KP1 + HD * D) * sizeof(ushort_t);
    const size_t wubytes = (size_t)(2 * HD * D) * sizeof(ushort_t);
    auto align512 = [](size_t v) { return (v + 511) & ~(size_t)511; };
    char* wsb = (char*)d_ws;

    // ---------------- primary: linear-trick path (A fp8, B bf16), fused tail ----------------
    size_t off = 0;
    const size_t o_w    = off; off = align512(off + wbytes);
    const size_t o_wu   = off; off = align512(off + wubytes);
    const size_t o_wbf  = off; off = align512(off + (size_t)E * DE * 2);
    const size_t o_af   = off; off = align512(off + (size_t)Nn * D);
    const size_t o_bf16 = off; off = align512(off + (size_t)Nn * D * 2);
    const size_t o_cnt  = off; off = align512(off + (size_t)Nn * 4);
    const size_t o_roff = off; off = align512(off + (size_t)Nn * 4);
    const size_t o_cur  = off; off = align512(off + (size_t)Nn * 4);
    const size_t o_perm = off; off = align512(off + (size_t)E * 4);
    const size_t o_sdst = off; off = align512(off + (size_t)E * 4);
    const size_t o_mh   = off; off = align512(off + (size_t)Nn * D * 4);
    const size_t primary_total = off;

    if (ws_size >= primary_total) {
        ushort_t* W1p  = (ushort_t*)(wsb + o_w);
        ushort_t* W2p  = W1p + 128 * KP1;
        ushort_t* Wu1p = (ushort_t*)(wsb + o_wu);
        ushort_t* Wu2p = Wu1p + HD * D;
        ushort_t* wbf  = (ushort_t*)(wsb + o_wbf);
        uchar_t*  Af   = (uchar_t*)(wsb + o_af);
        ushort_t* Bf16 = (ushort_t*)(wsb + o_bf16);
        int* cnt       = (int*)(wsb + o_cnt);
        int* roff      = (int*)(wsb + o_roff);
        int* cursor    = (int*)(wsb + o_cur);
        int* perm      = (int*)(wsb + o_perm);
        int* sdst      = (int*)(wsb + o_sdst);
        float* mh      = (float*)(wsb + o_mh);

        const int ntiles = (E + EB - 1) / EB;
        const int nblk   = (Nn + 63) / 64;
        hipMemsetAsync(cnt, 0, (size_t)Nn * 4, stream);
        fused_pre_kernel<<<dim3(1024), dim3(256), 0, stream>>>(
            Wm1, Wm2, Wu1, Wu2, W1p, W2p, Wu1p, Wu2p, dst, cnt, E);
        scan_kernel<<<dim3(1), dim3(1024), 0, stream>>>(cnt, roff, cursor, Nn);
        scatter_kernel<<<dim3((E + 255) / 256), dim3(256), 0, stream>>>(
            dst, cursor, roff, cnt, perm, sdst, w, wbf, mh, E, Nn);
        ab_kernel<<<dim3(nblk), dim3(NT), 0, stream>>>(f, W1p, Af, Bf16, Nn);
        edge_lin_kernel<<<dim3(ntiles), dim3(NT), 0, stream>>>(
            Af, Bf16, x, wbf, src, perm, sdst, W1p, bm1, mh, E);
        node_fused_kernel<<<dim3(nblk), dim3(NT), 0, stream>>>(
            f, mh, cnt, W2p, bm2, Wu1p, bu1, Wu2p, bu2, (float*)d_out, Nn);
        return;
    }

    // ---------------- fallback: bf16 pk-atomic path ----------------
    size_t off2 = 0;
    const size_t p_w  = off2; off2 = align512(off2 + wbytes);
    const size_t p_fb = off2; off2 = align512(off2 + (size_t)Nn * D * 2);
    const size_t p_ms = off2; off2 = align512(off2 + (size_t)Nn * D * 2);
    if (ws_size >= off2) {
        ushort_t* W1p  = (ushort_t*)(wsb + p_w);
        ushort_t* W2p  = W1p + 128 * KP1;
        ushort_t* fbf  = (ushort_t*)(wsb + p_fb);
        ushort_t* msum = (ushort_t*)(wsb + p_ms);
        const int rp_elems = 128 * KP1 + HD * D;
        hipMemsetAsync(msum, 0, (size_t)Nn * D * 2, stream);
        repack_kernel<<<dim3((rp_elems + 255) / 256), dim3(256), 0, stream>>>(Wm1, Wm2, W1p, W2p);
        const int n8 = Nn * D / 8;
        fconv_kernel<<<dim3((n8 + 255) / 256), dim3(256), 0, stream>>>(f, fbf, n8);
        edge_mfma_kernel<<<dim3((E + EB - 1) / EB), dim3(NT), 0, stream>>>(
            fbf, x, w, src, dst, W1p, bm1, W2p, bm2, msum, E);
        node_kernel<true><<<dim3((Nn + NB - 1) / NB), dim3(NT), 0, stream>>>(
            f, msum, Wu1, bu1, Wu2, bu2, (float*)d_out, Nn);
        return;
    }
}

// Round 23
// 243.682 us; speedup vs baseline: 1.7093x; 1.0367x over previous
//
#include <hip/hip_runtime.h>
#include <hip/hip_fp8.h>

#define D 128
#define HD 128
#define DE 16
#define MSG_IN 273
#define EB 64        // edges per tile
#define NT 256
#define KP1 288      // padded msg K = 9 chunks of 32
#define NCH2 4
#define NB 32
#define HID_PAD 132
#define CH8 (4 * EB * 64)
#define LDS1 (4 * EB * 64 + EB * 32)
// edge_lin LDS layout (bytes): A fp8 [0,8192) ; B bf16 [8192,24576) ; c8 bf16 [24576,28672)
#define OB 8192
#define OC 24576

typedef __attribute__((ext_vector_type(8))) short short8v;
typedef __attribute__((ext_vector_type(4))) float f32x4;
typedef __attribute__((ext_vector_type(2))) float f32x2;
typedef unsigned short ushort_t;
typedef unsigned char uchar_t;

#define GLOAD_LDS16(gp, lp) \
    __builtin_amdgcn_global_load_lds((const __attribute__((address_space(1))) unsigned int*)(gp), \
                                     (__attribute__((address_space(3))) unsigned int*)(lp), 16, 0, 0)

__device__ __forceinline__ unsigned short f2bf(float v) {
    unsigned int u = __builtin_bit_cast(unsigned int, v);
    u += 0x7fffu + ((u >> 16) & 1u);
    return (unsigned short)(u >> 16);
}
__device__ __forceinline__ float bf2f(ushort_t u) {
    return __builtin_bit_cast(float, (unsigned int)u << 16);
}
__device__ __forceinline__ unsigned int cvt_pk_bf16(float lo, float hi) {
    unsigned int r;
    asm("v_cvt_pk_bf16_f32 %0, %1, %2" : "=v"(r) : "v"(lo), "v"(hi));
    return r;
}
__device__ __forceinline__ uchar_t f8e(float v) {   // f32 -> e4m3 (HIP library)
    __hip_fp8_e4m3 t(v);
    return (uchar_t)t.__x;
}
// e4m3fn -> f32: normals 2^(e-7)(1+m/8); subnormals m/8*2^-6; sign bit preserved.
__device__ __forceinline__ float f8d(unsigned b) {
    unsigned t = ((b & 0x7fu) << 20) | ((b & 0x80u) << 24);
    return __builtin_bit_cast(float, t) * 0x1p120f;
}

// ---------------- fused prepass: repack weights + dst hist ----------------
__global__ void fused_pre_kernel(const float* __restrict__ Wm1, const float* __restrict__ Wm2,
                                 const float* __restrict__ Wu1, const float* __restrict__ Wu2,
                                 ushort_t* __restrict__ W1p, ushort_t* __restrict__ W2p,
                                 ushort_t* __restrict__ Wu1p, ushort_t* __restrict__ Wu2p,
                                 const int* __restrict__ dst, int* __restrict__ cnt,
                                 int E) {
    const int gid    = blockIdx.x * 256 + threadIdx.x;
    const int stride = gridDim.x * 256;
    const int rp1 = 128 * KP1;
    const int rp2 = rp1 + HD * D;
    const int rp_elems = rp2 + 2 * HD * D;
    for (int i = gid; i < rp_elems; i += stride) {
        if (i < rp1) {
            int n = i / KP1, k = i % KP1;
            W1p[i] = f2bf((k < MSG_IN) ? Wm1[(size_t)k * HD + n] : 0.f);
        } else if (i < rp2) {
            int i2 = i - rp1;
            int n = i2 / HD, k = i2 % HD;
            W2p[i2] = f2bf(Wm2[(size_t)k * D + n]);
        } else {
            int i2 = (i - rp2);
            const bool second = i2 >= HD * D;
            if (second) i2 -= HD * D;
            int n = i2 / HD, k = i2 % HD;
            if (second) Wu2p[i2] = f2bf(Wu2[(size_t)k * D + n]);
            else        Wu1p[i2] = f2bf(Wu1[(size_t)k * HD + n]);
        }
    }
    for (int i = gid; i < E; i += stride) atomicAdd(&cnt[dst[i]], 1);
}

// ---------------- CSR build: parallel scan -> scatter + w->bf16 + selective zero ----------------
__global__ __launch_bounds__(1024) void scan_kernel(const int* __restrict__ cnt,
                                                    int* __restrict__ roff,
                                                    int* __restrict__ cursor, int Nn) {
    __shared__ int wsum[16];
    const int t = threadIdx.x, l = t & 63, wid = t >> 6;
    int running = 0;
    for (int base = 0; base < Nn; base += 4096) {
        const int i0 = base + t * 4;
        int v0 = 0, v1 = 0, v2 = 0, v3 = 0;
        if (i0 + 3 < Nn) {
            int4 v = *(const int4*)(cnt + i0);
            v0 = v.x; v1 = v.y; v2 = v.z; v3 = v.w;
        } else {
            if (i0 + 0 < Nn) v0 = cnt[i0 + 0];
            if (i0 + 1 < Nn) v1 = cnt[i0 + 1];
            if (i0 + 2 < Nn) v2 = cnt[i0 + 2];
        }
        const int vsum = v0 + v1 + v2 + v3;
        int s = vsum;
        #pragma unroll
        for (int off = 1; off < 64; off <<= 1) {
            int u = __shfl_up(s, off, 64);
            if (l >= off) s += u;
        }
        if (l == 63) wsum[wid] = s;
        __syncthreads();
        if (wid == 0 && l < 16) {
            int xv = wsum[l];
            #pragma unroll
            for (int off = 1; off < 16; off <<= 1) {
                int u = __shfl_up(xv, off, 64);
                if (l >= off) xv += u;
            }
            wsum[l] = xv;
        }
        __syncthreads();
        const int prev  = (wid > 0) ? wsum[wid - 1] : 0;
        const int total = wsum[15];
        int ex = running + prev + (s - vsum);
        if (i0 + 0 < Nn) { roff[i0 + 0] = ex; cursor[i0 + 0] = ex; } ex += v0;
        if (i0 + 1 < Nn) { roff[i0 + 1] = ex; cursor[i0 + 1] = ex; } ex += v1;
        if (i0 + 2 < Nn) { roff[i0 + 2] = ex; cursor[i0 + 2] = ex; } ex += v2;
        if (i0 + 3 < Nn) { roff[i0 + 3] = ex; cursor[i0 + 3] = ex; }
        running += total;
        __syncthreads();
    }
}

__global__ void scatter_kernel(const int* __restrict__ dst, int* cursor,
                               const int* __restrict__ roff, const int* __restrict__ cnt,
                               int* __restrict__ perm, int* __restrict__ sdst,
                               const float* __restrict__ w, ushort_t* __restrict__ wbf,
                               float* __restrict__ mh, int E, int Nn) {
    const int gid    = blockIdx.x * 256 + threadIdx.x;
    const int stride = gridDim.x * 256;
    for (int i = gid; i < E; i += stride) {
        int d = dst[i];
        int s = atomicAdd(&cursor[d], 1);
        perm[s] = i;
        sdst[s] = d;
        // ride-along: w row i -> bf16
        const float* wp = w + (size_t)i * DE;
        ushort_t* op = wbf + (size_t)i * DE;
        #pragma unroll
        for (int q = 0; q < 2; ++q) {
            float4 v0 = *(const float4*)(wp + q * 8);
            float4 v1 = *(const float4*)(wp + q * 8 + 4);
            union { ushort_t us[8]; short8v v; } pk;
            pk.us[0] = f2bf(v0.x); pk.us[1] = f2bf(v0.y);
            pk.us[2] = f2bf(v0.z); pk.us[3] = f2bf(v0.w);
            pk.us[4] = f2bf(v1.x); pk.us[5] = f2bf(v1.y);
            pk.us[6] = f2bf(v1.z); pk.us[7] = f2bf(v1.w);
            *(short8v*)(op + q * 8) = pk.v;
        }
    }
    for (int n = gid; n < Nn; n += stride) {
        const int c = cnt[n];
        const int r = roff[n];
        const bool need0 = (c == 0) || (r / EB != (r + c - 1) / EB);
        if (need0) {
            float4 z = {0.f, 0.f, 0.f, 0.f};
            float* p = mh + (size_t)n * D;
            #pragma unroll
            for (int k = 0; k < 32; ++k) *(float4*)(p + k * 4) = z;
        }
    }
}

// ---------------- AB precompute: pair-packed outputs ----------------
// Af row layout: byte (wv*32 + col*2 + j) holds fp8 of logical column (wv*32 + j*16 + col).
// Bf16 row layout: u32 at ushort-index (wv*32 + col*2) holds bf16 pair (j=0 lo, j=1 hi).
__global__ __launch_bounds__(NT, 4) void ab_kernel(
    const float* __restrict__ f,
    const ushort_t* __restrict__ W1p,
    uchar_t* __restrict__ Af, ushort_t* __restrict__ Bf16, int Nn)
{
    __shared__ __align__(16) ushort_t lds[2 * 64 * 64];   // 16 KB

    const int t    = threadIdx.x;
    const int lane = t & 63;
    const int wv   = t >> 6;
    const int col  = lane & 15;
    const int g    = lane >> 4;
    const int n0   = blockIdx.x * 64;

    #pragma unroll
    for (int it = 0; it < 4; ++it) {
        const int gidx = it * 256 + t;
        const int row  = gidx >> 4;
        const int gr   = gidx & 15;
        const int pair = gr >> 3, s = gr & 7;
        const int sP   = s ^ (row & 7);
        const int gn   = min(n0 + row, Nn - 1);
        const size_t off = (size_t)gn * D + gr * 8;
        float4 v0 = *(const float4*)(f + off);
        float4 v1 = *(const float4*)(f + off + 4);
        union { ushort_t us[8]; short8v v; } pk;
        pk.us[0] = f2bf(v0.x); pk.us[1] = f2bf(v0.y);
        pk.us[2] = f2bf(v0.z); pk.us[3] = f2bf(v0.w);
        pk.us[4] = f2bf(v1.x); pk.us[5] = f2bf(v1.y);
        pk.us[6] = f2bf(v1.z); pk.us[7] = f2bf(v1.w);
        *(short8v*)&lds[(pair * 64 + row) * 64 + sP * 8] = pk.v;
    }
    __syncthreads();

    #pragma unroll
    for (int half = 0; half < 2; ++half) {          // 0: A (fp8), 1: B (bf16)
        f32x4 acc[4][2];
        #pragma unroll
        for (int rt = 0; rt < 4; ++rt) {
            acc[rt][0] = (f32x4){0.f, 0.f, 0.f, 0.f};
            acc[rt][1] = (f32x4){0.f, 0.f, 0.f, 0.f};
        }
        const int kbase = half * 128;
        #pragma unroll
        for (int c = 0; c < 4; ++c) {
            short8v b0 = *(const short8v*)&W1p[(size_t)(wv * 32 + col) * KP1 + kbase + c * 32 + g * 8];
            short8v b1 = *(const short8v*)&W1p[(size_t)(wv * 32 + 16 + col) * KP1 + kbase + c * 32 + g * 8];
            short8v a[4];
            #pragma unroll
            for (int rt = 0; rt < 4; ++rt) {
                const int row = rt * 16 + col;
                const int sP = (((c & 1) << 2) + g) ^ (row & 7);
                a[rt] = *(const short8v*)&lds[((c >> 1) * 64 + row) * 64 + sP * 8];
            }
            #pragma unroll
            for (int rt = 0; rt < 4; ++rt) {
                acc[rt][0] = __builtin_amdgcn_mfma_f32_16x16x32_bf16(a[rt], b0, acc[rt][0], 0, 0, 0);
                acc[rt][1] = __builtin_amdgcn_mfma_f32_16x16x32_bf16(a[rt], b1, acc[rt][1], 0, 0, 0);
            }
        }
        // pair-packed epilogue: each lane owns the (j=0, j=1) column pair
        #pragma unroll
        for (int rt = 0; rt < 4; ++rt)
            #pragma unroll
            for (int r = 0; r < 4; ++r) {
                const int row = rt * 16 + g * 4 + r;
                const int gn = n0 + row;
                if (gn < Nn) {
                    const int cp = wv * 32 + col * 2;
                    if (half == 0) {
                        ushort_t pk = (ushort_t)f8e(acc[rt][0][r]) |
                                      ((ushort_t)f8e(acc[rt][1][r]) << 8);
                        *(ushort_t*)(Af + (size_t)gn * D + cp) = pk;
                    } else {
                        *(unsigned int*)(Bf16 + (size_t)gn * D + cp) =
                            cvt_pk_bf16(acc[rt][0][r], acc[rt][1][r]);
                    }
                }
            }
    }
}

// ---------------- edge kernel v23: HW fp8 decode (cvt_pk_f32_fp8) on packed pairs ----------------
__global__ __launch_bounds__(NT, 5) void edge_lin_kernel(
    const uchar_t* __restrict__ Af, const ushort_t* __restrict__ Bf16,
    const float* __restrict__ x, const ushort_t* __restrict__ wbf,
    const int* __restrict__ src,
    const int* __restrict__ perm, const int* __restrict__ sdst,
    const ushort_t* __restrict__ W1p, const float* __restrict__ bm1,
    float* __restrict__ mh, int E)
{
    __shared__ __align__(16) uchar_t lds8[28672];   // A 8K | B 16K | c8 4K
    __shared__ int s_rid[EB];
    __shared__ int s_dgs[EB];

    const int t    = threadIdx.x;
    const int lane = t & 63;
    const int wv   = t >> 6;
    const int e0   = blockIdx.x * EB;
    const int nvalid = min(EB, E - e0);

    const int myd  = (e0 + lane < E) ? sdst[e0 + lane] : -1;
    const int prevd = (e0 > 0) ? sdst[e0 - 1] : -2;
    const int nextd = (e0 + EB < E) ? sdst[e0 + EB] : -2;

    const int dprev_l = __shfl_up(myd, 1, 64);
    const bool head = (lane == 0) || (myd != dprev_l);
    const unsigned long long mask = __ballot(head && (lane < nvalid));
    const unsigned long long le = (lane == 63) ? ~0ull : ((1ull << (lane + 1)) - 1ull);
    const int rid = (int)__popcll(mask & le) - 1;
    const int ndist = (int)__popcll(mask);
    s_rid[lane] = (rid < 0) ? 0 : rid;
    if (head && lane < nvalid) s_dgs[rid] = myd;

    {
        const int el8 = lane >> 3;
        const int s   = lane & 7;
        const int sl  = s ^ el8;
        const int slA = min(e0 + wv * 16 + el8,     E - 1);
        const int slB = min(e0 + wv * 16 + 8 + el8, E - 1);
        const int nsA = src[perm[slA]];
        const int nsB = src[perm[slB]];
        GLOAD_LDS16(Af + (size_t)nsA * D + sl * 16, &lds8[(wv * 16    ) * 128]);
        GLOAD_LDS16(Af + (size_t)nsB * D + sl * 16, &lds8[(wv * 16 + 8) * 128]);
    }
    {
        const int ntask = ndist * 16;
        for (int idx = t; idx < ntask; idx += NT) {
            const int rowr = idx >> 4;
            const int gr   = idx & 15;
            const int dg   = s_dgs[rowr];
            uint4 v = *(const uint4*)(Bf16 + (size_t)dg * D + gr * 8);
            const int phys = gr ^ (rowr & 15);
            *(uint4*)&lds8[OB + rowr * 256 + phys * 16] = v;
        }
    }
    {
        const int el = lane >> 2, q = lane & 3;
        const int qp = q ^ (el & 3);
        const int slot = e0 + wv * 16 + el;
        const bool ok = slot < E;
        const int sc = min(slot, E - 1);
        const int ge = perm[sc];
        union { ushort_t us[8]; short8v v; } pk;
        #pragma unroll
        for (int j = 0; j < 8; ++j) pk.us[j] = 0;
        if (ok) {
            if (q < 2) {
                pk.v = *(const short8v*)(wbf + (size_t)ge * DE + q * 8);
            } else if (q == 2) {
                const int ns = src[ge], nd = sdst[sc];
                float dx = x[ns*3+0] - x[nd*3+0];
                float dy = x[ns*3+1] - x[nd*3+1];
                float dz = x[ns*3+2] - x[nd*3+2];
                pk.us[0] = f2bf(dx*dx + dy*dy + dz*dz);
            }
        }
        *(short8v*)&lds8[OC + (wv * 16 + el) * 64 + qp * 16] = pk.v;
    }

    const int col = lane & 15;
    const int g   = lane >> 4;

    short8v bc0 = *(const short8v*)&W1p[(size_t)(wv * 32 + col) * KP1 + 256 + g * 8];
    short8v bc1 = *(const short8v*)&W1p[(size_t)(wv * 32 + 16 + col) * KP1 + 256 + g * 8];

    __syncthreads();   // B0

    f32x4 acc[4][2];
    {
        float bv0 = bm1[wv * 32 + col];
        float bv1 = bm1[wv * 32 + 16 + col];
        #pragma unroll
        for (int rt = 0; rt < 4; ++rt) {
            acc[rt][0] = (f32x4){bv0, bv0, bv0, bv0};
            acc[rt][1] = (f32x4){bv1, bv1, bv1, bv1};
        }
    }
    #pragma unroll
    for (int rt = 0; rt < 4; ++rt) {
        const int row = rt * 16 + col;
        const int sP8 = g ^ (row & 3);
        short8v a = *(const short8v*)&lds8[OC + row * 64 + sP8 * 16];
        acc[rt][0] = __builtin_amdgcn_mfma_f32_16x16x32_bf16(a, bc0, acc[rt][0], 0, 0, 0);
        acc[rt][1] = __builtin_amdgcn_mfma_f32_16x16x32_bf16(a, bc1, acc[rt][1], 0, 0, 0);
    }

    // ---- h = relu(acc + A + B); packed-pair loads + HW fp8 decode ----
    // A logical byte offset = wv*32 + col*2 (+1 for j=1): granule cgA = 2wv+(col>>3).
    // B logical byte offset = wv*64 + col*4 (+2 for j=1): granule cbB = 4wv+(col>>2).
    float h[4][2][4];
    const int cgA = 2 * wv + (col >> 3);
    const int coA = (col * 2) & 15;
    const int cbB = 4 * wv + (col >> 2);
    const int coB = (col & 3) * 4;
    #pragma unroll
    for (int rt = 0; rt < 4; ++rt) {
        #pragma unroll
        for (int r = 0; r < 4; ++r) {
            const int row = rt * 16 + g * 4 + r;
            const int rd  = s_rid[row];
            const int aadr = row * 128 + ((cgA ^ (row & 7)) << 4) + coA;
            const int badr = OB + rd * 256 + ((cbB ^ (rd & 15)) << 4) + coB;
            const ushort_t ap = *(const ushort_t*)&lds8[aadr];
            const unsigned bp = *(const unsigned*)&lds8[badr];
            f32x2 af = __builtin_amdgcn_cvt_pk_f32_fp8((int)ap, false);
            const float b0f = __builtin_bit_cast(float, bp << 16);
            const float b1f = __builtin_bit_cast(float, bp & 0xffff0000u);
            h[rt][0][r] = fmaxf(acc[rt][0][r] + af[0] + b0f, 0.f);
            h[rt][1][r] = fmaxf(acc[rt][1][r] + af[1] + b1f, 0.f);
        }
    }

    // ---- wave-local segment reduce -> mh (f32) ----
    float qs[4][2];
    #pragma unroll
    for (int rt = 0; rt < 4; ++rt) {
        qs[rt][0] = (h[rt][0][0] + h[rt][0][1]) + (h[rt][0][2] + h[rt][0][3]);
        qs[rt][1] = (h[rt][1][0] + h[rt][1][1]) + (h[rt][1][2] + h[rt][1][3]);
    }
    unsigned long long rem = mask;
    while (rem) {
        const int beg = (int)__builtin_ctzll(rem);
        rem &= rem - 1;
        const int end = rem ? (int)__builtin_ctzll(rem) : nvalid;
        const int dg  = __shfl(myd, beg, 64);

        float s0 = 0.f, s1 = 0.f;
        #pragma unroll
        for (int rt = 0; rt < 4; ++rt) {
            const int qb = rt * 16 + g * 4;
            const int lo = max(qb, beg);
            const int hi = min(qb + 4, end);
            if (lo < hi) {
                if (lo == qb && hi == qb + 4) {
                    s0 += qs[rt][0]; s1 += qs[rt][1];
                } else {
                    #pragma unroll
                    for (int r = 0; r < 4; ++r) {
                        const int sl = qb + r;
                        if (sl >= beg && sl < end) {
                            s0 += h[rt][0][r]; s1 += h[rt][1][r];
                        }
                    }
                }
            }
        }
        s0 += __shfl_xor(s0, 16, 64); s0 += __shfl_xor(s0, 32, 64);
        s1 += __shfl_xor(s1, 16, 64); s1 += __shfl_xor(s1, 32, 64);
        if (g == 0) {
            const bool bnd = (beg == 0 && dg == prevd) || (end == nvalid && dg == nextd);
            float* p = mh + (size_t)dg * D + wv * 32 + col;
            if (bnd) { atomicAdd(p, s0); atomicAdd(p + 16, s1); }
            else     { p[0] = s0; p[16] = s1; }
        }
    }
}

// ---------------- node_fused: msum = mh@Wm2 + cnt*bm2; hin = msum + f; node MLP -> out ----------------
__global__ __launch_bounds__(NT, 4) void node_fused_kernel(
    const float* __restrict__ f, const float* __restrict__ mh,
    const int* __restrict__ cnt,
    const ushort_t* __restrict__ W2p, const float* __restrict__ bm2,
    const ushort_t* __restrict__ Wu1p, const float* __restrict__ bu1,
    const ushort_t* __restrict__ Wu2p, const float* __restrict__ bu2,
    float* __restrict__ out, int Nn)
{
    __shared__ __align__(16) ushort_t lds[2 * 64 * 64];   // 16 KB
    __shared__ int s_cnt[64];

    const int t    = threadIdx.x;
    const int lane = t & 63;
    const int wv   = t >> 6;
    const int col  = lane & 15;
    const int g    = lane >> 4;
    const int n0   = blockIdx.x * 64;

    if (t < 64) s_cnt[t] = (n0 + t < Nn) ? cnt[n0 + t] : 0;

    #pragma unroll
    for (int it = 0; it < 4; ++it) {
        const int gidx = it * 256 + t;
        const int row  = gidx >> 4;
        const int gr   = gidx & 15;
        const int pair = gr >> 3, s = gr & 7;
        const int sP   = s ^ (row & 7);
        const int gn   = n0 + row;
        union { ushort_t us[8]; short8v v; } pk;
        if (gn < Nn) {
            const size_t off = (size_t)gn * D + gr * 8;
            float4 m0 = *(const float4*)(mh + off);
            float4 m1 = *(const float4*)(mh + off + 4);
            pk.us[0] = f2bf(m0.x); pk.us[1] = f2bf(m0.y);
            pk.us[2] = f2bf(m0.z); pk.us[3] = f2bf(m0.w);
            pk.us[4] = f2bf(m1.x); pk.us[5] = f2bf(m1.y);
            pk.us[6] = f2bf(m1.z); pk.us[7] = f2bf(m1.w);
        } else {
            #pragma unroll
            for (int j = 0; j < 8; ++j) pk.us[j] = 0;
        }
        *(short8v*)&lds[(pair * 64 + row) * 64 + sP * 8] = pk.v;
    }
    __syncthreads();   // B0: mh staged

    f32x4 acc[4][2];
    {
        const float bv0 = bm2[wv * 32 + col];
        const float bv1 = bm2[wv * 32 + 16 + col];
        #pragma unroll
        for (int rt = 0; rt < 4; ++rt)
            #pragma unroll
            for (int r = 0; r < 4; ++r) {
                const float cn = (float)s_cnt[rt * 16 + g * 4 + r];
                acc[rt][0][r] = cn * bv0;
                acc[rt][1][r] = cn * bv1;
            }
    }
    #pragma unroll
    for (int c = 0; c < 4; ++c) {
        short8v b0 = *(const short8v*)&W2p[(size_t)(wv * 32 + col) * HD + c * 32 + g * 8];
        short8v b1 = *(const short8v*)&W2p[(size_t)(wv * 32 + 16 + col) * HD + c * 32 + g * 8];
        short8v a[4];
        #pragma unroll
        for (int rt = 0; rt < 4; ++rt) {
            const int row = rt * 16 + col;
            const int sP = (((c & 1) << 2) + g) ^ (row & 7);
            a[rt] = *(const short8v*)&lds[((c >> 1) * 64 + row) * 64 + sP * 8];
        }
        #pragma unroll
        for (int rt = 0; rt < 4; ++rt) {
            acc[rt][0] = __builtin_amdgcn_mfma_f32_16x16x32_bf16(a[rt], b0, acc[rt][0], 0, 0, 0);
            acc[rt][1] = __builtin_amdgcn_mfma_f32_16x16x32_bf16(a[rt], b1, acc[rt][1], 0, 0, 0);
        }
    }
    __syncthreads();   // B1

    const int ph = wv >> 1;
    #pragma unroll
    for (int rt = 0; rt < 4; ++rt)
        #pragma unroll
        for (int r = 0; r < 4; ++r) {
            const int row = rt * 16 + g * 4 + r;
            const int gn = n0 + row;
            #pragma unroll
            for (int j = 0; j < 2; ++j) {
                const int ca = wv * 32 + j * 16 + col;
                float v = 0.f;
                if (gn < Nn) v = acc[rt][j][r] + f[(size_t)gn * D + ca];
                unsigned int pk2 = cvt_pk_bf16(v, v);
                const int sH = (((wv & 1) << 2) + j * 2 + (col >> 3)) ^ (row & 7);
                lds[(ph * 64 + row) * 64 + sH * 8 + (col & 7)] = (ushort_t)pk2;
            }
        }
    __syncthreads();   // B2

    const size_t wrow0 = (size_t)(wv * 32 + col) * HD;
    const size_t wrow1 = (size_t)(wv * 32 + 16 + col) * HD;
    f32x4 acc1[4][2];
    {
        float bv0 = bu1[wv * 32 + col];
        float bv1 = bu1[wv * 32 + 16 + col];
        #pragma unroll
        for (int rt = 0; rt < 4; ++rt) {
            acc1[rt][0] = (f32x4){bv0, bv0, bv0, bv0};
            acc1[rt][1] = (f32x4){bv1, bv1, bv1, bv1};
        }
    }
    #pragma unroll
    for (int c = 0; c < 4; ++c) {
        short8v b0 = *(const short8v*)&Wu1p[wrow0 + c * 32 + g * 8];
        short8v b1 = *(const short8v*)&Wu1p[wrow1 + c * 32 + g * 8];
        short8v a[4];
        #pragma unroll
        for (int rt = 0; rt < 4; ++rt) {
            const int row = rt * 16 + col;
            const int sP = (((c & 1) << 2) + g) ^ (row & 7);
            a[rt] = *(const short8v*)&lds[((c >> 1) * 64 + row) * 64 + sP * 8];
        }
        #pragma unroll
        for (int rt = 0; rt < 4; ++rt) {
            acc1[rt][0] = __builtin_amdgcn_mfma_f32_16x16x32_bf16(a[rt], b0, acc1[rt][0], 0, 0, 0);
            acc1[rt][1] = __builtin_amdgcn_mfma_f32_16x16x32_bf16(a[rt], b1, acc1[rt][1], 0, 0, 0);
        }
    }
    __syncthreads();   // B3

    #pragma unroll
    for (int rt = 0; rt < 4; ++rt)
        #pragma unroll
        for (int j = 0; j < 2; ++j)
            #pragma unroll
            for (int r = 0; r < 4; ++r) {
                const int row = rt * 16 + g * 4 + r;
                float v = fmaxf(acc1[rt][j][r], 0.f);
                unsigned int pk2 = cvt_pk_bf16(v, v);
                const int sH = (((wv & 1) << 2) + j * 2 + (col >> 3)) ^ (row & 7);
                lds[(ph * 64 + row) * 64 + sH * 8 + (col & 7)] = (ushort_t)pk2;
            }
    __syncthreads();   // B4

    f32x4 acc2[4][2];
    {
        float bv0 = bu2[wv * 32 + col];
        float bv1 = bu2[wv * 32 + 16 + col];
        #pragma unroll
        for (int rt = 0; rt < 4; ++rt) {
            acc2[rt][0] = (f32x4){bv0, bv0, bv0, bv0};
            acc2[rt][1] = (f32x4){bv1, bv1, bv1, bv1};
        }
    }
    #pragma unroll
    for (int c = 0; c < 4; ++c) {
        short8v b0 = *(const short8v*)&Wu2p[wrow0 + c * 32 + g * 8];
        short8v b1 = *(const short8v*)&Wu2p[wrow1 + c * 32 + g * 8];
        short8v a[4];
        #pragma unroll
        for (int rt = 0; rt < 4; ++rt) {
            const int row = rt * 16 + col;
            const int sP = (((c & 1) << 2) + g) ^ (row & 7);
            a[rt] = *(const short8v*)&lds[((c >> 1) * 64 + row) * 64 + sP * 8];
        }
        #pragma unroll
        for (int rt = 0; rt < 4; ++rt) {
            acc2[rt][0] = __builtin_amdgcn_mfma_f32_16x16x32_bf16(a[rt], b0, acc2[rt][0], 0, 0, 0);
            acc2[rt][1] = __builtin_amdgcn_mfma_f32_16x16x32_bf16(a[rt], b1, acc2[rt][1], 0, 0, 0);
        }
    }

    #pragma unroll
    for (int rt = 0; rt < 4; ++rt)
        #pragma unroll
        for (int r = 0; r < 4; ++r) {
            const int row = rt * 16 + g * 4 + r;
            const int gn = n0 + row;
            if (gn < Nn) {
                out[(size_t)gn * D + wv * 32 + col]      = acc2[rt][0][r];
                out[(size_t)gn * D + wv * 32 + 16 + col] = acc2[rt][1][r];
            }
        }
}

// ================= fallback kernels (bf16 pk-atomic path; unchanged) =================

__global__ void repack_kernel(const float* __restrict__ Wm1, const float* __restrict__ Wm2,
                              ushort_t* __restrict__ W1p, ushort_t* __restrict__ W2p) {
    int idx = blockIdx.x * 256 + threadIdx.x;
    const int n1 = 128 * KP1;
    if (idx < n1) {
        int n = idx / KP1, k = idx % KP1;
        W1p[idx] = f2bf((k < MSG_IN) ? Wm1[(size_t)k * HD + n] : 0.f);
    } else {
        int i2 = idx - n1;
        if (i2 < HD * D) {
            int n = i2 / HD, k = i2 % HD;
            W2p[i2] = f2bf(Wm2[(size_t)k * D + n]);
        }
    }
}

__global__ void fconv_kernel(const float* __restrict__ f, ushort_t* __restrict__ fb, int n8) {
    int i = blockIdx.x * 256 + threadIdx.x;
    if (i < n8) {
        float4 v0 = *(const float4*)(f + (size_t)i * 8);
        float4 v1 = *(const float4*)(f + (size_t)i * 8 + 4);
        union { ushort_t us[8]; short8v v; } pk;
        pk.us[0] = f2bf(v0.x); pk.us[1] = f2bf(v0.y);
        pk.us[2] = f2bf(v0.z); pk.us[3] = f2bf(v0.w);
        pk.us[4] = f2bf(v1.x); pk.us[5] = f2bf(v1.y);
        pk.us[6] = f2bf(v1.z); pk.us[7] = f2bf(v1.w);
        *(short8v*)(fb + (size_t)i * 8) = pk.v;
    }
}

__global__ __launch_bounds__(NT, 4) void edge_mfma_kernel(
    const ushort_t* __restrict__ fbf, const float* __restrict__ x,
    const float* __restrict__ w, const int* __restrict__ src,
    const int* __restrict__ dst,
    const ushort_t* __restrict__ W1p, const float* __restrict__ bm1,
    const ushort_t* __restrict__ W2p, const float* __restrict__ bm2,
    ushort_t* msum, int E)
{
    __shared__ __align__(16) ushort_t lds[LDS1];
    __shared__ int s_dst[EB];

    const int t    = threadIdx.x;
    const int lane = t & 63;
    const int wv   = t >> 6;
    const int e0   = blockIdx.x * EB;

    if (t < EB) s_dst[t] = (e0 + t < E) ? dst[e0 + t] : 0;
    {
        const int el8 = lane >> 3;
        const int s   = lane & 7;
        const int sl  = s ^ el8;
        const int geA = min(e0 + wv * 16 + el8,     E - 1);
        const int geB = min(e0 + wv * 16 + 8 + el8, E - 1);
        const int nsA = src[geA], ndA = dst[geA];
        const int nsB = src[geB], ndB = dst[geB];
        #pragma unroll
        for (int p = 0; p < 4; ++p) {
            const int n0 = (p < 2) ? nsA : ndA;
            const int n1 = (p < 2) ? nsB : ndB;
            const ushort_t* g0 = fbf + (size_t)n0 * D + (p & 1) * 64 + sl * 8;
            const ushort_t* g1 = fbf + (size_t)n1 * D + (p & 1) * 64 + sl * 8;
            GLOAD_LDS16(g0, &lds[(p * EB + wv * 16    ) * 64]);
            GLOAD_LDS16(g1, &lds[(p * EB + wv * 16 + 8) * 64]);
        }
    }
    {
        const int el = lane >> 2, q = lane & 3;
        const int qp = q ^ (el & 3);
        const int ge = e0 + wv * 16 + el;
        const bool ok = ge < E;
        const int gc = min(ge, E - 1);
        union { ushort_t us[8]; short8v v; } pk;
        #pragma unroll
        for (int j = 0; j < 8; ++j) pk.us[j] = 0;
        if (ok) {
            if (q < 2) {
                float4 w0 = *(const float4*)(w + (size_t)gc * DE + q * 8);
                float4 w1 = *(const float4*)(w + (size_t)gc * DE + q * 8 + 4);
                pk.us[0] = f2bf(w0.x); pk.us[1] = f2bf(w0.y);
                pk.us[2] = f2bf(w0.z); pk.us[3] = f2bf(w0.w);
                pk.us[4] = f2bf(w1.x); pk.us[5] = f2bf(w1.y);
                pk.us[6] = f2bf(w1.z); pk.us[7] = f2bf(w1.w);
            } else if (q == 2) {
                const int ns = src[gc], nd = dst[gc];
                float dx = x[ns*3+0] - x[nd*3+0];
                float dy = x[ns*3+1] - x[nd*3+1];
                float dz = x[ns*3+2] - x[nd*3+2];
                pk.us[0] = f2bf(dx*dx + dy*dy + dz*dz);
            }
        }
        *(short8v*)&lds[CH8 + (wv * 16 + el) * 32 + qp * 8] = pk.v;
    }

    const int col = lane & 15;
    const int g   = lane >> 4;
    const size_t wrow0 = (size_t)(wv * 32 + col) * KP1;
    const size_t wrow1 = (size_t)(wv * 32 + 16 + col) * KP1;
    short8v nb0 = *(const short8v*)&W1p[wrow0 + g * 8];
    short8v nb1 = *(const short8v*)&W1p[wrow1 + g * 8];
    __syncthreads();

    f32x4 acc[4][2];
    {
        float bv0 = bm1[wv * 32 + col];
        float bv1 = bm1[wv * 32 + 16 + col];
        #pragma unroll
        for (int rt = 0; rt < 4; ++rt) {
            acc[rt][0] = (f32x4){bv0, bv0, bv0, bv0};
            acc[rt][1] = (f32x4){bv1, bv1, bv1, bv1};
        }
    }
    #pragma unroll
    for (int c = 0; c < 9; ++c) {
        short8v b0 = nb0, b1 = nb1;
        if (c + 1 < 9) {
            nb0 = *(const short8v*)&W1p[wrow0 + (c + 1) * 32 + g * 8];
            nb1 = *(const short8v*)&W1p[wrow1 + (c + 1) * 32 + g * 8];
        }
        short8v a[4];
        #pragma unroll
        for (int rt = 0; rt < 4; ++rt) {
            const int row = rt * 16 + col;
            if (c < 8) {
                const int sP = (((c & 1) << 2) + g) ^ (row & 7);
                a[rt] = *(const short8v*)&lds[((c >> 1) * EB + row) * 64 + sP * 8];
            } else {
                const int sP = g ^ (row & 3);
                a[rt] = *(const short8v*)&lds[CH8 + row * 32 + sP * 8];
            }
        }
        #pragma unroll
        for (int rt = 0; rt < 4; ++rt) {
            acc[rt][0] = __builtin_amdgcn_mfma_f32_16x16x32_bf16(a[rt], b0, acc[rt][0], 0, 0, 0);
            acc[rt][1] = __builtin_amdgcn_mfma_f32_16x16x32_bf16(a[rt], b1, acc[rt][1], 0, 0, 0);
        }
    }
    __syncthreads();

    const int ph = wv >> 1;
    #pragma unroll
    for (int rt = 0; rt < 4; ++rt)
        #pragma unroll
        for (int j = 0; j < 2; ++j)
            #pragma unroll
            for (int r = 0; r < 4; ++r) {
                const int row = rt * 16 + g * 4 + r;
                float v = fmaxf(acc[rt][j][r], 0.f);
                unsigned int pk2 = cvt_pk_bf16(v, v);
                const int sH = (((wv & 1) << 2) + j * 2 + (col >> 3)) ^ (row & 7);
                lds[(ph * EB + row) * 64 + sH * 8 + (col & 7)] = (ushort_t)pk2;
            }
    __syncthreads();

    const size_t w2r0 = (size_t)(wv * 32 + col) * HD;
    const size_t w2r1 = (size_t)(wv * 32 + 16 + col) * HD;
    short8v m0 = *(const short8v*)&W2p[w2r0 + g * 8];
    short8v m1 = *(const short8v*)&W2p[w2r1 + g * 8];
    f32x4 acc2[4][2];
    {
        float bv0 = bm2[wv * 32 + col];
        float bv1 = bm2[wv * 32 + 16 + col];
        #pragma unroll
        for (int rt = 0; rt < 4; ++rt) {
            acc2[rt][0] = (f32x4){bv0, bv0, bv0, bv0};
            acc2[rt][1] = (f32x4){bv1, bv1, bv1, bv1};
        }
    }
    #pragma unroll
    for (int c = 0; c < NCH2; ++c) {
        short8v b0 = m0, b1 = m1;
        if (c + 1 < NCH2) {
            m0 = *(const short8v*)&W2p[w2r0 + (c + 1) * 32 + g * 8];
            m1 = *(const short8v*)&W2p[w2r1 + (c + 1) * 32 + g * 8];
        }
        short8v a[4];
        #pragma unroll
        for (int rt = 0; rt < 4; ++rt) {
            const int row = rt * 16 + col;
            const int sP = (((c & 1) << 2) + g) ^ (row & 7);
            a[rt] = *(const short8v*)&lds[((c >> 1) * EB + row) * 64 + sP * 8];
        }
        #pragma unroll
        for (int rt = 0; rt < 4; ++rt) {
            acc2[rt][0] = __builtin_amdgcn_mfma_f32_16x16x32_bf16(a[rt], b0, acc2[rt][0], 0, 0, 0);
            acc2[rt][1] = __builtin_amdgcn_mfma_f32_16x16x32_bf16(a[rt], b1, acc2[rt][1], 0, 0, 0);
        }
    }

    const bool even = (col & 1) == 0;
    #pragma unroll
    for (int rt = 0; rt < 4; ++rt)
        #pragma unroll
        for (int r = 0; r < 4; ++r) {
            const int e  = rt * 16 + g * 4 + r;
            const int ge = e0 + e;
            const int dg = s_dst[e];
            #pragma unroll
            for (int j = 0; j < 2; ++j) {
                float v  = acc2[rt][j][r];
                float vn = __shfl_xor(v, 1, 64);
                if (even && ge < E) {
                    unsigned int pk2 = cvt_pk_bf16(v, vn);
                    ushort_t* p = msum + (size_t)dg * D + wv * 32 + j * 16 + col;
                    asm volatile("global_atomic_pk_add_bf16 %0, %1, off"
                                 :: "v"(p), "v"(pk2) : "memory");
                }
            }
        }
}

template<bool MB16>
__global__ __launch_bounds__(NT, 4) void node_kernel(
    const float* __restrict__ f, const void* __restrict__ msum_v,
    const float* __restrict__ Wu1, const float* __restrict__ bu1,
    const float* __restrict__ Wu2, const float* __restrict__ bu2,
    float* out, int Nn)
{
    __shared__ __align__(16) float hin[NB][HID_PAD];
    __shared__ __align__(16) float hid[NB][HID_PAD];
    const int t  = threadIdx.x;
    const int n0 = blockIdx.x * NB;
    const int nn = min(NB, Nn - n0);

    {
        #pragma unroll
        for (int it = 0; it < 4; ++it) {
            const int idx = it * 1024 + t * 4;
            const int e   = idx >> 7;
            const int cb  = idx & 127;
            if (e < nn) {
                const size_t off = (size_t)(n0 + e) * D + cb;
                float4 mv;
                if (MB16) {
                    uint2 pk = *(const uint2*)((const ushort_t*)msum_v + off);
                    mv.x = bf2f((ushort_t)(pk.x & 0xffffu));
                    mv.y = bf2f((ushort_t)(pk.x >> 16));
                    mv.z = bf2f((ushort_t)(pk.y & 0xffffu));
                    mv.w = bf2f((ushort_t)(pk.y >> 16));
                } else {
                    mv = *(const float4*)((const float*)msum_v + off);
                }
                float4 fv = *(const float4*)&f[off];
                float4 o = {mv.x + fv.x, mv.y + fv.y, mv.z + fv.z, mv.w + fv.w};
                *(float4*)&hin[e][cb] = o;
            }
        }
    }
    __syncthreads();

    const int tc = t & 15, te2 = (t >> 4) * 2, c0 = tc * 8;
    float a1[2][8];
    #pragma unroll
    for (int c = 0; c < 8; ++c) { float bv = bu1[c0 + c]; a1[0][c] = bv; a1[1][c] = bv; }
    for (int i = 0; i < D; i += 4) {
        float m0[4], m1[4];
        *(float4*)m0 = *(const float4*)&hin[te2][i];
        *(float4*)m1 = *(const float4*)&hin[te2 + 1][i];
        #pragma unroll
        for (int r = 0; r < 4; ++r) {
            float wr[8];
            *(float4*)&wr[0] = *(const float4*)(Wu1 + (size_t)(i + r) * HD + c0);
            *(float4*)&wr[4] = *(const float4*)(Wu1 + (size_t)(i + r) * HD + c0 + 4);
            #pragma unroll
            for (int c = 0; c < 8; ++c) { a1[0][c] += m0[r]*wr[c]; a1[1][c] += m1[r]*wr[c]; }
        }
    }
    #pragma unroll
    for (int j = 0; j < 2; ++j) {
        float v[8];
        #pragma unroll
        for (int c = 0; c < 8; ++c) v[c] = fmaxf(a1[j][c], 0.f);
        *(float4*)&hid[te2 + j][c0] = *(float4*)&v[0];
        *(float4*)&hid[te2 + j][c0 + 4] = *(float4*)&v[4];
    }
    __syncthreads();
    float a2[2][8];
    #pragma unroll
    for (int c = 0; c < 8; ++c) { float bv = bu2[c0 + c]; a2[0][c] = bv; a2[1][c] = bv; }
    for (int h = 0; h < HD; h += 4) {
        float m0[4], m1[4];
        *(float4*)m0 = *(const float4*)&hid[te2][h];
        *(float4*)m1 = *(const float4*)&hid[te2 + 1][h];
        #pragma unroll
        for (int r = 0; r < 4; ++r) {
            float wr[8];
            *(float4*)&wr[0] = *(const float4*)(Wu2 + (size_t)(h + r) * D + c0);
            *(float4*)&wr[4] = *(const float4*)(Wu2 + (size_t)(h + r) * D + c0 + 4);
            #pragma unroll
            for (int c = 0; c < 8; ++c) { a2[0][c] += m0[r]*wr[c]; a2[1][c] += m1[r]*wr[c]; }
        }
    }
    #pragma unroll
    for (int j = 0; j < 2; ++j) {
        int e = te2 + j, gn = n0 + e;
        if (e < nn) {
            *(float4*)(out + (size_t)gn * D + c0) = *(float4*)&a2[j][0];
            *(float4*)(out + (size_t)gn * D + c0 + 4) = *(float4*)&a2[j][4];
        }
    }
}

extern "C" void kernel_launch(void* const* d_in, const int* in_sizes, int n_in,
                              void* d_out, int out_size, void* d_ws, size_t ws_size,
                              hipStream_t stream) {
    const float* f   = (const float*)d_in[0];
    const float* x   = (const float*)d_in[1];
    const float* w   = (const float*)d_in[2];
    const int*   src = (const int*)d_in[3];
    const int*   dst = (const int*)d_in[4];
    const float* Wm1 = (const float*)d_in[5];
    const float* bm1 = (const float*)d_in[6];
    const float* Wm2 = (const float*)d_in[7];
    const float* bm2 = (const float*)d_in[8];
    const float* Wu1 = (const float*)d_in[9];
    const float* bu1 = (const float*)d_in[10];
    const float* Wu2 = (const float*)d_in[11];
    const float* bu2 = (const float*)d_in[12];

    const int Nn = in_sizes[0] / D;
    const int E  = in_sizes[3];

    const size_t wbytes  = (size_t)(128 * KP1 + HD * D) * sizeof(ushort_t);
    const size_t wubytes = (size_t)(2 * HD * D) * sizeof(ushort_t);
    auto align512 = [](size_t v) { return (v + 511) & ~(size_t)511; };
    char* wsb = (char*)d_ws;

    // ---------------- primary: linear-trick path (A fp8, B bf16), pair-packed ----------------
    size_t off = 0;
    const size_t o_w    = off; off = align512(off + wbytes);
    const size_t o_wu   = off; off = align512(off + wubytes);
    const size_t o_wbf  = off; off = align512(off + (size_t)E * DE * 2);
    const size_t o_af   = off; off = align512(off + (size_t)Nn * D);
    const size_t o_bf16 = off; off = align512(off + (size_t)Nn * D * 2);
    const size_t o_cnt  = off; off = align512(off + (size_t)Nn * 4);
    const size_t o_roff = off; off = align512(off + (size_t)Nn * 4);
    const size_t o_cur  = off; off = align512(off + (size_t)Nn * 4);
    const size_t o_perm = off; off = align512(off + (size_t)E * 4);
    const size_t o_sdst = off; off = align512(off + (size_t)E * 4);
    const size_t o_mh   = off; off = align512(off + (size_t)Nn * D * 4);
    const size_t primary_total = off;

    if (ws_size >= primary_total) {
        ushort_t* W1p  = (ushort_t*)(wsb + o_w);
        ushort_t* W2p  = W1p + 128 * KP1;
        ushort_t* Wu1p = (ushort_t*)(wsb + o_wu);
        ushort_t* Wu2p = Wu1p + HD * D;
        ushort_t* wbf  = (ushort_t*)(wsb + o_wbf);
        uchar_t*  Af   = (uchar_t*)(wsb + o_af);
        ushort_t* Bf16 = (ushort_t*)(wsb + o_bf16);
        int* cnt       = (int*)(wsb + o_cnt);
        int* roff      = (int*)(wsb + o_roff);
        int* cursor    = (int*)(wsb + o_cur);
        int* perm      = (int*)(wsb + o_perm);
        int* sdst      = (int*)(wsb + o_sdst);
        float* mh      = (float*)(wsb + o_mh);

        const int ntiles = (E + EB - 1) / EB;
        const int nblk   = (Nn + 63) / 64;
        hipMemsetAsync(cnt, 0, (size_t)Nn * 4, stream);
        fused_pre_kernel<<<dim3(1024), dim3(256), 0, stream>>>(
            Wm1, Wm2, Wu1, Wu2, W1p, W2p, Wu1p, Wu2p, dst, cnt, E);
        scan_kernel<<<dim3(1), dim3(1024), 0, stream>>>(cnt, roff, cursor, Nn);
        scatter_kernel<<<dim3((E + 255) / 256), dim3(256), 0, stream>>>(
            dst, cursor, roff, cnt, perm, sdst, w, wbf, mh, E, Nn);
        ab_kernel<<<dim3(nblk), dim3(NT), 0, stream>>>(f, W1p, Af, Bf16, Nn);
        edge_lin_kernel<<<dim3(ntiles), dim3(NT), 0, stream>>>(
            Af, Bf16, x, wbf, src, perm, sdst, W1p, bm1, mh, E);
        node_fused_kernel<<<dim3(nblk), dim3(NT), 0, stream>>>(
            f, mh, cnt, W2p, bm2, Wu1p, bu1, Wu2p, bu2, (float*)d_out, Nn);
        return;
    }

    // ---------------- fallback: bf16 pk-atomic path ----------------
    size_t off2 = 0;
    const size_t p_w  = off2; off2 = align512(off2 + wbytes);
    const size_t p_fb = off2; off2 = align512(off2 + (size_t)Nn * D * 2);
    const size_t p_ms = off2; off2 = align512(off2 + (size_t)Nn * D * 2);
    if (ws_size >= off2) {
        ushort_t* W1p  = (ushort_t*)(wsb + p_w);
        ushort_t* W2p  = W1p + 128 * KP1;
        ushort_t* fbf  = (ushort_t*)(wsb + p_fb);
        ushort_t* msum = (ushort_t*)(wsb + p_ms);
        const int rp_elems = 128 * KP1 + HD * D;
        hipMemsetAsync(msum, 0, (size_t)Nn * D * 2, stream);
        repack_kernel<<<dim3((rp_elems + 255) / 256), dim3(256), 0, stream>>>(Wm1, Wm2, W1p, W2p);
        const int n8 = Nn * D / 8;
        fconv_kernel<<<dim3((n8 + 255) / 256), dim3(256), 0, stream>>>(f, fbf, n8);
        edge_mfma_kernel<<<dim3((E + EB - 1) / EB), dim3(NT), 0, stream>>>(
            fbf, x, w, src, dst, W1p, bm1, W2p, bm2, msum, E);
        node_kernel<true><<<dim3((Nn + NB - 1) / NB), dim3(NT), 0, stream>>>(
            f, msum, Wu1, bu1, Wu2, bu2, (float*)d_out, Nn);
        return;
    }
}

// Round 24
// 239.367 us; speedup vs baseline: 1.7401x; 1.0180x over previous
//
#include <hip/hip_runtime.h>
#include <hip/hip_fp8.h>

#define D 128
#define HD 128
#define DE 16
#define MSG_IN 273
#define EB 64        // edges per tile
#define NT 256
#define KP1 288      // padded msg K = 9 chunks of 32
#define NCH2 4
#define NB 32
#define HID_PAD 132
#define CH8 (4 * EB * 64)
#define LDS1 (4 * EB * 64 + EB * 32)
// edge_lin LDS layout (bytes): A fp8 [0,8192) ; B bf16 [8192,24576) ; c8 bf16 [24576,28672)
#define OB 8192
#define OC 24576

typedef __attribute__((ext_vector_type(8))) short short8v;
typedef __attribute__((ext_vector_type(4))) float f32x4;
typedef __attribute__((ext_vector_type(2))) float f32x2;
typedef unsigned short ushort_t;
typedef unsigned char uchar_t;

#define GLOAD_LDS16(gp, lp) \
    __builtin_amdgcn_global_load_lds((const __attribute__((address_space(1))) unsigned int*)(gp), \
                                     (__attribute__((address_space(3))) unsigned int*)(lp), 16, 0, 0)

__device__ __forceinline__ unsigned short f2bf(float v) {
    unsigned int u = __builtin_bit_cast(unsigned int, v);
    u += 0x7fffu + ((u >> 16) & 1u);
    return (unsigned short)(u >> 16);
}
__device__ __forceinline__ float bf2f(ushort_t u) {
    return __builtin_bit_cast(float, (unsigned int)u << 16);
}
__device__ __forceinline__ unsigned int cvt_pk_bf16(float lo, float hi) {
    unsigned int r;
    asm("v_cvt_pk_bf16_f32 %0, %1, %2" : "=v"(r) : "v"(lo), "v"(hi));
    return r;
}
__device__ __forceinline__ uchar_t f8e(float v) {   // f32 -> e4m3 (HIP library)
    __hip_fp8_e4m3 t(v);
    return (uchar_t)t.__x;
}
// e4m3fn -> f32: normals 2^(e-7)(1+m/8); subnormals m/8*2^-6; sign bit preserved.
__device__ __forceinline__ float f8d(unsigned b) {
    unsigned t = ((b & 0x7fu) << 20) | ((b & 0x80u) << 24);
    return __builtin_bit_cast(float, t) * 0x1p120f;
}

// ---------------- fused prepass: repack weights + dst hist ----------------
__global__ void fused_pre_kernel(const float* __restrict__ Wm1, const float* __restrict__ Wm2,
                                 const float* __restrict__ Wu1, const float* __restrict__ Wu2,
                                 ushort_t* __restrict__ W1p, ushort_t* __restrict__ W2p,
                                 ushort_t* __restrict__ Wu1p, ushort_t* __restrict__ Wu2p,
                                 const int* __restrict__ dst, int* __restrict__ cnt,
                                 int E) {
    const int gid    = blockIdx.x * 256 + threadIdx.x;
    const int stride = gridDim.x * 256;
    const int rp1 = 128 * KP1;
    const int rp2 = rp1 + HD * D;
    const int rp_elems = rp2 + 2 * HD * D;
    for (int i = gid; i < rp_elems; i += stride) {
        if (i < rp1) {
            int n = i / KP1, k = i % KP1;
            W1p[i] = f2bf((k < MSG_IN) ? Wm1[(size_t)k * HD + n] : 0.f);
        } else if (i < rp2) {
            int i2 = i - rp1;
            int n = i2 / HD, k = i2 % HD;
            W2p[i2] = f2bf(Wm2[(size_t)k * D + n]);
        } else {
            int i2 = (i - rp2);
            const bool second = i2 >= HD * D;
            if (second) i2 -= HD * D;
            int n = i2 / HD, k = i2 % HD;
            if (second) Wu2p[i2] = f2bf(Wu2[(size_t)k * D + n]);
            else        Wu1p[i2] = f2bf(Wu1[(size_t)k * HD + n]);
        }
    }
    for (int i = gid; i < E; i += stride) atomicAdd(&cnt[dst[i]], 1);
}

// ---------------- CSR build: parallel scan ----------------
__global__ __launch_bounds__(1024) void scan_kernel(const int* __restrict__ cnt,
                                                    int* __restrict__ roff,
                                                    int* __restrict__ cursor, int Nn) {
    __shared__ int wsum[16];
    const int t = threadIdx.x, l = t & 63, wid = t >> 6;
    int running = 0;
    for (int base = 0; base < Nn; base += 4096) {
        const int i0 = base + t * 4;
        int v0 = 0, v1 = 0, v2 = 0, v3 = 0;
        if (i0 + 3 < Nn) {
            int4 v = *(const int4*)(cnt + i0);
            v0 = v.x; v1 = v.y; v2 = v.z; v3 = v.w;
        } else {
            if (i0 + 0 < Nn) v0 = cnt[i0 + 0];
            if (i0 + 1 < Nn) v1 = cnt[i0 + 1];
            if (i0 + 2 < Nn) v2 = cnt[i0 + 2];
        }
        const int vsum = v0 + v1 + v2 + v3;
        int s = vsum;
        #pragma unroll
        for (int off = 1; off < 64; off <<= 1) {
            int u = __shfl_up(s, off, 64);
            if (l >= off) s += u;
        }
        if (l == 63) wsum[wid] = s;
        __syncthreads();
        if (wid == 0 && l < 16) {
            int xv = wsum[l];
            #pragma unroll
            for (int off = 1; off < 16; off <<= 1) {
                int u = __shfl_up(xv, off, 64);
                if (l >= off) xv += u;
            }
            wsum[l] = xv;
        }
        __syncthreads();
        const int prev  = (wid > 0) ? wsum[wid - 1] : 0;
        const int total = wsum[15];
        int ex = running + prev + (s - vsum);
        if (i0 + 0 < Nn) { roff[i0 + 0] = ex; cursor[i0 + 0] = ex; } ex += v0;
        if (i0 + 1 < Nn) { roff[i0 + 1] = ex; cursor[i0 + 1] = ex; } ex += v1;
        if (i0 + 2 < Nn) { roff[i0 + 2] = ex; cursor[i0 + 2] = ex; } ex += v2;
        if (i0 + 3 < Nn) { roff[i0 + 3] = ex; cursor[i0 + 3] = ex; }
        running += total;
        __syncthreads();
    }
}

// ---------------- mid_kernel: scatter (blocks [0,SB)) || ab precompute (blocks [SB,...)) ----------
// scatter: CSR scatter + w->bf16 + selective mh zero.
// ab: A = f@Wm1[0:128] -> fp8 pair-packed, B = f@Wm1[128:256] -> bf16 pair-packed.
__global__ __launch_bounds__(NT, 4) void mid_kernel(
    const int* __restrict__ dst, int* cursor,
    const int* __restrict__ roff, const int* __restrict__ cnt,
    int* __restrict__ perm, int* __restrict__ sdst,
    const float* __restrict__ w, ushort_t* __restrict__ wbf,
    float* __restrict__ mh,
    const float* __restrict__ f, const ushort_t* __restrict__ W1p,
    uchar_t* __restrict__ Af, ushort_t* __restrict__ Bf16,
    int E, int Nn, int SB)
{
    if ((int)blockIdx.x < SB) {
        // ---------------- scatter path ----------------
        const int gid    = blockIdx.x * 256 + threadIdx.x;
        const int stride = SB * 256;
        for (int i = gid; i < E; i += stride) {
            int d = dst[i];
            int s = atomicAdd(&cursor[d], 1);
            perm[s] = i;
            sdst[s] = d;
            const float* wp = w + (size_t)i * DE;
            ushort_t* op = wbf + (size_t)i * DE;
            #pragma unroll
            for (int q = 0; q < 2; ++q) {
                float4 v0 = *(const float4*)(wp + q * 8);
                float4 v1 = *(const float4*)(wp + q * 8 + 4);
                union { ushort_t us[8]; short8v v; } pk;
                pk.us[0] = f2bf(v0.x); pk.us[1] = f2bf(v0.y);
                pk.us[2] = f2bf(v0.z); pk.us[3] = f2bf(v0.w);
                pk.us[4] = f2bf(v1.x); pk.us[5] = f2bf(v1.y);
                pk.us[6] = f2bf(v1.z); pk.us[7] = f2bf(v1.w);
                *(short8v*)(op + q * 8) = pk.v;
            }
        }
        for (int n = gid; n < Nn; n += stride) {
            const int c = cnt[n];
            const int r = roff[n];
            const bool need0 = (c == 0) || (r / EB != (r + c - 1) / EB);
            if (need0) {
                float4 z = {0.f, 0.f, 0.f, 0.f};
                float* p = mh + (size_t)n * D;
                #pragma unroll
                for (int k = 0; k < 32; ++k) *(float4*)(p + k * 4) = z;
            }
        }
        return;
    }

    // ---------------- ab path ----------------
    __shared__ __align__(16) ushort_t lds[2 * 64 * 64];   // 16 KB

    const int t    = threadIdx.x;
    const int lane = t & 63;
    const int wv   = t >> 6;
    const int col  = lane & 15;
    const int g    = lane >> 4;
    const int n0   = ((int)blockIdx.x - SB) * 64;

    #pragma unroll
    for (int it = 0; it < 4; ++it) {
        const int gidx = it * 256 + t;
        const int row  = gidx >> 4;
        const int gr   = gidx & 15;
        const int pair = gr >> 3, s = gr & 7;
        const int sP   = s ^ (row & 7);
        const int gn   = min(n0 + row, Nn - 1);
        const size_t off = (size_t)gn * D + gr * 8;
        float4 v0 = *(const float4*)(f + off);
        float4 v1 = *(const float4*)(f + off + 4);
        union { ushort_t us[8]; short8v v; } pk;
        pk.us[0] = f2bf(v0.x); pk.us[1] = f2bf(v0.y);
        pk.us[2] = f2bf(v0.z); pk.us[3] = f2bf(v0.w);
        pk.us[4] = f2bf(v1.x); pk.us[5] = f2bf(v1.y);
        pk.us[6] = f2bf(v1.z); pk.us[7] = f2bf(v1.w);
        *(short8v*)&lds[(pair * 64 + row) * 64 + sP * 8] = pk.v;
    }
    __syncthreads();

    #pragma unroll
    for (int half = 0; half < 2; ++half) {          // 0: A (fp8), 1: B (bf16)
        f32x4 acc[4][2];
        #pragma unroll
        for (int rt = 0; rt < 4; ++rt) {
            acc[rt][0] = (f32x4){0.f, 0.f, 0.f, 0.f};
            acc[rt][1] = (f32x4){0.f, 0.f, 0.f, 0.f};
        }
        const int kbase = half * 128;
        #pragma unroll
        for (int c = 0; c < 4; ++c) {
            short8v b0 = *(const short8v*)&W1p[(size_t)(wv * 32 + col) * KP1 + kbase + c * 32 + g * 8];
            short8v b1 = *(const short8v*)&W1p[(size_t)(wv * 32 + 16 + col) * KP1 + kbase + c * 32 + g * 8];
            short8v a[4];
            #pragma unroll
            for (int rt = 0; rt < 4; ++rt) {
                const int row = rt * 16 + col;
                const int sP = (((c & 1) << 2) + g) ^ (row & 7);
                a[rt] = *(const short8v*)&lds[((c >> 1) * 64 + row) * 64 + sP * 8];
            }
            #pragma unroll
            for (int rt = 0; rt < 4; ++rt) {
                acc[rt][0] = __builtin_amdgcn_mfma_f32_16x16x32_bf16(a[rt], b0, acc[rt][0], 0, 0, 0);
                acc[rt][1] = __builtin_amdgcn_mfma_f32_16x16x32_bf16(a[rt], b1, acc[rt][1], 0, 0, 0);
            }
        }
        // pair-packed epilogue: each lane owns the (j=0, j=1) column pair
        #pragma unroll
        for (int rt = 0; rt < 4; ++rt)
            #pragma unroll
            for (int r = 0; r < 4; ++r) {
                const int row = rt * 16 + g * 4 + r;
                const int gn = n0 + row;
                if (gn < Nn) {
                    const int cp = wv * 32 + col * 2;
                    if (half == 0) {
                        ushort_t pk = (ushort_t)f8e(acc[rt][0][r]) |
                                      ((ushort_t)f8e(acc[rt][1][r]) << 8);
                        *(ushort_t*)(Af + (size_t)gn * D + cp) = pk;
                    } else {
                        *(unsigned int*)(Bf16 + (size_t)gn * D + cp) =
                            cvt_pk_bf16(acc[rt][0][r], acc[rt][1][r]);
                    }
                }
            }
    }
}

// ---------------- edge kernel: HW fp8 decode (cvt_pk_f32_fp8) on packed pairs ----------------
__global__ __launch_bounds__(NT, 5) void edge_lin_kernel(
    const uchar_t* __restrict__ Af, const ushort_t* __restrict__ Bf16,
    const float* __restrict__ x, const ushort_t* __restrict__ wbf,
    const int* __restrict__ src,
    const int* __restrict__ perm, const int* __restrict__ sdst,
    const ushort_t* __restrict__ W1p, const float* __restrict__ bm1,
    float* __restrict__ mh, int E)
{
    __shared__ __align__(16) uchar_t lds8[28672];   // A 8K | B 16K | c8 4K
    __shared__ int s_rid[EB];
    __shared__ int s_dgs[EB];

    const int t    = threadIdx.x;
    const int lane = t & 63;
    const int wv   = t >> 6;
    const int e0   = blockIdx.x * EB;
    const int nvalid = min(EB, E - e0);

    const int myd  = (e0 + lane < E) ? sdst[e0 + lane] : -1;
    const int prevd = (e0 > 0) ? sdst[e0 - 1] : -2;
    const int nextd = (e0 + EB < E) ? sdst[e0 + EB] : -2;

    const int dprev_l = __shfl_up(myd, 1, 64);
    const bool head = (lane == 0) || (myd != dprev_l);
    const unsigned long long mask = __ballot(head && (lane < nvalid));
    const unsigned long long le = (lane == 63) ? ~0ull : ((1ull << (lane + 1)) - 1ull);
    const int rid = (int)__popcll(mask & le) - 1;
    const int ndist = (int)__popcll(mask);
    s_rid[lane] = (rid < 0) ? 0 : rid;
    if (head && lane < nvalid) s_dgs[rid] = myd;

    {
        const int el8 = lane >> 3;
        const int s   = lane & 7;
        const int sl  = s ^ el8;
        const int slA = min(e0 + wv * 16 + el8,     E - 1);
        const int slB = min(e0 + wv * 16 + 8 + el8, E - 1);
        const int nsA = src[perm[slA]];
        const int nsB = src[perm[slB]];
        GLOAD_LDS16(Af + (size_t)nsA * D + sl * 16, &lds8[(wv * 16    ) * 128]);
        GLOAD_LDS16(Af + (size_t)nsB * D + sl * 16, &lds8[(wv * 16 + 8) * 128]);
    }
    {
        const int ntask = ndist * 16;
        for (int idx = t; idx < ntask; idx += NT) {
            const int rowr = idx >> 4;
            const int gr   = idx & 15;
            const int dg   = s_dgs[rowr];
            uint4 v = *(const uint4*)(Bf16 + (size_t)dg * D + gr * 8);
            const int phys = gr ^ (rowr & 15);
            *(uint4*)&lds8[OB + rowr * 256 + phys * 16] = v;
        }
    }
    {
        const int el = lane >> 2, q = lane & 3;
        const int qp = q ^ (el & 3);
        const int slot = e0 + wv * 16 + el;
        const bool ok = slot < E;
        const int sc = min(slot, E - 1);
        const int ge = perm[sc];
        union { ushort_t us[8]; short8v v; } pk;
        #pragma unroll
        for (int j = 0; j < 8; ++j) pk.us[j] = 0;
        if (ok) {
            if (q < 2) {
                pk.v = *(const short8v*)(wbf + (size_t)ge * DE + q * 8);
            } else if (q == 2) {
                const int ns = src[ge], nd = sdst[sc];
                float dx = x[ns*3+0] - x[nd*3+0];
                float dy = x[ns*3+1] - x[nd*3+1];
                float dz = x[ns*3+2] - x[nd*3+2];
                pk.us[0] = f2bf(dx*dx + dy*dy + dz*dz);
            }
        }
        *(short8v*)&lds8[OC + (wv * 16 + el) * 64 + qp * 16] = pk.v;
    }

    const int col = lane & 15;
    const int g   = lane >> 4;

    short8v bc0 = *(const short8v*)&W1p[(size_t)(wv * 32 + col) * KP1 + 256 + g * 8];
    short8v bc1 = *(const short8v*)&W1p[(size_t)(wv * 32 + 16 + col) * KP1 + 256 + g * 8];

    __syncthreads();   // B0

    f32x4 acc[4][2];
    {
        float bv0 = bm1[wv * 32 + col];
        float bv1 = bm1[wv * 32 + 16 + col];
        #pragma unroll
        for (int rt = 0; rt < 4; ++rt) {
            acc[rt][0] = (f32x4){bv0, bv0, bv0, bv0};
            acc[rt][1] = (f32x4){bv1, bv1, bv1, bv1};
        }
    }
    #pragma unroll
    for (int rt = 0; rt < 4; ++rt) {
        const int row = rt * 16 + col;
        const int sP8 = g ^ (row & 3);
        short8v a = *(const short8v*)&lds8[OC + row * 64 + sP8 * 16];
        acc[rt][0] = __builtin_amdgcn_mfma_f32_16x16x32_bf16(a, bc0, acc[rt][0], 0, 0, 0);
        acc[rt][1] = __builtin_amdgcn_mfma_f32_16x16x32_bf16(a, bc1, acc[rt][1], 0, 0, 0);
    }

    // ---- h = relu(acc + A + B); packed-pair loads + HW fp8 decode ----
    float h[4][2][4];
    const int cgA = 2 * wv + (col >> 3);
    const int coA = (col * 2) & 15;
    const int cbB = 4 * wv + (col >> 2);
    const int coB = (col & 3) * 4;
    #pragma unroll
    for (int rt = 0; rt < 4; ++rt) {
        #pragma unroll
        for (int r = 0; r < 4; ++r) {
            const int row = rt * 16 + g * 4 + r;
            const int rd  = s_rid[row];
            const int aadr = row * 128 + ((cgA ^ (row & 7)) << 4) + coA;
            const int badr = OB + rd * 256 + ((cbB ^ (rd & 15)) << 4) + coB;
            const ushort_t ap = *(const ushort_t*)&lds8[aadr];
            const unsigned bp = *(const unsigned*)&lds8[badr];
            f32x2 af = __builtin_amdgcn_cvt_pk_f32_fp8((int)ap, false);
            const float b0f = __builtin_bit_cast(float, bp << 16);
            const float b1f = __builtin_bit_cast(float, bp & 0xffff0000u);
            h[rt][0][r] = fmaxf(acc[rt][0][r] + af[0] + b0f, 0.f);
            h[rt][1][r] = fmaxf(acc[rt][1][r] + af[1] + b1f, 0.f);
        }
    }

    // ---- wave-local segment reduce -> mh (f32) ----
    float qs[4][2];
    #pragma unroll
    for (int rt = 0; rt < 4; ++rt) {
        qs[rt][0] = (h[rt][0][0] + h[rt][0][1]) + (h[rt][0][2] + h[rt][0][3]);
        qs[rt][1] = (h[rt][1][0] + h[rt][1][1]) + (h[rt][1][2] + h[rt][1][3]);
    }
    unsigned long long rem = mask;
    while (rem) {
        const int beg = (int)__builtin_ctzll(rem);
        rem &= rem - 1;
        const int end = rem ? (int)__builtin_ctzll(rem) : nvalid;
        const int dg  = __shfl(myd, beg, 64);

        float s0 = 0.f, s1 = 0.f;
        #pragma unroll
        for (int rt = 0; rt < 4; ++rt) {
            const int qb = rt * 16 + g * 4;
            const int lo = max(qb, beg);
            const int hi = min(qb + 4, end);
            if (lo < hi) {
                if (lo == qb && hi == qb + 4) {
                    s0 += qs[rt][0]; s1 += qs[rt][1];
                } else {
                    #pragma unroll
                    for (int r = 0; r < 4; ++r) {
                        const int sl = qb + r;
                        if (sl >= beg && sl < end) {
                            s0 += h[rt][0][r]; s1 += h[rt][1][r];
                        }
                    }
                }
            }
        }
        s0 += __shfl_xor(s0, 16, 64); s0 += __shfl_xor(s0, 32, 64);
        s1 += __shfl_xor(s1, 16, 64); s1 += __shfl_xor(s1, 32, 64);
        if (g == 0) {
            const bool bnd = (beg == 0 && dg == prevd) || (end == nvalid && dg == nextd);
            float* p = mh + (size_t)dg * D + wv * 32 + col;
            if (bnd) { atomicAdd(p, s0); atomicAdd(p + 16, s1); }
            else     { p[0] = s0; p[16] = s1; }
        }
    }
}

// ---------------- node_fused: msum = mh@Wm2 + cnt*bm2; hin = msum + f; node MLP -> out ----------------
__global__ __launch_bounds__(NT, 4) void node_fused_kernel(
    const float* __restrict__ f, const float* __restrict__ mh,
    const int* __restrict__ cnt,
    const ushort_t* __restrict__ W2p, const float* __restrict__ bm2,
    const ushort_t* __restrict__ Wu1p, const float* __restrict__ bu1,
    const ushort_t* __restrict__ Wu2p, const float* __restrict__ bu2,
    float* __restrict__ out, int Nn)
{
    __shared__ __align__(16) ushort_t lds[2 * 64 * 64];   // 16 KB
    __shared__ int s_cnt[64];

    const int t    = threadIdx.x;
    const int lane = t & 63;
    const int wv   = t >> 6;
    const int col  = lane & 15;
    const int g    = lane >> 4;
    const int n0   = blockIdx.x * 64;

    if (t < 64) s_cnt[t] = (n0 + t < Nn) ? cnt[n0 + t] : 0;

    #pragma unroll
    for (int it = 0; it < 4; ++it) {
        const int gidx = it * 256 + t;
        const int row  = gidx >> 4;
        const int gr   = gidx & 15;
        const int pair = gr >> 3, s = gr & 7;
        const int sP   = s ^ (row & 7);
        const int gn   = n0 + row;
        union { ushort_t us[8]; short8v v; } pk;
        if (gn < Nn) {
            const size_t off = (size_t)gn * D + gr * 8;
            float4 m0 = *(const float4*)(mh + off);
            float4 m1 = *(const float4*)(mh + off + 4);
            pk.us[0] = f2bf(m0.x); pk.us[1] = f2bf(m0.y);
            pk.us[2] = f2bf(m0.z); pk.us[3] = f2bf(m0.w);
            pk.us[4] = f2bf(m1.x); pk.us[5] = f2bf(m1.y);
            pk.us[6] = f2bf(m1.z); pk.us[7] = f2bf(m1.w);
        } else {
            #pragma unroll
            for (int j = 0; j < 8; ++j) pk.us[j] = 0;
        }
        *(short8v*)&lds[(pair * 64 + row) * 64 + sP * 8] = pk.v;
    }
    __syncthreads();   // B0: mh staged

    f32x4 acc[4][2];
    {
        const float bv0 = bm2[wv * 32 + col];
        const float bv1 = bm2[wv * 32 + 16 + col];
        #pragma unroll
        for (int rt = 0; rt < 4; ++rt)
            #pragma unroll
            for (int r = 0; r < 4; ++r) {
                const float cn = (float)s_cnt[rt * 16 + g * 4 + r];
                acc[rt][0][r] = cn * bv0;
                acc[rt][1][r] = cn * bv1;
            }
    }
    #pragma unroll
    for (int c = 0; c < 4; ++c) {
        short8v b0 = *(const short8v*)&W2p[(size_t)(wv * 32 + col) * HD + c * 32 + g * 8];
        short8v b1 = *(const short8v*)&W2p[(size_t)(wv * 32 + 16 + col) * HD + c * 32 + g * 8];
        short8v a[4];
        #pragma unroll
        for (int rt = 0; rt < 4; ++rt) {
            const int row = rt * 16 + col;
            const int sP = (((c & 1) << 2) + g) ^ (row & 7);
            a[rt] = *(const short8v*)&lds[((c >> 1) * 64 + row) * 64 + sP * 8];
        }
        #pragma unroll
        for (int rt = 0; rt < 4; ++rt) {
            acc[rt][0] = __builtin_amdgcn_mfma_f32_16x16x32_bf16(a[rt], b0, acc[rt][0], 0, 0, 0);
            acc[rt][1] = __builtin_amdgcn_mfma_f32_16x16x32_bf16(a[rt], b1, acc[rt][1], 0, 0, 0);
        }
    }
    __syncthreads();   // B1

    const int ph = wv >> 1;
    #pragma unroll
    for (int rt = 0; rt < 4; ++rt)
        #pragma unroll
        for (int r = 0; r < 4; ++r) {
            const int row = rt * 16 + g * 4 + r;
            const int gn = n0 + row;
            #pragma unroll
            for (int j = 0; j < 2; ++j) {
                const int ca = wv * 32 + j * 16 + col;
                float v = 0.f;
                if (gn < Nn) v = acc[rt][j][r] + f[(size_t)gn * D + ca];
                unsigned int pk2 = cvt_pk_bf16(v, v);
                const int sH = (((wv & 1) << 2) + j * 2 + (col >> 3)) ^ (row & 7);
                lds[(ph * 64 + row) * 64 + sH * 8 + (col & 7)] = (ushort_t)pk2;
            }
        }
    __syncthreads();   // B2

    const size_t wrow0 = (size_t)(wv * 32 + col) * HD;
    const size_t wrow1 = (size_t)(wv * 32 + 16 + col) * HD;
    f32x4 acc1[4][2];
    {
        float bv0 = bu1[wv * 32 + col];
        float bv1 = bu1[wv * 32 + 16 + col];
        #pragma unroll
        for (int rt = 0; rt < 4; ++rt) {
            acc1[rt][0] = (f32x4){bv0, bv0, bv0, bv0};
            acc1[rt][1] = (f32x4){bv1, bv1, bv1, bv1};
        }
    }
    #pragma unroll
    for (int c = 0; c < 4; ++c) {
        short8v b0 = *(const short8v*)&Wu1p[wrow0 + c * 32 + g * 8];
        short8v b1 = *(const short8v*)&Wu1p[wrow1 + c * 32 + g * 8];
        short8v a[4];
        #pragma unroll
        for (int rt = 0; rt < 4; ++rt) {
            const int row = rt * 16 + col;
            const int sP = (((c & 1) << 2) + g) ^ (row & 7);
            a[rt] = *(const short8v*)&lds[((c >> 1) * 64 + row) * 64 + sP * 8];
        }
        #pragma unroll
        for (int rt = 0; rt < 4; ++rt) {
            acc1[rt][0] = __builtin_amdgcn_mfma_f32_16x16x32_bf16(a[rt], b0, acc1[rt][0], 0, 0, 0);
            acc1[rt][1] = __builtin_amdgcn_mfma_f32_16x16x32_bf16(a[rt], b1, acc1[rt][1], 0, 0, 0);
        }
    }
    __syncthreads();   // B3

    #pragma unroll
    for (int rt = 0; rt < 4; ++rt)
        #pragma unroll
        for (int j = 0; j < 2; ++j)
            #pragma unroll
            for (int r = 0; r < 4; ++r) {
                const int row = rt * 16 + g * 4 + r;
                float v = fmaxf(acc1[rt][j][r], 0.f);
                unsigned int pk2 = cvt_pk_bf16(v, v);
                const int sH = (((wv & 1) << 2) + j * 2 + (col >> 3)) ^ (row & 7);
                lds[(ph * 64 + row) * 64 + sH * 8 + (col & 7)] = (ushort_t)pk2;
            }
    __syncthreads();   // B4

    f32x4 acc2[4][2];
    {
        float bv0 = bu2[wv * 32 + col];
        float bv1 = bu2[wv * 32 + 16 + col];
        #pragma unroll
        for (int rt = 0; rt < 4; ++rt) {
            acc2[rt][0] = (f32x4){bv0, bv0, bv0, bv0};
            acc2[rt][1] = (f32x4){bv1, bv1, bv1, bv1};
        }
    }
    #pragma unroll
    for (int c = 0; c < 4; ++c) {
        short8v b0 = *(const short8v*)&Wu2p[wrow0 + c * 32 + g * 8];
        short8v b1 = *(const short8v*)&Wu2p[wrow1 + c * 32 + g * 8];
        short8v a[4];
        #pragma unroll
        for (int rt = 0; rt < 4; ++rt) {
            const int row = rt * 16 + col;
            const int sP = (((c & 1) << 2) + g) ^ (row & 7);
            a[rt] = *(const short8v*)&lds[((c >> 1) * 64 + row) * 64 + sP * 8];
        }
        #pragma unroll
        for (int rt = 0; rt < 4; ++rt) {
            acc2[rt][0] = __builtin_amdgcn_mfma_f32_16x16x32_bf16(a[rt], b0, acc2[rt][0], 0, 0, 0);
            acc2[rt][1] = __builtin_amdgcn_mfma_f32_16x16x32_bf16(a[rt], b1, acc2[rt][1], 0, 0, 0);
        }
    }

    #pragma unroll
    for (int rt = 0; rt < 4; ++rt)
        #pragma unroll
        for (int r = 0; r < 4; ++r) {
            const int row = rt * 16 + g * 4 + r;
            const int gn = n0 + row;
            if (gn < Nn) {
                out[(size_t)gn * D + wv * 32 + col]      = acc2[rt][0][r];
                out[(size_t)gn * D + wv * 32 + 16 + col] = acc2[rt][1][r];
            }
        }
}

// ================= fallback kernels (bf16 pk-atomic path; unchanged) =================

__global__ void repack_kernel(const float* __restrict__ Wm1, const float* __restrict__ Wm2,
                              ushort_t* __restrict__ W1p, ushort_t* __restrict__ W2p) {
    int idx = blockIdx.x * 256 + threadIdx.x;
    const int n1 = 128 * KP1;
    if (idx < n1) {
        int n = idx / KP1, k = idx % KP1;
        W1p[idx] = f2bf((k < MSG_IN) ? Wm1[(size_t)k * HD + n] : 0.f);
    } else {
        int i2 = idx - n1;
        if (i2 < HD * D) {
            int n = i2 / HD, k = i2 % HD;
            W2p[i2] = f2bf(Wm2[(size_t)k * D + n]);
        }
    }
}

__global__ void fconv_kernel(const float* __restrict__ f, ushort_t* __restrict__ fb, int n8) {
    int i = blockIdx.x * 256 + threadIdx.x;
    if (i < n8) {
        float4 v0 = *(const float4*)(f + (size_t)i * 8);
        float4 v1 = *(const float4*)(f + (size_t)i * 8 + 4);
        union { ushort_t us[8]; short8v v; } pk;
        pk.us[0] = f2bf(v0.x); pk.us[1] = f2bf(v0.y);
        pk.us[2] = f2bf(v0.z); pk.us[3] = f2bf(v0.w);
        pk.us[4] = f2bf(v1.x); pk.us[5] = f2bf(v1.y);
        pk.us[6] = f2bf(v1.z); pk.us[7] = f2bf(v1.w);
        *(short8v*)(fb + (size_t)i * 8) = pk.v;
    }
}

__global__ __launch_bounds__(NT, 4) void edge_mfma_kernel(
    const ushort_t* __restrict__ fbf, const float* __restrict__ x,
    const float* __restrict__ w, const int* __restrict__ src,
    const int* __restrict__ dst,
    const ushort_t* __restrict__ W1p, const float* __restrict__ bm1,
    const ushort_t* __restrict__ W2p, const float* __restrict__ bm2,
    ushort_t* msum, int E)
{
    __shared__ __align__(16) ushort_t lds[LDS1];
    __shared__ int s_dst[EB];

    const int t    = threadIdx.x;
    const int lane = t & 63;
    const int wv   = t >> 6;
    const int e0   = blockIdx.x * EB;

    if (t < EB) s_dst[t] = (e0 + t < E) ? dst[e0 + t] : 0;
    {
        const int el8 = lane >> 3;
        const int s   = lane & 7;
        const int sl  = s ^ el8;
        const int geA = min(e0 + wv * 16 + el8,     E - 1);
        const int geB = min(e0 + wv * 16 + 8 + el8, E - 1);
        const int nsA = src[geA], ndA = dst[geA];
        const int nsB = src[geB], ndB = dst[geB];
        #pragma unroll
        for (int p = 0; p < 4; ++p) {
            const int n0 = (p < 2) ? nsA : ndA;
            const int n1 = (p < 2) ? nsB : ndB;
            const ushort_t* g0 = fbf + (size_t)n0 * D + (p & 1) * 64 + sl * 8;
            const ushort_t* g1 = fbf + (size_t)n1 * D + (p & 1) * 64 + sl * 8;
            GLOAD_LDS16(g0, &lds[(p * EB + wv * 16    ) * 64]);
            GLOAD_LDS16(g1, &lds[(p * EB + wv * 16 + 8) * 64]);
        }
    }
    {
        const int el = lane >> 2, q = lane & 3;
        const int qp = q ^ (el & 3);
        const int ge = e0 + wv * 16 + el;
        const bool ok = ge < E;
        const int gc = min(ge, E - 1);
        union { ushort_t us[8]; short8v v; } pk;
        #pragma unroll
        for (int j = 0; j < 8; ++j) pk.us[j] = 0;
        if (ok) {
            if (q < 2) {
                float4 w0 = *(const float4*)(w + (size_t)gc * DE + q * 8);
                float4 w1 = *(const float4*)(w + (size_t)gc * DE + q * 8 + 4);
                pk.us[0] = f2bf(w0.x); pk.us[1] = f2bf(w0.y);
                pk.us[2] = f2bf(w0.z); pk.us[3] = f2bf(w0.w);
                pk.us[4] = f2bf(w1.x); pk.us[5] = f2bf(w1.y);
                pk.us[6] = f2bf(w1.z); pk.us[7] = f2bf(w1.w);
            } else if (q == 2) {
                const int ns = src[gc], nd = dst[gc];
                float dx = x[ns*3+0] - x[nd*3+0];
                float dy = x[ns*3+1] - x[nd*3+1];
                float dz = x[ns*3+2] - x[nd*3+2];
                pk.us[0] = f2bf(dx*dx + dy*dy + dz*dz);
            }
        }
        *(short8v*)&lds[CH8 + (wv * 16 + el) * 32 + qp * 8] = pk.v;
    }

    const int col = lane & 15;
    const int g   = lane >> 4;
    const size_t wrow0 = (size_t)(wv * 32 + col) * KP1;
    const size_t wrow1 = (size_t)(wv * 32 + 16 + col) * KP1;
    short8v nb0 = *(const short8v*)&W1p[wrow0 + g * 8];
    short8v nb1 = *(const short8v*)&W1p[wrow1 + g * 8];
    __syncthreads();

    f32x4 acc[4][2];
    {
        float bv0 = bm1[wv * 32 + col];
        float bv1 = bm1[wv * 32 + 16 + col];
        #pragma unroll
        for (int rt = 0; rt < 4; ++rt) {
            acc[rt][0] = (f32x4){bv0, bv0, bv0, bv0};
            acc[rt][1] = (f32x4){bv1, bv1, bv1, bv1};
        }
    }
    #pragma unroll
    for (int c = 0; c < 9; ++c) {
        short8v b0 = nb0, b1 = nb1;
        if (c + 1 < 9) {
            nb0 = *(const short8v*)&W1p[wrow0 + (c + 1) * 32 + g * 8];
            nb1 = *(const short8v*)&W1p[wrow1 + (c + 1) * 32 + g * 8];
        }
        short8v a[4];
        #pragma unroll
        for (int rt = 0; rt < 4; ++rt) {
            const int row = rt * 16 + col;
            if (c < 8) {
                const int sP = (((c & 1) << 2) + g) ^ (row & 7);
                a[rt] = *(const short8v*)&lds[((c >> 1) * EB + row) * 64 + sP * 8];
            } else {
                const int sP = g ^ (row & 3);
                a[rt] = *(const short8v*)&lds[CH8 + row * 32 + sP * 8];
            }
        }
        #pragma unroll
        for (int rt = 0; rt < 4; ++rt) {
            acc[rt][0] = __builtin_amdgcn_mfma_f32_16x16x32_bf16(a[rt], b0, acc[rt][0], 0, 0, 0);
            acc[rt][1] = __builtin_amdgcn_mfma_f32_16x16x32_bf16(a[rt], b1, acc[rt][1], 0, 0, 0);
        }
    }
    __syncthreads();

    const int ph = wv >> 1;
    #pragma unroll
    for (int rt = 0; rt < 4; ++rt)
        #pragma unroll
        for (int j = 0; j < 2; ++j)
            #pragma unroll
            for (int r = 0; r < 4; ++r) {
                const int row = rt * 16 + g * 4 + r;
                float v = fmaxf(acc[rt][j][r], 0.f);
                unsigned int pk2 = cvt_pk_bf16(v, v);
                const int sH = (((wv & 1) << 2) + j * 2 + (col >> 3)) ^ (row & 7);
                lds[(ph * EB + row) * 64 + sH * 8 + (col & 7)] = (ushort_t)pk2;
            }
    __syncthreads();

    const size_t w2r0 = (size_t)(wv * 32 + col) * HD;
    const size_t w2r1 = (size_t)(wv * 32 + 16 + col) * HD;
    short8v m0 = *(const short8v*)&W2p[w2r0 + g * 8];
    short8v m1 = *(const short8v*)&W2p[w2r1 + g * 8];
    f32x4 acc2[4][2];
    {
        float bv0 = bm2[wv * 32 + col];
        float bv1 = bm2[wv * 32 + 16 + col];
        #pragma unroll
        for (int rt = 0; rt < 4; ++rt) {
            acc2[rt][0] = (f32x4){bv0, bv0, bv0, bv0};
            acc2[rt][1] = (f32x4){bv1, bv1, bv1, bv1};
        }
    }
    #pragma unroll
    for (int c = 0; c < NCH2; ++c) {
        short8v b0 = m0, b1 = m1;
        if (c + 1 < NCH2) {
            m0 = *(const short8v*)&W2p[w2r0 + (c + 1) * 32 + g * 8];
            m1 = *(const short8v*)&W2p[w2r1 + (c + 1) * 32 + g * 8];
        }
        short8v a[4];
        #pragma unroll
        for (int rt = 0; rt < 4; ++rt) {
            const int row = rt * 16 + col;
            const int sP = (((c & 1) << 2) + g) ^ (row & 7);
            a[rt] = *(const short8v*)&lds[((c >> 1) * EB + row) * 64 + sP * 8];
        }
        #pragma unroll
        for (int rt = 0; rt < 4; ++rt) {
            acc2[rt][0] = __builtin_amdgcn_mfma_f32_16x16x32_bf16(a[rt], b0, acc2[rt][0], 0, 0, 0);
            acc2[rt][1] = __builtin_amdgcn_mfma_f32_16x16x32_bf16(a[rt], b1, acc2[rt][1], 0, 0, 0);
        }
    }

    const bool even = (col & 1) == 0;
    #pragma unroll
    for (int rt = 0; rt < 4; ++rt)
        #pragma unroll
        for (int r = 0; r < 4; ++r) {
            const int e  = rt * 16 + g * 4 + r;
            const int ge = e0 + e;
            const int dg = s_dst[e];
            #pragma unroll
            for (int j = 0; j < 2; ++j) {
                float v  = acc2[rt][j][r];
                float vn = __shfl_xor(v, 1, 64);
                if (even && ge < E) {
                    unsigned int pk2 = cvt_pk_bf16(v, vn);
                    ushort_t* p = msum + (size_t)dg * D + wv * 32 + j * 16 + col;
                    asm volatile("global_atomic_pk_add_bf16 %0, %1, off"
                                 :: "v"(p), "v"(pk2) : "memory");
                }
            }
        }
}

template<bool MB16>
__global__ __launch_bounds__(NT, 4) void node_kernel(
    const float* __restrict__ f, const void* __restrict__ msum_v,
    const float* __restrict__ Wu1, const float* __restrict__ bu1,
    const float* __restrict__ Wu2, const float* __restrict__ bu2,
    float* out, int Nn)
{
    __shared__ __align__(16) float hin[NB][HID_PAD];
    __shared__ __align__(16) float hid[NB][HID_PAD];
    const int t  = threadIdx.x;
    const int n0 = blockIdx.x * NB;
    const int nn = min(NB, Nn - n0);

    {
        #pragma unroll
        for (int it = 0; it < 4; ++it) {
            const int idx = it * 1024 + t * 4;
            const int e   = idx >> 7;
            const int cb  = idx & 127;
            if (e < nn) {
                const size_t off = (size_t)(n0 + e) * D + cb;
                float4 mv;
                if (MB16) {
                    uint2 pk = *(const uint2*)((const ushort_t*)msum_v + off);
                    mv.x = bf2f((ushort_t)(pk.x & 0xffffu));
                    mv.y = bf2f((ushort_t)(pk.x >> 16));
                    mv.z = bf2f((ushort_t)(pk.y & 0xffffu));
                    mv.w = bf2f((ushort_t)(pk.y >> 16));
                } else {
                    mv = *(const float4*)((const float*)msum_v + off);
                }
                float4 fv = *(const float4*)&f[off];
                float4 o = {mv.x + fv.x, mv.y + fv.y, mv.z + fv.z, mv.w + fv.w};
                *(float4*)&hin[e][cb] = o;
            }
        }
    }
    __syncthreads();

    const int tc = t & 15, te2 = (t >> 4) * 2, c0 = tc * 8;
    float a1[2][8];
    #pragma unroll
    for (int c = 0; c < 8; ++c) { float bv = bu1[c0 + c]; a1[0][c] = bv; a1[1][c] = bv; }
    for (int i = 0; i < D; i += 4) {
        float m0[4], m1[4];
        *(float4*)m0 = *(const float4*)&hin[te2][i];
        *(float4*)m1 = *(const float4*)&hin[te2 + 1][i];
        #pragma unroll
        for (int r = 0; r < 4; ++r) {
            float wr[8];
            *(float4*)&wr[0] = *(const float4*)(Wu1 + (size_t)(i + r) * HD + c0);
            *(float4*)&wr[4] = *(const float4*)(Wu1 + (size_t)(i + r) * HD + c0 + 4);
            #pragma unroll
            for (int c = 0; c < 8; ++c) { a1[0][c] += m0[r]*wr[c]; a1[1][c] += m1[r]*wr[c]; }
        }
    }
    #pragma unroll
    for (int j = 0; j < 2; ++j) {
        float v[8];
        #pragma unroll
        for (int c = 0; c < 8; ++c) v[c] = fmaxf(a1[j][c], 0.f);
        *(float4*)&hid[te2 + j][c0] = *(float4*)&v[0];
        *(float4*)&hid[te2 + j][c0 + 4] = *(float4*)&v[4];
    }
    __syncthreads();
    float a2[2][8];
    #pragma unroll
    for (int c = 0; c < 8; ++c) { float bv = bu2[c0 + c]; a2[0][c] = bv; a2[1][c] = bv; }
    for (int h = 0; h < HD; h += 4) {
        float m0[4], m1[4];
        *(float4*)m0 = *(const float4*)&hid[te2][h];
        *(float4*)m1 = *(const float4*)&hid[te2 + 1][h];
        #pragma unroll
        for (int r = 0; r < 4; ++r) {
            float wr[8];
            *(float4*)&wr[0] = *(const float4*)(Wu2 + (size_t)(h + r) * D + c0);
            *(float4*)&wr[4] = *(const float4*)(Wu2 + (size_t)(h + r) * D + c0 + 4);
            #pragma unroll
            for (int c = 0; c < 8; ++c) { a2[0][c] += m0[r]*wr[c]; a2[1][c] += m1[r]*wr[c]; }
        }
    }
    #pragma unroll
    for (int j = 0; j < 2; ++j) {
        int e = te2 + j, gn = n0 + e;
        if (e < nn) {
            *(float4*)(out + (size_t)gn * D + c0) = *(float4*)&a2[j][0];
            *(float4*)(out + (size_t)gn * D + c0 + 4) = *(float4*)&a2[j][4];
        }
    }
}

extern "C" void kernel_launch(void* const* d_in, const int* in_sizes, int n_in,
                              void* d_out, int out_size, void* d_ws, size_t ws_size,
                              hipStream_t stream) {
    const float* f   = (const float*)d_in[0];
    const float* x   = (const float*)d_in[1];
    const float* w   = (const float*)d_in[2];
    const int*   src = (const int*)d_in[3];
    const int*   dst = (const int*)d_in[4];
    const float* Wm1 = (const float*)d_in[5];
    const float* bm1 = (const float*)d_in[6];
    const float* Wm2 = (const float*)d_in[7];
    const float* bm2 = (const float*)d_in[8];
    const float* Wu1 = (const float*)d_in[9];
    const float* bu1 = (const float*)d_in[10];
    const float* Wu2 = (const float*)d_in[11];
    const float* bu2 = (const float*)d_in[12];

    const int Nn = in_sizes[0] / D;
    const int E  = in_sizes[3];

    const size_t wbytes  = (size_t)(128 * KP1 + HD * D) * sizeof(ushort_t);
    const size_t wubytes = (size_t)(2 * HD * D) * sizeof(ushort_t);
    auto align512 = [](size_t v) { return (v + 511) & ~(size_t)511; };
    char* wsb = (char*)d_ws;

    // ---------------- primary: linear-trick path (A fp8, B bf16), pair-packed ----------------
    size_t off = 0;
    const size_t o_w    = off; off = align512(off + wbytes);
    const size_t o_wu   = off; off = align512(off + wubytes);
    const size_t o_wbf  = off; off = align512(off + (size_t)E * DE * 2);
    const size_t o_af   = off; off = align512(off + (size_t)Nn * D);
    const size_t o_bf16 = off; off = align512(off + (size_t)Nn * D * 2);
    const size_t o_cnt  = off; off = align512(off + (size_t)Nn * 4);
    const size_t o_roff = off; off = align512(off + (size_t)Nn * 4);
    const size_t o_cur  = off; off = align512(off + (size_t)Nn * 4);
    const size_t o_perm = off; off = align512(off + (size_t)E * 4);
    const size_t o_sdst = off; off = align512(off + (size_t)E * 4);
    const size_t o_mh   = off; off = align512(off + (size_t)Nn * D * 4);
    const size_t primary_total = off;

    if (ws_size >= primary_total) {
        ushort_t* W1p  = (ushort_t*)(wsb + o_w);
        ushort_t* W2p  = W1p + 128 * KP1;
        ushort_t* Wu1p = (ushort_t*)(wsb + o_wu);
        ushort_t* Wu2p = Wu1p + HD * D;
        ushort_t* wbf  = (ushort_t*)(wsb + o_wbf);
        uchar_t*  Af   = (uchar_t*)(wsb + o_af);
        ushort_t* Bf16 = (ushort_t*)(wsb + o_bf16);
        int* cnt       = (int*)(wsb + o_cnt);
        int* roff      = (int*)(wsb + o_roff);
        int* cursor    = (int*)(wsb + o_cur);
        int* perm      = (int*)(wsb + o_perm);
        int* sdst      = (int*)(wsb + o_sdst);
        float* mh      = (float*)(wsb + o_mh);

        const int ntiles = (E + EB - 1) / EB;
        const int nblk   = (Nn + 63) / 64;
        const int SB     = (E + 511) / 512;     // scatter blocks (grid-stride, 2 edges/thread)
        hipMemsetAsync(cnt, 0, (size_t)Nn * 4, stream);
        fused_pre_kernel<<<dim3(1024), dim3(256), 0, stream>>>(
            Wm1, Wm2, Wu1, Wu2, W1p, W2p, Wu1p, Wu2p, dst, cnt, E);
        scan_kernel<<<dim3(1), dim3(1024), 0, stream>>>(cnt, roff, cursor, Nn);
        mid_kernel<<<dim3(SB + nblk), dim3(NT), 0, stream>>>(
            dst, cursor, roff, cnt, perm, sdst, w, wbf, mh,
            f, W1p, Af, Bf16, E, Nn, SB);
        edge_lin_kernel<<<dim3(ntiles), dim3(NT), 0, stream>>>(
            Af, Bf16, x, wbf, src, perm, sdst, W1p, bm1, mh, E);
        node_fused_kernel<<<dim3(nblk), dim3(NT), 0, stream>>>(
            f, mh, cnt, W2p, bm2, Wu1p, bu1, Wu2p, bu2, (float*)d_out, Nn);
        return;
    }

    // ---------------- fallback: bf16 pk-atomic path ----------------
    size_t off2 = 0;
    const size_t p_w  = off2; off2 = align512(off2 + wbytes);
    const size_t p_fb = off2; off2 = align512(off2 + (size_t)Nn * D * 2);
    const size_t p_ms = off2; off2 = align512(off2 + (size_t)Nn * D * 2);
    if (ws_size >= off2) {
        ushort_t* W1p  = (ushort_t*)(wsb + p_w);
        ushort_t* W2p  = W1p + 128 * KP1;
        ushort_t* fbf  = (ushort_t*)(wsb + p_fb);
        ushort_t* msum = (ushort_t*)(wsb + p_ms);
        const int rp_elems = 128 * KP1 + HD * D;
        hipMemsetAsync(msum, 0, (size_t)Nn * D * 2, stream);
        repack_kernel<<<dim3((rp_elems + 255) / 256), dim3(256), 0, stream>>>(Wm1, Wm2, W1p, W2p);
        const int n8 = Nn * D / 8;
        fconv_kernel<<<dim3((n8 + 255) / 256), dim3(256), 0, stream>>>(f, fbf, n8);
        edge_mfma_kernel<<<dim3((E + EB - 1) / EB), dim3(NT), 0, stream>>>(
            fbf, x, w, src, dst, W1p, bm1, W2p, bm2, msum, E);
        node_kernel<true><<<dim3((Nn + NB - 1) / NB), dim3(NT), 0, stream>>>(
            f, msum, Wu1, bu1, Wu2, bu2, (float*)d_out, Nn);
        return;
    }
}